// Round 11
// baseline (2337.146 us; speedup 1.0000x reference)
//
#include <hip/hip_runtime.h>
#include <math.h>

#define N_NODES 20000
#define D_INN   512
#define DH      256
#define NCH     7
#define NE      320000
#define NE2     100000
#define NB      8192
#define H3      2304   // 512 + 7*256
#define MAXN    0.996f
#define LOG2E   1.44269504f

typedef unsigned short u16;
typedef __attribute__((ext_vector_type(8))) short bf16x8;
typedef __attribute__((ext_vector_type(4))) float f32x4;

__device__ __forceinline__ u16 f2b(float f) {    // RNE f32 -> bf16 bits
    unsigned int x = __float_as_uint(f);
    unsigned int r = (x + 0x7fffu + ((x >> 16) & 1u)) >> 16;
    return (u16)r;
}
__device__ __forceinline__ float b2f(u16 u) {
    return __uint_as_float(((unsigned int)u) << 16);
}
__device__ __forceinline__ float blo(unsigned int u) { return __uint_as_float(u << 16); }
__device__ __forceinline__ float bhi(unsigned int u) { return __uint_as_float(u & 0xffff0000u); }
__device__ __forceinline__ unsigned int pk2(float a, float b) {
    return (unsigned int)f2b(a) | ((unsigned int)f2b(b) << 16);
}

// ---- fast HW transcendentals (rel err ~1e-5, fine for bf16 tolerance) ----
__device__ __forceinline__ float rcp_f(float x) { return __builtin_amdgcn_rcpf(x); }
__device__ __forceinline__ float exp2_f(float x) { return __builtin_amdgcn_exp2f(x); }
__device__ __forceinline__ float log2_f(float x) { return __builtin_amdgcn_logf(x); }
__device__ __forceinline__ float tanh_fast(float x) {
    float xc = fminf(fmaxf(x, -15.f), 15.f);
    float t = exp2_f(xc * (2.f * LOG2E));
    return (t - 1.f) * rcp_f(t + 1.f);
}
__device__ __forceinline__ float artanh_fast(float x) {
    x = fminf(fmaxf(x, -1.0f + 1e-7f), 1.0f - 1e-7f);
    return 0.34657359f * log2_f((1.f + x) * rcp_f(1.f - x));
}
__device__ __forceinline__ float sigmoid_fast(float x) {
    return rcp_f(1.f + exp2_f(-x * LOG2E));
}

__device__ __forceinline__ float wave_sum(float v) {
    #pragma unroll
    for (int off = 32; off > 0; off >>= 1) v += __shfl_xor(v, off, 64);
    return v;
}

__device__ __forceinline__ float block_sum256(float v) {
    __shared__ float sred[4];
    #pragma unroll
    for (int off = 32; off > 0; off >>= 1) v += __shfl_down(v, off, 64);
    int lane = threadIdx.x & 63;
    int w = threadIdx.x >> 6;
    if (lane == 0) sred[w] = v;
    __syncthreads();
    float tot = sred[0] + sred[1] + sred[2] + sred[3];
    __syncthreads();
    return tot;
}

__global__ void k_zero(float* __restrict__ p, int n) {
    int i = blockIdx.x * 256 + threadIdx.x;
    if (i < n) p[i] = 0.0f;
}
__global__ void k_izero(int* __restrict__ p, int n) {
    int i = blockIdx.x * 256 + threadIdx.x;
    if (i < n) p[i] = 0;
}

__global__ void k_f2b(const float* __restrict__ s, u16* __restrict__ d, int n4) {
    int i = blockIdx.x * 256 + threadIdx.x;
    int stride = gridDim.x * 256;
    for (; i < n4; i += stride) {
        float4 v = ((const float4*)s)[i];
        uint2 o; o.x = pk2(v.x, v.y); o.y = pk2(v.z, v.w);
        ((uint2*)d)[i] = o;
    }
}

// Wd transpose -> bf16 (for Wc = Wg1 @ Wd via A@W^T kernel)
__global__ void k_twd(const float* __restrict__ Wd, u16* __restrict__ Wdt) {
    __shared__ float tile[16][17];
    int z = blockIdx.z;
    int bx = blockIdx.x * 16, by = blockIdx.y * 16;
    int tx = threadIdx.x & 15, ty = threadIdx.x >> 4;
    tile[ty][tx] = Wd[(size_t)z * DH * DH + (size_t)(by + ty) * DH + bx + tx];
    __syncthreads();
    Wdt[(size_t)z * DH * DH + (size_t)(bx + ty) * DH + by + tx] = f2b(tile[tx][ty]);
}

// cvec[z][j] = sum_k Wg1[z][j][k] * bd[z][k]   (f32)
__global__ void k_cvec(const float* __restrict__ Wg1, const float* __restrict__ bd,
                       float* __restrict__ cvec) {
    int z = blockIdx.x, j = threadIdx.x;
    const float* row = Wg1 + (size_t)z * DH * DH + (size_t)j * DH;
    const float* b = bd + (size_t)z * DH;
    float s = 0.f;
    for (int k = 0; k < DH; ++k) s = fmaf(row[k], b[k], s);
    cvec[(size_t)z * DH + j] = s;
}

// ===== merged CSR build: 2G z-slices (z<G: adj graph, z>=G: edge graph) =====
__global__ void k_hist2(const int* __restrict__ adjd, const int* __restrict__ edged,
                        int* __restrict__ cnt, int G) {
    int z = blockIdx.y;
    const int* dst = (z < G) ? adjd + (size_t)z * NE : edged + (size_t)(z - G) * NE;
    cnt += (size_t)z * N_NODES;
    int i = blockIdx.x * 256 + threadIdx.x;
    if (i < NE) atomicAdd(&cnt[dst[i]], 1);
}

// one block per slice; cnt becomes the cursor array in-place
__global__ void k_scan(int* __restrict__ cnt, int* __restrict__ rowptr) {
    int z = blockIdx.x;
    cnt += (size_t)z * N_NODES;
    rowptr += (size_t)z * (N_NODES + 1);
    __shared__ int part[256];
    int t = threadIdx.x;
    const int CH = (N_NODES + 255) / 256;
    int beg = t * CH;
    int end = beg + CH; if (end > N_NODES) end = N_NODES;
    int s = 0;
    for (int i = beg; i < end; ++i) s += cnt[i];
    part[t] = s;
    __syncthreads();
    for (int off = 1; off < 256; off <<= 1) {
        int v = (t >= off) ? part[t - off] : 0;
        __syncthreads();
        part[t] += v;
        __syncthreads();
    }
    int run = (t == 0) ? 0 : part[t - 1];
    for (int i = beg; i < end; ++i) {
        int c = cnt[i];
        rowptr[i] = run;
        cnt[i] = run;      // cursor init (in-place)
        run += c;
    }
    if (t == 255) rowptr[N_NODES] = part[255];
}

// place: adj slices write packed (src, val) uint2 (1 scatter store/edge);
// edge slices write int src.
__global__ void k_place2(const int* __restrict__ adjs, const int* __restrict__ adjd,
                         const float* __restrict__ adjv, const int* __restrict__ edges,
                         const int* __restrict__ edged, int* __restrict__ cursor,
                         uint2* __restrict__ padj, int* __restrict__ psrcE, int G) {
    int z = blockIdx.y;
    bool isadj = z < G;
    const int* src = isadj ? adjs + (size_t)z * NE : edges + (size_t)(z - G) * NE;
    const int* dst = isadj ? adjd + (size_t)z * NE : edged + (size_t)(z - G) * NE;
    cursor += (size_t)z * N_NODES;
    int i = blockIdx.x * 256 + threadIdx.x;
    if (i < NE) {
        int d = dst[i];
        int pos = atomicAdd(&cursor[d], 1);
        if (isadj) {
            uint2 p;
            p.x = (unsigned int)src[i];
            p.y = __float_as_uint(adjv[(size_t)z * NE + i]);
            padj[(size_t)z * NE + pos] = p;
        } else {
            psrcE[(size_t)(z - G) * NE + pos] = src[i];
        }
    }
}

// x_hyp = proj(expmap0(f1)) -> bf16; clamped row norm -> xhn (f32)
__global__ void k_expmap_proj_in(const float* __restrict__ f1,
                                 u16* __restrict__ xhyp, float* __restrict__ xhn) {
    int r = blockIdx.x, t = threadIdx.x;
    const float* u = f1 + (size_t)r * D_INN;
    float v0 = u[t], v1 = u[t + 256];
    float ss = block_sum256(v0 * v0 + v1 * v1);
    float nraw = sqrtf(ss);
    float n = fmaxf(nraw, 1e-15f);
    float c = tanh_fast(n) * rcp_f(n);
    float ny = c * nraw;
    float np = fmaxf(ny, 1e-15f);
    float s = (np > MAXN) ? MAXN * rcp_f(np) : 1.0f;
    float cs = c * s;
    u16* o = xhyp + (size_t)r * D_INN;
    o[t] = f2b(cs * v0);
    o[t + 256] = f2b(cs * v1);
    if (t == 0) xhn[r] = fminf(np, MAXN);
}

__global__ void k_hb(const float* __restrict__ b_hyp,
                     float* __restrict__ hb, float* __restrict__ hb2) {
    int i = blockIdx.x, t = threadIdx.x;
    float v = b_hyp[i * DH + t];
    float ss = block_sum256(v * v);
    float nraw = sqrtf(ss);
    float n = fmaxf(nraw, 1e-15f);
    float c = tanh_fast(n) * rcp_f(n);
    float ny = c * nraw;
    float np = fmaxf(ny, 1e-15f);
    float s = (np > MAXN) ? MAXN * rcp_f(np) : 1.0f;
    float hv = c * s * v;
    hb[i * DH + t] = hv;
    float s2 = block_sum256(hv * hv);
    if (t == 0) hb2[i] = s2;
}

// wave-per-node (4 nodes/block), lane = 4 feats via uint2; in-place bf16.
__global__ void k_rowfuse1(u16* __restrict__ T, const float* __restrict__ xhn,
                           const float* __restrict__ hb, const float* __restrict__ hb2) {
    int z = blockIdx.y;
    int n = blockIdx.x * 4 + (threadIdx.x >> 6);
    int lane = threadIdx.x & 63;
    u16* row = T + ((size_t)z * N_NODES + n) * DH;
    const float* hbz = hb + (size_t)z * DH;
    uint2 u = *(const uint2*)(row + lane * 4);
    float m0 = blo(u.x), m1 = bhi(u.x), m2 = blo(u.y), m3 = bhi(u.y);
    float ss = wave_sum(m0 * m0 + m1 * m1 + m2 * m2 + m3 * m3);
    float mxn_raw = sqrtf(ss);
    float mxn = fmaxf(mxn_raw, 1e-15f);
    float xn = xhn[n];
    float tt = tanh_fast(mxn * rcp_f(xn) * artanh_fast(xn));
    float coef = tt * rcp_f(mxn);
    float nres = coef * mxn_raw;
    float np = fmaxf(nres, 1e-15f);
    float s1 = (np > MAXN) ? MAXN * rcp_f(np) : 1.0f;
    float cs = coef * s1;
    float r0 = cs * m0, r1 = cs * m1, r2 = cs * m2, r3 = cs * m3;
    float n1 = fminf(np, MAXN);
    float4 hv = *(const float4*)(hbz + lane * 4);
    float xy = wave_sum(r0 * hv.x + r1 * hv.y + r2 * hv.z + r3 * hv.w);
    float x2 = n1 * n1, y2 = hb2[z];
    float ca = 1.0f + 2.0f * xy + y2;
    float cb = 1.0f - x2;
    float rden = rcp_f(fmaxf(1.0f + 2.0f * xy + x2 * y2, 1e-15f));
    float o0 = (ca * r0 + cb * hv.x) * rden;
    float o1 = (ca * r1 + cb * hv.y) * rden;
    float o2 = (ca * r2 + cb * hv.z) * rden;
    float o3 = (ca * r3 + cb * hv.w) * rden;
    float no2 = wave_sum(o0 * o0 + o1 * o1 + o2 * o2 + o3 * o3);
    float nop = fmaxf(sqrtf(no2), 1e-15f);
    float s2 = (nop > MAXN) ? MAXN * rcp_f(nop) : 1.0f;
    float n2 = fminf(nop, MAXN);
    float fin = artanh_fast(n2) * rcp_f(n2) * s2;
    uint2 o; o.x = pk2(fin * o0, fin * o1); o.y = pk2(fin * o2, fin * o3);
    *(uint2*)(row + lane * 4) = o;
}

// wave-per-node CSR gather (packed (src,val)) + fused rowfuse2 chain -> bf16 out
__global__ void k_gather_fuse2(const int* __restrict__ rowptr, const uint2* __restrict__ padj,
                               const u16* __restrict__ xt, u16* __restrict__ out) {
    int z = blockIdx.y;
    rowptr += (size_t)z * (N_NODES + 1);
    padj += (size_t)z * NE;
    xt += (size_t)z * N_NODES * DH;
    out += (size_t)z * N_NODES * DH;
    int n = blockIdx.x * 4 + (threadIdx.x >> 6);
    int lane = threadIdx.x & 63;
    int beg = rowptr[n], end = rowptr[n + 1];
    float a0 = 0.f, a1 = 0.f, a2 = 0.f, a3 = 0.f;
    for (int i = beg; i < end; ++i) {
        uint2 p = padj[i];
        float v = __uint_as_float(p.y);
        uint2 u = *(const uint2*)(xt + (size_t)p.x * DH + lane * 4);
        a0 = fmaf(v, blo(u.x), a0);
        a1 = fmaf(v, bhi(u.x), a1);
        a2 = fmaf(v, blo(u.y), a2);
        a3 = fmaf(v, bhi(u.y), a3);
    }
    float ss = wave_sum(a0 * a0 + a1 * a1 + a2 * a2 + a3 * a3);
    float nraw = sqrtf(ss);
    float n_ = fmaxf(nraw, 1e-15f);
    float c1 = tanh_fast(n_) * rcp_f(n_);
    float nh = c1 * nraw;
    float np1 = fmaxf(nh, 1e-15f);
    float s1 = (np1 > MAXN) ? MAXN * rcp_f(np1) : 1.0f;
    float n1 = fminf(np1, MAXN);
    float cu = artanh_fast(n1) * rcp_f(n1) * s1 * c1;
    float u0 = fmaxf(cu * a0, 0.f), u1 = fmaxf(cu * a1, 0.f);
    float u2 = fmaxf(cu * a2, 0.f), u3 = fmaxf(cu * a3, 0.f);
    float ss2 = wave_sum(u0 * u0 + u1 * u1 + u2 * u2 + u3 * u3);
    float n2raw = sqrtf(ss2);
    float n2 = fmaxf(n2raw, 1e-15f);
    float c3 = tanh_fast(n2) * rcp_f(n2);
    float ne = c3 * n2raw;
    float np3 = fmaxf(ne, 1e-15f);
    float s3 = (np3 > MAXN) ? MAXN * rcp_f(np3) : 1.0f;
    float n3 = fminf(np3, MAXN);
    float cf = artanh_fast(n3) * rcp_f(n3) * s3 * c3;
    uint2 o; o.x = pk2(cf * u0, cf * u1); o.y = pk2(cf * u2, cf * u3);
    *(uint2*)(out + (size_t)n * DH + lane * 4) = o;
}

// wave-per-node: out[n] = d[n] + sum_in d[src]; bf16 in/out
__global__ void k_gather_add(const int* __restrict__ rowptr, const int* __restrict__ psrc,
                             const u16* __restrict__ d, u16* __restrict__ out) {
    int z = blockIdx.y;
    rowptr += (size_t)z * (N_NODES + 1);
    psrc += (size_t)z * NE;
    d += (size_t)z * N_NODES * DH;
    out += (size_t)z * N_NODES * DH;
    int n = blockIdx.x * 4 + (threadIdx.x >> 6);
    int lane = threadIdx.x & 63;
    int beg = rowptr[n], end = rowptr[n + 1];
    uint2 u0v = *(const uint2*)(d + (size_t)n * DH + lane * 4);
    float a0 = blo(u0v.x), a1 = bhi(u0v.x), a2 = blo(u0v.y), a3 = bhi(u0v.y);
    for (int i = beg; i < end; ++i) {
        int s = psrc[i];
        uint2 u = *(const uint2*)(d + (size_t)s * DH + lane * 4);
        a0 += blo(u.x); a1 += bhi(u.x); a2 += blo(u.y); a3 += bhi(u.y);
    }
    uint2 o; o.x = pk2(a0, a1); o.y = pk2(a2, a3);
    *(uint2*)(out + (size_t)n * DH + lane * 4) = o;
}

// batched column stats from bf16
__global__ void k_colstats(const u16* __restrict__ zp,
                           float* __restrict__ csum, float* __restrict__ csq) {
    int z = blockIdx.y;
    zp += (size_t)z * N_NODES * DH;
    csum += (size_t)z * DH;
    csq += (size_t)z * DH;
    int t = threadIdx.x;
    int r0 = blockIdx.x * 100;
    float s = 0.0f, q = 0.0f;
    for (int r = r0; r < r0 + 100; ++r) {
        float v = b2f(zp[(size_t)r * DH + t]);
        s += v;
        q += v * v;
    }
    atomicAdd(&csum[t], s);
    atomicAdd(&csq[t], q);
}

// grid-stride uint2 batchnorm + tanh, in-place bf16 (total4 = G*N*DH/4)
__global__ void k_normtanh_v(u16* __restrict__ zp, const float* __restrict__ csum,
                             const float* __restrict__ csq, const float* __restrict__ gamma,
                             const float* __restrict__ beta, int total4) {
    const float inv_n = 1.0f / N_NODES;
    int i = blockIdx.x * 256 + threadIdx.x;
    int stride = gridDim.x * 256;
    for (; i < total4; i += stride) {
        int e0 = i * 4;
        int z = e0 / (N_NODES * DH);
        int j0 = e0 & (DH - 1);
        int zb = z * DH + j0;
        uint2 u = ((uint2*)zp)[i];
        float v[4] = {blo(u.x), bhi(u.x), blo(u.y), bhi(u.y)};
        #pragma unroll
        for (int k = 0; k < 4; ++k) {
            float mu = csum[zb + k] * inv_n;
            float var = csq[zb + k] * inv_n - mu * mu;
            float inv = __builtin_amdgcn_rsqf(var + 1e-5f);
            v[k] = tanh_fast((v[k] - mu) * inv * gamma[zb + k] + beta[zb + k]);
        }
        uint2 o; o.x = pk2(v[0], v[1]); o.y = pk2(v[2], v[3]);
        ((uint2*)zp)[i] = o;
    }
}

// f1 slice of S,P (cols 0..511): thread t -> 2 cols via float2, packed u32 store
__global__ void k_pair0(const int* __restrict__ ei, const int* __restrict__ eid,
                        const float* __restrict__ f1, u16* __restrict__ S,
                        u16* __restrict__ P) {
    int b = blockIdx.x, t = threadIdx.x;
    int e = eid[b];
    int n0 = ei[e], n1 = ei[NE2 + e];
    float2 a = *(const float2*)(f1 + (size_t)n0 * D_INN + t * 2);
    float2 c = *(const float2*)(f1 + (size_t)n1 * D_INN + t * 2);
    ((unsigned int*)(S + (size_t)b * H3))[t] = pk2(a.x + c.x, a.y + c.y);
    ((unsigned int*)(P + (size_t)b * H3))[t] = pk2(a.x * c.x, a.y * c.y);
}

// batched channel slice of S,P from z_ch; 4 edges/block, uint2 lanes
__global__ void k_gather_ch(const int* __restrict__ ei, const int* __restrict__ eid,
                            const u16* __restrict__ zch, u16* __restrict__ S,
                            u16* __restrict__ P, int col0base) {
    int z = blockIdx.y;
    const u16* zp = zch + (size_t)z * N_NODES * DH;
    int col0 = col0base + z * DH;
    int b = blockIdx.x * 4 + (threadIdx.x >> 6);
    int lane = threadIdx.x & 63;
    int e = eid[b];
    int n0 = ei[e], n1 = ei[NE2 + e];
    uint2 ua = *(const uint2*)(zp + (size_t)n0 * DH + lane * 4);
    uint2 ub = *(const uint2*)(zp + (size_t)n1 * DH + lane * 4);
    float a0 = blo(ua.x), a1 = bhi(ua.x), a2 = blo(ua.y), a3 = bhi(ua.y);
    float c0 = blo(ub.x), c1 = bhi(ub.x), c2 = blo(ub.y), c3 = bhi(ub.y);
    uint2 so; so.x = pk2(a0 + c0, a1 + c1); so.y = pk2(a2 + c2, a3 + c3);
    uint2 po; po.x = pk2(a0 * c0, a1 * c1); po.y = pk2(a2 * c2, a3 * c3);
    *(uint2*)(S + (size_t)b * H3 + col0 + lane * 4) = so;
    *(uint2*)(P + (size_t)b * H3 + col0 + lane * 4) = po;
}

__global__ void k_final(const float* __restrict__ h2, const float* __restrict__ Wf3,
                        const float* __restrict__ bf3, float* __restrict__ out) {
    int r = blockIdx.x, t = threadIdx.x;
    const float* hr = h2 + (size_t)r * 576;
    float acc[7] = {0, 0, 0, 0, 0, 0, 0};
    for (int cb = t; cb < 576; cb += 64) {
        float h = hr[cb];
        #pragma unroll
        for (int o = 0; o < 7; ++o) acc[o] = fmaf(h, Wf3[o * 576 + cb], acc[o]);
    }
    #pragma unroll
    for (int o = 0; o < 7; ++o) {
        #pragma unroll
        for (int off = 32; off > 0; off >>= 1) acc[o] += __shfl_down(acc[o], off, 64);
    }
    if (t == 0) {
        #pragma unroll
        for (int o = 0; o < 7; ++o) out[(size_t)r * 7 + o] = acc[o] + bf3[o];
    }
}

// ===== 256x256 bf16 MFMA GEMM, BK=64, 8 waves (512 thr), counted-vmcnt deep
// pipeline (T3/T4) + setprio (T5). 2 full-tile LDS buffers (128KB, 1 blk/CU).
// Per K-tile t: vmcnt(8) [allow next tile's 8 staging ops in flight] ->
// raw barrier -> 4 quadrants {ds_read frags, setprio(1), 16 MFMA, setprio(0)}
// -> raw barrier (all waves done reading buf) -> stage tile t+2 into this buf.
// Race-freedom: FIFO vmcnt + barrier#1 => tile t fully in LDS before reads;
// MFMA data-dep lgkm waits + barrier#2 => reads done before overwrite.
// LDS chunk swizzle: phys chunk = logical chunk ^ (row&7) on BOTH stage-source
// and ds_read (involution; 2-way bank alias = free). Stage via global_load_lds
// width-16, 64B-contiguous source rows. XCD-aware bijective block swizzle.
// EP: 2=sigmoid->bf16, 3=relu->bf16, 4=aux*relu->bf16, 5=bf16, 6=relu->f32,
//     7=bf16 with bias + (1+indeg[row])*cvec[col]
template <int EP>
__global__ __launch_bounds__(512, 2) void k_gemm256(
    const u16* __restrict__ A, const u16* __restrict__ W,
    const float* __restrict__ bias, void* __restrict__ outv,
    const u16* __restrict__ aux, const int* __restrict__ rpe,
    const float* __restrict__ cvec, int M, int N, int K,
    size_t sA, size_t sW, size_t sC, int sBias) {
    __shared__ short As[2 * 16384];   // [buf][256 rows][64 cols] bf16
    __shared__ short Ws[2 * 16384];
    const int z = blockIdx.z;
    A += (size_t)z * sA;
    W += (size_t)z * sW;
    const size_t zC = (size_t)z * sC;
    const int* rp = (EP == 7) ? rpe + (size_t)z * (N_NODES + 1) : nullptr;
    const float* cv = (EP == 7) ? cvec + (size_t)z * DH : nullptr;
    // XCD bijective swizzle within this z-slice
    const int gx = gridDim.x;
    const int nwg = gx * gridDim.y;
    const int orig = blockIdx.y * gx + blockIdx.x;
    const int q8 = nwg >> 3, r8 = nwg & 7, xcd = orig & 7;
    const int wg = (xcd < r8 ? xcd * (q8 + 1) : r8 * (q8 + 1) + (xcd - r8) * q8) + (orig >> 3);
    const int row0 = (wg / gx) * 256, col0 = (wg % gx) * 256;
    const int t = threadIdx.x;
    const int lane = t & 63;
    const int w = t >> 6;          // 0..7
    const int wr = w >> 2;         // 0..1  (M half)
    const int wc = w & 3;          // 0..3  (N quarter)
    // staging coords: lane -> row-in-64-row-round = w*8 + (lane>>3), phys chunk lane&7
    const int srow = w * 8 + (lane >> 3);
    const int csrc = (((lane & 7) ^ (lane >> 3)) * 8);   // shorts
    int grA[4], gcB[4];
    #pragma unroll
    for (int j = 0; j < 4; ++j) {
        int r = row0 + j * 64 + srow; grA[j] = (r < M) ? r : (M - 1);
        int c = col0 + j * 64 + srow; gcB[j] = (c < N) ? c : (N - 1);
    }
    const int nt = K >> 6;    // K-tiles of 64
    f32x4 acc[8][4] = {};

#define STAGE_TILE(KT, BUF)                                                              \
    do {                                                                                 \
        int kb = (KT) << 6;                                                              \
        _Pragma("unroll")                                                                \
        for (int j = 0; j < 4; ++j) {                                                    \
            __builtin_amdgcn_global_load_lds(                                            \
                (const __attribute__((address_space(1))) unsigned int*)(A + (size_t)grA[j] * K + kb + csrc), \
                (__attribute__((address_space(3))) unsigned int*)(As + (BUF) * 16384 + (j * 64 + w * 8) * 64), \
                16, 0, 0);                                                               \
            __builtin_amdgcn_global_load_lds(                                            \
                (const __attribute__((address_space(1))) unsigned int*)(W + (size_t)gcB[j] * K + kb + csrc), \
                (__attribute__((address_space(3))) unsigned int*)(Ws + (BUF) * 16384 + (j * 64 + w * 8) * 64), \
                16, 0, 0);                                                               \
        }                                                                                \
    } while (0)

    // prologue: stage tiles 0 and 1
    STAGE_TILE(0, 0);
    if (nt > 1) STAGE_TILE(1, 1);

    for (int kt = 0; kt < nt; ++kt) {
        if (kt + 1 < nt) { asm volatile("s_waitcnt vmcnt(8)" ::: "memory"); }
        else             { asm volatile("s_waitcnt vmcnt(0)" ::: "memory"); }
        __builtin_amdgcn_s_barrier();
        asm volatile("" ::: "memory");
        const short* Ab = As + (kt & 1) * 16384;
        const short* Bb = Ws + (kt & 1) * 16384;
        // B fragments for this wave (fixed across quadrants)
        bf16x8 bfr[4][2];
        #pragma unroll
        for (int nf = 0; nf < 4; ++nf)
            #pragma unroll
            for (int kk = 0; kk < 2; ++kk) {
                int br = wc * 64 + nf * 16 + (lane & 15);
                int q = kk * 4 + (lane >> 4);
                bfr[nf][kk] = *(const bf16x8*)(Bb + br * 64 + ((q ^ (lane & 7)) * 8));
            }
        #pragma unroll
        for (int qd = 0; qd < 4; ++qd) {
            bf16x8 af[2][2];
            #pragma unroll
            for (int m2 = 0; m2 < 2; ++m2)
                #pragma unroll
                for (int kk = 0; kk < 2; ++kk) {
                    int ar = wr * 128 + (qd * 2 + m2) * 16 + (lane & 15);
                    int q = kk * 4 + (lane >> 4);
                    af[m2][kk] = *(const bf16x8*)(Ab + ar * 64 + ((q ^ (lane & 7)) * 8));
                }
            __builtin_amdgcn_s_setprio(1);
            #pragma unroll
            for (int m2 = 0; m2 < 2; ++m2)
                #pragma unroll
                for (int nf = 0; nf < 4; ++nf)
                    #pragma unroll
                    for (int kk = 0; kk < 2; ++kk)
                        acc[qd * 2 + m2][nf] = __builtin_amdgcn_mfma_f32_16x16x32_bf16(
                            af[m2][kk], bfr[nf][kk], acc[qd * 2 + m2][nf], 0, 0, 0);
            __builtin_amdgcn_s_setprio(0);
        }
        asm volatile("" ::: "memory");
        __builtin_amdgcn_s_barrier();
        if (kt + 2 < nt) STAGE_TILE(kt + 2, (kt & 1));
    }
#undef STAGE_TILE

    // epilogue: C/D frag layout col=lane&15, row=(lane>>4)*4+reg
    const int cl = lane & 15, rh = (lane >> 4) * 4;
    #pragma unroll
    for (int mf = 0; mf < 8; ++mf) {
        float indf[4];
        if (EP == 7) {
            #pragma unroll
            for (int r = 0; r < 4; ++r) {
                int row = row0 + wr * 128 + mf * 16 + rh + r;
                if (row >= M) row = M - 1;
                indf[r] = 1.0f + (float)(rp[row + 1] - rp[row]);
            }
        }
        #pragma unroll
        for (int nf = 0; nf < 4; ++nf) {
            int col = col0 + wc * 64 + nf * 16 + cl;
            if (col >= N) continue;
            float bv = bias ? bias[z * sBias + col] : 0.0f;
            float cvc = (EP == 7) ? cv[col] : 0.0f;
            #pragma unroll
            for (int r = 0; r < 4; ++r) {
                int row = row0 + wr * 128 + mf * 16 + rh + r;
                if (row >= M) continue;
                float v = acc[mf][nf][r] + bv;
                size_t idx = zC + (size_t)row * N + col;
                if (EP == 2) ((u16*)outv)[idx] = f2b(sigmoid_fast(v));
                if (EP == 3) ((u16*)outv)[idx] = f2b(fmaxf(v, 0.0f));
                if (EP == 4) { float g = b2f(aux[idx]); ((u16*)outv)[idx] = f2b(g * fmaxf(v, 0.0f)); }
                if (EP == 5) ((u16*)outv)[idx] = f2b(v);
                if (EP == 6) ((float*)outv)[idx] = fmaxf(v, 0.0f);
                if (EP == 7) ((u16*)outv)[idx] = f2b(v + indf[r] * cvc);
            }
        }
    }
}

static inline void gemm_b(int ep, const u16* A, const u16* W, const float* bias, void* out,
                          const u16* aux, const int* rpe, const float* cvec,
                          int M, int N, int K, int Z,
                          size_t sA, size_t sW, size_t sC, int sBias, hipStream_t st) {
    dim3 g((N + 255) / 256, (M + 255) / 256, Z);
    switch (ep) {
        case 2: k_gemm256<2><<<g, 512, 0, st>>>(A, W, bias, out, aux, rpe, cvec, M, N, K, sA, sW, sC, sBias); break;
        case 3: k_gemm256<3><<<g, 512, 0, st>>>(A, W, bias, out, aux, rpe, cvec, M, N, K, sA, sW, sC, sBias); break;
        case 4: k_gemm256<4><<<g, 512, 0, st>>>(A, W, bias, out, aux, rpe, cvec, M, N, K, sA, sW, sC, sBias); break;
        case 5: k_gemm256<5><<<g, 512, 0, st>>>(A, W, bias, out, aux, rpe, cvec, M, N, K, sA, sW, sC, sBias); break;
        case 6: k_gemm256<6><<<g, 512, 0, st>>>(A, W, bias, out, aux, rpe, cvec, M, N, K, sA, sW, sC, sBias); break;
        case 7: k_gemm256<7><<<g, 512, 0, st>>>(A, W, bias, out, aux, rpe, cvec, M, N, K, sA, sW, sC, sBias); break;
    }
}

static inline void conv_w(const float* s, u16* d, size_t n, hipStream_t st) {
    int n4 = (int)(n / 4);
    int grid = (n4 + 255) / 256;
    if (grid > 2048) grid = 2048;
    k_f2b<<<grid, 256, 0, st>>>(s, d, n4);
}

extern "C" void kernel_launch(void* const* d_in, const int* in_sizes, int n_in, void* d_out,
                              int out_size, void* d_ws, size_t ws_size, hipStream_t stream) {
    const float* f1 = (const float*)d_in[0];
    const int* adj_src = (const int*)d_in[1];
    const int* adj_dst = (const int*)d_in[2];
    const float* adj_val = (const float*)d_in[3];
    const int* edge_src = (const int*)d_in[4];
    const int* edge_dst = (const int*)d_in[5];
    const int* edge_index = (const int*)d_in[6];
    const int* edge_id = (const int*)d_in[7];
    const float* W_hyp = (const float*)d_in[8];
    const float* b_hyp = (const float*)d_in[9];
    const float* Wd = (const float*)d_in[10];
    const float* bd = (const float*)d_in[11];
    const float* Wg1 = (const float*)d_in[12];
    const float* bg1 = (const float*)d_in[13];
    const float* gamma = (const float*)d_in[14];
    const float* beta = (const float*)d_in[15];
    const float* Wg2 = (const float*)d_in[16];
    const float* bg2 = (const float*)d_in[17];
    const float* Wgate = (const float*)d_in[18];
    const float* bgate = (const float*)d_in[19];
    const float* Wint = (const float*)d_in[20];
    const float* bint = (const float*)d_in[21];
    const float* Wout = (const float*)d_in[22];
    const float* bout = (const float*)d_in[23];
    const float* Wf1 = (const float*)d_in[24];
    const float* bf1 = (const float*)d_in[25];
    const float* Wf2 = (const float*)d_in[26];
    const float* bf2 = (const float*)d_in[27];
    const float* Wf3 = (const float*)d_in[28];
    const float* bf3 = (const float*)d_in[29];
    float* outp = (float*)d_out;

    // ---- workspace bump allocator (~240 MB) ----
    char* base = (char*)d_ws;
    size_t off = 0;
    auto alloc = [&](size_t bytes) -> char* {
        char* p = base + off;
        off += (bytes + 255) & ~(size_t)255;
        return p;
    };
    u16* Whyp_b = (u16*)alloc((size_t)NCH * DH * D_INN * 2);
    u16* Wdt_b  = (u16*)alloc((size_t)NCH * DH * DH * 2);   // Wd^T bf16
    u16* Wc_b   = (u16*)alloc((size_t)NCH * DH * DH * 2);   // Wg1 @ Wd
    u16* Wg1_b  = (u16*)alloc((size_t)NCH * DH * DH * 2);
    u16* Wg2_b  = (u16*)alloc((size_t)NCH * DH * DH * 2);
    u16* Wgate_b = (u16*)alloc((size_t)H3 * H3 * 2);
    u16* Wint_b  = (u16*)alloc((size_t)H3 * H3 * 2);
    u16* Wout_b  = (u16*)alloc((size_t)H3 * H3 * 2);
    u16* Wf1_b   = (u16*)alloc((size_t)1152 * H3 * 2);
    u16* Wf2_b   = (u16*)alloc((size_t)576 * 1152 * 2);
    u16* S_b = (u16*)alloc((size_t)NB * H3 * 2);
    u16* P_b = (u16*)alloc((size_t)NB * H3 * 2);
    const size_t NDB = (size_t)N_NODES * DH;       // per-channel elems
    u16* buf1 = (u16*)alloc(4 * NDB * 2);          // group ping
    u16* buf2 = (u16*)alloc(4 * NDB * 2);          // group pong
    u16* xhyp_b = (u16*)alloc((size_t)N_NODES * D_INN * 2);
    // merged CSR scratch (2G slices; G<=4): adj slices [0,G), edge slices [G,2G)
    int* cntC = (int*)alloc(8 * (size_t)N_NODES * 4);        // doubles as cursor
    int* rowptrC = (int*)alloc(8 * (size_t)(N_NODES + 1) * 4);
    uint2* padjC = (uint2*)alloc(4 * (size_t)NE * 8);        // packed (src,val)
    int* psrcE = (int*)alloc(4 * (size_t)NE * 4);
    float* xhn = (float*)alloc((size_t)N_NODES * 4);
    float* hb = (float*)alloc((size_t)NCH * DH * 4);
    float* hb2 = (float*)alloc(NCH * 4);
    float* csum = (float*)alloc((size_t)4 * DH * 4);
    float* csq = (float*)alloc((size_t)4 * DH * 4);
    float* cvec_d = (float*)alloc((size_t)NCH * DH * 4);
    // stage-C overlays (GNN buffers dead by then)
    u16* G_b = buf1;                 // 37.75 MB <= 40.96
    float* h2f = (float*)buf2;       // 18.87 MB <= 40.96

    const int EG = (NE + 255) / 256;

    conv_w(W_hyp, Whyp_b, (size_t)NCH * DH * D_INN, stream);
    conv_w(Wg1, Wg1_b, (size_t)NCH * DH * DH, stream);
    conv_w(Wg2, Wg2_b, (size_t)NCH * DH * DH, stream);
    conv_w(Wgate, Wgate_b, (size_t)H3 * H3, stream);
    conv_w(Wint, Wint_b, (size_t)H3 * H3, stream);
    conv_w(Wout, Wout_b, (size_t)H3 * H3, stream);
    conv_w(Wf1, Wf1_b, (size_t)1152 * H3, stream);
    conv_w(Wf2, Wf2_b, (size_t)576 * 1152, stream);
    // Wc = Wg1 @ Wd (via Wd^T), cvec = Wg1 @ bd
    k_twd<<<dim3(16, 16, NCH), 256, 0, stream>>>(Wd, Wdt_b);
    gemm_b(5, Wg1_b, Wdt_b, nullptr, Wc_b, nullptr, nullptr, nullptr,
           DH, DH, DH, NCH, (size_t)DH * DH, (size_t)DH * DH, (size_t)DH * DH, 0, stream);
    k_cvec<<<NCH, 256, 0, stream>>>(Wg1, bd, cvec_d);

    k_expmap_proj_in<<<N_NODES, 256, 0, stream>>>(f1, xhyp_b, xhn);
    k_hb<<<NCH, 256, 0, stream>>>(b_hyp, hb, hb2);
    k_pair0<<<NB, 256, 0, stream>>>(edge_index, edge_id, f1, S_b, P_b);

    const int g0s[2] = {0, 4};
    const int gns[2] = {4, 3};
    for (int gi = 0; gi < 2; ++gi) {
        const int g0 = g0s[gi], G = gns[gi];
        const size_t eoff = (size_t)g0 * NE;
        const int G2 = 2 * G;
        const int* rpE = rowptrC + (size_t)G * (N_NODES + 1);
        // --- merged CSR build (both graphs, one launch set) ---
        k_izero<<<(G2 * N_NODES + 255) / 256, 256, 0, stream>>>(cntC, G2 * N_NODES);
        k_hist2<<<dim3(EG, G2), 256, 0, stream>>>(adj_dst + eoff, edge_dst + eoff, cntC, G);
        k_scan<<<G2, 256, 0, stream>>>(cntC, rowptrC);
        k_place2<<<dim3(EG, G2), 256, 0, stream>>>(adj_src + eoff, adj_dst + eoff,
                                                   adj_val + eoff, edge_src + eoff,
                                                   edge_dst + eoff, cntC, padjC, psrcE, G);
        // --- batched pipeline ---
        gemm_b(5, xhyp_b, Whyp_b + (size_t)g0 * DH * D_INN, nullptr, buf1, nullptr,
               nullptr, nullptr, N_NODES, DH, D_INN, G, 0, (size_t)DH * D_INN, NDB, 0, stream);
        k_rowfuse1<<<dim3(N_NODES / 4, G), 256, 0, stream>>>(buf1, xhn, hb + g0 * DH, hb2 + g0);
        k_gather_fuse2<<<dim3(N_NODES / 4, G), 256, 0, stream>>>(rowptrC, padjC, buf1, buf2);
        // ug = (I + S_e) u
        k_gather_add<<<dim3(N_NODES / 4, G), 256, 0, stream>>>(rpE, psrcE, buf2, buf1);
        // z = ug @ Wc^T + (1+indeg)*cvec + bg1   (Wd GEMM fused away)
        gemm_b(7, buf1, Wc_b + (size_t)g0 * DH * DH, bg1 + g0 * DH, buf2, nullptr,
               rpE, cvec_d + (size_t)g0 * DH, N_NODES, DH, DH, G,
               NDB, (size_t)DH * DH, NDB, DH, stream);
        k_zero<<<(G * DH + 255) / 256, 256, 0, stream>>>(csum, G * DH);
        k_zero<<<(G * DH + 255) / 256, 256, 0, stream>>>(csq, G * DH);
        k_colstats<<<dim3(200, G), 256, 0, stream>>>(buf2, csum, csq);
        {
            int total4 = (int)(G * NDB / 4);
            int blocks = (total4 + 255) / 256;
            if (blocks > 2048) blocks = 2048;
            k_normtanh_v<<<blocks, 256, 0, stream>>>(buf2, csum, csq, gamma + g0 * DH,
                                                     beta + g0 * DH, total4);
        }
        gemm_b(5, buf2, Wg2_b + (size_t)g0 * DH * DH, bg2 + g0 * DH, buf1, nullptr,
               nullptr, nullptr, N_NODES, DH, DH, G, NDB, (size_t)DH * DH, NDB, DH, stream);
        k_gather_ch<<<dim3(NB / 4, G), 256, 0, stream>>>(edge_index, edge_id, buf1, S_b, P_b,
                                                         D_INN + g0 * DH);
    }

    // stage C (bf16 MFMA; gate->G_b, gi->S_b, g->P_b, h1->G_b, h2->h2f)
    gemm_b(2, S_b, Wgate_b, bgate, G_b, nullptr, nullptr, nullptr, NB, H3, H3, 1, 0, 0, 0, 0, stream);
    gemm_b(4, P_b, Wint_b, bint, S_b, G_b, nullptr, nullptr, NB, H3, H3, 1, 0, 0, 0, 0, stream);
    gemm_b(5, S_b, Wout_b, bout, P_b, nullptr, nullptr, nullptr, NB, H3, H3, 1, 0, 0, 0, 0, stream);
    gemm_b(3, P_b, Wf1_b, bf1, G_b, nullptr, nullptr, nullptr, NB, 1152, H3, 1, 0, 0, 0, 0, stream);
    gemm_b(6, G_b, Wf2_b, bf2, h2f, nullptr, nullptr, nullptr, NB, 576, 1152, 1, 0, 0, 0, 0, stream);
    k_final<<<NB, 64, 0, stream>>>(h2f, Wf3, bf3, outp);
}

// Round 12
// 2017.733 us; speedup vs baseline: 1.1583x; 1.1583x over previous
//
#include <hip/hip_runtime.h>
#include <math.h>

#define N_NODES 20000
#define D_INN   512
#define DH      256
#define NCH     7
#define NE      320000
#define NE2     100000
#define NB      8192
#define H3      2304   // 512 + 7*256
#define MAXN    0.996f
#define LOG2E   1.44269504f

typedef unsigned short u16;
typedef __attribute__((ext_vector_type(8))) short bf16x8;
typedef __attribute__((ext_vector_type(4))) float f32x4;

__device__ __forceinline__ u16 f2b(float f) {    // RNE f32 -> bf16 bits
    unsigned int x = __float_as_uint(f);
    unsigned int r = (x + 0x7fffu + ((x >> 16) & 1u)) >> 16;
    return (u16)r;
}
__device__ __forceinline__ float b2f(u16 u) {
    return __uint_as_float(((unsigned int)u) << 16);
}
__device__ __forceinline__ float blo(unsigned int u) { return __uint_as_float(u << 16); }
__device__ __forceinline__ float bhi(unsigned int u) { return __uint_as_float(u & 0xffff0000u); }
__device__ __forceinline__ unsigned int pk2(float a, float b) {
    return (unsigned int)f2b(a) | ((unsigned int)f2b(b) << 16);
}

// ---- fast HW transcendentals (rel err ~1e-5, fine for bf16 tolerance) ----
__device__ __forceinline__ float rcp_f(float x) { return __builtin_amdgcn_rcpf(x); }
__device__ __forceinline__ float exp2_f(float x) { return __builtin_amdgcn_exp2f(x); }
__device__ __forceinline__ float log2_f(float x) { return __builtin_amdgcn_logf(x); }
__device__ __forceinline__ float tanh_fast(float x) {
    float xc = fminf(fmaxf(x, -15.f), 15.f);
    float t = exp2_f(xc * (2.f * LOG2E));
    return (t - 1.f) * rcp_f(t + 1.f);
}
__device__ __forceinline__ float artanh_fast(float x) {
    x = fminf(fmaxf(x, -1.0f + 1e-7f), 1.0f - 1e-7f);
    return 0.34657359f * log2_f((1.f + x) * rcp_f(1.f - x));
}
__device__ __forceinline__ float sigmoid_fast(float x) {
    return rcp_f(1.f + exp2_f(-x * LOG2E));
}

__device__ __forceinline__ float wave_sum(float v) {
    #pragma unroll
    for (int off = 32; off > 0; off >>= 1) v += __shfl_xor(v, off, 64);
    return v;
}

__device__ __forceinline__ float block_sum256(float v) {
    __shared__ float sred[4];
    #pragma unroll
    for (int off = 32; off > 0; off >>= 1) v += __shfl_down(v, off, 64);
    int lane = threadIdx.x & 63;
    int w = threadIdx.x >> 6;
    if (lane == 0) sred[w] = v;
    __syncthreads();
    float tot = sred[0] + sred[1] + sred[2] + sred[3];
    __syncthreads();
    return tot;
}

__global__ void k_zero(float* __restrict__ p, int n) {
    int i = blockIdx.x * 256 + threadIdx.x;
    if (i < n) p[i] = 0.0f;
}
__global__ void k_izero(int* __restrict__ p, int n) {
    int i = blockIdx.x * 256 + threadIdx.x;
    if (i < n) p[i] = 0;
}

__global__ void k_f2b(const float* __restrict__ s, u16* __restrict__ d, int n4) {
    int i = blockIdx.x * 256 + threadIdx.x;
    int stride = gridDim.x * 256;
    for (; i < n4; i += stride) {
        float4 v = ((const float4*)s)[i];
        uint2 o; o.x = pk2(v.x, v.y); o.y = pk2(v.z, v.w);
        ((uint2*)d)[i] = o;
    }
}

// pack two bias vectors contiguously (for batched gate/int GEMM)
__global__ void k_bias2(const float* __restrict__ a, const float* __restrict__ b,
                        float* __restrict__ o) {
    int i = blockIdx.x * 256 + threadIdx.x;
    if (i < H3) o[i] = a[i];
    else if (i < 2 * H3) o[i] = b[i - H3];
}

// gi = gate * relu(tmp), all bf16, vectorized
__global__ void k_gi(const u16* __restrict__ gate, const u16* __restrict__ tmp,
                     u16* __restrict__ out, int total4) {
    int i = blockIdx.x * 256 + threadIdx.x;
    int stride = gridDim.x * 256;
    for (; i < total4; i += stride) {
        uint2 g = ((const uint2*)gate)[i];
        uint2 t = ((const uint2*)tmp)[i];
        uint2 o;
        o.x = pk2(blo(g.x) * fmaxf(blo(t.x), 0.f), bhi(g.x) * fmaxf(bhi(t.x), 0.f));
        o.y = pk2(blo(g.y) * fmaxf(blo(t.y), 0.f), bhi(g.y) * fmaxf(bhi(t.y), 0.f));
        ((uint2*)out)[i] = o;
    }
}

// Wd transpose -> bf16 (for Wc = Wg1 @ Wd via A@W^T kernel)
__global__ void k_twd(const float* __restrict__ Wd, u16* __restrict__ Wdt) {
    __shared__ float tile[16][17];
    int z = blockIdx.z;
    int bx = blockIdx.x * 16, by = blockIdx.y * 16;
    int tx = threadIdx.x & 15, ty = threadIdx.x >> 4;
    tile[ty][tx] = Wd[(size_t)z * DH * DH + (size_t)(by + ty) * DH + bx + tx];
    __syncthreads();
    Wdt[(size_t)z * DH * DH + (size_t)(bx + ty) * DH + by + tx] = f2b(tile[tx][ty]);
}

// cvec[z][j] = sum_k Wg1[z][j][k] * bd[z][k]   (f32)
__global__ void k_cvec(const float* __restrict__ Wg1, const float* __restrict__ bd,
                       float* __restrict__ cvec) {
    int z = blockIdx.x, j = threadIdx.x;
    const float* row = Wg1 + (size_t)z * DH * DH + (size_t)j * DH;
    const float* b = bd + (size_t)z * DH;
    float s = 0.f;
    for (int k = 0; k < DH; ++k) s = fmaf(row[k], b[k], s);
    cvec[(size_t)z * DH + j] = s;
}

// ===== merged CSR build: 2G z-slices (z<G: adj graph, z>=G: edge graph) =====
__global__ void k_hist2(const int* __restrict__ adjd, const int* __restrict__ edged,
                        int* __restrict__ cnt, int G) {
    int z = blockIdx.y;
    const int* dst = (z < G) ? adjd + (size_t)z * NE : edged + (size_t)(z - G) * NE;
    cnt += (size_t)z * N_NODES;
    int i = blockIdx.x * 256 + threadIdx.x;
    if (i < NE) atomicAdd(&cnt[dst[i]], 1);
}

// one block per slice; cnt becomes the cursor array in-place
__global__ void k_scan(int* __restrict__ cnt, int* __restrict__ rowptr) {
    int z = blockIdx.x;
    cnt += (size_t)z * N_NODES;
    rowptr += (size_t)z * (N_NODES + 1);
    __shared__ int part[256];
    int t = threadIdx.x;
    const int CH = (N_NODES + 255) / 256;
    int beg = t * CH;
    int end = beg + CH; if (end > N_NODES) end = N_NODES;
    int s = 0;
    for (int i = beg; i < end; ++i) s += cnt[i];
    part[t] = s;
    __syncthreads();
    for (int off = 1; off < 256; off <<= 1) {
        int v = (t >= off) ? part[t - off] : 0;
        __syncthreads();
        part[t] += v;
        __syncthreads();
    }
    int run = (t == 0) ? 0 : part[t - 1];
    for (int i = beg; i < end; ++i) {
        int c = cnt[i];
        rowptr[i] = run;
        cnt[i] = run;      // cursor init (in-place)
        run += c;
    }
    if (t == 255) rowptr[N_NODES] = part[255];
}

// place: adj slices write packed (src, val) uint2 (1 scatter store/edge);
// edge slices write int src.
__global__ void k_place2(const int* __restrict__ adjs, const int* __restrict__ adjd,
                         const float* __restrict__ adjv, const int* __restrict__ edges,
                         const int* __restrict__ edged, int* __restrict__ cursor,
                         uint2* __restrict__ padj, int* __restrict__ psrcE, int G) {
    int z = blockIdx.y;
    bool isadj = z < G;
    const int* src = isadj ? adjs + (size_t)z * NE : edges + (size_t)(z - G) * NE;
    const int* dst = isadj ? adjd + (size_t)z * NE : edged + (size_t)(z - G) * NE;
    cursor += (size_t)z * N_NODES;
    int i = blockIdx.x * 256 + threadIdx.x;
    if (i < NE) {
        int d = dst[i];
        int pos = atomicAdd(&cursor[d], 1);
        if (isadj) {
            uint2 p;
            p.x = (unsigned int)src[i];
            p.y = __float_as_uint(adjv[(size_t)z * NE + i]);
            padj[(size_t)z * NE + pos] = p;
        } else {
            psrcE[(size_t)(z - G) * NE + pos] = src[i];
        }
    }
}

// x_hyp = proj(expmap0(f1)) -> bf16; clamped row norm -> xhn (f32)
__global__ void k_expmap_proj_in(const float* __restrict__ f1,
                                 u16* __restrict__ xhyp, float* __restrict__ xhn) {
    int r = blockIdx.x, t = threadIdx.x;
    const float* u = f1 + (size_t)r * D_INN;
    float v0 = u[t], v1 = u[t + 256];
    float ss = block_sum256(v0 * v0 + v1 * v1);
    float nraw = sqrtf(ss);
    float n = fmaxf(nraw, 1e-15f);
    float c = tanh_fast(n) * rcp_f(n);
    float ny = c * nraw;
    float np = fmaxf(ny, 1e-15f);
    float s = (np > MAXN) ? MAXN * rcp_f(np) : 1.0f;
    float cs = c * s;
    u16* o = xhyp + (size_t)r * D_INN;
    o[t] = f2b(cs * v0);
    o[t + 256] = f2b(cs * v1);
    if (t == 0) xhn[r] = fminf(np, MAXN);
}

__global__ void k_hb(const float* __restrict__ b_hyp,
                     float* __restrict__ hb, float* __restrict__ hb2) {
    int i = blockIdx.x, t = threadIdx.x;
    float v = b_hyp[i * DH + t];
    float ss = block_sum256(v * v);
    float nraw = sqrtf(ss);
    float n = fmaxf(nraw, 1e-15f);
    float c = tanh_fast(n) * rcp_f(n);
    float ny = c * nraw;
    float np = fmaxf(ny, 1e-15f);
    float s = (np > MAXN) ? MAXN * rcp_f(np) : 1.0f;
    float hv = c * s * v;
    hb[i * DH + t] = hv;
    float s2 = block_sum256(hv * hv);
    if (t == 0) hb2[i] = s2;
}

// wave-per-node (4 nodes/block), lane = 4 feats via uint2; in-place bf16.
__global__ void k_rowfuse1(u16* __restrict__ T, const float* __restrict__ xhn,
                           const float* __restrict__ hb, const float* __restrict__ hb2) {
    int z = blockIdx.y;
    int n = blockIdx.x * 4 + (threadIdx.x >> 6);
    int lane = threadIdx.x & 63;
    u16* row = T + ((size_t)z * N_NODES + n) * DH;
    const float* hbz = hb + (size_t)z * DH;
    uint2 u = *(const uint2*)(row + lane * 4);
    float m0 = blo(u.x), m1 = bhi(u.x), m2 = blo(u.y), m3 = bhi(u.y);
    float ss = wave_sum(m0 * m0 + m1 * m1 + m2 * m2 + m3 * m3);
    float mxn_raw = sqrtf(ss);
    float mxn = fmaxf(mxn_raw, 1e-15f);
    float xn = xhn[n];
    float tt = tanh_fast(mxn * rcp_f(xn) * artanh_fast(xn));
    float coef = tt * rcp_f(mxn);
    float nres = coef * mxn_raw;
    float np = fmaxf(nres, 1e-15f);
    float s1 = (np > MAXN) ? MAXN * rcp_f(np) : 1.0f;
    float cs = coef * s1;
    float r0 = cs * m0, r1 = cs * m1, r2 = cs * m2, r3 = cs * m3;
    float n1 = fminf(np, MAXN);
    float4 hv = *(const float4*)(hbz + lane * 4);
    float xy = wave_sum(r0 * hv.x + r1 * hv.y + r2 * hv.z + r3 * hv.w);
    float x2 = n1 * n1, y2 = hb2[z];
    float ca = 1.0f + 2.0f * xy + y2;
    float cb = 1.0f - x2;
    float rden = rcp_f(fmaxf(1.0f + 2.0f * xy + x2 * y2, 1e-15f));
    float o0 = (ca * r0 + cb * hv.x) * rden;
    float o1 = (ca * r1 + cb * hv.y) * rden;
    float o2 = (ca * r2 + cb * hv.z) * rden;
    float o3 = (ca * r3 + cb * hv.w) * rden;
    float no2 = wave_sum(o0 * o0 + o1 * o1 + o2 * o2 + o3 * o3);
    float nop = fmaxf(sqrtf(no2), 1e-15f);
    float s2 = (nop > MAXN) ? MAXN * rcp_f(nop) : 1.0f;
    float n2 = fminf(nop, MAXN);
    float fin = artanh_fast(n2) * rcp_f(n2) * s2;
    uint2 o; o.x = pk2(fin * o0, fin * o1); o.y = pk2(fin * o2, fin * o3);
    *(uint2*)(row + lane * 4) = o;
}

// wave-per-node CSR gather (packed (src,val)) + fused rowfuse2 chain -> bf16 out
__global__ void k_gather_fuse2(const int* __restrict__ rowptr, const uint2* __restrict__ padj,
                               const u16* __restrict__ xt, u16* __restrict__ out) {
    int z = blockIdx.y;
    rowptr += (size_t)z * (N_NODES + 1);
    padj += (size_t)z * NE;
    xt += (size_t)z * N_NODES * DH;
    out += (size_t)z * N_NODES * DH;
    int n = blockIdx.x * 4 + (threadIdx.x >> 6);
    int lane = threadIdx.x & 63;
    int beg = rowptr[n], end = rowptr[n + 1];
    float a0 = 0.f, a1 = 0.f, a2 = 0.f, a3 = 0.f;
    for (int i = beg; i < end; ++i) {
        uint2 p = padj[i];
        float v = __uint_as_float(p.y);
        uint2 u = *(const uint2*)(xt + (size_t)p.x * DH + lane * 4);
        a0 = fmaf(v, blo(u.x), a0);
        a1 = fmaf(v, bhi(u.x), a1);
        a2 = fmaf(v, blo(u.y), a2);
        a3 = fmaf(v, bhi(u.y), a3);
    }
    float ss = wave_sum(a0 * a0 + a1 * a1 + a2 * a2 + a3 * a3);
    float nraw = sqrtf(ss);
    float n_ = fmaxf(nraw, 1e-15f);
    float c1 = tanh_fast(n_) * rcp_f(n_);
    float nh = c1 * nraw;
    float np1 = fmaxf(nh, 1e-15f);
    float s1 = (np1 > MAXN) ? MAXN * rcp_f(np1) : 1.0f;
    float n1 = fminf(np1, MAXN);
    float cu = artanh_fast(n1) * rcp_f(n1) * s1 * c1;
    float u0 = fmaxf(cu * a0, 0.f), u1 = fmaxf(cu * a1, 0.f);
    float u2 = fmaxf(cu * a2, 0.f), u3 = fmaxf(cu * a3, 0.f);
    float ss2 = wave_sum(u0 * u0 + u1 * u1 + u2 * u2 + u3 * u3);
    float n2raw = sqrtf(ss2);
    float n2 = fmaxf(n2raw, 1e-15f);
    float c3 = tanh_fast(n2) * rcp_f(n2);
    float ne = c3 * n2raw;
    float np3 = fmaxf(ne, 1e-15f);
    float s3 = (np3 > MAXN) ? MAXN * rcp_f(np3) : 1.0f;
    float n3 = fminf(np3, MAXN);
    float cf = artanh_fast(n3) * rcp_f(n3) * s3 * c3;
    uint2 o; o.x = pk2(cf * u0, cf * u1); o.y = pk2(cf * u2, cf * u3);
    *(uint2*)(out + (size_t)n * DH + lane * 4) = o;
}

// wave-per-node: out[n] = d[n] + sum_in d[src]; bf16 in/out
__global__ void k_gather_add(const int* __restrict__ rowptr, const int* __restrict__ psrc,
                             const u16* __restrict__ d, u16* __restrict__ out) {
    int z = blockIdx.y;
    rowptr += (size_t)z * (N_NODES + 1);
    psrc += (size_t)z * NE;
    d += (size_t)z * N_NODES * DH;
    out += (size_t)z * N_NODES * DH;
    int n = blockIdx.x * 4 + (threadIdx.x >> 6);
    int lane = threadIdx.x & 63;
    int beg = rowptr[n], end = rowptr[n + 1];
    uint2 u0v = *(const uint2*)(d + (size_t)n * DH + lane * 4);
    float a0 = blo(u0v.x), a1 = bhi(u0v.x), a2 = blo(u0v.y), a3 = bhi(u0v.y);
    for (int i = beg; i < end; ++i) {
        int s = psrc[i];
        uint2 u = *(const uint2*)(d + (size_t)s * DH + lane * 4);
        a0 += blo(u.x); a1 += bhi(u.x); a2 += blo(u.y); a3 += bhi(u.y);
    }
    uint2 o; o.x = pk2(a0, a1); o.y = pk2(a2, a3);
    *(uint2*)(out + (size_t)n * DH + lane * 4) = o;
}

// batched column stats from bf16
__global__ void k_colstats(const u16* __restrict__ zp,
                           float* __restrict__ csum, float* __restrict__ csq) {
    int z = blockIdx.y;
    zp += (size_t)z * N_NODES * DH;
    csum += (size_t)z * DH;
    csq += (size_t)z * DH;
    int t = threadIdx.x;
    int r0 = blockIdx.x * 100;
    float s = 0.0f, q = 0.0f;
    for (int r = r0; r < r0 + 100; ++r) {
        float v = b2f(zp[(size_t)r * DH + t]);
        s += v;
        q += v * v;
    }
    atomicAdd(&csum[t], s);
    atomicAdd(&csq[t], q);
}

// grid-stride uint2 batchnorm + tanh, in-place bf16 (total4 = G*N*DH/4)
__global__ void k_normtanh_v(u16* __restrict__ zp, const float* __restrict__ csum,
                             const float* __restrict__ csq, const float* __restrict__ gamma,
                             const float* __restrict__ beta, int total4) {
    const float inv_n = 1.0f / N_NODES;
    int i = blockIdx.x * 256 + threadIdx.x;
    int stride = gridDim.x * 256;
    for (; i < total4; i += stride) {
        int e0 = i * 4;
        int z = e0 / (N_NODES * DH);
        int j0 = e0 & (DH - 1);
        int zb = z * DH + j0;
        uint2 u = ((uint2*)zp)[i];
        float v[4] = {blo(u.x), bhi(u.x), blo(u.y), bhi(u.y)};
        #pragma unroll
        for (int k = 0; k < 4; ++k) {
            float mu = csum[zb + k] * inv_n;
            float var = csq[zb + k] * inv_n - mu * mu;
            float inv = __builtin_amdgcn_rsqf(var + 1e-5f);
            v[k] = tanh_fast((v[k] - mu) * inv * gamma[zb + k] + beta[zb + k]);
        }
        uint2 o; o.x = pk2(v[0], v[1]); o.y = pk2(v[2], v[3]);
        ((uint2*)zp)[i] = o;
    }
}

// f1 slice of S,P (cols 0..511): thread t -> 2 cols via float2, packed u32 store
__global__ void k_pair0(const int* __restrict__ ei, const int* __restrict__ eid,
                        const float* __restrict__ f1, u16* __restrict__ S,
                        u16* __restrict__ P) {
    int b = blockIdx.x, t = threadIdx.x;
    int e = eid[b];
    int n0 = ei[e], n1 = ei[NE2 + e];
    float2 a = *(const float2*)(f1 + (size_t)n0 * D_INN + t * 2);
    float2 c = *(const float2*)(f1 + (size_t)n1 * D_INN + t * 2);
    ((unsigned int*)(S + (size_t)b * H3))[t] = pk2(a.x + c.x, a.y + c.y);
    ((unsigned int*)(P + (size_t)b * H3))[t] = pk2(a.x * c.x, a.y * c.y);
}

// batched channel slice of S,P from z_ch; 4 edges/block, uint2 lanes
__global__ void k_gather_ch(const int* __restrict__ ei, const int* __restrict__ eid,
                            const u16* __restrict__ zch, u16* __restrict__ S,
                            u16* __restrict__ P, int col0base) {
    int z = blockIdx.y;
    const u16* zp = zch + (size_t)z * N_NODES * DH;
    int col0 = col0base + z * DH;
    int b = blockIdx.x * 4 + (threadIdx.x >> 6);
    int lane = threadIdx.x & 63;
    int e = eid[b];
    int n0 = ei[e], n1 = ei[NE2 + e];
    uint2 ua = *(const uint2*)(zp + (size_t)n0 * DH + lane * 4);
    uint2 ub = *(const uint2*)(zp + (size_t)n1 * DH + lane * 4);
    float a0 = blo(ua.x), a1 = bhi(ua.x), a2 = blo(ua.y), a3 = bhi(ua.y);
    float c0 = blo(ub.x), c1 = bhi(ub.x), c2 = blo(ub.y), c3 = bhi(ub.y);
    uint2 so; so.x = pk2(a0 + c0, a1 + c1); so.y = pk2(a2 + c2, a3 + c3);
    uint2 po; po.x = pk2(a0 * c0, a1 * c1); po.y = pk2(a2 * c2, a3 * c3);
    *(uint2*)(S + (size_t)b * H3 + col0 + lane * 4) = so;
    *(uint2*)(P + (size_t)b * H3 + col0 + lane * 4) = po;
}

__global__ void k_final(const float* __restrict__ h2, const float* __restrict__ Wf3,
                        const float* __restrict__ bf3, float* __restrict__ out) {
    int r = blockIdx.x, t = threadIdx.x;
    const float* hr = h2 + (size_t)r * 576;
    float acc[7] = {0, 0, 0, 0, 0, 0, 0};
    for (int cb = t; cb < 576; cb += 64) {
        float h = hr[cb];
        #pragma unroll
        for (int o = 0; o < 7; ++o) acc[o] = fmaf(h, Wf3[o * 576 + cb], acc[o]);
    }
    #pragma unroll
    for (int o = 0; o < 7; ++o) {
        #pragma unroll
        for (int off = 32; off > 0; off >>= 1) acc[o] += __shfl_down(acc[o], off, 64);
    }
    if (t == 0) {
        #pragma unroll
        for (int o = 0; o < 7; ++o) out[(size_t)r * 7 + o] = acc[o] + bf3[o];
    }
}

// ===== bf16 MFMA GEMM (batched over blockIdx.z with strides). R10 structure:
// global_load_lds width-16 coalesced staging (chunk^row involution swizzle,
// 0 bank conflicts), XCD-aware bijective block swizzle per z.
// EP: 2=sigmoid->bf16, 3=relu->bf16, 5=bf16, 6=relu->f32,
//     7=bf16 + bias + (1+indeg[row])*cvec[col],
//     8=z==0? sigmoid->bf16 : bf16 (for batched gate/int)
template <int EP>
__global__ __launch_bounds__(256, 2) void k_gemm_mfma(
    const u16* __restrict__ A, const u16* __restrict__ W,
    const float* __restrict__ bias, void* __restrict__ outv,
    const int* __restrict__ rpe, const float* __restrict__ cvec,
    int M, int N, int K, size_t sA, size_t sW, size_t sC, int sBias) {
    __shared__ short As[4096];   // 8 groups x 1KB
    __shared__ short Ws[4096];
    const int z = blockIdx.z;
    A += (size_t)z * sA;
    W += (size_t)z * sW;
    const size_t zC = (size_t)z * sC;
    const int* rp = (EP == 7) ? rpe + (size_t)z * (N_NODES + 1) : nullptr;
    const float* cv = (EP == 7) ? cvec + (size_t)z * DH : nullptr;
    // XCD bijective swizzle within this z-slice
    const int gx = gridDim.x;
    const int nwg = gx * gridDim.y;
    const int orig = blockIdx.y * gx + blockIdx.x;
    const int q8 = nwg >> 3, r8 = nwg & 7, xcd = orig & 7;
    const int wg = (xcd < r8 ? xcd * (q8 + 1) : r8 * (q8 + 1) + (xcd - r8) * q8) + (orig >> 3);
    const int row0 = (wg / gx) * 128, col0 = (wg % gx) * 128;
    const int t = threadIdx.x;
    const int lane = t & 63;
    const int w = t >> 6;
    const int wr = w >> 1, wc = w & 1;
    // staging: lane l -> row-in-group l>>2, global chunk (l&3)^((l>>3)&3)
    const int sr = lane >> 2;
    const int csrc = (lane & 3) ^ ((lane >> 3) & 3);
    int gr[2], gc[2];
    #pragma unroll
    for (int p = 0; p < 2; ++p) {
        int g = w + p * 4;
        gr[p] = row0 + g * 16 + sr; if (gr[p] >= M) gr[p] = M - 1;
        gc[p] = col0 + g * 16 + sr; if (gc[p] >= N) gc[p] = N - 1;
    }
    // fragment read offset (shorts): row fr, chunk q -> fr*32 + (q^((fr>>1)&3))*8
    const int fr = lane & 15, fq = lane >> 4;
    const int rdoff = fr * 32 + ((fq ^ ((fr >> 1) & 3)) * 8);
    f32x4 acc[4][4] = {};
    for (int k0 = 0; k0 < K; k0 += 32) {
        #pragma unroll
        for (int p = 0; p < 2; ++p) {
            int g = w + p * 4;
            __builtin_amdgcn_global_load_lds(
                (const __attribute__((address_space(1))) unsigned int*)(A + (size_t)gr[p] * K + k0 + csrc * 8),
                (__attribute__((address_space(3))) unsigned int*)(As + g * 512), 16, 0, 0);
            __builtin_amdgcn_global_load_lds(
                (const __attribute__((address_space(1))) unsigned int*)(W + (size_t)gc[p] * K + k0 + csrc * 8),
                (__attribute__((address_space(3))) unsigned int*)(Ws + g * 512), 16, 0, 0);
        }
        __syncthreads();
        bf16x8 af[4], bfr[4];
        #pragma unroll
        for (int m = 0; m < 4; ++m)
            af[m] = *(const bf16x8*)(As + (wr * 4 + m) * 512 + rdoff);
        #pragma unroll
        for (int n = 0; n < 4; ++n)
            bfr[n] = *(const bf16x8*)(Ws + (wc * 4 + n) * 512 + rdoff);
        #pragma unroll
        for (int m = 0; m < 4; ++m)
            #pragma unroll
            for (int n = 0; n < 4; ++n)
                acc[m][n] = __builtin_amdgcn_mfma_f32_16x16x32_bf16(af[m], bfr[n], acc[m][n], 0, 0, 0);
        __syncthreads();
    }
    const int cl = lane & 15, rh = (lane >> 4) * 4;
    #pragma unroll
    for (int m = 0; m < 4; ++m) {
        float indf[4];
        if (EP == 7) {
            #pragma unroll
            for (int r = 0; r < 4; ++r) {
                int row = row0 + wr * 64 + m * 16 + rh + r;
                if (row >= M) row = M - 1;
                indf[r] = 1.0f + (float)(rp[row + 1] - rp[row]);
            }
        }
        #pragma unroll
        for (int n = 0; n < 4; ++n) {
            int col = col0 + wc * 64 + n * 16 + cl;
            if (col >= N) continue;
            float bv = bias ? bias[z * sBias + col] : 0.0f;
            float cvc = (EP == 7) ? cv[col] : 0.0f;
            #pragma unroll
            for (int r = 0; r < 4; ++r) {
                int row = row0 + wr * 64 + m * 16 + rh + r;
                if (row >= M) continue;
                float v = acc[m][n][r] + bv;
                size_t idx = zC + (size_t)row * N + col;
                if (EP == 2) ((u16*)outv)[idx] = f2b(sigmoid_fast(v));
                if (EP == 3) ((u16*)outv)[idx] = f2b(fmaxf(v, 0.0f));
                if (EP == 5) ((u16*)outv)[idx] = f2b(v);
                if (EP == 6) ((float*)outv)[idx] = fmaxf(v, 0.0f);
                if (EP == 7) ((u16*)outv)[idx] = f2b(v + indf[r] * cvc);
                if (EP == 8) ((u16*)outv)[idx] = (z == 0) ? f2b(sigmoid_fast(v)) : f2b(v);
            }
        }
    }
}

static inline void gemm_b(int ep, const u16* A, const u16* W, const float* bias, void* out,
                          const int* rpe, const float* cvec,
                          int M, int N, int K, int Z,
                          size_t sA, size_t sW, size_t sC, int sBias, hipStream_t st) {
    dim3 g((N + 127) / 128, (M + 127) / 128, Z);
    switch (ep) {
        case 2: k_gemm_mfma<2><<<g, 256, 0, st>>>(A, W, bias, out, rpe, cvec, M, N, K, sA, sW, sC, sBias); break;
        case 3: k_gemm_mfma<3><<<g, 256, 0, st>>>(A, W, bias, out, rpe, cvec, M, N, K, sA, sW, sC, sBias); break;
        case 5: k_gemm_mfma<5><<<g, 256, 0, st>>>(A, W, bias, out, rpe, cvec, M, N, K, sA, sW, sC, sBias); break;
        case 6: k_gemm_mfma<6><<<g, 256, 0, st>>>(A, W, bias, out, rpe, cvec, M, N, K, sA, sW, sC, sBias); break;
        case 7: k_gemm_mfma<7><<<g, 256, 0, st>>>(A, W, bias, out, rpe, cvec, M, N, K, sA, sW, sC, sBias); break;
        case 8: k_gemm_mfma<8><<<g, 256, 0, st>>>(A, W, bias, out, rpe, cvec, M, N, K, sA, sW, sC, sBias); break;
    }
}

static inline void conv_w(const float* s, u16* d, size_t n, hipStream_t st) {
    int n4 = (int)(n / 4);
    int grid = (n4 + 255) / 256;
    if (grid > 2048) grid = 2048;
    k_f2b<<<grid, 256, 0, st>>>(s, d, n4);
}

extern "C" void kernel_launch(void* const* d_in, const int* in_sizes, int n_in, void* d_out,
                              int out_size, void* d_ws, size_t ws_size, hipStream_t stream) {
    const float* f1 = (const float*)d_in[0];
    const int* adj_src = (const int*)d_in[1];
    const int* adj_dst = (const int*)d_in[2];
    const float* adj_val = (const float*)d_in[3];
    const int* edge_src = (const int*)d_in[4];
    const int* edge_dst = (const int*)d_in[5];
    const int* edge_index = (const int*)d_in[6];
    const int* edge_id = (const int*)d_in[7];
    const float* W_hyp = (const float*)d_in[8];
    const float* b_hyp = (const float*)d_in[9];
    const float* Wd = (const float*)d_in[10];
    const float* bd = (const float*)d_in[11];
    const float* Wg1 = (const float*)d_in[12];
    const float* bg1 = (const float*)d_in[13];
    const float* gamma = (const float*)d_in[14];
    const float* beta = (const float*)d_in[15];
    const float* Wg2 = (const float*)d_in[16];
    const float* bg2 = (const float*)d_in[17];
    const float* Wgate = (const float*)d_in[18];
    const float* bgate = (const float*)d_in[19];
    const float* Wint = (const float*)d_in[20];
    const float* bint = (const float*)d_in[21];
    const float* Wout = (const float*)d_in[22];
    const float* bout = (const float*)d_in[23];
    const float* Wf1 = (const float*)d_in[24];
    const float* bf1 = (const float*)d_in[25];
    const float* Wf2 = (const float*)d_in[26];
    const float* bf2 = (const float*)d_in[27];
    const float* Wf3 = (const float*)d_in[28];
    const float* bf3 = (const float*)d_in[29];
    float* outp = (float*)d_out;

    // ---- workspace bump allocator (~240 MB) ----
    char* base = (char*)d_ws;
    size_t off = 0;
    auto alloc = [&](size_t bytes) -> char* {
        char* p = base + off;
        off += (bytes + 255) & ~(size_t)255;
        return p;
    };
    u16* Whyp_b = (u16*)alloc((size_t)NCH * DH * D_INN * 2);
    u16* Wdt_b  = (u16*)alloc((size_t)NCH * DH * DH * 2);   // Wd^T bf16
    u16* Wc_b   = (u16*)alloc((size_t)NCH * DH * DH * 2);   // Wg1 @ Wd
    u16* Wg1_b  = (u16*)alloc((size_t)NCH * DH * DH * 2);
    u16* Wg2_b  = (u16*)alloc((size_t)NCH * DH * DH * 2);
    u16* Wgate_b = (u16*)alloc((size_t)H3 * H3 * 2);        // Wint_b must follow!
    u16* Wint_b  = (u16*)alloc((size_t)H3 * H3 * 2);
    u16* Wout_b  = (u16*)alloc((size_t)H3 * H3 * 2);
    u16* Wf1_b   = (u16*)alloc((size_t)1152 * H3 * 2);
    u16* Wf2_b   = (u16*)alloc((size_t)576 * 1152 * 2);
    u16* S_b = (u16*)alloc((size_t)NB * H3 * 2);            // P_b must follow!
    u16* P_b = (u16*)alloc((size_t)NB * H3 * 2);
    const size_t NDB = (size_t)N_NODES * DH;       // per-channel elems
    u16* buf1 = (u16*)alloc(4 * NDB * 2);          // group ping (buf2 follows)
    u16* buf2 = (u16*)alloc(4 * NDB * 2);          // group pong
    u16* xhyp_b = (u16*)alloc((size_t)N_NODES * D_INN * 2);
    // merged CSR scratch (2G slices; G<=4): adj slices [0,G), edge slices [G,2G)
    int* cntC = (int*)alloc(8 * (size_t)N_NODES * 4);        // doubles as cursor
    int* rowptrC = (int*)alloc(8 * (size_t)(N_NODES + 1) * 4);
    uint2* padjC = (uint2*)alloc(4 * (size_t)NE * 8);        // packed (src,val)
    int* psrcE = (int*)alloc(4 * (size_t)NE * 4);
    float* xhn = (float*)alloc((size_t)N_NODES * 4);
    float* hb = (float*)alloc((size_t)NCH * DH * 4);
    float* hb2 = (float*)alloc(NCH * 4);
    float* csum = (float*)alloc((size_t)4 * DH * 4);
    float* csq = (float*)alloc((size_t)4 * DH * 4);
    float* cvec_d = (float*)alloc((size_t)NCH * DH * 4);
    float* bias2 = (float*)alloc((size_t)2 * H3 * 4);
    // stage-C overlays (GNN buffers dead by then):
    // batched gate/int writes 2 slices of NB*H3 bf16 starting at buf1 (75.5MB
    // spanning buf1+buf2 = 81.9MB available). h1 -> buf1[0..18.87MB],
    // h2f -> buf2 start (tmp slice dead by then).
    u16* GT = buf1;                  // gate slice 0, int-pre slice 1
    float* h2f = (float*)buf2;

    const int EG = (NE + 255) / 256;

    conv_w(W_hyp, Whyp_b, (size_t)NCH * DH * D_INN, stream);
    conv_w(Wg1, Wg1_b, (size_t)NCH * DH * DH, stream);
    conv_w(Wg2, Wg2_b, (size_t)NCH * DH * DH, stream);
    conv_w(Wgate, Wgate_b, (size_t)H3 * H3, stream);
    conv_w(Wint, Wint_b, (size_t)H3 * H3, stream);
    conv_w(Wout, Wout_b, (size_t)H3 * H3, stream);
    conv_w(Wf1, Wf1_b, (size_t)1152 * H3, stream);
    conv_w(Wf2, Wf2_b, (size_t)576 * 1152, stream);
    k_bias2<<<(2 * H3 + 255) / 256, 256, 0, stream>>>(bgate, bint, bias2);
    // Wc = Wg1 @ Wd (via Wd^T), cvec = Wg1 @ bd
    k_twd<<<dim3(16, 16, NCH), 256, 0, stream>>>(Wd, Wdt_b);
    gemm_b(5, Wg1_b, Wdt_b, nullptr, Wc_b, nullptr, nullptr,
           DH, DH, DH, NCH, (size_t)DH * DH, (size_t)DH * DH, (size_t)DH * DH, 0, stream);
    k_cvec<<<NCH, 256, 0, stream>>>(Wg1, bd, cvec_d);

    k_expmap_proj_in<<<N_NODES, 256, 0, stream>>>(f1, xhyp_b, xhn);
    k_hb<<<NCH, 256, 0, stream>>>(b_hyp, hb, hb2);
    k_pair0<<<NB, 256, 0, stream>>>(edge_index, edge_id, f1, S_b, P_b);

    const int g0s[2] = {0, 4};
    const int gns[2] = {4, 3};
    for (int gi = 0; gi < 2; ++gi) {
        const int g0 = g0s[gi], G = gns[gi];
        const size_t eoff = (size_t)g0 * NE;
        const int G2 = 2 * G;
        const int* rpE = rowptrC + (size_t)G * (N_NODES + 1);
        // --- merged CSR build (both graphs, one launch set) ---
        k_izero<<<(G2 * N_NODES + 255) / 256, 256, 0, stream>>>(cntC, G2 * N_NODES);
        k_hist2<<<dim3(EG, G2), 256, 0, stream>>>(adj_dst + eoff, edge_dst + eoff, cntC, G);
        k_scan<<<G2, 256, 0, stream>>>(cntC, rowptrC);
        k_place2<<<dim3(EG, G2), 256, 0, stream>>>(adj_src + eoff, adj_dst + eoff,
                                                   adj_val + eoff, edge_src + eoff,
                                                   edge_dst + eoff, cntC, padjC, psrcE, G);
        // --- batched pipeline ---
        gemm_b(5, xhyp_b, Whyp_b + (size_t)g0 * DH * D_INN, nullptr, buf1, nullptr,
               nullptr, N_NODES, DH, D_INN, G, 0, (size_t)DH * D_INN, NDB, 0, stream);
        k_rowfuse1<<<dim3(N_NODES / 4, G), 256, 0, stream>>>(buf1, xhn, hb + g0 * DH, hb2 + g0);
        k_gather_fuse2<<<dim3(N_NODES / 4, G), 256, 0, stream>>>(rowptrC, padjC, buf1, buf2);
        // ug = (I + S_e) u
        k_gather_add<<<dim3(N_NODES / 4, G), 256, 0, stream>>>(rpE, psrcE, buf2, buf1);
        // z = ug @ Wc^T + (1+indeg)*cvec + bg1   (Wd GEMM fused away)
        gemm_b(7, buf1, Wc_b + (size_t)g0 * DH * DH, bg1 + g0 * DH, buf2,
               rpE, cvec_d + (size_t)g0 * DH, N_NODES, DH, DH, G,
               NDB, (size_t)DH * DH, NDB, DH, stream);
        k_zero<<<(G * DH + 255) / 256, 256, 0, stream>>>(csum, G * DH);
        k_zero<<<(G * DH + 255) / 256, 256, 0, stream>>>(csq, G * DH);
        k_colstats<<<dim3(200, G), 256, 0, stream>>>(buf2, csum, csq);
        {
            int total4 = (int)(G * NDB / 4);
            int blocks = (total4 + 255) / 256;
            if (blocks > 2048) blocks = 2048;
            k_normtanh_v<<<blocks, 256, 0, stream>>>(buf2, csum, csq, gamma + g0 * DH,
                                                     beta + g0 * DH, total4);
        }
        gemm_b(5, buf2, Wg2_b + (size_t)g0 * DH * DH, bg2 + g0 * DH, buf1, nullptr,
               nullptr, N_NODES, DH, DH, G, NDB, (size_t)DH * DH, NDB, DH, stream);
        k_gather_ch<<<dim3(NB / 4, G), 256, 0, stream>>>(edge_index, edge_id, buf1, S_b, P_b,
                                                         D_INN + g0 * DH);
    }

    // stage C: batched gate/int (Z=2; S_b||P_b and Wgate||Wint contiguous),
    // then gi elementwise, then the chain.
    gemm_b(8, S_b, Wgate_b, bias2, GT, nullptr, nullptr, NB, H3, H3, 2,
           (size_t)NB * H3, (size_t)H3 * H3, (size_t)NB * H3, H3, stream);
    {
        int total4 = NB * H3 / 4;
        int blocks = (total4 + 255) / 256;
        if (blocks > 2048) blocks = 2048;
        k_gi<<<blocks, 256, 0, stream>>>(GT, GT + (size_t)NB * H3, S_b, total4);
    }
    gemm_b(5, S_b, Wout_b, bout, P_b, nullptr, nullptr, NB, H3, H3, 1, 0, 0, 0, 0, stream);
    gemm_b(3, P_b, Wf1_b, bf1, buf1, nullptr, nullptr, NB, 1152, H3, 1, 0, 0, 0, 0, stream);
    gemm_b(6, buf1, Wf2_b, bf2, h2f, nullptr, nullptr, NB, 576, 1152, 1, 0, 0, 0, 0, stream);
    k_final<<<NB, 64, 0, stream>>>(h2f, Wf3, bf3, outp);
}

// Round 13
// 1946.604 us; speedup vs baseline: 1.2006x; 1.0365x over previous
//
#include <hip/hip_runtime.h>
#include <math.h>

#define N_NODES 20000
#define D_INN   512
#define DH      256
#define NCH     7
#define NE      320000
#define NE2     100000
#define NB      8192
#define H3      2304   // 512 + 7*256
#define MAXN    0.996f
#define LOG2E   1.44269504f

typedef unsigned short u16;
typedef __attribute__((ext_vector_type(8))) short bf16x8;
typedef __attribute__((ext_vector_type(4))) float f32x4;

__device__ __forceinline__ u16 f2b(float f) {    // RNE f32 -> bf16 bits
    unsigned int x = __float_as_uint(f);
    unsigned int r = (x + 0x7fffu + ((x >> 16) & 1u)) >> 16;
    return (u16)r;
}
__device__ __forceinline__ float b2f(u16 u) {
    return __uint_as_float(((unsigned int)u) << 16);
}
__device__ __forceinline__ float blo(unsigned int u) { return __uint_as_float(u << 16); }
__device__ __forceinline__ float bhi(unsigned int u) { return __uint_as_float(u & 0xffff0000u); }
__device__ __forceinline__ unsigned int pk2(float a, float b) {
    return (unsigned int)f2b(a) | ((unsigned int)f2b(b) << 16);
}

// ---- fast HW transcendentals (rel err ~1e-5, fine for bf16 tolerance) ----
__device__ __forceinline__ float rcp_f(float x) { return __builtin_amdgcn_rcpf(x); }
__device__ __forceinline__ float exp2_f(float x) { return __builtin_amdgcn_exp2f(x); }
__device__ __forceinline__ float log2_f(float x) { return __builtin_amdgcn_logf(x); }
__device__ __forceinline__ float tanh_fast(float x) {
    float xc = fminf(fmaxf(x, -15.f), 15.f);
    float t = exp2_f(xc * (2.f * LOG2E));
    return (t - 1.f) * rcp_f(t + 1.f);
}
__device__ __forceinline__ float artanh_fast(float x) {
    x = fminf(fmaxf(x, -1.0f + 1e-7f), 1.0f - 1e-7f);
    return 0.34657359f * log2_f((1.f + x) * rcp_f(1.f - x));
}
__device__ __forceinline__ float sigmoid_fast(float x) {
    return rcp_f(1.f + exp2_f(-x * LOG2E));
}

__device__ __forceinline__ float wave_sum(float v) {
    #pragma unroll
    for (int off = 32; off > 0; off >>= 1) v += __shfl_xor(v, off, 64);
    return v;
}

__device__ __forceinline__ float block_sum256(float v) {
    __shared__ float sred[4];
    #pragma unroll
    for (int off = 32; off > 0; off >>= 1) v += __shfl_down(v, off, 64);
    int lane = threadIdx.x & 63;
    int w = threadIdx.x >> 6;
    if (lane == 0) sred[w] = v;
    __syncthreads();
    float tot = sred[0] + sred[1] + sred[2] + sred[3];
    __syncthreads();
    return tot;
}

__global__ void k_zero(float* __restrict__ p, int n) {
    int i = blockIdx.x * 256 + threadIdx.x;
    if (i < n) p[i] = 0.0f;
}
__global__ void k_izero(int* __restrict__ p, int n) {
    int i = blockIdx.x * 256 + threadIdx.x;
    if (i < n) p[i] = 0;
}

__global__ void k_f2b(const float* __restrict__ s, u16* __restrict__ d, int n4) {
    int i = blockIdx.x * 256 + threadIdx.x;
    int stride = gridDim.x * 256;
    for (; i < n4; i += stride) {
        float4 v = ((const float4*)s)[i];
        uint2 o; o.x = pk2(v.x, v.y); o.y = pk2(v.z, v.w);
        ((uint2*)d)[i] = o;
    }
}

// pack two bias vectors contiguously (for batched gate/int GEMM)
__global__ void k_bias2(const float* __restrict__ a, const float* __restrict__ b,
                        float* __restrict__ o) {
    int i = blockIdx.x * 256 + threadIdx.x;
    if (i < H3) o[i] = a[i];
    else if (i < 2 * H3) o[i] = b[i - H3];
}

// gi = gate * relu(tmp), all bf16, vectorized
__global__ void k_gi(const u16* __restrict__ gate, const u16* __restrict__ tmp,
                     u16* __restrict__ out, int total4) {
    int i = blockIdx.x * 256 + threadIdx.x;
    int stride = gridDim.x * 256;
    for (; i < total4; i += stride) {
        uint2 g = ((const uint2*)gate)[i];
        uint2 t = ((const uint2*)tmp)[i];
        uint2 o;
        o.x = pk2(blo(g.x) * fmaxf(blo(t.x), 0.f), bhi(g.x) * fmaxf(bhi(t.x), 0.f));
        o.y = pk2(blo(g.y) * fmaxf(blo(t.y), 0.f), bhi(g.y) * fmaxf(bhi(t.y), 0.f));
        ((uint2*)out)[i] = o;
    }
}

// Wd transpose -> bf16 (for Wc = Wg1 @ Wd via A@W^T kernel)
__global__ void k_twd(const float* __restrict__ Wd, u16* __restrict__ Wdt) {
    __shared__ float tile[16][17];
    int z = blockIdx.z;
    int bx = blockIdx.x * 16, by = blockIdx.y * 16;
    int tx = threadIdx.x & 15, ty = threadIdx.x >> 4;
    tile[ty][tx] = Wd[(size_t)z * DH * DH + (size_t)(by + ty) * DH + bx + tx];
    __syncthreads();
    Wdt[(size_t)z * DH * DH + (size_t)(bx + ty) * DH + by + tx] = f2b(tile[tx][ty]);
}

// 2304x2304 transpose f32 -> bf16 (WoutT[i][j] = Wout[j][i])
__global__ void k_tr(const float* __restrict__ Win, u16* __restrict__ Wt) {
    __shared__ float tile[16][17];
    int bx = blockIdx.x * 16, by = blockIdx.y * 16;
    int tx = threadIdx.x & 15, ty = threadIdx.x >> 4;
    tile[ty][tx] = Win[(size_t)(by + ty) * H3 + bx + tx];
    __syncthreads();
    Wt[(size_t)(bx + ty) * H3 + by + tx] = f2b(tile[tx][ty]);
}

// bcomb[r] = sum_j Wf1[r][j]*bout[j] + bf1[r]  (wave per row, 4 rows/block)
__global__ void k_bvec(const float* __restrict__ Wf1, const float* __restrict__ bout,
                       const float* __restrict__ bf1, float* __restrict__ bcomb) {
    int r = blockIdx.x * 4 + (threadIdx.x >> 6);
    int lane = threadIdx.x & 63;
    const float* row = Wf1 + (size_t)r * H3;
    float s = 0.f;
    for (int j = lane; j < H3; j += 64) s = fmaf(row[j], bout[j], s);
    s = wave_sum(s);
    if (lane == 0) bcomb[r] = s + bf1[r];
}

// cvec[z][j] = sum_k Wg1[z][j][k] * bd[z][k]   (f32)
__global__ void k_cvec(const float* __restrict__ Wg1, const float* __restrict__ bd,
                       float* __restrict__ cvec) {
    int z = blockIdx.x, j = threadIdx.x;
    const float* row = Wg1 + (size_t)z * DH * DH + (size_t)j * DH;
    const float* b = bd + (size_t)z * DH;
    float s = 0.f;
    for (int k = 0; k < DH; ++k) s = fmaf(row[k], b[k], s);
    cvec[(size_t)z * DH + j] = s;
}

// ===== merged CSR build: 2G z-slices (z<G: adj graph, z>=G: edge graph) =====
__global__ void k_hist2(const int* __restrict__ adjd, const int* __restrict__ edged,
                        int* __restrict__ cnt, int G) {
    int z = blockIdx.y;
    const int* dst = (z < G) ? adjd + (size_t)z * NE : edged + (size_t)(z - G) * NE;
    cnt += (size_t)z * N_NODES;
    int i = blockIdx.x * 256 + threadIdx.x;
    if (i < NE) atomicAdd(&cnt[dst[i]], 1);
}

// one block per slice; cnt becomes the cursor array in-place
__global__ void k_scan(int* __restrict__ cnt, int* __restrict__ rowptr) {
    int z = blockIdx.x;
    cnt += (size_t)z * N_NODES;
    rowptr += (size_t)z * (N_NODES + 1);
    __shared__ int part[256];
    int t = threadIdx.x;
    const int CH = (N_NODES + 255) / 256;
    int beg = t * CH;
    int end = beg + CH; if (end > N_NODES) end = N_NODES;
    int s = 0;
    for (int i = beg; i < end; ++i) s += cnt[i];
    part[t] = s;
    __syncthreads();
    for (int off = 1; off < 256; off <<= 1) {
        int v = (t >= off) ? part[t - off] : 0;
        __syncthreads();
        part[t] += v;
        __syncthreads();
    }
    int run = (t == 0) ? 0 : part[t - 1];
    for (int i = beg; i < end; ++i) {
        int c = cnt[i];
        rowptr[i] = run;
        cnt[i] = run;      // cursor init (in-place)
        run += c;
    }
    if (t == 255) rowptr[N_NODES] = part[255];
}

// place: adj slices write packed (src, val) uint2 (1 scatter store/edge);
// edge slices write int src.
__global__ void k_place2(const int* __restrict__ adjs, const int* __restrict__ adjd,
                         const float* __restrict__ adjv, const int* __restrict__ edges,
                         const int* __restrict__ edged, int* __restrict__ cursor,
                         uint2* __restrict__ padj, int* __restrict__ psrcE, int G) {
    int z = blockIdx.y;
    bool isadj = z < G;
    const int* src = isadj ? adjs + (size_t)z * NE : edges + (size_t)(z - G) * NE;
    const int* dst = isadj ? adjd + (size_t)z * NE : edged + (size_t)(z - G) * NE;
    cursor += (size_t)z * N_NODES;
    int i = blockIdx.x * 256 + threadIdx.x;
    if (i < NE) {
        int d = dst[i];
        int pos = atomicAdd(&cursor[d], 1);
        if (isadj) {
            uint2 p;
            p.x = (unsigned int)src[i];
            p.y = __float_as_uint(adjv[(size_t)z * NE + i]);
            padj[(size_t)z * NE + pos] = p;
        } else {
            psrcE[(size_t)(z - G) * NE + pos] = src[i];
        }
    }
}

// x_hyp = proj(expmap0(f1)) -> bf16; clamped row norm -> xhn (f32)
__global__ void k_expmap_proj_in(const float* __restrict__ f1,
                                 u16* __restrict__ xhyp, float* __restrict__ xhn) {
    int r = blockIdx.x, t = threadIdx.x;
    const float* u = f1 + (size_t)r * D_INN;
    float v0 = u[t], v1 = u[t + 256];
    float ss = block_sum256(v0 * v0 + v1 * v1);
    float nraw = sqrtf(ss);
    float n = fmaxf(nraw, 1e-15f);
    float c = tanh_fast(n) * rcp_f(n);
    float ny = c * nraw;
    float np = fmaxf(ny, 1e-15f);
    float s = (np > MAXN) ? MAXN * rcp_f(np) : 1.0f;
    float cs = c * s;
    u16* o = xhyp + (size_t)r * D_INN;
    o[t] = f2b(cs * v0);
    o[t + 256] = f2b(cs * v1);
    if (t == 0) xhn[r] = fminf(np, MAXN);
}

__global__ void k_hb(const float* __restrict__ b_hyp,
                     float* __restrict__ hb, float* __restrict__ hb2) {
    int i = blockIdx.x, t = threadIdx.x;
    float v = b_hyp[i * DH + t];
    float ss = block_sum256(v * v);
    float nraw = sqrtf(ss);
    float n = fmaxf(nraw, 1e-15f);
    float c = tanh_fast(n) * rcp_f(n);
    float ny = c * nraw;
    float np = fmaxf(ny, 1e-15f);
    float s = (np > MAXN) ? MAXN * rcp_f(np) : 1.0f;
    float hv = c * s * v;
    hb[i * DH + t] = hv;
    float s2 = block_sum256(hv * hv);
    if (t == 0) hb2[i] = s2;
}

// wave-per-node (4 nodes/block), lane = 4 feats via uint2; in-place bf16.
__global__ void k_rowfuse1(u16* __restrict__ T, const float* __restrict__ xhn,
                           const float* __restrict__ hb, const float* __restrict__ hb2) {
    int z = blockIdx.y;
    int n = blockIdx.x * 4 + (threadIdx.x >> 6);
    int lane = threadIdx.x & 63;
    u16* row = T + ((size_t)z * N_NODES + n) * DH;
    const float* hbz = hb + (size_t)z * DH;
    uint2 u = *(const uint2*)(row + lane * 4);
    float m0 = blo(u.x), m1 = bhi(u.x), m2 = blo(u.y), m3 = bhi(u.y);
    float ss = wave_sum(m0 * m0 + m1 * m1 + m2 * m2 + m3 * m3);
    float mxn_raw = sqrtf(ss);
    float mxn = fmaxf(mxn_raw, 1e-15f);
    float xn = xhn[n];
    float tt = tanh_fast(mxn * rcp_f(xn) * artanh_fast(xn));
    float coef = tt * rcp_f(mxn);
    float nres = coef * mxn_raw;
    float np = fmaxf(nres, 1e-15f);
    float s1 = (np > MAXN) ? MAXN * rcp_f(np) : 1.0f;
    float cs = coef * s1;
    float r0 = cs * m0, r1 = cs * m1, r2 = cs * m2, r3 = cs * m3;
    float n1 = fminf(np, MAXN);
    float4 hv = *(const float4*)(hbz + lane * 4);
    float xy = wave_sum(r0 * hv.x + r1 * hv.y + r2 * hv.z + r3 * hv.w);
    float x2 = n1 * n1, y2 = hb2[z];
    float ca = 1.0f + 2.0f * xy + y2;
    float cb = 1.0f - x2;
    float rden = rcp_f(fmaxf(1.0f + 2.0f * xy + x2 * y2, 1e-15f));
    float o0 = (ca * r0 + cb * hv.x) * rden;
    float o1 = (ca * r1 + cb * hv.y) * rden;
    float o2 = (ca * r2 + cb * hv.z) * rden;
    float o3 = (ca * r3 + cb * hv.w) * rden;
    float no2 = wave_sum(o0 * o0 + o1 * o1 + o2 * o2 + o3 * o3);
    float nop = fmaxf(sqrtf(no2), 1e-15f);
    float s2 = (nop > MAXN) ? MAXN * rcp_f(nop) : 1.0f;
    float n2 = fminf(nop, MAXN);
    float fin = artanh_fast(n2) * rcp_f(n2) * s2;
    uint2 o; o.x = pk2(fin * o0, fin * o1); o.y = pk2(fin * o2, fin * o3);
    *(uint2*)(row + lane * 4) = o;
}

// wave-per-node CSR gather (packed (src,val)) + fused rowfuse2 chain -> bf16 out
__global__ void k_gather_fuse2(const int* __restrict__ rowptr, const uint2* __restrict__ padj,
                               const u16* __restrict__ xt, u16* __restrict__ out) {
    int z = blockIdx.y;
    rowptr += (size_t)z * (N_NODES + 1);
    padj += (size_t)z * NE;
    xt += (size_t)z * N_NODES * DH;
    out += (size_t)z * N_NODES * DH;
    int n = blockIdx.x * 4 + (threadIdx.x >> 6);
    int lane = threadIdx.x & 63;
    int beg = rowptr[n], end = rowptr[n + 1];
    float a0 = 0.f, a1 = 0.f, a2 = 0.f, a3 = 0.f;
    for (int i = beg; i < end; ++i) {
        uint2 p = padj[i];
        float v = __uint_as_float(p.y);
        uint2 u = *(const uint2*)(xt + (size_t)p.x * DH + lane * 4);
        a0 = fmaf(v, blo(u.x), a0);
        a1 = fmaf(v, bhi(u.x), a1);
        a2 = fmaf(v, blo(u.y), a2);
        a3 = fmaf(v, bhi(u.y), a3);
    }
    float ss = wave_sum(a0 * a0 + a1 * a1 + a2 * a2 + a3 * a3);
    float nraw = sqrtf(ss);
    float n_ = fmaxf(nraw, 1e-15f);
    float c1 = tanh_fast(n_) * rcp_f(n_);
    float nh = c1 * nraw;
    float np1 = fmaxf(nh, 1e-15f);
    float s1 = (np1 > MAXN) ? MAXN * rcp_f(np1) : 1.0f;
    float n1 = fminf(np1, MAXN);
    float cu = artanh_fast(n1) * rcp_f(n1) * s1 * c1;
    float u0 = fmaxf(cu * a0, 0.f), u1 = fmaxf(cu * a1, 0.f);
    float u2 = fmaxf(cu * a2, 0.f), u3 = fmaxf(cu * a3, 0.f);
    float ss2 = wave_sum(u0 * u0 + u1 * u1 + u2 * u2 + u3 * u3);
    float n2raw = sqrtf(ss2);
    float n2 = fmaxf(n2raw, 1e-15f);
    float c3 = tanh_fast(n2) * rcp_f(n2);
    float ne = c3 * n2raw;
    float np3 = fmaxf(ne, 1e-15f);
    float s3 = (np3 > MAXN) ? MAXN * rcp_f(np3) : 1.0f;
    float n3 = fminf(np3, MAXN);
    float cf = artanh_fast(n3) * rcp_f(n3) * s3 * c3;
    uint2 o; o.x = pk2(cf * u0, cf * u1); o.y = pk2(cf * u2, cf * u3);
    *(uint2*)(out + (size_t)n * DH + lane * 4) = o;
}

// wave-per-node: out[n] = d[n] + sum_in d[src]; bf16 in/out
__global__ void k_gather_add(const int* __restrict__ rowptr, const int* __restrict__ psrc,
                             const u16* __restrict__ d, u16* __restrict__ out) {
    int z = blockIdx.y;
    rowptr += (size_t)z * (N_NODES + 1);
    psrc += (size_t)z * NE;
    d += (size_t)z * N_NODES * DH;
    out += (size_t)z * N_NODES * DH;
    int n = blockIdx.x * 4 + (threadIdx.x >> 6);
    int lane = threadIdx.x & 63;
    int beg = rowptr[n], end = rowptr[n + 1];
    uint2 u0v = *(const uint2*)(d + (size_t)n * DH + lane * 4);
    float a0 = blo(u0v.x), a1 = bhi(u0v.x), a2 = blo(u0v.y), a3 = bhi(u0v.y);
    for (int i = beg; i < end; ++i) {
        int s = psrc[i];
        uint2 u = *(const uint2*)(d + (size_t)s * DH + lane * 4);
        a0 += blo(u.x); a1 += bhi(u.x); a2 += blo(u.y); a3 += bhi(u.y);
    }
    uint2 o; o.x = pk2(a0, a1); o.y = pk2(a2, a3);
    *(uint2*)(out + (size_t)n * DH + lane * 4) = o;
}

// batched column stats from bf16
__global__ void k_colstats(const u16* __restrict__ zp,
                           float* __restrict__ csum, float* __restrict__ csq) {
    int z = blockIdx.y;
    zp += (size_t)z * N_NODES * DH;
    csum += (size_t)z * DH;
    csq += (size_t)z * DH;
    int t = threadIdx.x;
    int r0 = blockIdx.x * 100;
    float s = 0.0f, q = 0.0f;
    for (int r = r0; r < r0 + 100; ++r) {
        float v = b2f(zp[(size_t)r * DH + t]);
        s += v;
        q += v * v;
    }
    atomicAdd(&csum[t], s);
    atomicAdd(&csq[t], q);
}

// grid-stride uint2 batchnorm + tanh, in-place bf16 (total4 = G*N*DH/4)
__global__ void k_normtanh_v(u16* __restrict__ zp, const float* __restrict__ csum,
                             const float* __restrict__ csq, const float* __restrict__ gamma,
                             const float* __restrict__ beta, int total4) {
    const float inv_n = 1.0f / N_NODES;
    int i = blockIdx.x * 256 + threadIdx.x;
    int stride = gridDim.x * 256;
    for (; i < total4; i += stride) {
        int e0 = i * 4;
        int z = e0 / (N_NODES * DH);
        int j0 = e0 & (DH - 1);
        int zb = z * DH + j0;
        uint2 u = ((uint2*)zp)[i];
        float v[4] = {blo(u.x), bhi(u.x), blo(u.y), bhi(u.y)};
        #pragma unroll
        for (int k = 0; k < 4; ++k) {
            float mu = csum[zb + k] * inv_n;
            float var = csq[zb + k] * inv_n - mu * mu;
            float inv = __builtin_amdgcn_rsqf(var + 1e-5f);
            v[k] = tanh_fast((v[k] - mu) * inv * gamma[zb + k] + beta[zb + k]);
        }
        uint2 o; o.x = pk2(v[0], v[1]); o.y = pk2(v[2], v[3]);
        ((uint2*)zp)[i] = o;
    }
}

// f1 slice of S,P (cols 0..511): thread t -> 2 cols via float2, packed u32 store
__global__ void k_pair0(const int* __restrict__ ei, const int* __restrict__ eid,
                        const float* __restrict__ f1, u16* __restrict__ S,
                        u16* __restrict__ P) {
    int b = blockIdx.x, t = threadIdx.x;
    int e = eid[b];
    int n0 = ei[e], n1 = ei[NE2 + e];
    float2 a = *(const float2*)(f1 + (size_t)n0 * D_INN + t * 2);
    float2 c = *(const float2*)(f1 + (size_t)n1 * D_INN + t * 2);
    ((unsigned int*)(S + (size_t)b * H3))[t] = pk2(a.x + c.x, a.y + c.y);
    ((unsigned int*)(P + (size_t)b * H3))[t] = pk2(a.x * c.x, a.y * c.y);
}

// batched channel slice of S,P from z_ch; 4 edges/block, uint2 lanes
__global__ void k_gather_ch(const int* __restrict__ ei, const int* __restrict__ eid,
                            const u16* __restrict__ zch, u16* __restrict__ S,
                            u16* __restrict__ P, int col0base) {
    int z = blockIdx.y;
    const u16* zp = zch + (size_t)z * N_NODES * DH;
    int col0 = col0base + z * DH;
    int b = blockIdx.x * 4 + (threadIdx.x >> 6);
    int lane = threadIdx.x & 63;
    int e = eid[b];
    int n0 = ei[e], n1 = ei[NE2 + e];
    uint2 ua = *(const uint2*)(zp + (size_t)n0 * DH + lane * 4);
    uint2 ub = *(const uint2*)(zp + (size_t)n1 * DH + lane * 4);
    float a0 = blo(ua.x), a1 = bhi(ua.x), a2 = blo(ua.y), a3 = bhi(ua.y);
    float c0 = blo(ub.x), c1 = bhi(ub.x), c2 = blo(ub.y), c3 = bhi(ub.y);
    uint2 so; so.x = pk2(a0 + c0, a1 + c1); so.y = pk2(a2 + c2, a3 + c3);
    uint2 po; po.x = pk2(a0 * c0, a1 * c1); po.y = pk2(a2 * c2, a3 * c3);
    *(uint2*)(S + (size_t)b * H3 + col0 + lane * 4) = so;
    *(uint2*)(P + (size_t)b * H3 + col0 + lane * 4) = po;
}

__global__ void k_final(const u16* __restrict__ h2, const float* __restrict__ Wf3,
                        const float* __restrict__ bf3, float* __restrict__ out) {
    int r = blockIdx.x, t = threadIdx.x;
    const u16* hr = h2 + (size_t)r * 576;
    float acc[7] = {0, 0, 0, 0, 0, 0, 0};
    for (int cb = t; cb < 576; cb += 64) {
        float h = b2f(hr[cb]);
        #pragma unroll
        for (int o = 0; o < 7; ++o) acc[o] = fmaf(h, Wf3[o * 576 + cb], acc[o]);
    }
    #pragma unroll
    for (int o = 0; o < 7; ++o) {
        #pragma unroll
        for (int off = 32; off > 0; off >>= 1) acc[o] += __shfl_down(acc[o], off, 64);
    }
    if (t == 0) {
        #pragma unroll
        for (int o = 0; o < 7; ++o) out[(size_t)r * 7 + o] = acc[o] + bf3[o];
    }
}

// ===== bf16 MFMA GEMM (batched over blockIdx.z with strides). R10 structure:
// global_load_lds width-16 coalesced staging (chunk^row involution swizzle,
// 0 bank conflicts), XCD-aware bijective block swizzle per z.
// EP: 2=sigmoid->bf16, 3=relu->bf16, 5=bf16, 6=relu->f32,
//     7=bf16 + bias + (1+indeg[row])*cvec[col],
//     8=z==0? sigmoid->bf16 : bf16 (for batched gate/int)
template <int EP>
__global__ __launch_bounds__(256, 2) void k_gemm_mfma(
    const u16* __restrict__ A, const u16* __restrict__ W,
    const float* __restrict__ bias, void* __restrict__ outv,
    const int* __restrict__ rpe, const float* __restrict__ cvec,
    int M, int N, int K, size_t sA, size_t sW, size_t sC, int sBias) {
    __shared__ short As[4096];   // 8 groups x 1KB
    __shared__ short Ws[4096];
    const int z = blockIdx.z;
    A += (size_t)z * sA;
    W += (size_t)z * sW;
    const size_t zC = (size_t)z * sC;
    const int* rp = (EP == 7) ? rpe + (size_t)z * (N_NODES + 1) : nullptr;
    const float* cv = (EP == 7) ? cvec + (size_t)z * DH : nullptr;
    // XCD bijective swizzle within this z-slice
    const int gx = gridDim.x;
    const int nwg = gx * gridDim.y;
    const int orig = blockIdx.y * gx + blockIdx.x;
    const int q8 = nwg >> 3, r8 = nwg & 7, xcd = orig & 7;
    const int wg = (xcd < r8 ? xcd * (q8 + 1) : r8 * (q8 + 1) + (xcd - r8) * q8) + (orig >> 3);
    const int row0 = (wg / gx) * 128, col0 = (wg % gx) * 128;
    const int t = threadIdx.x;
    const int lane = t & 63;
    const int w = t >> 6;
    const int wr = w >> 1, wc = w & 1;
    // staging: lane l -> row-in-group l>>2, global chunk (l&3)^((l>>3)&3)
    const int sr = lane >> 2;
    const int csrc = (lane & 3) ^ ((lane >> 3) & 3);
    int gr[2], gc[2];
    #pragma unroll
    for (int p = 0; p < 2; ++p) {
        int g = w + p * 4;
        gr[p] = row0 + g * 16 + sr; if (gr[p] >= M) gr[p] = M - 1;
        gc[p] = col0 + g * 16 + sr; if (gc[p] >= N) gc[p] = N - 1;
    }
    // fragment read offset (shorts): row fr, chunk q -> fr*32 + (q^((fr>>1)&3))*8
    const int fr = lane & 15, fq = lane >> 4;
    const int rdoff = fr * 32 + ((fq ^ ((fr >> 1) & 3)) * 8);
    f32x4 acc[4][4] = {};
    for (int k0 = 0; k0 < K; k0 += 32) {
        #pragma unroll
        for (int p = 0; p < 2; ++p) {
            int g = w + p * 4;
            __builtin_amdgcn_global_load_lds(
                (const __attribute__((address_space(1))) unsigned int*)(A + (size_t)gr[p] * K + k0 + csrc * 8),
                (__attribute__((address_space(3))) unsigned int*)(As + g * 512), 16, 0, 0);
            __builtin_amdgcn_global_load_lds(
                (const __attribute__((address_space(1))) unsigned int*)(W + (size_t)gc[p] * K + k0 + csrc * 8),
                (__attribute__((address_space(3))) unsigned int*)(Ws + g * 512), 16, 0, 0);
        }
        __syncthreads();
        bf16x8 af[4], bfr[4];
        #pragma unroll
        for (int m = 0; m < 4; ++m)
            af[m] = *(const bf16x8*)(As + (wr * 4 + m) * 512 + rdoff);
        #pragma unroll
        for (int n = 0; n < 4; ++n)
            bfr[n] = *(const bf16x8*)(Ws + (wc * 4 + n) * 512 + rdoff);
        #pragma unroll
        for (int m = 0; m < 4; ++m)
            #pragma unroll
            for (int n = 0; n < 4; ++n)
                acc[m][n] = __builtin_amdgcn_mfma_f32_16x16x32_bf16(af[m], bfr[n], acc[m][n], 0, 0, 0);
        __syncthreads();
    }
    const int cl = lane & 15, rh = (lane >> 4) * 4;
    #pragma unroll
    for (int m = 0; m < 4; ++m) {
        float indf[4];
        if (EP == 7) {
            #pragma unroll
            for (int r = 0; r < 4; ++r) {
                int row = row0 + wr * 64 + m * 16 + rh + r;
                if (row >= M) row = M - 1;
                indf[r] = 1.0f + (float)(rp[row + 1] - rp[row]);
            }
        }
        #pragma unroll
        for (int n = 0; n < 4; ++n) {
            int col = col0 + wc * 64 + n * 16 + cl;
            if (col >= N) continue;
            float bv = bias ? bias[z * sBias + col] : 0.0f;
            float cvc = (EP == 7) ? cv[col] : 0.0f;
            #pragma unroll
            for (int r = 0; r < 4; ++r) {
                int row = row0 + wr * 64 + m * 16 + rh + r;
                if (row >= M) continue;
                float v = acc[m][n][r] + bv;
                size_t idx = zC + (size_t)row * N + col;
                if (EP == 2) ((u16*)outv)[idx] = f2b(sigmoid_fast(v));
                if (EP == 3) ((u16*)outv)[idx] = f2b(fmaxf(v, 0.0f));
                if (EP == 5) ((u16*)outv)[idx] = f2b(v);
                if (EP == 6) ((float*)outv)[idx] = fmaxf(v, 0.0f);
                if (EP == 7) ((u16*)outv)[idx] = f2b(v + indf[r] * cvc);
                if (EP == 8) ((u16*)outv)[idx] = (z == 0) ? f2b(sigmoid_fast(v)) : f2b(v);
            }
        }
    }
}

static inline void gemm_b(int ep, const u16* A, const u16* W, const float* bias, void* out,
                          const int* rpe, const float* cvec,
                          int M, int N, int K, int Z,
                          size_t sA, size_t sW, size_t sC, int sBias, hipStream_t st) {
    dim3 g((N + 127) / 128, (M + 127) / 128, Z);
    switch (ep) {
        case 2: k_gemm_mfma<2><<<g, 256, 0, st>>>(A, W, bias, out, rpe, cvec, M, N, K, sA, sW, sC, sBias); break;
        case 3: k_gemm_mfma<3><<<g, 256, 0, st>>>(A, W, bias, out, rpe, cvec, M, N, K, sA, sW, sC, sBias); break;
        case 5: k_gemm_mfma<5><<<g, 256, 0, st>>>(A, W, bias, out, rpe, cvec, M, N, K, sA, sW, sC, sBias); break;
        case 6: k_gemm_mfma<6><<<g, 256, 0, st>>>(A, W, bias, out, rpe, cvec, M, N, K, sA, sW, sC, sBias); break;
        case 7: k_gemm_mfma<7><<<g, 256, 0, st>>>(A, W, bias, out, rpe, cvec, M, N, K, sA, sW, sC, sBias); break;
        case 8: k_gemm_mfma<8><<<g, 256, 0, st>>>(A, W, bias, out, rpe, cvec, M, N, K, sA, sW, sC, sBias); break;
    }
}

static inline void conv_w(const float* s, u16* d, size_t n, hipStream_t st) {
    int n4 = (int)(n / 4);
    int grid = (n4 + 255) / 256;
    if (grid > 2048) grid = 2048;
    k_f2b<<<grid, 256, 0, st>>>(s, d, n4);
}

extern "C" void kernel_launch(void* const* d_in, const int* in_sizes, int n_in, void* d_out,
                              int out_size, void* d_ws, size_t ws_size, hipStream_t stream) {
    const float* f1 = (const float*)d_in[0];
    const int* adj_src = (const int*)d_in[1];
    const int* adj_dst = (const int*)d_in[2];
    const float* adj_val = (const float*)d_in[3];
    const int* edge_src = (const int*)d_in[4];
    const int* edge_dst = (const int*)d_in[5];
    const int* edge_index = (const int*)d_in[6];
    const int* edge_id = (const int*)d_in[7];
    const float* W_hyp = (const float*)d_in[8];
    const float* b_hyp = (const float*)d_in[9];
    const float* Wd = (const float*)d_in[10];
    const float* bd = (const float*)d_in[11];
    const float* Wg1 = (const float*)d_in[12];
    const float* bg1 = (const float*)d_in[13];
    const float* gamma = (const float*)d_in[14];
    const float* beta = (const float*)d_in[15];
    const float* Wg2 = (const float*)d_in[16];
    const float* bg2 = (const float*)d_in[17];
    const float* Wgate = (const float*)d_in[18];
    const float* bgate = (const float*)d_in[19];
    const float* Wint = (const float*)d_in[20];
    const float* bint = (const float*)d_in[21];
    const float* Wout = (const float*)d_in[22];
    const float* bout = (const float*)d_in[23];
    const float* Wf1 = (const float*)d_in[24];
    const float* bf1 = (const float*)d_in[25];
    const float* Wf2 = (const float*)d_in[26];
    const float* bf2 = (const float*)d_in[27];
    const float* Wf3 = (const float*)d_in[28];
    const float* bf3 = (const float*)d_in[29];
    float* outp = (float*)d_out;

    // ---- workspace bump allocator (~244 MB) ----
    char* base = (char*)d_ws;
    size_t off = 0;
    auto alloc = [&](size_t bytes) -> char* {
        char* p = base + off;
        off += (bytes + 255) & ~(size_t)255;
        return p;
    };
    u16* Whyp_b = (u16*)alloc((size_t)NCH * DH * D_INN * 2);
    u16* Wdt_b  = (u16*)alloc((size_t)NCH * DH * DH * 2);   // Wd^T bf16
    u16* Wc_b   = (u16*)alloc((size_t)NCH * DH * DH * 2);   // Wg1 @ Wd
    u16* Wg1_b  = (u16*)alloc((size_t)NCH * DH * DH * 2);
    u16* Wg2_b  = (u16*)alloc((size_t)NCH * DH * DH * 2);
    u16* Wgate_b = (u16*)alloc((size_t)H3 * H3 * 2);        // Wint_b must follow!
    u16* Wint_b  = (u16*)alloc((size_t)H3 * H3 * 2);
    u16* WoutT_b = (u16*)alloc((size_t)H3 * H3 * 2);        // Wout^T bf16
    u16* Wf1_b   = (u16*)alloc((size_t)1152 * H3 * 2);
    u16* Wcomb_b = (u16*)alloc((size_t)1152 * H3 * 2);      // Wf1 @ Wout
    u16* Wf2_b   = (u16*)alloc((size_t)576 * 1152 * 2);
    u16* S_b = (u16*)alloc((size_t)NB * H3 * 2);            // P_b must follow!
    u16* P_b = (u16*)alloc((size_t)NB * H3 * 2);
    const size_t NDB = (size_t)N_NODES * DH;       // per-channel elems
    u16* buf1 = (u16*)alloc(4 * NDB * 2);          // group ping (buf2 follows)
    u16* buf2 = (u16*)alloc(4 * NDB * 2);          // group pong
    u16* xhyp_b = (u16*)alloc((size_t)N_NODES * D_INN * 2);
    // merged CSR scratch (2G slices; G<=4): adj slices [0,G), edge slices [G,2G)
    int* cntC = (int*)alloc(8 * (size_t)N_NODES * 4);        // doubles as cursor
    int* rowptrC = (int*)alloc(8 * (size_t)(N_NODES + 1) * 4);
    uint2* padjC = (uint2*)alloc(4 * (size_t)NE * 8);        // packed (src,val)
    int* psrcE = (int*)alloc(4 * (size_t)NE * 4);
    float* xhn = (float*)alloc((size_t)N_NODES * 4);
    float* hb = (float*)alloc((size_t)NCH * DH * 4);
    float* hb2 = (float*)alloc(NCH * 4);
    float* csum = (float*)alloc((size_t)4 * DH * 4);
    float* csq = (float*)alloc((size_t)4 * DH * 4);
    float* cvec_d = (float*)alloc((size_t)NCH * DH * 4);
    float* bias2 = (float*)alloc((size_t)2 * H3 * 4);
    float* bcomb = (float*)alloc((size_t)1152 * 4);
    // stage-C overlays (GNN buffers dead by then):
    // batched gate/int writes 2 slices of NB*H3 bf16 starting at buf1
    // (75.5MB across buf1+buf2=81.9MB). h1 -> buf1 head; h2 (bf16) -> buf2 head.
    u16* GT = buf1;                  // gate slice 0, int-pre slice 1
    u16* h2b = buf2;

    const int EG = (NE + 255) / 256;

    conv_w(W_hyp, Whyp_b, (size_t)NCH * DH * D_INN, stream);
    conv_w(Wg1, Wg1_b, (size_t)NCH * DH * DH, stream);
    conv_w(Wg2, Wg2_b, (size_t)NCH * DH * DH, stream);
    conv_w(Wgate, Wgate_b, (size_t)H3 * H3, stream);
    conv_w(Wint, Wint_b, (size_t)H3 * H3, stream);
    conv_w(Wf1, Wf1_b, (size_t)1152 * H3, stream);
    conv_w(Wf2, Wf2_b, (size_t)576 * 1152, stream);
    k_bias2<<<(2 * H3 + 255) / 256, 256, 0, stream>>>(bgate, bint, bias2);
    // Wc = Wg1 @ Wd (via Wd^T), cvec = Wg1 @ bd
    k_twd<<<dim3(16, 16, NCH), 256, 0, stream>>>(Wd, Wdt_b);
    gemm_b(5, Wg1_b, Wdt_b, nullptr, Wc_b, nullptr, nullptr,
           DH, DH, DH, NCH, (size_t)DH * DH, (size_t)DH * DH, (size_t)DH * DH, 0, stream);
    k_cvec<<<NCH, 256, 0, stream>>>(Wg1, bd, cvec_d);
    // Wcomb = Wf1 @ Wout (Wout GEMM fused into Wf1), bcomb = Wf1@bout + bf1
    k_tr<<<dim3(144, 144), 256, 0, stream>>>(Wout, WoutT_b);
    gemm_b(5, Wf1_b, WoutT_b, nullptr, Wcomb_b, nullptr, nullptr,
           1152, H3, H3, 1, 0, 0, 0, 0, stream);
    k_bvec<<<1152 / 4, 256, 0, stream>>>(Wf1, bout, bf1, bcomb);

    k_expmap_proj_in<<<N_NODES, 256, 0, stream>>>(f1, xhyp_b, xhn);
    k_hb<<<NCH, 256, 0, stream>>>(b_hyp, hb, hb2);
    k_pair0<<<NB, 256, 0, stream>>>(edge_index, edge_id, f1, S_b, P_b);

    const int g0s[2] = {0, 4};
    const int gns[2] = {4, 3};
    for (int gi = 0; gi < 2; ++gi) {
        const int g0 = g0s[gi], G = gns[gi];
        const size_t eoff = (size_t)g0 * NE;
        const int G2 = 2 * G;
        const int* rpE = rowptrC + (size_t)G * (N_NODES + 1);
        // --- merged CSR build (both graphs, one launch set) ---
        k_izero<<<(G2 * N_NODES + 255) / 256, 256, 0, stream>>>(cntC, G2 * N_NODES);
        k_hist2<<<dim3(EG, G2), 256, 0, stream>>>(adj_dst + eoff, edge_dst + eoff, cntC, G);
        k_scan<<<G2, 256, 0, stream>>>(cntC, rowptrC);
        k_place2<<<dim3(EG, G2), 256, 0, stream>>>(adj_src + eoff, adj_dst + eoff,
                                                   adj_val + eoff, edge_src + eoff,
                                                   edge_dst + eoff, cntC, padjC, psrcE, G);
        // --- batched pipeline ---
        gemm_b(5, xhyp_b, Whyp_b + (size_t)g0 * DH * D_INN, nullptr, buf1, nullptr,
               nullptr, N_NODES, DH, D_INN, G, 0, (size_t)DH * D_INN, NDB, 0, stream);
        k_rowfuse1<<<dim3(N_NODES / 4, G), 256, 0, stream>>>(buf1, xhn, hb + g0 * DH, hb2 + g0);
        k_gather_fuse2<<<dim3(N_NODES / 4, G), 256, 0, stream>>>(rowptrC, padjC, buf1, buf2);
        // ug = (I + S_e) u
        k_gather_add<<<dim3(N_NODES / 4, G), 256, 0, stream>>>(rpE, psrcE, buf2, buf1);
        // z = ug @ Wc^T + (1+indeg)*cvec + bg1   (Wd GEMM fused away)
        gemm_b(7, buf1, Wc_b + (size_t)g0 * DH * DH, bg1 + g0 * DH, buf2,
               rpE, cvec_d + (size_t)g0 * DH, N_NODES, DH, DH, G,
               NDB, (size_t)DH * DH, NDB, DH, stream);
        k_zero<<<(G * DH + 255) / 256, 256, 0, stream>>>(csum, G * DH);
        k_zero<<<(G * DH + 255) / 256, 256, 0, stream>>>(csq, G * DH);
        k_colstats<<<dim3(200, G), 256, 0, stream>>>(buf2, csum, csq);
        {
            int total4 = (int)(G * NDB / 4);
            int blocks = (total4 + 255) / 256;
            if (blocks > 2048) blocks = 2048;
            k_normtanh_v<<<blocks, 256, 0, stream>>>(buf2, csum, csq, gamma + g0 * DH,
                                                     beta + g0 * DH, total4);
        }
        gemm_b(5, buf2, Wg2_b + (size_t)g0 * DH * DH, bg2 + g0 * DH, buf1, nullptr,
               nullptr, N_NODES, DH, DH, G, NDB, (size_t)DH * DH, NDB, DH, stream);
        k_gather_ch<<<dim3(NB / 4, G), 256, 0, stream>>>(edge_index, edge_id, buf1, S_b, P_b,
                                                         D_INN + g0 * DH);
    }

    // stage C: batched gate/int (Z=2), gi elementwise, then fused h1 (Wout
    // folded into Wf1 via Wcomb), h2 (bf16), final.
    gemm_b(8, S_b, Wgate_b, bias2, GT, nullptr, nullptr, NB, H3, H3, 2,
           (size_t)NB * H3, (size_t)H3 * H3, (size_t)NB * H3, H3, stream);
    {
        int total4 = NB * H3 / 4;
        int blocks = (total4 + 255) / 256;
        if (blocks > 2048) blocks = 2048;
        k_gi<<<blocks, 256, 0, stream>>>(GT, GT + (size_t)NB * H3, S_b, total4);
    }
    // h1 = relu(gi @ Wcomb^T + bcomb)   [replaces Wout GEMM + Wf1 GEMM]
    gemm_b(3, S_b, Wcomb_b, bcomb, buf1, nullptr, nullptr, NB, 1152, H3, 1, 0, 0, 0, 0, stream);
    // h2 = relu(h1 @ Wf2^T + bf2) -> bf16
    gemm_b(3, buf1, Wf2_b, bf2, h2b, nullptr, nullptr, NB, 576, 1152, 1, 0, 0, 0, 0, stream);
    k_final<<<NB, 64, 0, stream>>>(h2b, Wf3, bf3, outp);
}

// Round 14
// 1946.590 us; speedup vs baseline: 1.2006x; 1.0000x over previous
//
#include <hip/hip_runtime.h>
#include <math.h>

#define N_NODES 20000
#define D_INN   512
#define DH      256
#define NCH     7
#define NE      320000
#define NE2     100000
#define NB      8192
#define H3      2304   // 512 + 7*256
#define MAXN    0.996f
#define LOG2E   1.44269504f

typedef unsigned short u16;
typedef __attribute__((ext_vector_type(8))) short bf16x8;
typedef __attribute__((ext_vector_type(4))) float f32x4;

__device__ __forceinline__ u16 f2b(float f) {    // RNE f32 -> bf16 bits
    unsigned int x = __float_as_uint(f);
    unsigned int r = (x + 0x7fffu + ((x >> 16) & 1u)) >> 16;
    return (u16)r;
}
__device__ __forceinline__ float b2f(u16 u) {
    return __uint_as_float(((unsigned int)u) << 16);
}
__device__ __forceinline__ float blo(unsigned int u) { return __uint_as_float(u << 16); }
__device__ __forceinline__ float bhi(unsigned int u) { return __uint_as_float(u & 0xffff0000u); }
__device__ __forceinline__ unsigned int pk2(float a, float b) {
    return (unsigned int)f2b(a) | ((unsigned int)f2b(b) << 16);
}

// ---- fast HW transcendentals (rel err ~1e-5, fine for bf16 tolerance) ----
__device__ __forceinline__ float rcp_f(float x) { return __builtin_amdgcn_rcpf(x); }
__device__ __forceinline__ float exp2_f(float x) { return __builtin_amdgcn_exp2f(x); }
__device__ __forceinline__ float log2_f(float x) { return __builtin_amdgcn_logf(x); }
__device__ __forceinline__ float tanh_fast(float x) {
    float xc = fminf(fmaxf(x, -15.f), 15.f);
    float t = exp2_f(xc * (2.f * LOG2E));
    return (t - 1.f) * rcp_f(t + 1.f);
}
__device__ __forceinline__ float artanh_fast(float x) {
    x = fminf(fmaxf(x, -1.0f + 1e-7f), 1.0f - 1e-7f);
    return 0.34657359f * log2_f((1.f + x) * rcp_f(1.f - x));
}
__device__ __forceinline__ float sigmoid_fast(float x) {
    return rcp_f(1.f + exp2_f(-x * LOG2E));
}

__device__ __forceinline__ float wave_sum(float v) {
    #pragma unroll
    for (int off = 32; off > 0; off >>= 1) v += __shfl_xor(v, off, 64);
    return v;
}

__device__ __forceinline__ float block_sum256(float v) {
    __shared__ float sred[4];
    #pragma unroll
    for (int off = 32; off > 0; off >>= 1) v += __shfl_down(v, off, 64);
    int lane = threadIdx.x & 63;
    int w = threadIdx.x >> 6;
    if (lane == 0) sred[w] = v;
    __syncthreads();
    float tot = sred[0] + sred[1] + sred[2] + sred[3];
    __syncthreads();
    return tot;
}

__global__ void k_zero(float* __restrict__ p, int n) {
    int i = blockIdx.x * 256 + threadIdx.x;
    if (i < n) p[i] = 0.0f;
}
__global__ void k_izero(int* __restrict__ p, int n) {
    int i = blockIdx.x * 256 + threadIdx.x;
    if (i < n) p[i] = 0;
}

__global__ void k_f2b(const float* __restrict__ s, u16* __restrict__ d, int n4) {
    int i = blockIdx.x * 256 + threadIdx.x;
    int stride = gridDim.x * 256;
    for (; i < n4; i += stride) {
        float4 v = ((const float4*)s)[i];
        uint2 o; o.x = pk2(v.x, v.y); o.y = pk2(v.z, v.w);
        ((uint2*)d)[i] = o;
    }
}

// pack two bias vectors contiguously (for batched gate/int GEMM)
__global__ void k_bias2(const float* __restrict__ a, const float* __restrict__ b,
                        float* __restrict__ o) {
    int i = blockIdx.x * 256 + threadIdx.x;
    if (i < H3) o[i] = a[i];
    else if (i < 2 * H3) o[i] = b[i - H3];
}

// gi = gate * relu(tmp), all bf16, vectorized
__global__ void k_gi(const u16* __restrict__ gate, const u16* __restrict__ tmp,
                     u16* __restrict__ out, int total4) {
    int i = blockIdx.x * 256 + threadIdx.x;
    int stride = gridDim.x * 256;
    for (; i < total4; i += stride) {
        uint2 g = ((const uint2*)gate)[i];
        uint2 t = ((const uint2*)tmp)[i];
        uint2 o;
        o.x = pk2(blo(g.x) * fmaxf(blo(t.x), 0.f), bhi(g.x) * fmaxf(bhi(t.x), 0.f));
        o.y = pk2(blo(g.y) * fmaxf(blo(t.y), 0.f), bhi(g.y) * fmaxf(bhi(t.y), 0.f));
        ((uint2*)out)[i] = o;
    }
}

// Wd transpose -> bf16 (for Wc = Wg1 @ Wd via A@W^T kernel)
__global__ void k_twd(const float* __restrict__ Wd, u16* __restrict__ Wdt) {
    __shared__ float tile[16][17];
    int z = blockIdx.z;
    int bx = blockIdx.x * 16, by = blockIdx.y * 16;
    int tx = threadIdx.x & 15, ty = threadIdx.x >> 4;
    tile[ty][tx] = Wd[(size_t)z * DH * DH + (size_t)(by + ty) * DH + bx + tx];
    __syncthreads();
    Wdt[(size_t)z * DH * DH + (size_t)(bx + ty) * DH + by + tx] = f2b(tile[tx][ty]);
}

// 2304x2304 transpose f32 -> bf16 (WoutT[i][j] = Wout[j][i])
__global__ void k_tr(const float* __restrict__ Win, u16* __restrict__ Wt) {
    __shared__ float tile[16][17];
    int bx = blockIdx.x * 16, by = blockIdx.y * 16;
    int tx = threadIdx.x & 15, ty = threadIdx.x >> 4;
    tile[ty][tx] = Win[(size_t)(by + ty) * H3 + bx + tx];
    __syncthreads();
    Wt[(size_t)(bx + ty) * H3 + by + tx] = f2b(tile[tx][ty]);
}

// bcomb[r] = sum_j Wf1[r][j]*bout[j] + bf1[r]  (wave per row, 4 rows/block)
__global__ void k_bvec(const float* __restrict__ Wf1, const float* __restrict__ bout,
                       const float* __restrict__ bf1, float* __restrict__ bcomb) {
    int r = blockIdx.x * 4 + (threadIdx.x >> 6);
    int lane = threadIdx.x & 63;
    const float* row = Wf1 + (size_t)r * H3;
    float s = 0.f;
    for (int j = lane; j < H3; j += 64) s = fmaf(row[j], bout[j], s);
    s = wave_sum(s);
    if (lane == 0) bcomb[r] = s + bf1[r];
}

// cvec[z][j] = sum_k Wg1[z][j][k] * bd[z][k]   (f32)
__global__ void k_cvec(const float* __restrict__ Wg1, const float* __restrict__ bd,
                       float* __restrict__ cvec) {
    int z = blockIdx.x, j = threadIdx.x;
    const float* row = Wg1 + (size_t)z * DH * DH + (size_t)j * DH;
    const float* b = bd + (size_t)z * DH;
    float s = 0.f;
    for (int k = 0; k < DH; ++k) s = fmaf(row[k], b[k], s);
    cvec[(size_t)z * DH + j] = s;
}

// ===== merged CSR build: 2G z-slices (z<G: adj graph, z>=G: edge graph) =====
__global__ void k_hist2(const int* __restrict__ adjd, const int* __restrict__ edged,
                        int* __restrict__ cnt, int G) {
    int z = blockIdx.y;
    const int* dst = (z < G) ? adjd + (size_t)z * NE : edged + (size_t)(z - G) * NE;
    cnt += (size_t)z * N_NODES;
    int i = blockIdx.x * 256 + threadIdx.x;
    if (i < NE) atomicAdd(&cnt[dst[i]], 1);
}

// one block per slice; cnt becomes the cursor array in-place
__global__ void k_scan(int* __restrict__ cnt, int* __restrict__ rowptr) {
    int z = blockIdx.x;
    cnt += (size_t)z * N_NODES;
    rowptr += (size_t)z * (N_NODES + 1);
    __shared__ int part[256];
    int t = threadIdx.x;
    const int CH = (N_NODES + 255) / 256;
    int beg = t * CH;
    int end = beg + CH; if (end > N_NODES) end = N_NODES;
    int s = 0;
    for (int i = beg; i < end; ++i) s += cnt[i];
    part[t] = s;
    __syncthreads();
    for (int off = 1; off < 256; off <<= 1) {
        int v = (t >= off) ? part[t - off] : 0;
        __syncthreads();
        part[t] += v;
        __syncthreads();
    }
    int run = (t == 0) ? 0 : part[t - 1];
    for (int i = beg; i < end; ++i) {
        int c = cnt[i];
        rowptr[i] = run;
        cnt[i] = run;      // cursor init (in-place)
        run += c;
    }
    if (t == 255) rowptr[N_NODES] = part[255];
}

// place: adj slices write packed (src, val) uint2 (1 scatter store/edge);
// edge slices write int src.
__global__ void k_place2(const int* __restrict__ adjs, const int* __restrict__ adjd,
                         const float* __restrict__ adjv, const int* __restrict__ edges,
                         const int* __restrict__ edged, int* __restrict__ cursor,
                         uint2* __restrict__ padj, int* __restrict__ psrcE, int G) {
    int z = blockIdx.y;
    bool isadj = z < G;
    const int* src = isadj ? adjs + (size_t)z * NE : edges + (size_t)(z - G) * NE;
    const int* dst = isadj ? adjd + (size_t)z * NE : edged + (size_t)(z - G) * NE;
    cursor += (size_t)z * N_NODES;
    int i = blockIdx.x * 256 + threadIdx.x;
    if (i < NE) {
        int d = dst[i];
        int pos = atomicAdd(&cursor[d], 1);
        if (isadj) {
            uint2 p;
            p.x = (unsigned int)src[i];
            p.y = __float_as_uint(adjv[(size_t)z * NE + i]);
            padj[(size_t)z * NE + pos] = p;
        } else {
            psrcE[(size_t)(z - G) * NE + pos] = src[i];
        }
    }
}

// x_hyp = proj(expmap0(f1)) -> bf16; clamped row norm -> xhn (f32)
__global__ void k_expmap_proj_in(const float* __restrict__ f1,
                                 u16* __restrict__ xhyp, float* __restrict__ xhn) {
    int r = blockIdx.x, t = threadIdx.x;
    const float* u = f1 + (size_t)r * D_INN;
    float v0 = u[t], v1 = u[t + 256];
    float ss = block_sum256(v0 * v0 + v1 * v1);
    float nraw = sqrtf(ss);
    float n = fmaxf(nraw, 1e-15f);
    float c = tanh_fast(n) * rcp_f(n);
    float ny = c * nraw;
    float np = fmaxf(ny, 1e-15f);
    float s = (np > MAXN) ? MAXN * rcp_f(np) : 1.0f;
    float cs = c * s;
    u16* o = xhyp + (size_t)r * D_INN;
    o[t] = f2b(cs * v0);
    o[t + 256] = f2b(cs * v1);
    if (t == 0) xhn[r] = fminf(np, MAXN);
}

__global__ void k_hb(const float* __restrict__ b_hyp,
                     float* __restrict__ hb, float* __restrict__ hb2) {
    int i = blockIdx.x, t = threadIdx.x;
    float v = b_hyp[i * DH + t];
    float ss = block_sum256(v * v);
    float nraw = sqrtf(ss);
    float n = fmaxf(nraw, 1e-15f);
    float c = tanh_fast(n) * rcp_f(n);
    float ny = c * nraw;
    float np = fmaxf(ny, 1e-15f);
    float s = (np > MAXN) ? MAXN * rcp_f(np) : 1.0f;
    float hv = c * s * v;
    hb[i * DH + t] = hv;
    float s2 = block_sum256(hv * hv);
    if (t == 0) hb2[i] = s2;
}

// wave-per-node (4 nodes/block), lane = 4 feats via uint2; in-place bf16.
__global__ void k_rowfuse1(u16* __restrict__ T, const float* __restrict__ xhn,
                           const float* __restrict__ hb, const float* __restrict__ hb2) {
    int z = blockIdx.y;
    int n = blockIdx.x * 4 + (threadIdx.x >> 6);
    int lane = threadIdx.x & 63;
    u16* row = T + ((size_t)z * N_NODES + n) * DH;
    const float* hbz = hb + (size_t)z * DH;
    uint2 u = *(const uint2*)(row + lane * 4);
    float m0 = blo(u.x), m1 = bhi(u.x), m2 = blo(u.y), m3 = bhi(u.y);
    float ss = wave_sum(m0 * m0 + m1 * m1 + m2 * m2 + m3 * m3);
    float mxn_raw = sqrtf(ss);
    float mxn = fmaxf(mxn_raw, 1e-15f);
    float xn = xhn[n];
    float tt = tanh_fast(mxn * rcp_f(xn) * artanh_fast(xn));
    float coef = tt * rcp_f(mxn);
    float nres = coef * mxn_raw;
    float np = fmaxf(nres, 1e-15f);
    float s1 = (np > MAXN) ? MAXN * rcp_f(np) : 1.0f;
    float cs = coef * s1;
    float r0 = cs * m0, r1 = cs * m1, r2 = cs * m2, r3 = cs * m3;
    float n1 = fminf(np, MAXN);
    float4 hv = *(const float4*)(hbz + lane * 4);
    float xy = wave_sum(r0 * hv.x + r1 * hv.y + r2 * hv.z + r3 * hv.w);
    float x2 = n1 * n1, y2 = hb2[z];
    float ca = 1.0f + 2.0f * xy + y2;
    float cb = 1.0f - x2;
    float rden = rcp_f(fmaxf(1.0f + 2.0f * xy + x2 * y2, 1e-15f));
    float o0 = (ca * r0 + cb * hv.x) * rden;
    float o1 = (ca * r1 + cb * hv.y) * rden;
    float o2 = (ca * r2 + cb * hv.z) * rden;
    float o3 = (ca * r3 + cb * hv.w) * rden;
    float no2 = wave_sum(o0 * o0 + o1 * o1 + o2 * o2 + o3 * o3);
    float nop = fmaxf(sqrtf(no2), 1e-15f);
    float s2 = (nop > MAXN) ? MAXN * rcp_f(nop) : 1.0f;
    float n2 = fminf(nop, MAXN);
    float fin = artanh_fast(n2) * rcp_f(n2) * s2;
    uint2 o; o.x = pk2(fin * o0, fin * o1); o.y = pk2(fin * o2, fin * o3);
    *(uint2*)(row + lane * 4) = o;
}

// wave-per-node CSR gather (packed (src,val)) + fused rowfuse2 chain -> bf16 out
__global__ void k_gather_fuse2(const int* __restrict__ rowptr, const uint2* __restrict__ padj,
                               const u16* __restrict__ xt, u16* __restrict__ out) {
    int z = blockIdx.y;
    rowptr += (size_t)z * (N_NODES + 1);
    padj += (size_t)z * NE;
    xt += (size_t)z * N_NODES * DH;
    out += (size_t)z * N_NODES * DH;
    int n = blockIdx.x * 4 + (threadIdx.x >> 6);
    int lane = threadIdx.x & 63;
    int beg = rowptr[n], end = rowptr[n + 1];
    float a0 = 0.f, a1 = 0.f, a2 = 0.f, a3 = 0.f;
    for (int i = beg; i < end; ++i) {
        uint2 p = padj[i];
        float v = __uint_as_float(p.y);
        uint2 u = *(const uint2*)(xt + (size_t)p.x * DH + lane * 4);
        a0 = fmaf(v, blo(u.x), a0);
        a1 = fmaf(v, bhi(u.x), a1);
        a2 = fmaf(v, blo(u.y), a2);
        a3 = fmaf(v, bhi(u.y), a3);
    }
    float ss = wave_sum(a0 * a0 + a1 * a1 + a2 * a2 + a3 * a3);
    float nraw = sqrtf(ss);
    float n_ = fmaxf(nraw, 1e-15f);
    float c1 = tanh_fast(n_) * rcp_f(n_);
    float nh = c1 * nraw;
    float np1 = fmaxf(nh, 1e-15f);
    float s1 = (np1 > MAXN) ? MAXN * rcp_f(np1) : 1.0f;
    float n1 = fminf(np1, MAXN);
    float cu = artanh_fast(n1) * rcp_f(n1) * s1 * c1;
    float u0 = fmaxf(cu * a0, 0.f), u1 = fmaxf(cu * a1, 0.f);
    float u2 = fmaxf(cu * a2, 0.f), u3 = fmaxf(cu * a3, 0.f);
    float ss2 = wave_sum(u0 * u0 + u1 * u1 + u2 * u2 + u3 * u3);
    float n2raw = sqrtf(ss2);
    float n2 = fmaxf(n2raw, 1e-15f);
    float c3 = tanh_fast(n2) * rcp_f(n2);
    float ne = c3 * n2raw;
    float np3 = fmaxf(ne, 1e-15f);
    float s3 = (np3 > MAXN) ? MAXN * rcp_f(np3) : 1.0f;
    float n3 = fminf(np3, MAXN);
    float cf = artanh_fast(n3) * rcp_f(n3) * s3 * c3;
    uint2 o; o.x = pk2(cf * u0, cf * u1); o.y = pk2(cf * u2, cf * u3);
    *(uint2*)(out + (size_t)n * DH + lane * 4) = o;
}

// wave-per-node: out[n] = d[n] + sum_in d[src]; bf16 in/out
__global__ void k_gather_add(const int* __restrict__ rowptr, const int* __restrict__ psrc,
                             const u16* __restrict__ d, u16* __restrict__ out) {
    int z = blockIdx.y;
    rowptr += (size_t)z * (N_NODES + 1);
    psrc += (size_t)z * NE;
    d += (size_t)z * N_NODES * DH;
    out += (size_t)z * N_NODES * DH;
    int n = blockIdx.x * 4 + (threadIdx.x >> 6);
    int lane = threadIdx.x & 63;
    int beg = rowptr[n], end = rowptr[n + 1];
    uint2 u0v = *(const uint2*)(d + (size_t)n * DH + lane * 4);
    float a0 = blo(u0v.x), a1 = bhi(u0v.x), a2 = blo(u0v.y), a3 = bhi(u0v.y);
    for (int i = beg; i < end; ++i) {
        int s = psrc[i];
        uint2 u = *(const uint2*)(d + (size_t)s * DH + lane * 4);
        a0 += blo(u.x); a1 += bhi(u.x); a2 += blo(u.y); a3 += bhi(u.y);
    }
    uint2 o; o.x = pk2(a0, a1); o.y = pk2(a2, a3);
    *(uint2*)(out + (size_t)n * DH + lane * 4) = o;
}

// batched column stats from bf16
__global__ void k_colstats(const u16* __restrict__ zp,
                           float* __restrict__ csum, float* __restrict__ csq) {
    int z = blockIdx.y;
    zp += (size_t)z * N_NODES * DH;
    csum += (size_t)z * DH;
    csq += (size_t)z * DH;
    int t = threadIdx.x;
    int r0 = blockIdx.x * 100;
    float s = 0.0f, q = 0.0f;
    for (int r = r0; r < r0 + 100; ++r) {
        float v = b2f(zp[(size_t)r * DH + t]);
        s += v;
        q += v * v;
    }
    atomicAdd(&csum[t], s);
    atomicAdd(&csq[t], q);
}

// grid-stride uint2 batchnorm + tanh, in-place bf16 (total4 = G*N*DH/4)
__global__ void k_normtanh_v(u16* __restrict__ zp, const float* __restrict__ csum,
                             const float* __restrict__ csq, const float* __restrict__ gamma,
                             const float* __restrict__ beta, int total4) {
    const float inv_n = 1.0f / N_NODES;
    int i = blockIdx.x * 256 + threadIdx.x;
    int stride = gridDim.x * 256;
    for (; i < total4; i += stride) {
        int e0 = i * 4;
        int z = e0 / (N_NODES * DH);
        int j0 = e0 & (DH - 1);
        int zb = z * DH + j0;
        uint2 u = ((uint2*)zp)[i];
        float v[4] = {blo(u.x), bhi(u.x), blo(u.y), bhi(u.y)};
        #pragma unroll
        for (int k = 0; k < 4; ++k) {
            float mu = csum[zb + k] * inv_n;
            float var = csq[zb + k] * inv_n - mu * mu;
            float inv = __builtin_amdgcn_rsqf(var + 1e-5f);
            v[k] = tanh_fast((v[k] - mu) * inv * gamma[zb + k] + beta[zb + k]);
        }
        uint2 o; o.x = pk2(v[0], v[1]); o.y = pk2(v[2], v[3]);
        ((uint2*)zp)[i] = o;
    }
}

// f1 slice of S,P (cols 0..511): thread t -> 2 cols via float2, packed u32 store
__global__ void k_pair0(const int* __restrict__ ei, const int* __restrict__ eid,
                        const float* __restrict__ f1, u16* __restrict__ S,
                        u16* __restrict__ P) {
    int b = blockIdx.x, t = threadIdx.x;
    int e = eid[b];
    int n0 = ei[e], n1 = ei[NE2 + e];
    float2 a = *(const float2*)(f1 + (size_t)n0 * D_INN + t * 2);
    float2 c = *(const float2*)(f1 + (size_t)n1 * D_INN + t * 2);
    ((unsigned int*)(S + (size_t)b * H3))[t] = pk2(a.x + c.x, a.y + c.y);
    ((unsigned int*)(P + (size_t)b * H3))[t] = pk2(a.x * c.x, a.y * c.y);
}

// batched channel slice of S,P from z_ch; 4 edges/block, uint2 lanes
__global__ void k_gather_ch(const int* __restrict__ ei, const int* __restrict__ eid,
                            const u16* __restrict__ zch, u16* __restrict__ S,
                            u16* __restrict__ P, int col0base) {
    int z = blockIdx.y;
    const u16* zp = zch + (size_t)z * N_NODES * DH;
    int col0 = col0base + z * DH;
    int b = blockIdx.x * 4 + (threadIdx.x >> 6);
    int lane = threadIdx.x & 63;
    int e = eid[b];
    int n0 = ei[e], n1 = ei[NE2 + e];
    uint2 ua = *(const uint2*)(zp + (size_t)n0 * DH + lane * 4);
    uint2 ub = *(const uint2*)(zp + (size_t)n1 * DH + lane * 4);
    float a0 = blo(ua.x), a1 = bhi(ua.x), a2 = blo(ua.y), a3 = bhi(ua.y);
    float c0 = blo(ub.x), c1 = bhi(ub.x), c2 = blo(ub.y), c3 = bhi(ub.y);
    uint2 so; so.x = pk2(a0 + c0, a1 + c1); so.y = pk2(a2 + c2, a3 + c3);
    uint2 po; po.x = pk2(a0 * c0, a1 * c1); po.y = pk2(a2 * c2, a3 * c3);
    *(uint2*)(S + (size_t)b * H3 + col0 + lane * 4) = so;
    *(uint2*)(P + (size_t)b * H3 + col0 + lane * 4) = po;
}

__global__ void k_final(const u16* __restrict__ h2, const float* __restrict__ Wf3,
                        const float* __restrict__ bf3, float* __restrict__ out) {
    int r = blockIdx.x, t = threadIdx.x;
    const u16* hr = h2 + (size_t)r * 576;
    float acc[7] = {0, 0, 0, 0, 0, 0, 0};
    for (int cb = t; cb < 576; cb += 64) {
        float h = b2f(hr[cb]);
        #pragma unroll
        for (int o = 0; o < 7; ++o) acc[o] = fmaf(h, Wf3[o * 576 + cb], acc[o]);
    }
    #pragma unroll
    for (int o = 0; o < 7; ++o) {
        #pragma unroll
        for (int off = 32; off > 0; off >>= 1) acc[o] += __shfl_down(acc[o], off, 64);
    }
    if (t == 0) {
        #pragma unroll
        for (int o = 0; o < 7; ++o) out[(size_t)r * 7 + o] = acc[o] + bf3[o];
    }
}

// ===== bf16 MFMA GEMM (batched over blockIdx.z with strides). R10 structure:
// global_load_lds width-16 coalesced staging (chunk^row involution swizzle,
// 0 bank conflicts). FULL-GRID (3D, z included) bijective XCD swizzle: HW
// dispatches blocks in (x,y,z)-linear round-robin across 8 XCDs, so orig must
// include z or Z-batched slices with nwg%8!=0 scramble locality.
// EP: 2=sigmoid->bf16, 3=relu->bf16, 5=bf16, 6=relu->f32,
//     7=bf16 + bias + (1+indeg[row])*cvec[col],
//     8=z==0? sigmoid->bf16 : bf16 (for batched gate/int)
template <int EP>
__global__ __launch_bounds__(256, 2) void k_gemm_mfma(
    const u16* __restrict__ A, const u16* __restrict__ W,
    const float* __restrict__ bias, void* __restrict__ outv,
    const int* __restrict__ rpe, const float* __restrict__ cvec,
    int M, int N, int K, size_t sA, size_t sW, size_t sC, int sBias) {
    __shared__ short As[4096];   // 8 groups x 1KB
    __shared__ short Ws[4096];
    // 3D bijective XCD swizzle over the whole grid
    const int gx = gridDim.x, gy = gridDim.y;
    const int plane = gx * gy;
    const int total = plane * gridDim.z;
    const int orig = (blockIdx.z * gy + blockIdx.y) * gx + blockIdx.x;
    const int q8 = total >> 3, r8 = total & 7, xcd = orig & 7;
    const int wg = (xcd < r8 ? xcd * (q8 + 1) : r8 * (q8 + 1) + (xcd - r8) * q8) + (orig >> 3);
    const int z = wg / plane;
    const int rem = wg - z * plane;
    const int row0 = (rem / gx) * 128, col0 = (rem % gx) * 128;
    A += (size_t)z * sA;
    W += (size_t)z * sW;
    const size_t zC = (size_t)z * sC;
    const int* rp = (EP == 7) ? rpe + (size_t)z * (N_NODES + 1) : nullptr;
    const float* cv = (EP == 7) ? cvec + (size_t)z * DH : nullptr;
    const int t = threadIdx.x;
    const int lane = t & 63;
    const int w = t >> 6;
    const int wr = w >> 1, wc = w & 1;
    // staging: lane l -> row-in-group l>>2, global chunk (l&3)^((l>>3)&3)
    const int sr = lane >> 2;
    const int csrc = (lane & 3) ^ ((lane >> 3) & 3);
    int gr[2], gc[2];
    #pragma unroll
    for (int p = 0; p < 2; ++p) {
        int g = w + p * 4;
        gr[p] = row0 + g * 16 + sr; if (gr[p] >= M) gr[p] = M - 1;
        gc[p] = col0 + g * 16 + sr; if (gc[p] >= N) gc[p] = N - 1;
    }
    // fragment read offset (shorts): row fr, chunk q -> fr*32 + (q^((fr>>1)&3))*8
    const int fr = lane & 15, fq = lane >> 4;
    const int rdoff = fr * 32 + ((fq ^ ((fr >> 1) & 3)) * 8);
    f32x4 acc[4][4] = {};
    for (int k0 = 0; k0 < K; k0 += 32) {
        #pragma unroll
        for (int p = 0; p < 2; ++p) {
            int g = w + p * 4;
            __builtin_amdgcn_global_load_lds(
                (const __attribute__((address_space(1))) unsigned int*)(A + (size_t)gr[p] * K + k0 + csrc * 8),
                (__attribute__((address_space(3))) unsigned int*)(As + g * 512), 16, 0, 0);
            __builtin_amdgcn_global_load_lds(
                (const __attribute__((address_space(1))) unsigned int*)(W + (size_t)gc[p] * K + k0 + csrc * 8),
                (__attribute__((address_space(3))) unsigned int*)(Ws + g * 512), 16, 0, 0);
        }
        __syncthreads();
        bf16x8 af[4], bfr[4];
        #pragma unroll
        for (int m = 0; m < 4; ++m)
            af[m] = *(const bf16x8*)(As + (wr * 4 + m) * 512 + rdoff);
        #pragma unroll
        for (int n = 0; n < 4; ++n)
            bfr[n] = *(const bf16x8*)(Ws + (wc * 4 + n) * 512 + rdoff);
        #pragma unroll
        for (int m = 0; m < 4; ++m)
            #pragma unroll
            for (int n = 0; n < 4; ++n)
                acc[m][n] = __builtin_amdgcn_mfma_f32_16x16x32_bf16(af[m], bfr[n], acc[m][n], 0, 0, 0);
        __syncthreads();
    }
    const int cl = lane & 15, rh = (lane >> 4) * 4;
    #pragma unroll
    for (int m = 0; m < 4; ++m) {
        float indf[4];
        if (EP == 7) {
            #pragma unroll
            for (int r = 0; r < 4; ++r) {
                int row = row0 + wr * 64 + m * 16 + rh + r;
                if (row >= M) row = M - 1;
                indf[r] = 1.0f + (float)(rp[row + 1] - rp[row]);
            }
        }
        #pragma unroll
        for (int n = 0; n < 4; ++n) {
            int col = col0 + wc * 64 + n * 16 + cl;
            if (col >= N) continue;
            float bv = bias ? bias[z * sBias + col] : 0.0f;
            float cvc = (EP == 7) ? cv[col] : 0.0f;
            #pragma unroll
            for (int r = 0; r < 4; ++r) {
                int row = row0 + wr * 64 + m * 16 + rh + r;
                if (row >= M) continue;
                float v = acc[m][n][r] + bv;
                size_t idx = zC + (size_t)row * N + col;
                if (EP == 2) ((u16*)outv)[idx] = f2b(sigmoid_fast(v));
                if (EP == 3) ((u16*)outv)[idx] = f2b(fmaxf(v, 0.0f));
                if (EP == 5) ((u16*)outv)[idx] = f2b(v);
                if (EP == 6) ((float*)outv)[idx] = fmaxf(v, 0.0f);
                if (EP == 7) ((u16*)outv)[idx] = f2b(v + indf[r] * cvc);
                if (EP == 8) ((u16*)outv)[idx] = (z == 0) ? f2b(sigmoid_fast(v)) : f2b(v);
            }
        }
    }
}

static inline void gemm_b(int ep, const u16* A, const u16* W, const float* bias, void* out,
                          const int* rpe, const float* cvec,
                          int M, int N, int K, int Z,
                          size_t sA, size_t sW, size_t sC, int sBias, hipStream_t st) {
    dim3 g((N + 127) / 128, (M + 127) / 128, Z);
    switch (ep) {
        case 2: k_gemm_mfma<2><<<g, 256, 0, st>>>(A, W, bias, out, rpe, cvec, M, N, K, sA, sW, sC, sBias); break;
        case 3: k_gemm_mfma<3><<<g, 256, 0, st>>>(A, W, bias, out, rpe, cvec, M, N, K, sA, sW, sC, sBias); break;
        case 5: k_gemm_mfma<5><<<g, 256, 0, st>>>(A, W, bias, out, rpe, cvec, M, N, K, sA, sW, sC, sBias); break;
        case 6: k_gemm_mfma<6><<<g, 256, 0, st>>>(A, W, bias, out, rpe, cvec, M, N, K, sA, sW, sC, sBias); break;
        case 7: k_gemm_mfma<7><<<g, 256, 0, st>>>(A, W, bias, out, rpe, cvec, M, N, K, sA, sW, sC, sBias); break;
        case 8: k_gemm_mfma<8><<<g, 256, 0, st>>>(A, W, bias, out, rpe, cvec, M, N, K, sA, sW, sC, sBias); break;
    }
}

static inline void conv_w(const float* s, u16* d, size_t n, hipStream_t st) {
    int n4 = (int)(n / 4);
    int grid = (n4 + 255) / 256;
    if (grid > 2048) grid = 2048;
    k_f2b<<<grid, 256, 0, st>>>(s, d, n4);
}

extern "C" void kernel_launch(void* const* d_in, const int* in_sizes, int n_in, void* d_out,
                              int out_size, void* d_ws, size_t ws_size, hipStream_t stream) {
    const float* f1 = (const float*)d_in[0];
    const int* adj_src = (const int*)d_in[1];
    const int* adj_dst = (const int*)d_in[2];
    const float* adj_val = (const float*)d_in[3];
    const int* edge_src = (const int*)d_in[4];
    const int* edge_dst = (const int*)d_in[5];
    const int* edge_index = (const int*)d_in[6];
    const int* edge_id = (const int*)d_in[7];
    const float* W_hyp = (const float*)d_in[8];
    const float* b_hyp = (const float*)d_in[9];
    const float* Wd = (const float*)d_in[10];
    const float* bd = (const float*)d_in[11];
    const float* Wg1 = (const float*)d_in[12];
    const float* bg1 = (const float*)d_in[13];
    const float* gamma = (const float*)d_in[14];
    const float* beta = (const float*)d_in[15];
    const float* Wg2 = (const float*)d_in[16];
    const float* bg2 = (const float*)d_in[17];
    const float* Wgate = (const float*)d_in[18];
    const float* bgate = (const float*)d_in[19];
    const float* Wint = (const float*)d_in[20];
    const float* bint = (const float*)d_in[21];
    const float* Wout = (const float*)d_in[22];
    const float* bout = (const float*)d_in[23];
    const float* Wf1 = (const float*)d_in[24];
    const float* bf1 = (const float*)d_in[25];
    const float* Wf2 = (const float*)d_in[26];
    const float* bf2 = (const float*)d_in[27];
    const float* Wf3 = (const float*)d_in[28];
    const float* bf3 = (const float*)d_in[29];
    float* outp = (float*)d_out;

    // Group partition: single Z=7 group if workspace allows (~281 MB needed),
    // else the proven 2-group (4+3) layout (~227 MB).
    const bool single = ws_size >= 283000000ull;
    const int ngroups = single ? 1 : 2;
    const int GM = single ? 7 : 4;
    int g0s[2] = {0, 4};
    int gns[2] = {GM, 3};

    // ---- workspace bump allocator ----
    char* base = (char*)d_ws;
    size_t off = 0;
    auto alloc = [&](size_t bytes) -> char* {
        char* p = base + off;
        off += (bytes + 255) & ~(size_t)255;
        return p;
    };
    u16* Whyp_b = (u16*)alloc((size_t)NCH * DH * D_INN * 2);
    u16* Wc_b   = (u16*)alloc((size_t)NCH * DH * DH * 2);   // Wg1 @ Wd
    u16* Wg1_b  = (u16*)alloc((size_t)NCH * DH * DH * 2);
    u16* Wg2_b  = (u16*)alloc((size_t)NCH * DH * DH * 2);
    u16* Wgate_b = (u16*)alloc((size_t)H3 * H3 * 2);        // Wint_b must follow!
    u16* Wint_b  = (u16*)alloc((size_t)H3 * H3 * 2);
    u16* Wcomb_b = (u16*)alloc((size_t)1152 * H3 * 2);      // Wf1 @ Wout
    u16* Wf2_b   = (u16*)alloc((size_t)576 * 1152 * 2);
    u16* S_b = (u16*)alloc((size_t)NB * H3 * 2);            // P_b must follow!
    u16* P_b = (u16*)alloc((size_t)NB * H3 * 2);
    const size_t NDB = (size_t)N_NODES * DH;       // per-channel elems
    u16* buf1 = (u16*)alloc((size_t)GM * NDB * 2); // group ping (buf2 follows)
    u16* buf2 = (u16*)alloc((size_t)GM * NDB * 2); // group pong
    // xhyp: in single mode alias buf2 head (dead before buf2 first written);
    // in 2-group mode it must persist across groups -> separate.
    u16* xhyp_b = single ? buf2 : (u16*)alloc((size_t)N_NODES * D_INN * 2);
    // CSR scratch (2*GM slices): adj slices [0,G), edge slices [G,2G)
    int* cntC = (int*)alloc((size_t)2 * GM * N_NODES * 4);   // doubles as cursor
    int* rowptrC = (int*)alloc((size_t)2 * GM * (N_NODES + 1) * 4);
    uint2* padjC = (uint2*)alloc((size_t)GM * NE * 8);       // packed (src,val)
    int* psrcE = (int*)alloc((size_t)GM * NE * 4);
    float* xhn = (float*)alloc((size_t)N_NODES * 4);
    float* hb = (float*)alloc((size_t)NCH * DH * 4);
    float* hb2 = (float*)alloc(NCH * 4);
    float* csum = (float*)alloc((size_t)GM * DH * 4);        // csq follows
    float* csq = (float*)alloc((size_t)GM * DH * 4);
    float* cvec_d = (float*)alloc((size_t)NCH * DH * 4);
    float* bias2 = (float*)alloc((size_t)2 * H3 * 4);
    float* bcomb = (float*)alloc((size_t)1152 * 4);
    // precompute-only temp weights alias into buf1 (idle until GNN phase):
    u16* WoutT_b = buf1;                          // 10.62 MB
    u16* Wf1_b = buf1 + (size_t)H3 * H3;          // +5.31 MB
    u16* Wdt_b = Wf1_b + (size_t)1152 * H3;       // +0.92 MB (total 16.8 <= buf1)
    // stage-C overlays (GNN buffers dead by then): GT spans buf1(+buf2 tail);
    // h1 -> buf1 head after k_gi; h2 (bf16) -> buf2 head.
    u16* GT = buf1;
    u16* h2b = buf2;

    const int EG = (NE + 255) / 256;

    conv_w(W_hyp, Whyp_b, (size_t)NCH * DH * D_INN, stream);
    conv_w(Wg1, Wg1_b, (size_t)NCH * DH * DH, stream);
    conv_w(Wg2, Wg2_b, (size_t)NCH * DH * DH, stream);
    conv_w(Wgate, Wgate_b, (size_t)H3 * H3, stream);
    conv_w(Wint, Wint_b, (size_t)H3 * H3, stream);
    conv_w(Wf1, Wf1_b, (size_t)1152 * H3, stream);
    conv_w(Wf2, Wf2_b, (size_t)576 * 1152, stream);
    k_bias2<<<(2 * H3 + 255) / 256, 256, 0, stream>>>(bgate, bint, bias2);
    // Wc = Wg1 @ Wd (via Wd^T), cvec = Wg1 @ bd
    k_twd<<<dim3(16, 16, NCH), 256, 0, stream>>>(Wd, Wdt_b);
    gemm_b(5, Wg1_b, Wdt_b, nullptr, Wc_b, nullptr, nullptr,
           DH, DH, DH, NCH, (size_t)DH * DH, (size_t)DH * DH, (size_t)DH * DH, 0, stream);
    k_cvec<<<NCH, 256, 0, stream>>>(Wg1, bd, cvec_d);
    // Wcomb = Wf1 @ Wout (Wout GEMM folded into Wf1), bcomb = Wf1@bout + bf1
    k_tr<<<dim3(144, 144), 256, 0, stream>>>(Wout, WoutT_b);
    gemm_b(5, Wf1_b, WoutT_b, nullptr, Wcomb_b, nullptr, nullptr,
           1152, H3, H3, 1, 0, 0, 0, 0, stream);
    k_bvec<<<1152 / 4, 256, 0, stream>>>(Wf1, bout, bf1, bcomb);

    k_expmap_proj_in<<<N_NODES, 256, 0, stream>>>(f1, xhyp_b, xhn);
    k_hb<<<NCH, 256, 0, stream>>>(b_hyp, hb, hb2);
    k_pair0<<<NB, 256, 0, stream>>>(edge_index, edge_id, f1, S_b, P_b);

    for (int gi = 0; gi < ngroups; ++gi) {
        const int g0 = g0s[gi], G = gns[gi];
        const size_t eoff = (size_t)g0 * NE;
        const int G2 = 2 * G;
        const int* rpE = rowptrC + (size_t)G * (N_NODES + 1);
        // --- merged CSR build (both graphs, one launch set) ---
        k_izero<<<(G2 * N_NODES + 255) / 256, 256, 0, stream>>>(cntC, G2 * N_NODES);
        k_hist2<<<dim3(EG, G2), 256, 0, stream>>>(adj_dst + eoff, edge_dst + eoff, cntC, G);
        k_scan<<<G2, 256, 0, stream>>>(cntC, rowptrC);
        k_place2<<<dim3(EG, G2), 256, 0, stream>>>(adj_src + eoff, adj_dst + eoff,
                                                   adj_val + eoff, edge_src + eoff,
                                                   edge_dst + eoff, cntC, padjC, psrcE, G);
        // --- batched pipeline ---
        gemm_b(5, xhyp_b, Whyp_b + (size_t)g0 * DH * D_INN, nullptr, buf1, nullptr,
               nullptr, N_NODES, DH, D_INN, G, 0, (size_t)DH * D_INN, NDB, 0, stream);
        k_rowfuse1<<<dim3(N_NODES / 4, G), 256, 0, stream>>>(buf1, xhn, hb + g0 * DH, hb2 + g0);
        k_gather_fuse2<<<dim3(N_NODES / 4, G), 256, 0, stream>>>(rowptrC, padjC, buf1, buf2);
        // ug = (I + S_e) u
        k_gather_add<<<dim3(N_NODES / 4, G), 256, 0, stream>>>(rpE, psrcE, buf2, buf1);
        // z = ug @ Wc^T + (1+indeg)*cvec + bg1   (Wd GEMM fused away)
        gemm_b(7, buf1, Wc_b + (size_t)g0 * DH * DH, bg1 + g0 * DH, buf2,
               rpE, cvec_d + (size_t)g0 * DH, N_NODES, DH, DH, G,
               NDB, (size_t)DH * DH, NDB, DH, stream);
        k_zero<<<(2 * GM * DH + 255) / 256, 256, 0, stream>>>(csum, 2 * GM * DH);
        k_colstats<<<dim3(200, G), 256, 0, stream>>>(buf2, csum, csq);
        {
            int total4 = (int)(G * NDB / 4);
            int blocks = (total4 + 255) / 256;
            if (blocks > 2048) blocks = 2048;
            k_normtanh_v<<<blocks, 256, 0, stream>>>(buf2, csum, csq, gamma + g0 * DH,
                                                     beta + g0 * DH, total4);
        }
        gemm_b(5, buf2, Wg2_b + (size_t)g0 * DH * DH, bg2 + g0 * DH, buf1, nullptr,
               nullptr, N_NODES, DH, DH, G, NDB, (size_t)DH * DH, NDB, DH, stream);
        k_gather_ch<<<dim3(NB / 4, G), 256, 0, stream>>>(edge_index, edge_id, buf1, S_b, P_b,
                                                         D_INN + g0 * DH);
    }

    // stage C: batched gate/int (Z=2), gi elementwise, fused h1 (Wout folded
    // into Wf1 via Wcomb), h2 (bf16), final.
    gemm_b(8, S_b, Wgate_b, bias2, GT, nullptr, nullptr, NB, H3, H3, 2,
           (size_t)NB * H3, (size_t)H3 * H3, (size_t)NB * H3, H3, stream);
    {
        int total4 = NB * H3 / 4;
        int blocks = (total4 + 255) / 256;
        if (blocks > 2048) blocks = 2048;
        k_gi<<<blocks, 256, 0, stream>>>(GT, GT + (size_t)NB * H3, S_b, total4);
    }
    // h1 = relu(gi @ Wcomb^T + bcomb)
    gemm_b(3, S_b, Wcomb_b, bcomb, buf1, nullptr, nullptr, NB, 1152, H3, 1, 0, 0, 0, 0, stream);
    // h2 = relu(h1 @ Wf2^T + bf2) -> bf16
    gemm_b(3, buf1, Wf2_b, bf2, h2b, nullptr, nullptr, NB, 576, 1152, 1, 0, 0, 0, 0, stream);
    k_final<<<NB, 64, 0, stream>>>(h2b, Wf3, bf3, outp);
}

// Round 15
// 1884.515 us; speedup vs baseline: 1.2402x; 1.0329x over previous
//
#include <hip/hip_runtime.h>
#include <math.h>

#define N_NODES 20000
#define D_INN   512
#define DH      256
#define NCH     7
#define NE      320000
#define NE2     100000
#define NB      8192
#define H3      2304   // 512 + 7*256
#define MAXN    0.996f
#define LOG2E   1.44269504f

typedef unsigned short u16;
typedef __attribute__((ext_vector_type(8))) short bf16x8;
typedef __attribute__((ext_vector_type(4))) float f32x4;

__device__ __forceinline__ u16 f2b(float f) {    // RNE f32 -> bf16 bits
    unsigned int x = __float_as_uint(f);
    unsigned int r = (x + 0x7fffu + ((x >> 16) & 1u)) >> 16;
    return (u16)r;
}
__device__ __forceinline__ float b2f(u16 u) {
    return __uint_as_float(((unsigned int)u) << 16);
}
__device__ __forceinline__ float blo(unsigned int u) { return __uint_as_float(u << 16); }
__device__ __forceinline__ float bhi(unsigned int u) { return __uint_as_float(u & 0xffff0000u); }
__device__ __forceinline__ unsigned int pk2(float a, float b) {
    return (unsigned int)f2b(a) | ((unsigned int)f2b(b) << 16);
}

// ---- fast HW transcendentals (rel err ~1e-5, fine for bf16 tolerance) ----
__device__ __forceinline__ float rcp_f(float x) { return __builtin_amdgcn_rcpf(x); }
__device__ __forceinline__ float exp2_f(float x) { return __builtin_amdgcn_exp2f(x); }
__device__ __forceinline__ float log2_f(float x) { return __builtin_amdgcn_logf(x); }
__device__ __forceinline__ float tanh_fast(float x) {
    float xc = fminf(fmaxf(x, -15.f), 15.f);
    float t = exp2_f(xc * (2.f * LOG2E));
    return (t - 1.f) * rcp_f(t + 1.f);
}
__device__ __forceinline__ float artanh_fast(float x) {
    x = fminf(fmaxf(x, -1.0f + 1e-7f), 1.0f - 1e-7f);
    return 0.34657359f * log2_f((1.f + x) * rcp_f(1.f - x));
}
__device__ __forceinline__ float sigmoid_fast(float x) {
    return rcp_f(1.f + exp2_f(-x * LOG2E));
}

__device__ __forceinline__ float wave_sum(float v) {
    #pragma unroll
    for (int off = 32; off > 0; off >>= 1) v += __shfl_xor(v, off, 64);
    return v;
}

__device__ __forceinline__ float block_sum256(float v) {
    __shared__ float sred[4];
    #pragma unroll
    for (int off = 32; off > 0; off >>= 1) v += __shfl_down(v, off, 64);
    int lane = threadIdx.x & 63;
    int w = threadIdx.x >> 6;
    if (lane == 0) sred[w] = v;
    __syncthreads();
    float tot = sred[0] + sred[1] + sred[2] + sred[3];
    __syncthreads();
    return tot;
}

__global__ void k_zero(float* __restrict__ p, int n) {
    int i = blockIdx.x * 256 + threadIdx.x;
    if (i < n) p[i] = 0.0f;
}
__global__ void k_izero(int* __restrict__ p, int n) {
    int i = blockIdx.x * 256 + threadIdx.x;
    if (i < n) p[i] = 0;
}

__global__ void k_f2b(const float* __restrict__ s, u16* __restrict__ d, int n4) {
    int i = blockIdx.x * 256 + threadIdx.x;
    int stride = gridDim.x * 256;
    for (; i < n4; i += stride) {
        float4 v = ((const float4*)s)[i];
        uint2 o; o.x = pk2(v.x, v.y); o.y = pk2(v.z, v.w);
        ((uint2*)d)[i] = o;
    }
}

// pack two bias vectors contiguously (for batched gate/int GEMM)
__global__ void k_bias2(const float* __restrict__ a, const float* __restrict__ b,
                        float* __restrict__ o) {
    int i = blockIdx.x * 256 + threadIdx.x;
    if (i < H3) o[i] = a[i];
    else if (i < 2 * H3) o[i] = b[i - H3];
}

// gi = gate * relu(tmp), all bf16, vectorized
__global__ void k_gi(const u16* __restrict__ gate, const u16* __restrict__ tmp,
                     u16* __restrict__ out, int total4) {
    int i = blockIdx.x * 256 + threadIdx.x;
    int stride = gridDim.x * 256;
    for (; i < total4; i += stride) {
        uint2 g = ((const uint2*)gate)[i];
        uint2 t = ((const uint2*)tmp)[i];
        uint2 o;
        o.x = pk2(blo(g.x) * fmaxf(blo(t.x), 0.f), bhi(g.x) * fmaxf(bhi(t.x), 0.f));
        o.y = pk2(blo(g.y) * fmaxf(blo(t.y), 0.f), bhi(g.y) * fmaxf(bhi(t.y), 0.f));
        ((uint2*)out)[i] = o;
    }
}

// Wd transpose -> bf16 (for Wc = Wg1 @ Wd via A@W^T kernel)
__global__ void k_twd(const float* __restrict__ Wd, u16* __restrict__ Wdt) {
    __shared__ float tile[16][17];
    int z = blockIdx.z;
    int bx = blockIdx.x * 16, by = blockIdx.y * 16;
    int tx = threadIdx.x & 15, ty = threadIdx.x >> 4;
    tile[ty][tx] = Wd[(size_t)z * DH * DH + (size_t)(by + ty) * DH + bx + tx];
    __syncthreads();
    Wdt[(size_t)z * DH * DH + (size_t)(bx + ty) * DH + by + tx] = f2b(tile[tx][ty]);
}

// 2304x2304 transpose f32 -> bf16 (WoutT[i][j] = Wout[j][i])
__global__ void k_tr(const float* __restrict__ Win, u16* __restrict__ Wt) {
    __shared__ float tile[16][17];
    int bx = blockIdx.x * 16, by = blockIdx.y * 16;
    int tx = threadIdx.x & 15, ty = threadIdx.x >> 4;
    tile[ty][tx] = Win[(size_t)(by + ty) * H3 + bx + tx];
    __syncthreads();
    Wt[(size_t)(bx + ty) * H3 + by + tx] = f2b(tile[tx][ty]);
}

// bcomb[r] = sum_j Wf1[r][j]*bout[j] + bf1[r]  (wave per row, 4 rows/block)
__global__ void k_bvec(const float* __restrict__ Wf1, const float* __restrict__ bout,
                       const float* __restrict__ bf1, float* __restrict__ bcomb) {
    int r = blockIdx.x * 4 + (threadIdx.x >> 6);
    int lane = threadIdx.x & 63;
    const float* row = Wf1 + (size_t)r * H3;
    float s = 0.f;
    for (int j = lane; j < H3; j += 64) s = fmaf(row[j], bout[j], s);
    s = wave_sum(s);
    if (lane == 0) bcomb[r] = s + bf1[r];
}

// cvec[z][j] = sum_k Wg1[z][j][k] * bd[z][k]   (f32)
__global__ void k_cvec(const float* __restrict__ Wg1, const float* __restrict__ bd,
                       float* __restrict__ cvec) {
    int z = blockIdx.x, j = threadIdx.x;
    const float* row = Wg1 + (size_t)z * DH * DH + (size_t)j * DH;
    const float* b = bd + (size_t)z * DH;
    float s = 0.f;
    for (int k = 0; k < DH; ++k) s = fmaf(row[k], b[k], s);
    cvec[(size_t)z * DH + j] = s;
}

// ===== merged CSR build: 2G z-slices (z<G: adj graph, z>=G: edge graph) =====
__global__ void k_hist2(const int* __restrict__ adjd, const int* __restrict__ edged,
                        int* __restrict__ cnt, int G) {
    int z = blockIdx.y;
    const int* dst = (z < G) ? adjd + (size_t)z * NE : edged + (size_t)(z - G) * NE;
    cnt += (size_t)z * N_NODES;
    int i = blockIdx.x * 256 + threadIdx.x;
    if (i < NE) atomicAdd(&cnt[dst[i]], 1);
}

// one block per slice; cnt becomes the cursor array in-place
__global__ void k_scan(int* __restrict__ cnt, int* __restrict__ rowptr) {
    int z = blockIdx.x;
    cnt += (size_t)z * N_NODES;
    rowptr += (size_t)z * (N_NODES + 1);
    __shared__ int part[256];
    int t = threadIdx.x;
    const int CH = (N_NODES + 255) / 256;
    int beg = t * CH;
    int end = beg + CH; if (end > N_NODES) end = N_NODES;
    int s = 0;
    for (int i = beg; i < end; ++i) s += cnt[i];
    part[t] = s;
    __syncthreads();
    for (int off = 1; off < 256; off <<= 1) {
        int v = (t >= off) ? part[t - off] : 0;
        __syncthreads();
        part[t] += v;
        __syncthreads();
    }
    int run = (t == 0) ? 0 : part[t - 1];
    for (int i = beg; i < end; ++i) {
        int c = cnt[i];
        rowptr[i] = run;
        cnt[i] = run;      // cursor init (in-place)
        run += c;
    }
    if (t == 255) rowptr[N_NODES] = part[255];
}

// place: adj slices write packed (src, val) uint2 (1 scatter store/edge);
// edge slices write int src.
__global__ void k_place2(const int* __restrict__ adjs, const int* __restrict__ adjd,
                         const float* __restrict__ adjv, const int* __restrict__ edges,
                         const int* __restrict__ edged, int* __restrict__ cursor,
                         uint2* __restrict__ padj, int* __restrict__ psrcE, int G) {
    int z = blockIdx.y;
    bool isadj = z < G;
    const int* src = isadj ? adjs + (size_t)z * NE : edges + (size_t)(z - G) * NE;
    const int* dst = isadj ? adjd + (size_t)z * NE : edged + (size_t)(z - G) * NE;
    cursor += (size_t)z * N_NODES;
    int i = blockIdx.x * 256 + threadIdx.x;
    if (i < NE) {
        int d = dst[i];
        int pos = atomicAdd(&cursor[d], 1);
        if (isadj) {
            uint2 p;
            p.x = (unsigned int)src[i];
            p.y = __float_as_uint(adjv[(size_t)z * NE + i]);
            padj[(size_t)z * NE + pos] = p;
        } else {
            psrcE[(size_t)(z - G) * NE + pos] = src[i];
        }
    }
}

// x_hyp = proj(expmap0(f1)) -> bf16; clamped row norm -> xhn (f32)
__global__ void k_expmap_proj_in(const float* __restrict__ f1,
                                 u16* __restrict__ xhyp, float* __restrict__ xhn) {
    int r = blockIdx.x, t = threadIdx.x;
    const float* u = f1 + (size_t)r * D_INN;
    float v0 = u[t], v1 = u[t + 256];
    float ss = block_sum256(v0 * v0 + v1 * v1);
    float nraw = sqrtf(ss);
    float n = fmaxf(nraw, 1e-15f);
    float c = tanh_fast(n) * rcp_f(n);
    float ny = c * nraw;
    float np = fmaxf(ny, 1e-15f);
    float s = (np > MAXN) ? MAXN * rcp_f(np) : 1.0f;
    float cs = c * s;
    u16* o = xhyp + (size_t)r * D_INN;
    o[t] = f2b(cs * v0);
    o[t + 256] = f2b(cs * v1);
    if (t == 0) xhn[r] = fminf(np, MAXN);
}

__global__ void k_hb(const float* __restrict__ b_hyp,
                     float* __restrict__ hb, float* __restrict__ hb2) {
    int i = blockIdx.x, t = threadIdx.x;
    float v = b_hyp[i * DH + t];
    float ss = block_sum256(v * v);
    float nraw = sqrtf(ss);
    float n = fmaxf(nraw, 1e-15f);
    float c = tanh_fast(n) * rcp_f(n);
    float ny = c * nraw;
    float np = fmaxf(ny, 1e-15f);
    float s = (np > MAXN) ? MAXN * rcp_f(np) : 1.0f;
    float hv = c * s * v;
    hb[i * DH + t] = hv;
    float s2 = block_sum256(hv * hv);
    if (t == 0) hb2[i] = s2;
}

// wave-per-node (4 nodes/block), lane = 4 feats via uint2; in-place bf16.
__global__ void k_rowfuse1(u16* __restrict__ T, const float* __restrict__ xhn,
                           const float* __restrict__ hb, const float* __restrict__ hb2) {
    int z = blockIdx.y;
    int n = blockIdx.x * 4 + (threadIdx.x >> 6);
    int lane = threadIdx.x & 63;
    u16* row = T + ((size_t)z * N_NODES + n) * DH;
    const float* hbz = hb + (size_t)z * DH;
    uint2 u = *(const uint2*)(row + lane * 4);
    float m0 = blo(u.x), m1 = bhi(u.x), m2 = blo(u.y), m3 = bhi(u.y);
    float ss = wave_sum(m0 * m0 + m1 * m1 + m2 * m2 + m3 * m3);
    float mxn_raw = sqrtf(ss);
    float mxn = fmaxf(mxn_raw, 1e-15f);
    float xn = xhn[n];
    float tt = tanh_fast(mxn * rcp_f(xn) * artanh_fast(xn));
    float coef = tt * rcp_f(mxn);
    float nres = coef * mxn_raw;
    float np = fmaxf(nres, 1e-15f);
    float s1 = (np > MAXN) ? MAXN * rcp_f(np) : 1.0f;
    float cs = coef * s1;
    float r0 = cs * m0, r1 = cs * m1, r2 = cs * m2, r3 = cs * m3;
    float n1 = fminf(np, MAXN);
    float4 hv = *(const float4*)(hbz + lane * 4);
    float xy = wave_sum(r0 * hv.x + r1 * hv.y + r2 * hv.z + r3 * hv.w);
    float x2 = n1 * n1, y2 = hb2[z];
    float ca = 1.0f + 2.0f * xy + y2;
    float cb = 1.0f - x2;
    float rden = rcp_f(fmaxf(1.0f + 2.0f * xy + x2 * y2, 1e-15f));
    float o0 = (ca * r0 + cb * hv.x) * rden;
    float o1 = (ca * r1 + cb * hv.y) * rden;
    float o2 = (ca * r2 + cb * hv.z) * rden;
    float o3 = (ca * r3 + cb * hv.w) * rden;
    float no2 = wave_sum(o0 * o0 + o1 * o1 + o2 * o2 + o3 * o3);
    float nop = fmaxf(sqrtf(no2), 1e-15f);
    float s2 = (nop > MAXN) ? MAXN * rcp_f(nop) : 1.0f;
    float n2 = fminf(nop, MAXN);
    float fin = artanh_fast(n2) * rcp_f(n2) * s2;
    uint2 o; o.x = pk2(fin * o0, fin * o1); o.y = pk2(fin * o2, fin * o3);
    *(uint2*)(row + lane * 4) = o;
}

// wave-per-node CSR gather (packed (src,val)) + fused rowfuse2 chain -> bf16 out
__global__ void k_gather_fuse2(const int* __restrict__ rowptr, const uint2* __restrict__ padj,
                               const u16* __restrict__ xt, u16* __restrict__ out) {
    int z = blockIdx.y;
    rowptr += (size_t)z * (N_NODES + 1);
    padj += (size_t)z * NE;
    xt += (size_t)z * N_NODES * DH;
    out += (size_t)z * N_NODES * DH;
    int n = blockIdx.x * 4 + (threadIdx.x >> 6);
    int lane = threadIdx.x & 63;
    int beg = rowptr[n], end = rowptr[n + 1];
    float a0 = 0.f, a1 = 0.f, a2 = 0.f, a3 = 0.f;
    for (int i = beg; i < end; ++i) {
        uint2 p = padj[i];
        float v = __uint_as_float(p.y);
        uint2 u = *(const uint2*)(xt + (size_t)p.x * DH + lane * 4);
        a0 = fmaf(v, blo(u.x), a0);
        a1 = fmaf(v, bhi(u.x), a1);
        a2 = fmaf(v, blo(u.y), a2);
        a3 = fmaf(v, bhi(u.y), a3);
    }
    float ss = wave_sum(a0 * a0 + a1 * a1 + a2 * a2 + a3 * a3);
    float nraw = sqrtf(ss);
    float n_ = fmaxf(nraw, 1e-15f);
    float c1 = tanh_fast(n_) * rcp_f(n_);
    float nh = c1 * nraw;
    float np1 = fmaxf(nh, 1e-15f);
    float s1 = (np1 > MAXN) ? MAXN * rcp_f(np1) : 1.0f;
    float n1 = fminf(np1, MAXN);
    float cu = artanh_fast(n1) * rcp_f(n1) * s1 * c1;
    float u0 = fmaxf(cu * a0, 0.f), u1 = fmaxf(cu * a1, 0.f);
    float u2 = fmaxf(cu * a2, 0.f), u3 = fmaxf(cu * a3, 0.f);
    float ss2 = wave_sum(u0 * u0 + u1 * u1 + u2 * u2 + u3 * u3);
    float n2raw = sqrtf(ss2);
    float n2 = fmaxf(n2raw, 1e-15f);
    float c3 = tanh_fast(n2) * rcp_f(n2);
    float ne = c3 * n2raw;
    float np3 = fmaxf(ne, 1e-15f);
    float s3 = (np3 > MAXN) ? MAXN * rcp_f(np3) : 1.0f;
    float n3 = fminf(np3, MAXN);
    float cf = artanh_fast(n3) * rcp_f(n3) * s3 * c3;
    uint2 o; o.x = pk2(cf * u0, cf * u1); o.y = pk2(cf * u2, cf * u3);
    *(uint2*)(out + (size_t)n * DH + lane * 4) = o;
}

// wave-per-node: out[n] = d[n] + sum_in d[src]; bf16 in/out
__global__ void k_gather_add(const int* __restrict__ rowptr, const int* __restrict__ psrc,
                             const u16* __restrict__ d, u16* __restrict__ out) {
    int z = blockIdx.y;
    rowptr += (size_t)z * (N_NODES + 1);
    psrc += (size_t)z * NE;
    d += (size_t)z * N_NODES * DH;
    out += (size_t)z * N_NODES * DH;
    int n = blockIdx.x * 4 + (threadIdx.x >> 6);
    int lane = threadIdx.x & 63;
    int beg = rowptr[n], end = rowptr[n + 1];
    uint2 u0v = *(const uint2*)(d + (size_t)n * DH + lane * 4);
    float a0 = blo(u0v.x), a1 = bhi(u0v.x), a2 = blo(u0v.y), a3 = bhi(u0v.y);
    for (int i = beg; i < end; ++i) {
        int s = psrc[i];
        uint2 u = *(const uint2*)(d + (size_t)s * DH + lane * 4);
        a0 += blo(u.x); a1 += bhi(u.x); a2 += blo(u.y); a3 += bhi(u.y);
    }
    uint2 o; o.x = pk2(a0, a1); o.y = pk2(a2, a3);
    *(uint2*)(out + (size_t)n * DH + lane * 4) = o;
}

// batched column stats from bf16
__global__ void k_colstats(const u16* __restrict__ zp,
                           float* __restrict__ csum, float* __restrict__ csq) {
    int z = blockIdx.y;
    zp += (size_t)z * N_NODES * DH;
    csum += (size_t)z * DH;
    csq += (size_t)z * DH;
    int t = threadIdx.x;
    int r0 = blockIdx.x * 100;
    float s = 0.0f, q = 0.0f;
    for (int r = r0; r < r0 + 100; ++r) {
        float v = b2f(zp[(size_t)r * DH + t]);
        s += v;
        q += v * v;
    }
    atomicAdd(&csum[t], s);
    atomicAdd(&csq[t], q);
}

// grid-stride uint2 batchnorm + tanh, in-place bf16 (total4 = G*N*DH/4)
__global__ void k_normtanh_v(u16* __restrict__ zp, const float* __restrict__ csum,
                             const float* __restrict__ csq, const float* __restrict__ gamma,
                             const float* __restrict__ beta, int total4) {
    const float inv_n = 1.0f / N_NODES;
    int i = blockIdx.x * 256 + threadIdx.x;
    int stride = gridDim.x * 256;
    for (; i < total4; i += stride) {
        int e0 = i * 4;
        int z = e0 / (N_NODES * DH);
        int j0 = e0 & (DH - 1);
        int zb = z * DH + j0;
        uint2 u = ((uint2*)zp)[i];
        float v[4] = {blo(u.x), bhi(u.x), blo(u.y), bhi(u.y)};
        #pragma unroll
        for (int k = 0; k < 4; ++k) {
            float mu = csum[zb + k] * inv_n;
            float var = csq[zb + k] * inv_n - mu * mu;
            float inv = __builtin_amdgcn_rsqf(var + 1e-5f);
            v[k] = tanh_fast((v[k] - mu) * inv * gamma[zb + k] + beta[zb + k]);
        }
        uint2 o; o.x = pk2(v[0], v[1]); o.y = pk2(v[2], v[3]);
        ((uint2*)zp)[i] = o;
    }
}

// f1 slice of S,P (cols 0..511): thread t -> 2 cols via float2, packed u32 store
__global__ void k_pair0(const int* __restrict__ ei, const int* __restrict__ eid,
                        const float* __restrict__ f1, u16* __restrict__ S,
                        u16* __restrict__ P) {
    int b = blockIdx.x, t = threadIdx.x;
    int e = eid[b];
    int n0 = ei[e], n1 = ei[NE2 + e];
    float2 a = *(const float2*)(f1 + (size_t)n0 * D_INN + t * 2);
    float2 c = *(const float2*)(f1 + (size_t)n1 * D_INN + t * 2);
    ((unsigned int*)(S + (size_t)b * H3))[t] = pk2(a.x + c.x, a.y + c.y);
    ((unsigned int*)(P + (size_t)b * H3))[t] = pk2(a.x * c.x, a.y * c.y);
}

// batched channel slice of S,P from z_ch; 4 edges/block, uint2 lanes
__global__ void k_gather_ch(const int* __restrict__ ei, const int* __restrict__ eid,
                            const u16* __restrict__ zch, u16* __restrict__ S,
                            u16* __restrict__ P, int col0base) {
    int z = blockIdx.y;
    const u16* zp = zch + (size_t)z * N_NODES * DH;
    int col0 = col0base + z * DH;
    int b = blockIdx.x * 4 + (threadIdx.x >> 6);
    int lane = threadIdx.x & 63;
    int e = eid[b];
    int n0 = ei[e], n1 = ei[NE2 + e];
    uint2 ua = *(const uint2*)(zp + (size_t)n0 * DH + lane * 4);
    uint2 ub = *(const uint2*)(zp + (size_t)n1 * DH + lane * 4);
    float a0 = blo(ua.x), a1 = bhi(ua.x), a2 = blo(ua.y), a3 = bhi(ua.y);
    float c0 = blo(ub.x), c1 = bhi(ub.x), c2 = blo(ub.y), c3 = bhi(ub.y);
    uint2 so; so.x = pk2(a0 + c0, a1 + c1); so.y = pk2(a2 + c2, a3 + c3);
    uint2 po; po.x = pk2(a0 * c0, a1 * c1); po.y = pk2(a2 * c2, a3 * c3);
    *(uint2*)(S + (size_t)b * H3 + col0 + lane * 4) = so;
    *(uint2*)(P + (size_t)b * H3 + col0 + lane * 4) = po;
}

__global__ void k_final(const u16* __restrict__ h2, const float* __restrict__ Wf3,
                        const float* __restrict__ bf3, float* __restrict__ out) {
    int r = blockIdx.x, t = threadIdx.x;
    const u16* hr = h2 + (size_t)r * 576;
    float acc[7] = {0, 0, 0, 0, 0, 0, 0};
    for (int cb = t; cb < 576; cb += 64) {
        float h = b2f(hr[cb]);
        #pragma unroll
        for (int o = 0; o < 7; ++o) acc[o] = fmaf(h, Wf3[o * 576 + cb], acc[o]);
    }
    #pragma unroll
    for (int o = 0; o < 7; ++o) {
        #pragma unroll
        for (int off = 32; off > 0; off >>= 1) acc[o] += __shfl_down(acc[o], off, 64);
    }
    if (t == 0) {
        #pragma unroll
        for (int o = 0; o < 7; ++o) out[(size_t)r * 7 + o] = acc[o] + bf3[o];
    }
}

// ===== bf16 MFMA GEMM, BK=64 (batched over z with strides).
// global_load_lds width-16 coalesced staging: per 8-row block, lane l ->
// row l>>3, src chunk (l&7)^(l>>3) (involution with read swizzle); LDS dest
// linear. Fragment ds_read_b128 at row*64 + ((q^(row&7))*8) shorts -> 8
// distinct 4-bank spans x 2 lanes = 2-way alias (free). Halves barrier
// drains vs BK=32 (32 MFMA/wave per K-step). LDS 32KB, 2 blocks/CU.
// FULL-GRID 3D bijective XCD swizzle (z included).
// EP: 2=sigmoid->bf16, 3=relu->bf16, 5=bf16, 6=relu->f32,
//     7=bf16 + bias + (1+indeg[row])*cvec[col],
//     8=z==0? sigmoid->bf16 : bf16 (for batched gate/int)
template <int EP>
__global__ __launch_bounds__(256, 2) void k_gemm_mfma(
    const u16* __restrict__ A, const u16* __restrict__ W,
    const float* __restrict__ bias, void* __restrict__ outv,
    const int* __restrict__ rpe, const float* __restrict__ cvec,
    int M, int N, int K, size_t sA, size_t sW, size_t sC, int sBias) {
    __shared__ short As[8192];   // 128 rows x 64 cols bf16
    __shared__ short Ws[8192];
    // 3D bijective XCD swizzle over the whole grid
    const int gx = gridDim.x, gy = gridDim.y;
    const int plane = gx * gy;
    const int total = plane * gridDim.z;
    const int orig = (blockIdx.z * gy + blockIdx.y) * gx + blockIdx.x;
    const int q8 = total >> 3, r8 = total & 7, xcd = orig & 7;
    const int wg = (xcd < r8 ? xcd * (q8 + 1) : r8 * (q8 + 1) + (xcd - r8) * q8) + (orig >> 3);
    const int z = wg / plane;
    const int rem = wg - z * plane;
    const int row0 = (rem / gx) * 128, col0 = (rem % gx) * 128;
    A += (size_t)z * sA;
    W += (size_t)z * sW;
    const size_t zC = (size_t)z * sC;
    const int* rp = (EP == 7) ? rpe + (size_t)z * (N_NODES + 1) : nullptr;
    const float* cv = (EP == 7) ? cvec + (size_t)z * DH : nullptr;
    const int t = threadIdx.x;
    const int lane = t & 63;
    const int w = t >> 6;
    const int wr = w >> 1, wc = w & 1;
    // staging: lane l -> row-in-8block l>>3, src chunk (l&7)^(l>>3)
    const int sr8 = lane >> 3;
    const int csrc = (lane & 7) ^ sr8;
    int gr[4], gc[4];
    #pragma unroll
    for (int p = 0; p < 4; ++p) {
        int rb = w + p * 4;                // 0..15 (8-row blocks)
        gr[p] = row0 + rb * 8 + sr8; if (gr[p] >= M) gr[p] = M - 1;
        gc[p] = col0 + rb * 8 + sr8; if (gc[p] >= N) gc[p] = N - 1;
    }
    const int fr = lane & 15, fq4 = lane >> 4;   // logical chunk q = kk*4 + fq4
    f32x4 acc[4][4] = {};
    for (int k0 = 0; k0 < K; k0 += 64) {
        #pragma unroll
        for (int p = 0; p < 4; ++p) {
            int rb = w + p * 4;
            __builtin_amdgcn_global_load_lds(
                (const __attribute__((address_space(1))) unsigned int*)(A + (size_t)gr[p] * K + k0 + csrc * 8),
                (__attribute__((address_space(3))) unsigned int*)(As + rb * 512), 16, 0, 0);
            __builtin_amdgcn_global_load_lds(
                (const __attribute__((address_space(1))) unsigned int*)(W + (size_t)gc[p] * K + k0 + csrc * 8),
                (__attribute__((address_space(3))) unsigned int*)(Ws + rb * 512), 16, 0, 0);
        }
        __syncthreads();
        bf16x8 af[4][2], bfr[4][2];
        #pragma unroll
        for (int m = 0; m < 4; ++m) {
            int ar = wr * 64 + m * 16 + fr;
            #pragma unroll
            for (int kk = 0; kk < 2; ++kk) {
                int q = kk * 4 + fq4;
                af[m][kk] = *(const bf16x8*)(As + ar * 64 + ((q ^ (ar & 7)) * 8));
            }
        }
        #pragma unroll
        for (int n = 0; n < 4; ++n) {
            int br = wc * 64 + n * 16 + fr;
            #pragma unroll
            for (int kk = 0; kk < 2; ++kk) {
                int q = kk * 4 + fq4;
                bfr[n][kk] = *(const bf16x8*)(Ws + br * 64 + ((q ^ (br & 7)) * 8));
            }
        }
        #pragma unroll
        for (int m = 0; m < 4; ++m)
            #pragma unroll
            for (int n = 0; n < 4; ++n)
                #pragma unroll
                for (int kk = 0; kk < 2; ++kk)
                    acc[m][n] = __builtin_amdgcn_mfma_f32_16x16x32_bf16(
                        af[m][kk], bfr[n][kk], acc[m][n], 0, 0, 0);
        __syncthreads();
    }
    const int cl = lane & 15, rh = (lane >> 4) * 4;
    #pragma unroll
    for (int m = 0; m < 4; ++m) {
        float indf[4];
        if (EP == 7) {
            #pragma unroll
            for (int r = 0; r < 4; ++r) {
                int row = row0 + wr * 64 + m * 16 + rh + r;
                if (row >= M) row = M - 1;
                indf[r] = 1.0f + (float)(rp[row + 1] - rp[row]);
            }
        }
        #pragma unroll
        for (int n = 0; n < 4; ++n) {
            int col = col0 + wc * 64 + n * 16 + cl;
            if (col >= N) continue;
            float bv = bias ? bias[z * sBias + col] : 0.0f;
            float cvc = (EP == 7) ? cv[col] : 0.0f;
            #pragma unroll
            for (int r = 0; r < 4; ++r) {
                int row = row0 + wr * 64 + m * 16 + rh + r;
                if (row >= M) continue;
                float v = acc[m][n][r] + bv;
                size_t idx = zC + (size_t)row * N + col;
                if (EP == 2) ((u16*)outv)[idx] = f2b(sigmoid_fast(v));
                if (EP == 3) ((u16*)outv)[idx] = f2b(fmaxf(v, 0.0f));
                if (EP == 5) ((u16*)outv)[idx] = f2b(v);
                if (EP == 6) ((float*)outv)[idx] = fmaxf(v, 0.0f);
                if (EP == 7) ((u16*)outv)[idx] = f2b(v + indf[r] * cvc);
                if (EP == 8) ((u16*)outv)[idx] = (z == 0) ? f2b(sigmoid_fast(v)) : f2b(v);
            }
        }
    }
}

static inline void gemm_b(int ep, const u16* A, const u16* W, const float* bias, void* out,
                          const int* rpe, const float* cvec,
                          int M, int N, int K, int Z,
                          size_t sA, size_t sW, size_t sC, int sBias, hipStream_t st) {
    dim3 g((N + 127) / 128, (M + 127) / 128, Z);
    switch (ep) {
        case 2: k_gemm_mfma<2><<<g, 256, 0, st>>>(A, W, bias, out, rpe, cvec, M, N, K, sA, sW, sC, sBias); break;
        case 3: k_gemm_mfma<3><<<g, 256, 0, st>>>(A, W, bias, out, rpe, cvec, M, N, K, sA, sW, sC, sBias); break;
        case 5: k_gemm_mfma<5><<<g, 256, 0, st>>>(A, W, bias, out, rpe, cvec, M, N, K, sA, sW, sC, sBias); break;
        case 6: k_gemm_mfma<6><<<g, 256, 0, st>>>(A, W, bias, out, rpe, cvec, M, N, K, sA, sW, sC, sBias); break;
        case 7: k_gemm_mfma<7><<<g, 256, 0, st>>>(A, W, bias, out, rpe, cvec, M, N, K, sA, sW, sC, sBias); break;
        case 8: k_gemm_mfma<8><<<g, 256, 0, st>>>(A, W, bias, out, rpe, cvec, M, N, K, sA, sW, sC, sBias); break;
    }
}

static inline void conv_w(const float* s, u16* d, size_t n, hipStream_t st) {
    int n4 = (int)(n / 4);
    int grid = (n4 + 255) / 256;
    if (grid > 2048) grid = 2048;
    k_f2b<<<grid, 256, 0, st>>>(s, d, n4);
}

extern "C" void kernel_launch(void* const* d_in, const int* in_sizes, int n_in, void* d_out,
                              int out_size, void* d_ws, size_t ws_size, hipStream_t stream) {
    const float* f1 = (const float*)d_in[0];
    const int* adj_src = (const int*)d_in[1];
    const int* adj_dst = (const int*)d_in[2];
    const float* adj_val = (const float*)d_in[3];
    const int* edge_src = (const int*)d_in[4];
    const int* edge_dst = (const int*)d_in[5];
    const int* edge_index = (const int*)d_in[6];
    const int* edge_id = (const int*)d_in[7];
    const float* W_hyp = (const float*)d_in[8];
    const float* b_hyp = (const float*)d_in[9];
    const float* Wd = (const float*)d_in[10];
    const float* bd = (const float*)d_in[11];
    const float* Wg1 = (const float*)d_in[12];
    const float* bg1 = (const float*)d_in[13];
    const float* gamma = (const float*)d_in[14];
    const float* beta = (const float*)d_in[15];
    const float* Wg2 = (const float*)d_in[16];
    const float* bg2 = (const float*)d_in[17];
    const float* Wgate = (const float*)d_in[18];
    const float* bgate = (const float*)d_in[19];
    const float* Wint = (const float*)d_in[20];
    const float* bint = (const float*)d_in[21];
    const float* Wout = (const float*)d_in[22];
    const float* bout = (const float*)d_in[23];
    const float* Wf1 = (const float*)d_in[24];
    const float* bf1 = (const float*)d_in[25];
    const float* Wf2 = (const float*)d_in[26];
    const float* bf2 = (const float*)d_in[27];
    const float* Wf3 = (const float*)d_in[28];
    const float* bf3 = (const float*)d_in[29];
    float* outp = (float*)d_out;

    // Group partition: single Z=7 group if workspace allows (~281 MB needed),
    // else the proven 2-group (4+3) layout (~227 MB).
    const bool single = ws_size >= 283000000ull;
    const int ngroups = single ? 1 : 2;
    const int GM = single ? 7 : 4;
    int g0s[2] = {0, 4};
    int gns[2] = {GM, 3};

    // ---- workspace bump allocator ----
    char* base = (char*)d_ws;
    size_t off = 0;
    auto alloc = [&](size_t bytes) -> char* {
        char* p = base + off;
        off += (bytes + 255) & ~(size_t)255;
        return p;
    };
    u16* Whyp_b = (u16*)alloc((size_t)NCH * DH * D_INN * 2);
    u16* Wc_b   = (u16*)alloc((size_t)NCH * DH * DH * 2);   // Wg1 @ Wd
    u16* Wg1_b  = (u16*)alloc((size_t)NCH * DH * DH * 2);
    u16* Wg2_b  = (u16*)alloc((size_t)NCH * DH * DH * 2);
    u16* Wgate_b = (u16*)alloc((size_t)H3 * H3 * 2);        // Wint_b must follow!
    u16* Wint_b  = (u16*)alloc((size_t)H3 * H3 * 2);
    u16* Wcomb_b = (u16*)alloc((size_t)1152 * H3 * 2);      // Wf1 @ Wout
    u16* Wf2_b   = (u16*)alloc((size_t)576 * 1152 * 2);
    u16* S_b = (u16*)alloc((size_t)NB * H3 * 2);            // P_b must follow!
    u16* P_b = (u16*)alloc((size_t)NB * H3 * 2);
    const size_t NDB = (size_t)N_NODES * DH;       // per-channel elems
    u16* buf1 = (u16*)alloc((size_t)GM * NDB * 2); // group ping (buf2 follows)
    u16* buf2 = (u16*)alloc((size_t)GM * NDB * 2); // group pong
    // xhyp: in single mode alias buf2 head (dead before buf2 first written);
    // in 2-group mode it must persist across groups -> separate.
    u16* xhyp_b = single ? buf2 : (u16*)alloc((size_t)N_NODES * D_INN * 2);
    // CSR scratch (2*GM slices): adj slices [0,G), edge slices [G,2G)
    int* cntC = (int*)alloc((size_t)2 * GM * N_NODES * 4);   // doubles as cursor
    int* rowptrC = (int*)alloc((size_t)2 * GM * (N_NODES + 1) * 4);
    uint2* padjC = (uint2*)alloc((size_t)GM * NE * 8);       // packed (src,val)
    int* psrcE = (int*)alloc((size_t)GM * NE * 4);
    float* xhn = (float*)alloc((size_t)N_NODES * 4);
    float* hb = (float*)alloc((size_t)NCH * DH * 4);
    float* hb2 = (float*)alloc(NCH * 4);
    float* csum = (float*)alloc((size_t)GM * DH * 4);        // csq follows
    float* csq = (float*)alloc((size_t)GM * DH * 4);
    float* cvec_d = (float*)alloc((size_t)NCH * DH * 4);
    float* bias2 = (float*)alloc((size_t)2 * H3 * 4);
    float* bcomb = (float*)alloc((size_t)1152 * 4);
    // precompute-only temp weights alias into buf1 (idle until GNN phase):
    u16* WoutT_b = buf1;                          // 10.62 MB
    u16* Wf1_b = buf1 + (size_t)H3 * H3;          // +5.31 MB
    u16* Wdt_b = Wf1_b + (size_t)1152 * H3;       // +0.92 MB (total 16.8 <= buf1)
    // stage-C overlays (GNN buffers dead by then): GT spans buf1(+buf2 tail);
    // h1 -> buf1 head after k_gi; h2 (bf16) -> buf2 head.
    u16* GT = buf1;
    u16* h2b = buf2;

    const int EG = (NE + 255) / 256;

    conv_w(W_hyp, Whyp_b, (size_t)NCH * DH * D_INN, stream);
    conv_w(Wg1, Wg1_b, (size_t)NCH * DH * DH, stream);
    conv_w(Wg2, Wg2_b, (size_t)NCH * DH * DH, stream);
    conv_w(Wgate, Wgate_b, (size_t)H3 * H3, stream);
    conv_w(Wint, Wint_b, (size_t)H3 * H3, stream);
    conv_w(Wf1, Wf1_b, (size_t)1152 * H3, stream);
    conv_w(Wf2, Wf2_b, (size_t)576 * 1152, stream);
    k_bias2<<<(2 * H3 + 255) / 256, 256, 0, stream>>>(bgate, bint, bias2);
    // Wc = Wg1 @ Wd (via Wd^T), cvec = Wg1 @ bd
    k_twd<<<dim3(16, 16, NCH), 256, 0, stream>>>(Wd, Wdt_b);
    gemm_b(5, Wg1_b, Wdt_b, nullptr, Wc_b, nullptr, nullptr,
           DH, DH, DH, NCH, (size_t)DH * DH, (size_t)DH * DH, (size_t)DH * DH, 0, stream);
    k_cvec<<<NCH, 256, 0, stream>>>(Wg1, bd, cvec_d);
    // Wcomb = Wf1 @ Wout (Wout GEMM folded into Wf1), bcomb = Wf1@bout + bf1
    k_tr<<<dim3(144, 144), 256, 0, stream>>>(Wout, WoutT_b);
    gemm_b(5, Wf1_b, WoutT_b, nullptr, Wcomb_b, nullptr, nullptr,
           1152, H3, H3, 1, 0, 0, 0, 0, stream);
    k_bvec<<<1152 / 4, 256, 0, stream>>>(Wf1, bout, bf1, bcomb);

    k_expmap_proj_in<<<N_NODES, 256, 0, stream>>>(f1, xhyp_b, xhn);
    k_hb<<<NCH, 256, 0, stream>>>(b_hyp, hb, hb2);
    k_pair0<<<NB, 256, 0, stream>>>(edge_index, edge_id, f1, S_b, P_b);

    for (int gi = 0; gi < ngroups; ++gi) {
        const int g0 = g0s[gi], G = gns[gi];
        const size_t eoff = (size_t)g0 * NE;
        const int G2 = 2 * G;
        const int* rpE = rowptrC + (size_t)G * (N_NODES + 1);
        // --- merged CSR build (both graphs, one launch set) ---
        k_izero<<<(G2 * N_NODES + 255) / 256, 256, 0, stream>>>(cntC, G2 * N_NODES);
        k_hist2<<<dim3(EG, G2), 256, 0, stream>>>(adj_dst + eoff, edge_dst + eoff, cntC, G);
        k_scan<<<G2, 256, 0, stream>>>(cntC, rowptrC);
        k_place2<<<dim3(EG, G2), 256, 0, stream>>>(adj_src + eoff, adj_dst + eoff,
                                                   adj_val + eoff, edge_src + eoff,
                                                   edge_dst + eoff, cntC, padjC, psrcE, G);
        // --- batched pipeline ---
        gemm_b(5, xhyp_b, Whyp_b + (size_t)g0 * DH * D_INN, nullptr, buf1, nullptr,
               nullptr, N_NODES, DH, D_INN, G, 0, (size_t)DH * D_INN, NDB, 0, stream);
        k_rowfuse1<<<dim3(N_NODES / 4, G), 256, 0, stream>>>(buf1, xhn, hb + g0 * DH, hb2 + g0);
        k_gather_fuse2<<<dim3(N_NODES / 4, G), 256, 0, stream>>>(rowptrC, padjC, buf1, buf2);
        // ug = (I + S_e) u
        k_gather_add<<<dim3(N_NODES / 4, G), 256, 0, stream>>>(rpE, psrcE, buf2, buf1);
        // z = ug @ Wc^T + (1+indeg)*cvec + bg1   (Wd GEMM fused away)
        gemm_b(7, buf1, Wc_b + (size_t)g0 * DH * DH, bg1 + g0 * DH, buf2,
               rpE, cvec_d + (size_t)g0 * DH, N_NODES, DH, DH, G,
               NDB, (size_t)DH * DH, NDB, DH, stream);
        k_zero<<<(2 * GM * DH + 255) / 256, 256, 0, stream>>>(csum, 2 * GM * DH);
        k_colstats<<<dim3(200, G), 256, 0, stream>>>(buf2, csum, csq);
        {
            int total4 = (int)(G * NDB / 4);
            int blocks = (total4 + 255) / 256;
            if (blocks > 2048) blocks = 2048;
            k_normtanh_v<<<blocks, 256, 0, stream>>>(buf2, csum, csq, gamma + g0 * DH,
                                                     beta + g0 * DH, total4);
        }
        gemm_b(5, buf2, Wg2_b + (size_t)g0 * DH * DH, bg2 + g0 * DH, buf1, nullptr,
               nullptr, N_NODES, DH, DH, G, NDB, (size_t)DH * DH, NDB, DH, stream);
        k_gather_ch<<<dim3(NB / 4, G), 256, 0, stream>>>(edge_index, edge_id, buf1, S_b, P_b,
                                                         D_INN + g0 * DH);
    }

    // stage C: batched gate/int (Z=2), gi elementwise, fused h1 (Wout folded
    // into Wf1 via Wcomb), h2 (bf16), final.
    gemm_b(8, S_b, Wgate_b, bias2, GT, nullptr, nullptr, NB, H3, H3, 2,
           (size_t)NB * H3, (size_t)H3 * H3, (size_t)NB * H3, H3, stream);
    {
        int total4 = NB * H3 / 4;
        int blocks = (total4 + 255) / 256;
        if (blocks > 2048) blocks = 2048;
        k_gi<<<blocks, 256, 0, stream>>>(GT, GT + (size_t)NB * H3, S_b, total4);
    }
    // h1 = relu(gi @ Wcomb^T + bcomb)
    gemm_b(3, S_b, Wcomb_b, bcomb, buf1, nullptr, nullptr, NB, 1152, H3, 1, 0, 0, 0, 0, stream);
    // h2 = relu(h1 @ Wf2^T + bf2) -> bf16
    gemm_b(3, buf1, Wf2_b, bf2, h2b, nullptr, nullptr, NB, 576, 1152, 1, 0, 0, 0, 0, stream);
    k_final<<<NB, 64, 0, stream>>>(h2b, Wf3, bf3, outp);
}

// Round 16
// 1600.692 us; speedup vs baseline: 1.4601x; 1.1773x over previous
//
#include <hip/hip_runtime.h>
#include <math.h>

#define N_NODES 20000
#define D_INN   512
#define DH      256
#define NCH     7
#define NE      320000
#define NE2     100000
#define NB      8192
#define H3      2304   // 512 + 7*256
#define MAXN    0.996f
#define LOG2E   1.44269504f

typedef unsigned short u16;
typedef __attribute__((ext_vector_type(8))) short bf16x8;
typedef __attribute__((ext_vector_type(4))) float f32x4;

__device__ __forceinline__ u16 f2b(float f) {    // RNE f32 -> bf16 bits
    unsigned int x = __float_as_uint(f);
    unsigned int r = (x + 0x7fffu + ((x >> 16) & 1u)) >> 16;
    return (u16)r;
}
__device__ __forceinline__ float b2f(u16 u) {
    return __uint_as_float(((unsigned int)u) << 16);
}
__device__ __forceinline__ float blo(unsigned int u) { return __uint_as_float(u << 16); }
__device__ __forceinline__ float bhi(unsigned int u) { return __uint_as_float(u & 0xffff0000u); }
__device__ __forceinline__ unsigned int pk2(float a, float b) {
    return (unsigned int)f2b(a) | ((unsigned int)f2b(b) << 16);
}

// ---- fast HW transcendentals (rel err ~1e-5, fine for bf16 tolerance) ----
__device__ __forceinline__ float rcp_f(float x) { return __builtin_amdgcn_rcpf(x); }
__device__ __forceinline__ float exp2_f(float x) { return __builtin_amdgcn_exp2f(x); }
__device__ __forceinline__ float log2_f(float x) { return __builtin_amdgcn_logf(x); }
__device__ __forceinline__ float tanh_fast(float x) {
    float xc = fminf(fmaxf(x, -15.f), 15.f);
    float t = exp2_f(xc * (2.f * LOG2E));
    return (t - 1.f) * rcp_f(t + 1.f);
}
__device__ __forceinline__ float artanh_fast(float x) {
    x = fminf(fmaxf(x, -1.0f + 1e-7f), 1.0f - 1e-7f);
    return 0.34657359f * log2_f((1.f + x) * rcp_f(1.f - x));
}
__device__ __forceinline__ float sigmoid_fast(float x) {
    return rcp_f(1.f + exp2_f(-x * LOG2E));
}

__device__ __forceinline__ float wave_sum(float v) {
    #pragma unroll
    for (int off = 32; off > 0; off >>= 1) v += __shfl_xor(v, off, 64);
    return v;
}

__device__ __forceinline__ float block_sum256(float v) {
    __shared__ float sred[4];
    #pragma unroll
    for (int off = 32; off > 0; off >>= 1) v += __shfl_down(v, off, 64);
    int lane = threadIdx.x & 63;
    int w = threadIdx.x >> 6;
    if (lane == 0) sred[w] = v;
    __syncthreads();
    float tot = sred[0] + sred[1] + sred[2] + sred[3];
    __syncthreads();
    return tot;
}

__global__ void k_zero(float* __restrict__ p, int n) {
    int i = blockIdx.x * 256 + threadIdx.x;
    if (i < n) p[i] = 0.0f;
}
__global__ void k_izero(int* __restrict__ p, int n) {
    int i = blockIdx.x * 256 + threadIdx.x;
    if (i < n) p[i] = 0;
}

__global__ void k_f2b(const float* __restrict__ s, u16* __restrict__ d, int n4) {
    int i = blockIdx.x * 256 + threadIdx.x;
    int stride = gridDim.x * 256;
    for (; i < n4; i += stride) {
        float4 v = ((const float4*)s)[i];
        uint2 o; o.x = pk2(v.x, v.y); o.y = pk2(v.z, v.w);
        ((uint2*)d)[i] = o;
    }
}

// pack two bias vectors contiguously (for batched gate/int GEMM)
__global__ void k_bias2(const float* __restrict__ a, const float* __restrict__ b,
                        float* __restrict__ o) {
    int i = blockIdx.x * 256 + threadIdx.x;
    if (i < H3) o[i] = a[i];
    else if (i < 2 * H3) o[i] = b[i - H3];
}

// gi = gate * relu(tmp), all bf16, vectorized
__global__ void k_gi(const u16* __restrict__ gate, const u16* __restrict__ tmp,
                     u16* __restrict__ out, int total4) {
    int i = blockIdx.x * 256 + threadIdx.x;
    int stride = gridDim.x * 256;
    for (; i < total4; i += stride) {
        uint2 g = ((const uint2*)gate)[i];
        uint2 t = ((const uint2*)tmp)[i];
        uint2 o;
        o.x = pk2(blo(g.x) * fmaxf(blo(t.x), 0.f), bhi(g.x) * fmaxf(bhi(t.x), 0.f));
        o.y = pk2(blo(g.y) * fmaxf(blo(t.y), 0.f), bhi(g.y) * fmaxf(bhi(t.y), 0.f));
        ((uint2*)out)[i] = o;
    }
}

// Wd transpose -> bf16 (for Wc = Wg1 @ Wd via A@W^T kernel)
__global__ void k_twd(const float* __restrict__ Wd, u16* __restrict__ Wdt) {
    __shared__ float tile[16][17];
    int z = blockIdx.z;
    int bx = blockIdx.x * 16, by = blockIdx.y * 16;
    int tx = threadIdx.x & 15, ty = threadIdx.x >> 4;
    tile[ty][tx] = Wd[(size_t)z * DH * DH + (size_t)(by + ty) * DH + bx + tx];
    __syncthreads();
    Wdt[(size_t)z * DH * DH + (size_t)(bx + ty) * DH + by + tx] = f2b(tile[tx][ty]);
}

// 2304x2304 transpose f32 -> bf16 (WoutT[i][j] = Wout[j][i])
__global__ void k_tr(const float* __restrict__ Win, u16* __restrict__ Wt) {
    __shared__ float tile[16][17];
    int bx = blockIdx.x * 16, by = blockIdx.y * 16;
    int tx = threadIdx.x & 15, ty = threadIdx.x >> 4;
    tile[ty][tx] = Win[(size_t)(by + ty) * H3 + bx + tx];
    __syncthreads();
    Wt[(size_t)(bx + ty) * H3 + by + tx] = f2b(tile[tx][ty]);
}

// bcomb[r] = sum_j Wf1[r][j]*bout[j] + bf1[r]  (wave per row, 4 rows/block)
__global__ void k_bvec(const float* __restrict__ Wf1, const float* __restrict__ bout,
                       const float* __restrict__ bf1, float* __restrict__ bcomb) {
    int r = blockIdx.x * 4 + (threadIdx.x >> 6);
    int lane = threadIdx.x & 63;
    const float* row = Wf1 + (size_t)r * H3;
    float s = 0.f;
    for (int j = lane; j < H3; j += 64) s = fmaf(row[j], bout[j], s);
    s = wave_sum(s);
    if (lane == 0) bcomb[r] = s + bf1[r];
}

// cvec[z][j] = sum_k Wg1[z][j][k] * bd[z][k]   (f32)
__global__ void k_cvec(const float* __restrict__ Wg1, const float* __restrict__ bd,
                       float* __restrict__ cvec) {
    int z = blockIdx.x, j = threadIdx.x;
    const float* row = Wg1 + (size_t)z * DH * DH + (size_t)j * DH;
    const float* b = bd + (size_t)z * DH;
    float s = 0.f;
    for (int k = 0; k < DH; ++k) s = fmaf(row[k], b[k], s);
    cvec[(size_t)z * DH + j] = s;
}

// ===== merged CSR build: 2G z-slices (z<G: adj graph, z>=G: edge graph) =====
__global__ void k_hist2(const int* __restrict__ adjd, const int* __restrict__ edged,
                        int* __restrict__ cnt, int G) {
    int z = blockIdx.y;
    const int* dst = (z < G) ? adjd + (size_t)z * NE : edged + (size_t)(z - G) * NE;
    cnt += (size_t)z * N_NODES;
    int i = blockIdx.x * 256 + threadIdx.x;
    if (i < NE) atomicAdd(&cnt[dst[i]], 1);
}

// one block per slice; cnt becomes the cursor array in-place
__global__ void k_scan(int* __restrict__ cnt, int* __restrict__ rowptr) {
    int z = blockIdx.x;
    cnt += (size_t)z * N_NODES;
    rowptr += (size_t)z * (N_NODES + 1);
    __shared__ int part[256];
    int t = threadIdx.x;
    const int CH = (N_NODES + 255) / 256;
    int beg = t * CH;
    int end = beg + CH; if (end > N_NODES) end = N_NODES;
    int s = 0;
    for (int i = beg; i < end; ++i) s += cnt[i];
    part[t] = s;
    __syncthreads();
    for (int off = 1; off < 256; off <<= 1) {
        int v = (t >= off) ? part[t - off] : 0;
        __syncthreads();
        part[t] += v;
        __syncthreads();
    }
    int run = (t == 0) ? 0 : part[t - 1];
    for (int i = beg; i < end; ++i) {
        int c = cnt[i];
        rowptr[i] = run;
        cnt[i] = run;      // cursor init (in-place)
        run += c;
    }
    if (t == 255) rowptr[N_NODES] = part[255];
}

// place: adj slices write packed (src, val) uint2 (1 scatter store/edge);
// edge slices write int src.
__global__ void k_place2(const int* __restrict__ adjs, const int* __restrict__ adjd,
                         const float* __restrict__ adjv, const int* __restrict__ edges,
                         const int* __restrict__ edged, int* __restrict__ cursor,
                         uint2* __restrict__ padj, int* __restrict__ psrcE, int G) {
    int z = blockIdx.y;
    bool isadj = z < G;
    const int* src = isadj ? adjs + (size_t)z * NE : edges + (size_t)(z - G) * NE;
    const int* dst = isadj ? adjd + (size_t)z * NE : edged + (size_t)(z - G) * NE;
    cursor += (size_t)z * N_NODES;
    int i = blockIdx.x * 256 + threadIdx.x;
    if (i < NE) {
        int d = dst[i];
        int pos = atomicAdd(&cursor[d], 1);
        if (isadj) {
            uint2 p;
            p.x = (unsigned int)src[i];
            p.y = __float_as_uint(adjv[(size_t)z * NE + i]);
            padj[(size_t)z * NE + pos] = p;
        } else {
            psrcE[(size_t)(z - G) * NE + pos] = src[i];
        }
    }
}

// x_hyp = proj(expmap0(f1)) -> bf16; clamped row norm -> xhn (f32)
__global__ void k_expmap_proj_in(const float* __restrict__ f1,
                                 u16* __restrict__ xhyp, float* __restrict__ xhn) {
    int r = blockIdx.x, t = threadIdx.x;
    const float* u = f1 + (size_t)r * D_INN;
    float v0 = u[t], v1 = u[t + 256];
    float ss = block_sum256(v0 * v0 + v1 * v1);
    float nraw = sqrtf(ss);
    float n = fmaxf(nraw, 1e-15f);
    float c = tanh_fast(n) * rcp_f(n);
    float ny = c * nraw;
    float np = fmaxf(ny, 1e-15f);
    float s = (np > MAXN) ? MAXN * rcp_f(np) : 1.0f;
    float cs = c * s;
    u16* o = xhyp + (size_t)r * D_INN;
    o[t] = f2b(cs * v0);
    o[t + 256] = f2b(cs * v1);
    if (t == 0) xhn[r] = fminf(np, MAXN);
}

__global__ void k_hb(const float* __restrict__ b_hyp,
                     float* __restrict__ hb, float* __restrict__ hb2) {
    int i = blockIdx.x, t = threadIdx.x;
    float v = b_hyp[i * DH + t];
    float ss = block_sum256(v * v);
    float nraw = sqrtf(ss);
    float n = fmaxf(nraw, 1e-15f);
    float c = tanh_fast(n) * rcp_f(n);
    float ny = c * nraw;
    float np = fmaxf(ny, 1e-15f);
    float s = (np > MAXN) ? MAXN * rcp_f(np) : 1.0f;
    float hv = c * s * v;
    hb[i * DH + t] = hv;
    float s2 = block_sum256(hv * hv);
    if (t == 0) hb2[i] = s2;
}

// wave-per-node (4 nodes/block), lane = 4 feats via uint2; in-place bf16.
__global__ void k_rowfuse1(u16* __restrict__ T, const float* __restrict__ xhn,
                           const float* __restrict__ hb, const float* __restrict__ hb2) {
    int z = blockIdx.y;
    int n = blockIdx.x * 4 + (threadIdx.x >> 6);
    int lane = threadIdx.x & 63;
    u16* row = T + ((size_t)z * N_NODES + n) * DH;
    const float* hbz = hb + (size_t)z * DH;
    uint2 u = *(const uint2*)(row + lane * 4);
    float m0 = blo(u.x), m1 = bhi(u.x), m2 = blo(u.y), m3 = bhi(u.y);
    float ss = wave_sum(m0 * m0 + m1 * m1 + m2 * m2 + m3 * m3);
    float mxn_raw = sqrtf(ss);
    float mxn = fmaxf(mxn_raw, 1e-15f);
    float xn = xhn[n];
    float tt = tanh_fast(mxn * rcp_f(xn) * artanh_fast(xn));
    float coef = tt * rcp_f(mxn);
    float nres = coef * mxn_raw;
    float np = fmaxf(nres, 1e-15f);
    float s1 = (np > MAXN) ? MAXN * rcp_f(np) : 1.0f;
    float cs = coef * s1;
    float r0 = cs * m0, r1 = cs * m1, r2 = cs * m2, r3 = cs * m3;
    float n1 = fminf(np, MAXN);
    float4 hv = *(const float4*)(hbz + lane * 4);
    float xy = wave_sum(r0 * hv.x + r1 * hv.y + r2 * hv.z + r3 * hv.w);
    float x2 = n1 * n1, y2 = hb2[z];
    float ca = 1.0f + 2.0f * xy + y2;
    float cb = 1.0f - x2;
    float rden = rcp_f(fmaxf(1.0f + 2.0f * xy + x2 * y2, 1e-15f));
    float o0 = (ca * r0 + cb * hv.x) * rden;
    float o1 = (ca * r1 + cb * hv.y) * rden;
    float o2 = (ca * r2 + cb * hv.z) * rden;
    float o3 = (ca * r3 + cb * hv.w) * rden;
    float no2 = wave_sum(o0 * o0 + o1 * o1 + o2 * o2 + o3 * o3);
    float nop = fmaxf(sqrtf(no2), 1e-15f);
    float s2 = (nop > MAXN) ? MAXN * rcp_f(nop) : 1.0f;
    float n2 = fminf(nop, MAXN);
    float fin = artanh_fast(n2) * rcp_f(n2) * s2;
    uint2 o; o.x = pk2(fin * o0, fin * o1); o.y = pk2(fin * o2, fin * o3);
    *(uint2*)(row + lane * 4) = o;
}

// wave-per-node CSR gather (packed (src,val)), 2-way ILP unroll, + fused
// rowfuse2 hyperbolic chain -> bf16 out
__global__ void k_gather_fuse2(const int* __restrict__ rowptr, const uint2* __restrict__ padj,
                               const u16* __restrict__ xt, u16* __restrict__ out) {
    int z = blockIdx.y;
    rowptr += (size_t)z * (N_NODES + 1);
    padj += (size_t)z * NE;
    xt += (size_t)z * N_NODES * DH;
    out += (size_t)z * N_NODES * DH;
    int n = blockIdx.x * 4 + (threadIdx.x >> 6);
    int lane = threadIdx.x & 63;
    int beg = rowptr[n], end = rowptr[n + 1];
    float a0 = 0.f, a1 = 0.f, a2 = 0.f, a3 = 0.f;
    float b0 = 0.f, b1 = 0.f, b2 = 0.f, b3 = 0.f;
    int i = beg;
    for (; i + 2 <= end; i += 2) {
        uint2 p0 = padj[i];
        uint2 p1 = padj[i + 1];
        uint2 x0 = *(const uint2*)(xt + (size_t)p0.x * DH + lane * 4);
        uint2 x1 = *(const uint2*)(xt + (size_t)p1.x * DH + lane * 4);
        float v0 = __uint_as_float(p0.y), v1 = __uint_as_float(p1.y);
        a0 = fmaf(v0, blo(x0.x), a0);
        a1 = fmaf(v0, bhi(x0.x), a1);
        a2 = fmaf(v0, blo(x0.y), a2);
        a3 = fmaf(v0, bhi(x0.y), a3);
        b0 = fmaf(v1, blo(x1.x), b0);
        b1 = fmaf(v1, bhi(x1.x), b1);
        b2 = fmaf(v1, blo(x1.y), b2);
        b3 = fmaf(v1, bhi(x1.y), b3);
    }
    if (i < end) {
        uint2 p = padj[i];
        uint2 x0 = *(const uint2*)(xt + (size_t)p.x * DH + lane * 4);
        float v = __uint_as_float(p.y);
        a0 = fmaf(v, blo(x0.x), a0);
        a1 = fmaf(v, bhi(x0.x), a1);
        a2 = fmaf(v, blo(x0.y), a2);
        a3 = fmaf(v, bhi(x0.y), a3);
    }
    a0 += b0; a1 += b1; a2 += b2; a3 += b3;
    float ss = wave_sum(a0 * a0 + a1 * a1 + a2 * a2 + a3 * a3);
    float nraw = sqrtf(ss);
    float n_ = fmaxf(nraw, 1e-15f);
    float c1 = tanh_fast(n_) * rcp_f(n_);
    float nh = c1 * nraw;
    float np1 = fmaxf(nh, 1e-15f);
    float s1 = (np1 > MAXN) ? MAXN * rcp_f(np1) : 1.0f;
    float n1 = fminf(np1, MAXN);
    float cu = artanh_fast(n1) * rcp_f(n1) * s1 * c1;
    float u0 = fmaxf(cu * a0, 0.f), u1 = fmaxf(cu * a1, 0.f);
    float u2 = fmaxf(cu * a2, 0.f), u3 = fmaxf(cu * a3, 0.f);
    float ss2 = wave_sum(u0 * u0 + u1 * u1 + u2 * u2 + u3 * u3);
    float n2raw = sqrtf(ss2);
    float n2 = fmaxf(n2raw, 1e-15f);
    float c3 = tanh_fast(n2) * rcp_f(n2);
    float ne = c3 * n2raw;
    float np3 = fmaxf(ne, 1e-15f);
    float s3 = (np3 > MAXN) ? MAXN * rcp_f(np3) : 1.0f;
    float n3 = fminf(np3, MAXN);
    float cf = artanh_fast(n3) * rcp_f(n3) * s3 * c3;
    uint2 o; o.x = pk2(cf * u0, cf * u1); o.y = pk2(cf * u2, cf * u3);
    *(uint2*)(out + (size_t)n * DH + lane * 4) = o;
}

// wave-per-node: out[n] = d[n] + sum_in d[src]; 2-way ILP unroll; bf16 in/out
__global__ void k_gather_add(const int* __restrict__ rowptr, const int* __restrict__ psrc,
                             const u16* __restrict__ d, u16* __restrict__ out) {
    int z = blockIdx.y;
    rowptr += (size_t)z * (N_NODES + 1);
    psrc += (size_t)z * NE;
    d += (size_t)z * N_NODES * DH;
    out += (size_t)z * N_NODES * DH;
    int n = blockIdx.x * 4 + (threadIdx.x >> 6);
    int lane = threadIdx.x & 63;
    int beg = rowptr[n], end = rowptr[n + 1];
    uint2 u0v = *(const uint2*)(d + (size_t)n * DH + lane * 4);
    float a0 = blo(u0v.x), a1 = bhi(u0v.x), a2 = blo(u0v.y), a3 = bhi(u0v.y);
    float b0 = 0.f, b1 = 0.f, b2 = 0.f, b3 = 0.f;
    int i = beg;
    for (; i + 2 <= end; i += 2) {
        int s0 = psrc[i], s1 = psrc[i + 1];
        uint2 x0 = *(const uint2*)(d + (size_t)s0 * DH + lane * 4);
        uint2 x1 = *(const uint2*)(d + (size_t)s1 * DH + lane * 4);
        a0 += blo(x0.x); a1 += bhi(x0.x); a2 += blo(x0.y); a3 += bhi(x0.y);
        b0 += blo(x1.x); b1 += bhi(x1.x); b2 += blo(x1.y); b3 += bhi(x1.y);
    }
    if (i < end) {
        int s0 = psrc[i];
        uint2 x0 = *(const uint2*)(d + (size_t)s0 * DH + lane * 4);
        a0 += blo(x0.x); a1 += bhi(x0.x); a2 += blo(x0.y); a3 += bhi(x0.y);
    }
    a0 += b0; a1 += b1; a2 += b2; a3 += b3;
    uint2 o; o.x = pk2(a0, a1); o.y = pk2(a2, a3);
    *(uint2*)(out + (size_t)n * DH + lane * 4) = o;
}

// batched column stats from bf16
__global__ void k_colstats(const u16* __restrict__ zp,
                           float* __restrict__ csum, float* __restrict__ csq) {
    int z = blockIdx.y;
    zp += (size_t)z * N_NODES * DH;
    csum += (size_t)z * DH;
    csq += (size_t)z * DH;
    int t = threadIdx.x;
    int r0 = blockIdx.x * 100;
    float s = 0.0f, q = 0.0f;
    for (int r = r0; r < r0 + 100; ++r) {
        float v = b2f(zp[(size_t)r * DH + t]);
        s += v;
        q += v * v;
    }
    atomicAdd(&csum[t], s);
    atomicAdd(&csq[t], q);
}

// grid-stride uint2 batchnorm + tanh, in-place bf16 (total4 = G*N*DH/4)
__global__ void k_normtanh_v(u16* __restrict__ zp, const float* __restrict__ csum,
                             const float* __restrict__ csq, const float* __restrict__ gamma,
                             const float* __restrict__ beta, int total4) {
    const float inv_n = 1.0f / N_NODES;
    int i = blockIdx.x * 256 + threadIdx.x;
    int stride = gridDim.x * 256;
    for (; i < total4; i += stride) {
        int e0 = i * 4;
        int z = e0 / (N_NODES * DH);
        int j0 = e0 & (DH - 1);
        int zb = z * DH + j0;
        uint2 u = ((uint2*)zp)[i];
        float v[4] = {blo(u.x), bhi(u.x), blo(u.y), bhi(u.y)};
        #pragma unroll
        for (int k = 0; k < 4; ++k) {
            float mu = csum[zb + k] * inv_n;
            float var = csq[zb + k] * inv_n - mu * mu;
            float inv = __builtin_amdgcn_rsqf(var + 1e-5f);
            v[k] = tanh_fast((v[k] - mu) * inv * gamma[zb + k] + beta[zb + k]);
        }
        uint2 o; o.x = pk2(v[0], v[1]); o.y = pk2(v[2], v[3]);
        ((uint2*)zp)[i] = o;
    }
}

// f1 slice of S,P (cols 0..511): thread t -> 2 cols via float2, packed u32 store
__global__ void k_pair0(const int* __restrict__ ei, const int* __restrict__ eid,
                        const float* __restrict__ f1, u16* __restrict__ S,
                        u16* __restrict__ P) {
    int b = blockIdx.x, t = threadIdx.x;
    int e = eid[b];
    int n0 = ei[e], n1 = ei[NE2 + e];
    float2 a = *(const float2*)(f1 + (size_t)n0 * D_INN + t * 2);
    float2 c = *(const float2*)(f1 + (size_t)n1 * D_INN + t * 2);
    ((unsigned int*)(S + (size_t)b * H3))[t] = pk2(a.x + c.x, a.y + c.y);
    ((unsigned int*)(P + (size_t)b * H3))[t] = pk2(a.x * c.x, a.y * c.y);
}

// batched channel slice of S,P from z_ch; 4 edges/block, uint2 lanes
__global__ void k_gather_ch(const int* __restrict__ ei, const int* __restrict__ eid,
                            const u16* __restrict__ zch, u16* __restrict__ S,
                            u16* __restrict__ P, int col0base) {
    int z = blockIdx.y;
    const u16* zp = zch + (size_t)z * N_NODES * DH;
    int col0 = col0base + z * DH;
    int b = blockIdx.x * 4 + (threadIdx.x >> 6);
    int lane = threadIdx.x & 63;
    int e = eid[b];
    int n0 = ei[e], n1 = ei[NE2 + e];
    uint2 ua = *(const uint2*)(zp + (size_t)n0 * DH + lane * 4);
    uint2 ub = *(const uint2*)(zp + (size_t)n1 * DH + lane * 4);
    float a0 = blo(ua.x), a1 = bhi(ua.x), a2 = blo(ua.y), a3 = bhi(ua.y);
    float c0 = blo(ub.x), c1 = bhi(ub.x), c2 = blo(ub.y), c3 = bhi(ub.y);
    uint2 so; so.x = pk2(a0 + c0, a1 + c1); so.y = pk2(a2 + c2, a3 + c3);
    uint2 po; po.x = pk2(a0 * c0, a1 * c1); po.y = pk2(a2 * c2, a3 * c3);
    *(uint2*)(S + (size_t)b * H3 + col0 + lane * 4) = so;
    *(uint2*)(P + (size_t)b * H3 + col0 + lane * 4) = po;
}

__global__ void k_final(const u16* __restrict__ h2, const float* __restrict__ Wf3,
                        const float* __restrict__ bf3, float* __restrict__ out) {
    int r = blockIdx.x, t = threadIdx.x;
    const u16* hr = h2 + (size_t)r * 576;
    float acc[7] = {0, 0, 0, 0, 0, 0, 0};
    for (int cb = t; cb < 576; cb += 64) {
        float h = b2f(hr[cb]);
        #pragma unroll
        for (int o = 0; o < 7; ++o) acc[o] = fmaf(h, Wf3[o * 576 + cb], acc[o]);
    }
    #pragma unroll
    for (int o = 0; o < 7; ++o) {
        #pragma unroll
        for (int off = 32; off > 0; off >>= 1) acc[o] += __shfl_down(acc[o], off, 64);
    }
    if (t == 0) {
        #pragma unroll
        for (int o = 0; o < 7; ++o) out[(size_t)r * 7 + o] = acc[o] + bf3[o];
    }
}

// ===== bf16 MFMA GEMM, BK=64 (batched over z with strides).
// global_load_lds width-16 coalesced staging: per 8-row block, lane l ->
// row l>>3, src chunk (l&7)^(l>>3) (involution with read swizzle); LDS dest
// linear. Fragment ds_read_b128 at row*64 + ((q^(row&7))*8) shorts -> 2-way
// bank alias (free). LDS 32KB, 2 blocks/CU. FULL-GRID 3D bijective XCD swizzle.
// EP: 2=sigmoid->bf16, 3=relu->bf16, 5=bf16, 6=relu->f32,
//     7=bf16 + bias + (1+indeg[row])*cvec[col],
//     8=z==0? sigmoid->bf16 : bf16 (for batched gate/int)
template <int EP>
__global__ __launch_bounds__(256, 2) void k_gemm_mfma(
    const u16* __restrict__ A, const u16* __restrict__ W,
    const float* __restrict__ bias, void* __restrict__ outv,
    const int* __restrict__ rpe, const float* __restrict__ cvec,
    int M, int N, int K, size_t sA, size_t sW, size_t sC, int sBias) {
    __shared__ short As[8192];   // 128 rows x 64 cols bf16
    __shared__ short Ws[8192];
    // 3D bijective XCD swizzle over the whole grid
    const int gx = gridDim.x, gy = gridDim.y;
    const int plane = gx * gy;
    const int total = plane * gridDim.z;
    const int orig = (blockIdx.z * gy + blockIdx.y) * gx + blockIdx.x;
    const int q8 = total >> 3, r8 = total & 7, xcd = orig & 7;
    const int wg = (xcd < r8 ? xcd * (q8 + 1) : r8 * (q8 + 1) + (xcd - r8) * q8) + (orig >> 3);
    const int z = wg / plane;
    const int rem = wg - z * plane;
    const int row0 = (rem / gx) * 128, col0 = (rem % gx) * 128;
    A += (size_t)z * sA;
    W += (size_t)z * sW;
    const size_t zC = (size_t)z * sC;
    const int* rp = (EP == 7) ? rpe + (size_t)z * (N_NODES + 1) : nullptr;
    const float* cv = (EP == 7) ? cvec + (size_t)z * DH : nullptr;
    const int t = threadIdx.x;
    const int lane = t & 63;
    const int w = t >> 6;
    const int wr = w >> 1, wc = w & 1;
    // staging: lane l -> row-in-8block l>>3, src chunk (l&7)^(l>>3)
    const int sr8 = lane >> 3;
    const int csrc = (lane & 7) ^ sr8;
    int gr[4], gc[4];
    #pragma unroll
    for (int p = 0; p < 4; ++p) {
        int rb = w + p * 4;                // 0..15 (8-row blocks)
        gr[p] = row0 + rb * 8 + sr8; if (gr[p] >= M) gr[p] = M - 1;
        gc[p] = col0 + rb * 8 + sr8; if (gc[p] >= N) gc[p] = N - 1;
    }
    const int fr = lane & 15, fq4 = lane >> 4;   // logical chunk q = kk*4 + fq4
    f32x4 acc[4][4] = {};
    for (int k0 = 0; k0 < K; k0 += 64) {
        #pragma unroll
        for (int p = 0; p < 4; ++p) {
            int rb = w + p * 4;
            __builtin_amdgcn_global_load_lds(
                (const __attribute__((address_space(1))) unsigned int*)(A + (size_t)gr[p] * K + k0 + csrc * 8),
                (__attribute__((address_space(3))) unsigned int*)(As + rb * 512), 16, 0, 0);
            __builtin_amdgcn_global_load_lds(
                (const __attribute__((address_space(1))) unsigned int*)(W + (size_t)gc[p] * K + k0 + csrc * 8),
                (__attribute__((address_space(3))) unsigned int*)(Ws + rb * 512), 16, 0, 0);
        }
        __syncthreads();
        bf16x8 af[4][2], bfr[4][2];
        #pragma unroll
        for (int m = 0; m < 4; ++m) {
            int ar = wr * 64 + m * 16 + fr;
            #pragma unroll
            for (int kk = 0; kk < 2; ++kk) {
                int q = kk * 4 + fq4;
                af[m][kk] = *(const bf16x8*)(As + ar * 64 + ((q ^ (ar & 7)) * 8));
            }
        }
        #pragma unroll
        for (int n = 0; n < 4; ++n) {
            int br = wc * 64 + n * 16 + fr;
            #pragma unroll
            for (int kk = 0; kk < 2; ++kk) {
                int q = kk * 4 + fq4;
                bfr[n][kk] = *(const bf16x8*)(Ws + br * 64 + ((q ^ (br & 7)) * 8));
            }
        }
        #pragma unroll
        for (int m = 0; m < 4; ++m)
            #pragma unroll
            for (int n = 0; n < 4; ++n)
                #pragma unroll
                for (int kk = 0; kk < 2; ++kk)
                    acc[m][n] = __builtin_amdgcn_mfma_f32_16x16x32_bf16(
                        af[m][kk], bfr[n][kk], acc[m][n], 0, 0, 0);
        __syncthreads();
    }
    const int cl = lane & 15, rh = (lane >> 4) * 4;
    #pragma unroll
    for (int m = 0; m < 4; ++m) {
        float indf[4];
        if (EP == 7) {
            #pragma unroll
            for (int r = 0; r < 4; ++r) {
                int row = row0 + wr * 64 + m * 16 + rh + r;
                if (row >= M) row = M - 1;
                indf[r] = 1.0f + (float)(rp[row + 1] - rp[row]);
            }
        }
        #pragma unroll
        for (int n = 0; n < 4; ++n) {
            int col = col0 + wc * 64 + n * 16 + cl;
            if (col >= N) continue;
            float bv = bias ? bias[z * sBias + col] : 0.0f;
            float cvc = (EP == 7) ? cv[col] : 0.0f;
            #pragma unroll
            for (int r = 0; r < 4; ++r) {
                int row = row0 + wr * 64 + m * 16 + rh + r;
                if (row >= M) continue;
                float v = acc[m][n][r] + bv;
                size_t idx = zC + (size_t)row * N + col;
                if (EP == 2) ((u16*)outv)[idx] = f2b(sigmoid_fast(v));
                if (EP == 3) ((u16*)outv)[idx] = f2b(fmaxf(v, 0.0f));
                if (EP == 5) ((u16*)outv)[idx] = f2b(v);
                if (EP == 6) ((float*)outv)[idx] = fmaxf(v, 0.0f);
                if (EP == 7) ((u16*)outv)[idx] = f2b(v + indf[r] * cvc);
                if (EP == 8) ((u16*)outv)[idx] = (z == 0) ? f2b(sigmoid_fast(v)) : f2b(v);
            }
        }
    }
}

static inline void gemm_b(int ep, const u16* A, const u16* W, const float* bias, void* out,
                          const int* rpe, const float* cvec,
                          int M, int N, int K, int Z,
                          size_t sA, size_t sW, size_t sC, int sBias, hipStream_t st) {
    dim3 g((N + 127) / 128, (M + 127) / 128, Z);
    switch (ep) {
        case 2: k_gemm_mfma<2><<<g, 256, 0, st>>>(A, W, bias, out, rpe, cvec, M, N, K, sA, sW, sC, sBias); break;
        case 3: k_gemm_mfma<3><<<g, 256, 0, st>>>(A, W, bias, out, rpe, cvec, M, N, K, sA, sW, sC, sBias); break;
        case 5: k_gemm_mfma<5><<<g, 256, 0, st>>>(A, W, bias, out, rpe, cvec, M, N, K, sA, sW, sC, sBias); break;
        case 6: k_gemm_mfma<6><<<g, 256, 0, st>>>(A, W, bias, out, rpe, cvec, M, N, K, sA, sW, sC, sBias); break;
        case 7: k_gemm_mfma<7><<<g, 256, 0, st>>>(A, W, bias, out, rpe, cvec, M, N, K, sA, sW, sC, sBias); break;
        case 8: k_gemm_mfma<8><<<g, 256, 0, st>>>(A, W, bias, out, rpe, cvec, M, N, K, sA, sW, sC, sBias); break;
    }
}

static inline void conv_w(const float* s, u16* d, size_t n, hipStream_t st) {
    int n4 = (int)(n / 4);
    int grid = (n4 + 255) / 256;
    if (grid > 2048) grid = 2048;
    k_f2b<<<grid, 256, 0, st>>>(s, d, n4);
}

extern "C" void kernel_launch(void* const* d_in, const int* in_sizes, int n_in, void* d_out,
                              int out_size, void* d_ws, size_t ws_size, hipStream_t stream) {
    const float* f1 = (const float*)d_in[0];
    const int* adj_src = (const int*)d_in[1];
    const int* adj_dst = (const int*)d_in[2];
    const float* adj_val = (const float*)d_in[3];
    const int* edge_src = (const int*)d_in[4];
    const int* edge_dst = (const int*)d_in[5];
    const int* edge_index = (const int*)d_in[6];
    const int* edge_id = (const int*)d_in[7];
    const float* W_hyp = (const float*)d_in[8];
    const float* b_hyp = (const float*)d_in[9];
    const float* Wd = (const float*)d_in[10];
    const float* bd = (const float*)d_in[11];
    const float* Wg1 = (const float*)d_in[12];
    const float* bg1 = (const float*)d_in[13];
    const float* gamma = (const float*)d_in[14];
    const float* beta = (const float*)d_in[15];
    const float* Wg2 = (const float*)d_in[16];
    const float* bg2 = (const float*)d_in[17];
    const float* Wgate = (const float*)d_in[18];
    const float* bgate = (const float*)d_in[19];
    const float* Wint = (const float*)d_in[20];
    const float* bint = (const float*)d_in[21];
    const float* Wout = (const float*)d_in[22];
    const float* bout = (const float*)d_in[23];
    const float* Wf1 = (const float*)d_in[24];
    const float* bf1 = (const float*)d_in[25];
    const float* Wf2 = (const float*)d_in[26];
    const float* bf2 = (const float*)d_in[27];
    const float* Wf3 = (const float*)d_in[28];
    const float* bf3 = (const float*)d_in[29];
    float* outp = (float*)d_out;

    // Single Z=7 group if workspace allows. Footprint (CSR aliased into the
    // S_b/P_b regions, which are only written post-GNN in single mode)
    // = 253.29 MB; R2's proven-working layout implies ws_size >= 253.48 MB,
    // so this engages with verified margin. 2-group (4+3) fallback kept.
    const bool single = ws_size >= 253400000ull;
    const int ngroups = single ? 1 : 2;
    const int GM = single ? 7 : 4;
    int g0s[2] = {0, 4};
    int gns[2] = {GM, 3};

    // ---- workspace bump allocator ----
    char* base = (char*)d_ws;
    size_t off = 0;
    auto alloc = [&](size_t bytes) -> char* {
        char* p = base + off;
        off += (bytes + 255) & ~(size_t)255;
        return p;
    };
    u16* Whyp_b = (u16*)alloc((size_t)NCH * DH * D_INN * 2);
    u16* Wc_b   = (u16*)alloc((size_t)NCH * DH * DH * 2);   // Wg1 @ Wd
    u16* Wg1_b  = (u16*)alloc((size_t)NCH * DH * DH * 2);
    u16* Wg2_b  = (u16*)alloc((size_t)NCH * DH * DH * 2);
    u16* Wgate_b = (u16*)alloc((size_t)H3 * H3 * 2);        // Wint_b must follow!
    u16* Wint_b  = (u16*)alloc((size_t)H3 * H3 * 2);
    u16* Wcomb_b = (u16*)alloc((size_t)1152 * H3 * 2);      // Wf1 @ Wout
    u16* Wf2_b   = (u16*)alloc((size_t)576 * 1152 * 2);
    u16* S_b = (u16*)alloc((size_t)NB * H3 * 2);            // P_b must follow!
    u16* P_b = (u16*)alloc((size_t)NB * H3 * 2);
    const size_t NDB = (size_t)N_NODES * DH;       // per-channel elems
    u16* buf1 = (u16*)alloc((size_t)GM * NDB * 2); // group ping (buf2 follows)
    u16* buf2 = (u16*)alloc((size_t)GM * NDB * 2); // group pong
    // xhyp: in single mode alias buf2 head (dead before buf2 first written);
    // in 2-group mode it must persist across groups -> separate.
    u16* xhyp_b = single ? buf2 : (u16*)alloc((size_t)N_NODES * D_INN * 2);
    // CSR scratch (2*GM slices): adj slices [0,G), edge slices [G,2G).
    // Single mode: alias into S_b (padj+psrcE = 26.9MB <= 37.75) and P_b
    // (cnt+rowptr = 2.24MB) -- safe because S/P are written only after the
    // last CSR consumer (pair0/gather_ch moved post-GNN).
    int* cntC; int* rowptrC; uint2* padjC; int* psrcE;
    if (single) {
        padjC = (uint2*)S_b;                                   // 17,920,000 B
        psrcE = (int*)((char*)S_b + (size_t)GM * NE * 8);      // +8,960,000 B
        cntC = (int*)P_b;                                      // 1,120,000 B
        rowptrC = (int*)((char*)P_b + (size_t)2 * GM * N_NODES * 4);
    } else {
        cntC = (int*)alloc((size_t)2 * GM * N_NODES * 4);
        rowptrC = (int*)alloc((size_t)2 * GM * (N_NODES + 1) * 4);
        padjC = (uint2*)alloc((size_t)GM * NE * 8);
        psrcE = (int*)alloc((size_t)GM * NE * 4);
    }
    float* xhn = (float*)alloc((size_t)N_NODES * 4);
    float* hb = (float*)alloc((size_t)NCH * DH * 4);
    float* hb2 = (float*)alloc(NCH * 4);
    float* csum = (float*)alloc((size_t)GM * DH * 4);        // csq follows
    float* csq = (float*)alloc((size_t)GM * DH * 4);
    float* cvec_d = (float*)alloc((size_t)NCH * DH * 4);
    float* bias2 = (float*)alloc((size_t)2 * H3 * 4);
    float* bcomb = (float*)alloc((size_t)1152 * 4);
    // precompute-only temp weights alias into buf1 (idle until GNN phase):
    u16* WoutT_b = buf1;                          // 10.62 MB
    u16* Wf1_b = buf1 + (size_t)H3 * H3;          // +5.31 MB
    u16* Wdt_b = Wf1_b + (size_t)1152 * H3;       // +0.92 MB (total 16.8 <= buf1)
    // stage-C overlays (GNN buffers dead by then): GT spans buf1(+buf2 head);
    // h1 -> buf1 head after k_gi; h2 (bf16) -> buf2 head.
    u16* GT = buf1;
    u16* h2b = buf2;

    const int EG = (NE + 255) / 256;

    conv_w(W_hyp, Whyp_b, (size_t)NCH * DH * D_INN, stream);
    conv_w(Wg1, Wg1_b, (size_t)NCH * DH * DH, stream);
    conv_w(Wg2, Wg2_b, (size_t)NCH * DH * DH, stream);
    conv_w(Wgate, Wgate_b, (size_t)H3 * H3, stream);
    conv_w(Wint, Wint_b, (size_t)H3 * H3, stream);
    conv_w(Wf1, Wf1_b, (size_t)1152 * H3, stream);
    conv_w(Wf2, Wf2_b, (size_t)576 * 1152, stream);
    k_bias2<<<(2 * H3 + 255) / 256, 256, 0, stream>>>(bgate, bint, bias2);
    // Wc = Wg1 @ Wd (via Wd^T), cvec = Wg1 @ bd
    k_twd<<<dim3(16, 16, NCH), 256, 0, stream>>>(Wd, Wdt_b);
    gemm_b(5, Wg1_b, Wdt_b, nullptr, Wc_b, nullptr, nullptr,
           DH, DH, DH, NCH, (size_t)DH * DH, (size_t)DH * DH, (size_t)DH * DH, 0, stream);
    k_cvec<<<NCH, 256, 0, stream>>>(Wg1, bd, cvec_d);
    // Wcomb = Wf1 @ Wout (Wout GEMM folded into Wf1), bcomb = Wf1@bout + bf1
    k_tr<<<dim3(144, 144), 256, 0, stream>>>(Wout, WoutT_b);
    gemm_b(5, Wf1_b, WoutT_b, nullptr, Wcomb_b, nullptr, nullptr,
           1152, H3, H3, 1, 0, 0, 0, 0, stream);
    k_bvec<<<1152 / 4, 256, 0, stream>>>(Wf1, bout, bf1, bcomb);

    k_expmap_proj_in<<<N_NODES, 256, 0, stream>>>(f1, xhyp_b, xhn);
    k_hb<<<NCH, 256, 0, stream>>>(b_hyp, hb, hb2);
    if (!single) k_pair0<<<NB, 256, 0, stream>>>(edge_index, edge_id, f1, S_b, P_b);

    for (int gi = 0; gi < ngroups; ++gi) {
        const int g0 = g0s[gi], G = gns[gi];
        const size_t eoff = (size_t)g0 * NE;
        const int G2 = 2 * G;
        const int* rpE = rowptrC + (size_t)G * (N_NODES + 1);
        // --- merged CSR build (both graphs, one launch set) ---
        k_izero<<<(G2 * N_NODES + 255) / 256, 256, 0, stream>>>(cntC, G2 * N_NODES);
        k_hist2<<<dim3(EG, G2), 256, 0, stream>>>(adj_dst + eoff, edge_dst + eoff, cntC, G);
        k_scan<<<G2, 256, 0, stream>>>(cntC, rowptrC);
        k_place2<<<dim3(EG, G2), 256, 0, stream>>>(adj_src + eoff, adj_dst + eoff,
                                                   adj_val + eoff, edge_src + eoff,
                                                   edge_dst + eoff, cntC, padjC, psrcE, G);
        // --- batched pipeline ---
        gemm_b(5, xhyp_b, Whyp_b + (size_t)g0 * DH * D_INN, nullptr, buf1, nullptr,
               nullptr, N_NODES, DH, D_INN, G, 0, (size_t)DH * D_INN, NDB, 0, stream);
        k_rowfuse1<<<dim3(N_NODES / 4, G), 256, 0, stream>>>(buf1, xhn, hb + g0 * DH, hb2 + g0);
        k_gather_fuse2<<<dim3(N_NODES / 4, G), 256, 0, stream>>>(rowptrC, padjC, buf1, buf2);
        // ug = (I + S_e) u
        k_gather_add<<<dim3(N_NODES / 4, G), 256, 0, stream>>>(rpE, psrcE, buf2, buf1);
        // z = ug @ Wc^T + (1+indeg)*cvec + bg1   (Wd GEMM fused away)
        gemm_b(7, buf1, Wc_b + (size_t)g0 * DH * DH, bg1 + g0 * DH, buf2,
               rpE, cvec_d + (size_t)g0 * DH, N_NODES, DH, DH, G,
               NDB, (size_t)DH * DH, NDB, DH, stream);
        k_zero<<<(2 * GM * DH + 255) / 256, 256, 0, stream>>>(csum, 2 * GM * DH);
        k_colstats<<<dim3(200, G), 256, 0, stream>>>(buf2, csum, csq);
        {
            int total4 = (int)(G * NDB / 4);
            int blocks = (total4 + 255) / 256;
            if (blocks > 2048) blocks = 2048;
            k_normtanh_v<<<blocks, 256, 0, stream>>>(buf2, csum, csq, gamma + g0 * DH,
                                                     beta + g0 * DH, total4);
        }
        gemm_b(5, buf2, Wg2_b + (size_t)g0 * DH * DH, bg2 + g0 * DH, buf1, nullptr,
               nullptr, N_NODES, DH, DH, G, NDB, (size_t)DH * DH, NDB, DH, stream);
        if (!single)
            k_gather_ch<<<dim3(NB / 4, G), 256, 0, stream>>>(edge_index, edge_id, buf1,
                                                             S_b, P_b, D_INN + g0 * DH);
    }
    if (single) {
        // CSR scratch (aliased in S_b/P_b) is dead now; build S,P.
        k_pair0<<<NB, 256, 0, stream>>>(edge_index, edge_id, f1, S_b, P_b);
        k_gather_ch<<<dim3(NB / 4, 7), 256, 0, stream>>>(edge_index, edge_id, buf1,
                                                         S_b, P_b, D_INN);
    }

    // stage C: batched gate/int (Z=2), gi elementwise, fused h1 (Wout folded
    // into Wf1 via Wcomb), h2 (bf16), final.
    gemm_b(8, S_b, Wgate_b, bias2, GT, nullptr, nullptr, NB, H3, H3, 2,
           (size_t)NB * H3, (size_t)H3 * H3, (size_t)NB * H3, H3, stream);
    {
        int total4 = NB * H3 / 4;
        int blocks = (total4 + 255) / 256;
        if (blocks > 2048) blocks = 2048;
        k_gi<<<blocks, 256, 0, stream>>>(GT, GT + (size_t)NB * H3, S_b, total4);
    }
    // h1 = relu(gi @ Wcomb^T + bcomb)
    gemm_b(3, S_b, Wcomb_b, bcomb, buf1, nullptr, nullptr, NB, 1152, H3, 1, 0, 0, 0, 0, stream);
    // h2 = relu(h1 @ Wf2^T + bf2) -> bf16
    gemm_b(3, buf1, Wf2_b, bf2, h2b, nullptr, nullptr, NB, 576, 1152, 1, 0, 0, 0, 0, stream);
    k_final<<<NB, 64, 0, stream>>>(h2b, Wf3, bf3, outp);
}

// Round 17
// 1526.557 us; speedup vs baseline: 1.5310x; 1.0486x over previous
//
#include <hip/hip_runtime.h>
#include <math.h>

#define N_NODES 20000
#define D_INN   512
#define DH      256
#define NCH     7
#define NE      320000
#define NE2     100000
#define NB      8192
#define H3      2304   // 512 + 7*256
#define MAXN    0.996f
#define LOG2E   1.44269504f
#define NBUK    40     // dst buckets of 512 nodes
#define BSH     9

typedef unsigned short u16;
typedef __attribute__((ext_vector_type(8))) short bf16x8;
typedef __attribute__((ext_vector_type(4))) float f32x4;

__device__ __forceinline__ u16 f2b(float f) {    // RNE f32 -> bf16 bits
    unsigned int x = __float_as_uint(f);
    unsigned int r = (x + 0x7fffu + ((x >> 16) & 1u)) >> 16;
    return (u16)r;
}
__device__ __forceinline__ float b2f(u16 u) {
    return __uint_as_float(((unsigned int)u) << 16);
}
__device__ __forceinline__ float blo(unsigned int u) { return __uint_as_float(u << 16); }
__device__ __forceinline__ float bhi(unsigned int u) { return __uint_as_float(u & 0xffff0000u); }
__device__ __forceinline__ unsigned int pk2(float a, float b) {
    return (unsigned int)f2b(a) | ((unsigned int)f2b(b) << 16);
}

// ---- fast HW transcendentals (rel err ~1e-5, fine for bf16 tolerance) ----
__device__ __forceinline__ float rcp_f(float x) { return __builtin_amdgcn_rcpf(x); }
__device__ __forceinline__ float exp2_f(float x) { return __builtin_amdgcn_exp2f(x); }
__device__ __forceinline__ float log2_f(float x) { return __builtin_amdgcn_logf(x); }
__device__ __forceinline__ float tanh_fast(float x) {
    float xc = fminf(fmaxf(x, -15.f), 15.f);
    float t = exp2_f(xc * (2.f * LOG2E));
    return (t - 1.f) * rcp_f(t + 1.f);
}
__device__ __forceinline__ float artanh_fast(float x) {
    x = fminf(fmaxf(x, -1.0f + 1e-7f), 1.0f - 1e-7f);
    return 0.34657359f * log2_f((1.f + x) * rcp_f(1.f - x));
}
__device__ __forceinline__ float sigmoid_fast(float x) {
    return rcp_f(1.f + exp2_f(-x * LOG2E));
}

__device__ __forceinline__ float wave_sum(float v) {
    #pragma unroll
    for (int off = 32; off > 0; off >>= 1) v += __shfl_xor(v, off, 64);
    return v;
}

__device__ __forceinline__ float block_sum256(float v) {
    __shared__ float sred[4];
    #pragma unroll
    for (int off = 32; off > 0; off >>= 1) v += __shfl_down(v, off, 64);
    int lane = threadIdx.x & 63;
    int w = threadIdx.x >> 6;
    if (lane == 0) sred[w] = v;
    __syncthreads();
    float tot = sred[0] + sred[1] + sred[2] + sred[3];
    __syncthreads();
    return tot;
}

__global__ void k_zero(float* __restrict__ p, int n) {
    int i = blockIdx.x * 256 + threadIdx.x;
    if (i < n) p[i] = 0.0f;
}
__global__ void k_izero(int* __restrict__ p, int n) {
    int i = blockIdx.x * 256 + threadIdx.x;
    if (i < n) p[i] = 0;
}

__global__ void k_f2b(const float* __restrict__ s, u16* __restrict__ d, int n4) {
    int i = blockIdx.x * 256 + threadIdx.x;
    int stride = gridDim.x * 256;
    for (; i < n4; i += stride) {
        float4 v = ((const float4*)s)[i];
        uint2 o; o.x = pk2(v.x, v.y); o.y = pk2(v.z, v.w);
        ((uint2*)d)[i] = o;
    }
}

// pack two bias vectors contiguously (for batched gate/int GEMM)
__global__ void k_bias2(const float* __restrict__ a, const float* __restrict__ b,
                        float* __restrict__ o) {
    int i = blockIdx.x * 256 + threadIdx.x;
    if (i < H3) o[i] = a[i];
    else if (i < 2 * H3) o[i] = b[i - H3];
}

// gi = gate * relu(tmp), all bf16, vectorized
__global__ void k_gi(const u16* __restrict__ gate, const u16* __restrict__ tmp,
                     u16* __restrict__ out, int total4) {
    int i = blockIdx.x * 256 + threadIdx.x;
    int stride = gridDim.x * 256;
    for (; i < total4; i += stride) {
        uint2 g = ((const uint2*)gate)[i];
        uint2 t = ((const uint2*)tmp)[i];
        uint2 o;
        o.x = pk2(blo(g.x) * fmaxf(blo(t.x), 0.f), bhi(g.x) * fmaxf(bhi(t.x), 0.f));
        o.y = pk2(blo(g.y) * fmaxf(blo(t.y), 0.f), bhi(g.y) * fmaxf(bhi(t.y), 0.f));
        ((uint2*)out)[i] = o;
    }
}

// Wd transpose -> bf16 (for Wc = Wg1 @ Wd via A@W^T kernel)
__global__ void k_twd(const float* __restrict__ Wd, u16* __restrict__ Wdt) {
    __shared__ float tile[16][17];
    int z = blockIdx.z;
    int bx = blockIdx.x * 16, by = blockIdx.y * 16;
    int tx = threadIdx.x & 15, ty = threadIdx.x >> 4;
    tile[ty][tx] = Wd[(size_t)z * DH * DH + (size_t)(by + ty) * DH + bx + tx];
    __syncthreads();
    Wdt[(size_t)z * DH * DH + (size_t)(bx + ty) * DH + by + tx] = f2b(tile[tx][ty]);
}

// 2304x2304 transpose f32 -> bf16 (WoutT[i][j] = Wout[j][i])
__global__ void k_tr(const float* __restrict__ Win, u16* __restrict__ Wt) {
    __shared__ float tile[16][17];
    int bx = blockIdx.x * 16, by = blockIdx.y * 16;
    int tx = threadIdx.x & 15, ty = threadIdx.x >> 4;
    tile[ty][tx] = Win[(size_t)(by + ty) * H3 + bx + tx];
    __syncthreads();
    Wt[(size_t)(bx + ty) * H3 + by + tx] = f2b(tile[tx][ty]);
}

// bcomb[r] = sum_j Wf1[r][j]*bout[j] + bf1[r]  (wave per row, 4 rows/block)
__global__ void k_bvec(const float* __restrict__ Wf1, const float* __restrict__ bout,
                       const float* __restrict__ bf1, float* __restrict__ bcomb) {
    int r = blockIdx.x * 4 + (threadIdx.x >> 6);
    int lane = threadIdx.x & 63;
    const float* row = Wf1 + (size_t)r * H3;
    float s = 0.f;
    for (int j = lane; j < H3; j += 64) s = fmaf(row[j], bout[j], s);
    s = wave_sum(s);
    if (lane == 0) bcomb[r] = s + bf1[r];
}

// cvec[z][j] = sum_k Wg1[z][j][k] * bd[z][k]   (f32)
__global__ void k_cvec(const float* __restrict__ Wg1, const float* __restrict__ bd,
                       float* __restrict__ cvec) {
    int z = blockIdx.x, j = threadIdx.x;
    const float* row = Wg1 + (size_t)z * DH * DH + (size_t)j * DH;
    const float* b = bd + (size_t)z * DH;
    float s = 0.f;
    for (int k = 0; k < DH; ++k) s = fmaf(row[k], b[k], s);
    cvec[(size_t)z * DH + j] = s;
}

// ===== merged CSR build: 2G z-slices (z<G: adj graph, z>=G: edge graph) =====
__global__ void k_hist2(const int* __restrict__ adjd, const int* __restrict__ edged,
                        int* __restrict__ cnt, int G) {
    int z = blockIdx.y;
    const int* dst = (z < G) ? adjd + (size_t)z * NE : edged + (size_t)(z - G) * NE;
    cnt += (size_t)z * N_NODES;
    int i = blockIdx.x * 256 + threadIdx.x;
    if (i < NE) atomicAdd(&cnt[dst[i]], 1);
}

// one block per slice; cnt becomes the cursor array in-place
__global__ void k_scan(int* __restrict__ cnt, int* __restrict__ rowptr) {
    int z = blockIdx.x;
    cnt += (size_t)z * N_NODES;
    rowptr += (size_t)z * (N_NODES + 1);
    __shared__ int part[256];
    int t = threadIdx.x;
    const int CH = (N_NODES + 255) / 256;
    int beg = t * CH;
    int end = beg + CH; if (end > N_NODES) end = N_NODES;
    int s = 0;
    for (int i = beg; i < end; ++i) s += cnt[i];
    part[t] = s;
    __syncthreads();
    for (int off = 1; off < 256; off <<= 1) {
        int v = (t >= off) ? part[t - off] : 0;
        __syncthreads();
        part[t] += v;
        __syncthreads();
    }
    int run = (t == 0) ? 0 : part[t - 1];
    for (int i = beg; i < end; ++i) {
        int c = cnt[i];
        rowptr[i] = run;
        cnt[i] = run;      // cursor init (in-place)
        run += c;
    }
    if (t == 255) rowptr[N_NODES] = part[255];
}

// legacy 1-phase place (2-group fallback path)
__global__ void k_place2(const int* __restrict__ adjs, const int* __restrict__ adjd,
                         const float* __restrict__ adjv, const int* __restrict__ edges,
                         const int* __restrict__ edged, int* __restrict__ cursor,
                         uint2* __restrict__ padj, int* __restrict__ psrcE, int G) {
    int z = blockIdx.y;
    bool isadj = z < G;
    const int* src = isadj ? adjs + (size_t)z * NE : edges + (size_t)(z - G) * NE;
    const int* dst = isadj ? adjd + (size_t)z * NE : edged + (size_t)(z - G) * NE;
    cursor += (size_t)z * N_NODES;
    int i = blockIdx.x * 256 + threadIdx.x;
    if (i < NE) {
        int d = dst[i];
        int pos = atomicAdd(&cursor[d], 1);
        if (isadj) {
            uint2 p;
            p.x = (unsigned int)src[i];
            p.y = __float_as_uint(adjv[(size_t)z * NE + i]);
            padj[(size_t)z * NE + pos] = p;
        } else {
            psrcE[(size_t)(z - G) * NE + pos] = src[i];
        }
    }
}

// bucket cursors init: bcur[z][b] = rowptr[z][b*512]
__global__ void k_bcur(const int* __restrict__ rowptr, int* __restrict__ bcur, int G2) {
    int i = blockIdx.x * 256 + threadIdx.x;
    if (i < G2 * NBUK) {
        int z = i / NBUK, b = i - z * NBUK;
        bcur[i] = rowptr[(size_t)z * (N_NODES + 1) + (b << BSH)];
    }
}

// phase A: bin edges into bucket-contiguous scratch (regions = final CSR
// bucket ranges). LDS-aggregated claims: one global atomic per bucket/block,
// writes land in ~contiguous runs. (src,dst) packed 15+15 bits.
__global__ void k_binA(const int* __restrict__ adjs, const int* __restrict__ adjd,
                       const float* __restrict__ adjv, const int* __restrict__ edges,
                       const int* __restrict__ edged, int* __restrict__ bcur,
                       uint2* __restrict__ scrA, unsigned int* __restrict__ scrE, int G) {
    int z = blockIdx.y;
    bool isadj = z < G;
    const int* src = isadj ? adjs + (size_t)z * NE : edges + (size_t)(z - G) * NE;
    const int* dst = isadj ? adjd + (size_t)z * NE : edged + (size_t)(z - G) * NE;
    __shared__ int hcnt[NBUK];
    __shared__ int gbase[NBUK];
    int t = threadIdx.x;
    int i = blockIdx.x * 256 + t;
    if (t < NBUK) hcnt[t] = 0;
    __syncthreads();
    int s = 0, d = 0, buk = 0, rank = 0;
    bool valid = i < NE;
    if (valid) {
        s = src[i]; d = dst[i];
        buk = d >> BSH;
        rank = atomicAdd(&hcnt[buk], 1);
    }
    __syncthreads();
    if (t < NBUK && hcnt[t] > 0)
        gbase[t] = atomicAdd(&bcur[z * NBUK + t], hcnt[t]);
    __syncthreads();
    if (valid) {
        int pos = gbase[buk] + rank;
        unsigned int sd = (unsigned int)s | ((unsigned int)d << 15);
        if (isadj) {
            uint2 p; p.x = sd; p.y = __float_as_uint(adjv[(size_t)z * NE + i]);
            scrA[(size_t)z * NE + pos] = p;
        } else {
            scrE[(size_t)(z - G) * NE + pos] = sd;
        }
    }
}

// phase B: one block per (bucket, z). LDS cursors for the bucket's 512 nodes;
// reads coalesced from bucket region; final scatter confined to the bucket's
// ~64KB CSR window (L2-absorbed).
__global__ void k_placeB(const int* __restrict__ rowptr, const uint2* __restrict__ scrA,
                         const unsigned int* __restrict__ scrE, uint2* __restrict__ padj,
                         int* __restrict__ psrcE, int G) {
    int z = blockIdx.y;
    int b = blockIdx.x;
    bool isadj = z < G;
    const int* rp = rowptr + (size_t)z * (N_NODES + 1);
    __shared__ int cur[512];
    int t = threadIdx.x;
    int n0 = b << BSH;
    for (int k = t; k < 512; k += 256) {
        int node = n0 + k;
        cur[k] = (node < N_NODES) ? rp[node] : 0;
    }
    __syncthreads();
    int beg = rp[n0];
    int nend = n0 + 512; if (nend > N_NODES) nend = N_NODES;
    int end = rp[nend];
    if (isadj) {
        const uint2* sc = scrA + (size_t)z * NE;
        uint2* out = padj + (size_t)z * NE;
        for (int i = beg + t; i < end; i += 256) {
            uint2 p = sc[i];
            int d = (int)((p.x >> 15) & 0x7fffu);
            int pos = atomicAdd(&cur[d - n0], 1);
            uint2 o; o.x = p.x & 0x7fffu; o.y = p.y;
            out[pos] = o;
        }
    } else {
        const unsigned int* sc = scrE + (size_t)(z - G) * NE;
        int* out = psrcE + (size_t)(z - G) * NE;
        for (int i = beg + t; i < end; i += 256) {
            unsigned int p = sc[i];
            int d = (int)((p >> 15) & 0x7fffu);
            int pos = atomicAdd(&cur[d - n0], 1);
            out[pos] = (int)(p & 0x7fffu);
        }
    }
}

// x_hyp = proj(expmap0(f1)) -> bf16; clamped row norm -> xhn (f32)
__global__ void k_expmap_proj_in(const float* __restrict__ f1,
                                 u16* __restrict__ xhyp, float* __restrict__ xhn) {
    int r = blockIdx.x, t = threadIdx.x;
    const float* u = f1 + (size_t)r * D_INN;
    float v0 = u[t], v1 = u[t + 256];
    float ss = block_sum256(v0 * v0 + v1 * v1);
    float nraw = sqrtf(ss);
    float n = fmaxf(nraw, 1e-15f);
    float c = tanh_fast(n) * rcp_f(n);
    float ny = c * nraw;
    float np = fmaxf(ny, 1e-15f);
    float s = (np > MAXN) ? MAXN * rcp_f(np) : 1.0f;
    float cs = c * s;
    u16* o = xhyp + (size_t)r * D_INN;
    o[t] = f2b(cs * v0);
    o[t + 256] = f2b(cs * v1);
    if (t == 0) xhn[r] = fminf(np, MAXN);
}

__global__ void k_hb(const float* __restrict__ b_hyp,
                     float* __restrict__ hb, float* __restrict__ hb2) {
    int i = blockIdx.x, t = threadIdx.x;
    float v = b_hyp[i * DH + t];
    float ss = block_sum256(v * v);
    float nraw = sqrtf(ss);
    float n = fmaxf(nraw, 1e-15f);
    float c = tanh_fast(n) * rcp_f(n);
    float ny = c * nraw;
    float np = fmaxf(ny, 1e-15f);
    float s = (np > MAXN) ? MAXN * rcp_f(np) : 1.0f;
    float hv = c * s * v;
    hb[i * DH + t] = hv;
    float s2 = block_sum256(hv * hv);
    if (t == 0) hb2[i] = s2;
}

// wave-per-node (4 nodes/block), lane = 4 feats via uint2; in-place bf16.
__global__ void k_rowfuse1(u16* __restrict__ T, const float* __restrict__ xhn,
                           const float* __restrict__ hb, const float* __restrict__ hb2) {
    int z = blockIdx.y;
    int n = blockIdx.x * 4 + (threadIdx.x >> 6);
    int lane = threadIdx.x & 63;
    u16* row = T + ((size_t)z * N_NODES + n) * DH;
    const float* hbz = hb + (size_t)z * DH;
    uint2 u = *(const uint2*)(row + lane * 4);
    float m0 = blo(u.x), m1 = bhi(u.x), m2 = blo(u.y), m3 = bhi(u.y);
    float ss = wave_sum(m0 * m0 + m1 * m1 + m2 * m2 + m3 * m3);
    float mxn_raw = sqrtf(ss);
    float mxn = fmaxf(mxn_raw, 1e-15f);
    float xn = xhn[n];
    float tt = tanh_fast(mxn * rcp_f(xn) * artanh_fast(xn));
    float coef = tt * rcp_f(mxn);
    float nres = coef * mxn_raw;
    float np = fmaxf(nres, 1e-15f);
    float s1 = (np > MAXN) ? MAXN * rcp_f(np) : 1.0f;
    float cs = coef * s1;
    float r0 = cs * m0, r1 = cs * m1, r2 = cs * m2, r3 = cs * m3;
    float n1 = fminf(np, MAXN);
    float4 hv = *(const float4*)(hbz + lane * 4);
    float xy = wave_sum(r0 * hv.x + r1 * hv.y + r2 * hv.z + r3 * hv.w);
    float x2 = n1 * n1, y2 = hb2[z];
    float ca = 1.0f + 2.0f * xy + y2;
    float cb = 1.0f - x2;
    float rden = rcp_f(fmaxf(1.0f + 2.0f * xy + x2 * y2, 1e-15f));
    float o0 = (ca * r0 + cb * hv.x) * rden;
    float o1 = (ca * r1 + cb * hv.y) * rden;
    float o2 = (ca * r2 + cb * hv.z) * rden;
    float o3 = (ca * r3 + cb * hv.w) * rden;
    float no2 = wave_sum(o0 * o0 + o1 * o1 + o2 * o2 + o3 * o3);
    float nop = fmaxf(sqrtf(no2), 1e-15f);
    float s2 = (nop > MAXN) ? MAXN * rcp_f(nop) : 1.0f;
    float n2 = fminf(nop, MAXN);
    float fin = artanh_fast(n2) * rcp_f(n2) * s2;
    uint2 o; o.x = pk2(fin * o0, fin * o1); o.y = pk2(fin * o2, fin * o3);
    *(uint2*)(row + lane * 4) = o;
}

// wave-per-node CSR gather (packed (src,val)), 2-way ILP unroll, + fused
// rowfuse2 hyperbolic chain -> bf16 out
__global__ void k_gather_fuse2(const int* __restrict__ rowptr, const uint2* __restrict__ padj,
                               const u16* __restrict__ xt, u16* __restrict__ out) {
    int z = blockIdx.y;
    rowptr += (size_t)z * (N_NODES + 1);
    padj += (size_t)z * NE;
    xt += (size_t)z * N_NODES * DH;
    out += (size_t)z * N_NODES * DH;
    int n = blockIdx.x * 4 + (threadIdx.x >> 6);
    int lane = threadIdx.x & 63;
    int beg = rowptr[n], end = rowptr[n + 1];
    float a0 = 0.f, a1 = 0.f, a2 = 0.f, a3 = 0.f;
    float b0 = 0.f, b1 = 0.f, b2 = 0.f, b3 = 0.f;
    int i = beg;
    for (; i + 2 <= end; i += 2) {
        uint2 p0 = padj[i];
        uint2 p1 = padj[i + 1];
        uint2 x0 = *(const uint2*)(xt + (size_t)p0.x * DH + lane * 4);
        uint2 x1 = *(const uint2*)(xt + (size_t)p1.x * DH + lane * 4);
        float v0 = __uint_as_float(p0.y), v1 = __uint_as_float(p1.y);
        a0 = fmaf(v0, blo(x0.x), a0);
        a1 = fmaf(v0, bhi(x0.x), a1);
        a2 = fmaf(v0, blo(x0.y), a2);
        a3 = fmaf(v0, bhi(x0.y), a3);
        b0 = fmaf(v1, blo(x1.x), b0);
        b1 = fmaf(v1, bhi(x1.x), b1);
        b2 = fmaf(v1, blo(x1.y), b2);
        b3 = fmaf(v1, bhi(x1.y), b3);
    }
    if (i < end) {
        uint2 p = padj[i];
        uint2 x0 = *(const uint2*)(xt + (size_t)p.x * DH + lane * 4);
        float v = __uint_as_float(p.y);
        a0 = fmaf(v, blo(x0.x), a0);
        a1 = fmaf(v, bhi(x0.x), a1);
        a2 = fmaf(v, blo(x0.y), a2);
        a3 = fmaf(v, bhi(x0.y), a3);
    }
    a0 += b0; a1 += b1; a2 += b2; a3 += b3;
    float ss = wave_sum(a0 * a0 + a1 * a1 + a2 * a2 + a3 * a3);
    float nraw = sqrtf(ss);
    float n_ = fmaxf(nraw, 1e-15f);
    float c1 = tanh_fast(n_) * rcp_f(n_);
    float nh = c1 * nraw;
    float np1 = fmaxf(nh, 1e-15f);
    float s1 = (np1 > MAXN) ? MAXN * rcp_f(np1) : 1.0f;
    float n1 = fminf(np1, MAXN);
    float cu = artanh_fast(n1) * rcp_f(n1) * s1 * c1;
    float u0 = fmaxf(cu * a0, 0.f), u1 = fmaxf(cu * a1, 0.f);
    float u2 = fmaxf(cu * a2, 0.f), u3 = fmaxf(cu * a3, 0.f);
    float ss2 = wave_sum(u0 * u0 + u1 * u1 + u2 * u2 + u3 * u3);
    float n2raw = sqrtf(ss2);
    float n2 = fmaxf(n2raw, 1e-15f);
    float c3 = tanh_fast(n2) * rcp_f(n2);
    float ne = c3 * n2raw;
    float np3 = fmaxf(ne, 1e-15f);
    float s3 = (np3 > MAXN) ? MAXN * rcp_f(np3) : 1.0f;
    float n3 = fminf(np3, MAXN);
    float cf = artanh_fast(n3) * rcp_f(n3) * s3 * c3;
    uint2 o; o.x = pk2(cf * u0, cf * u1); o.y = pk2(cf * u2, cf * u3);
    *(uint2*)(out + (size_t)n * DH + lane * 4) = o;
}

// wave-per-node: out[n] = d[n] + sum_in d[src]; 2-way ILP unroll; bf16 in/out
__global__ void k_gather_add(const int* __restrict__ rowptr, const int* __restrict__ psrc,
                             const u16* __restrict__ d, u16* __restrict__ out) {
    int z = blockIdx.y;
    rowptr += (size_t)z * (N_NODES + 1);
    psrc += (size_t)z * NE;
    d += (size_t)z * N_NODES * DH;
    out += (size_t)z * N_NODES * DH;
    int n = blockIdx.x * 4 + (threadIdx.x >> 6);
    int lane = threadIdx.x & 63;
    int beg = rowptr[n], end = rowptr[n + 1];
    uint2 u0v = *(const uint2*)(d + (size_t)n * DH + lane * 4);
    float a0 = blo(u0v.x), a1 = bhi(u0v.x), a2 = blo(u0v.y), a3 = bhi(u0v.y);
    float b0 = 0.f, b1 = 0.f, b2 = 0.f, b3 = 0.f;
    int i = beg;
    for (; i + 2 <= end; i += 2) {
        int s0 = psrc[i], s1 = psrc[i + 1];
        uint2 x0 = *(const uint2*)(d + (size_t)s0 * DH + lane * 4);
        uint2 x1 = *(const uint2*)(d + (size_t)s1 * DH + lane * 4);
        a0 += blo(x0.x); a1 += bhi(x0.x); a2 += blo(x0.y); a3 += bhi(x0.y);
        b0 += blo(x1.x); b1 += bhi(x1.x); b2 += blo(x1.y); b3 += bhi(x1.y);
    }
    if (i < end) {
        int s0 = psrc[i];
        uint2 x0 = *(const uint2*)(d + (size_t)s0 * DH + lane * 4);
        a0 += blo(x0.x); a1 += bhi(x0.x); a2 += blo(x0.y); a3 += bhi(x0.y);
    }
    a0 += b0; a1 += b1; a2 += b2; a3 += b3;
    uint2 o; o.x = pk2(a0, a1); o.y = pk2(a2, a3);
    *(uint2*)(out + (size_t)n * DH + lane * 4) = o;
}

// batched column stats from bf16
__global__ void k_colstats(const u16* __restrict__ zp,
                           float* __restrict__ csum, float* __restrict__ csq) {
    int z = blockIdx.y;
    zp += (size_t)z * N_NODES * DH;
    csum += (size_t)z * DH;
    csq += (size_t)z * DH;
    int t = threadIdx.x;
    int r0 = blockIdx.x * 100;
    float s = 0.0f, q = 0.0f;
    for (int r = r0; r < r0 + 100; ++r) {
        float v = b2f(zp[(size_t)r * DH + t]);
        s += v;
        q += v * v;
    }
    atomicAdd(&csum[t], s);
    atomicAdd(&csq[t], q);
}

// grid-stride uint2 batchnorm + tanh, in-place bf16 (total4 = G*N*DH/4)
__global__ void k_normtanh_v(u16* __restrict__ zp, const float* __restrict__ csum,
                             const float* __restrict__ csq, const float* __restrict__ gamma,
                             const float* __restrict__ beta, int total4) {
    const float inv_n = 1.0f / N_NODES;
    int i = blockIdx.x * 256 + threadIdx.x;
    int stride = gridDim.x * 256;
    for (; i < total4; i += stride) {
        int e0 = i * 4;
        int z = e0 / (N_NODES * DH);
        int j0 = e0 & (DH - 1);
        int zb = z * DH + j0;
        uint2 u = ((uint2*)zp)[i];
        float v[4] = {blo(u.x), bhi(u.x), blo(u.y), bhi(u.y)};
        #pragma unroll
        for (int k = 0; k < 4; ++k) {
            float mu = csum[zb + k] * inv_n;
            float var = csq[zb + k] * inv_n - mu * mu;
            float inv = __builtin_amdgcn_rsqf(var + 1e-5f);
            v[k] = tanh_fast((v[k] - mu) * inv * gamma[zb + k] + beta[zb + k]);
        }
        uint2 o; o.x = pk2(v[0], v[1]); o.y = pk2(v[2], v[3]);
        ((uint2*)zp)[i] = o;
    }
}

// f1 slice of S,P (cols 0..511): thread t -> 2 cols via float2, packed u32 store
__global__ void k_pair0(const int* __restrict__ ei, const int* __restrict__ eid,
                        const float* __restrict__ f1, u16* __restrict__ S,
                        u16* __restrict__ P) {
    int b = blockIdx.x, t = threadIdx.x;
    int e = eid[b];
    int n0 = ei[e], n1 = ei[NE2 + e];
    float2 a = *(const float2*)(f1 + (size_t)n0 * D_INN + t * 2);
    float2 c = *(const float2*)(f1 + (size_t)n1 * D_INN + t * 2);
    ((unsigned int*)(S + (size_t)b * H3))[t] = pk2(a.x + c.x, a.y + c.y);
    ((unsigned int*)(P + (size_t)b * H3))[t] = pk2(a.x * c.x, a.y * c.y);
}

// batched channel slice of S,P from z_ch; 4 edges/block, uint2 lanes
__global__ void k_gather_ch(const int* __restrict__ ei, const int* __restrict__ eid,
                            const u16* __restrict__ zch, u16* __restrict__ S,
                            u16* __restrict__ P, int col0base) {
    int z = blockIdx.y;
    const u16* zp = zch + (size_t)z * N_NODES * DH;
    int col0 = col0base + z * DH;
    int b = blockIdx.x * 4 + (threadIdx.x >> 6);
    int lane = threadIdx.x & 63;
    int e = eid[b];
    int n0 = ei[e], n1 = ei[NE2 + e];
    uint2 ua = *(const uint2*)(zp + (size_t)n0 * DH + lane * 4);
    uint2 ub = *(const uint2*)(zp + (size_t)n1 * DH + lane * 4);
    float a0 = blo(ua.x), a1 = bhi(ua.x), a2 = blo(ua.y), a3 = bhi(ua.y);
    float c0 = blo(ub.x), c1 = bhi(ub.x), c2 = blo(ub.y), c3 = bhi(ub.y);
    uint2 so; so.x = pk2(a0 + c0, a1 + c1); so.y = pk2(a2 + c2, a3 + c3);
    uint2 po; po.x = pk2(a0 * c0, a1 * c1); po.y = pk2(a2 * c2, a3 * c3);
    *(uint2*)(S + (size_t)b * H3 + col0 + lane * 4) = so;
    *(uint2*)(P + (size_t)b * H3 + col0 + lane * 4) = po;
}

__global__ void k_final(const u16* __restrict__ h2, const float* __restrict__ Wf3,
                        const float* __restrict__ bf3, float* __restrict__ out) {
    int r = blockIdx.x, t = threadIdx.x;
    const u16* hr = h2 + (size_t)r * 576;
    float acc[7] = {0, 0, 0, 0, 0, 0, 0};
    for (int cb = t; cb < 576; cb += 64) {
        float h = b2f(hr[cb]);
        #pragma unroll
        for (int o = 0; o < 7; ++o) acc[o] = fmaf(h, Wf3[o * 576 + cb], acc[o]);
    }
    #pragma unroll
    for (int o = 0; o < 7; ++o) {
        #pragma unroll
        for (int off = 32; off > 0; off >>= 1) acc[o] += __shfl_down(acc[o], off, 64);
    }
    if (t == 0) {
        #pragma unroll
        for (int o = 0; o < 7; ++o) out[(size_t)r * 7 + o] = acc[o] + bf3[o];
    }
}

// ===== bf16 MFMA GEMM, BK=64 (batched over z with strides).
// global_load_lds width-16 coalesced staging: per 8-row block, lane l ->
// row l>>3, src chunk (l&7)^(l>>3) (involution with read swizzle); LDS dest
// linear. Fragment ds_read_b128 at row*64 + ((q^(row&7))*8) shorts -> 2-way
// bank alias (free). LDS 32KB, 2 blocks/CU. FULL-GRID 3D bijective XCD swizzle.
// EP: 2=sigmoid->bf16, 3=relu->bf16, 5=bf16, 6=relu->f32,
//     7=bf16 + bias + (1+indeg[row])*cvec[col],
//     8=z==0? sigmoid->bf16 : bf16 (for batched gate/int)
template <int EP>
__global__ __launch_bounds__(256, 2) void k_gemm_mfma(
    const u16* __restrict__ A, const u16* __restrict__ W,
    const float* __restrict__ bias, void* __restrict__ outv,
    const int* __restrict__ rpe, const float* __restrict__ cvec,
    int M, int N, int K, size_t sA, size_t sW, size_t sC, int sBias) {
    __shared__ short As[8192];   // 128 rows x 64 cols bf16
    __shared__ short Ws[8192];
    // 3D bijective XCD swizzle over the whole grid
    const int gx = gridDim.x, gy = gridDim.y;
    const int plane = gx * gy;
    const int total = plane * gridDim.z;
    const int orig = (blockIdx.z * gy + blockIdx.y) * gx + blockIdx.x;
    const int q8 = total >> 3, r8 = total & 7, xcd = orig & 7;
    const int wg = (xcd < r8 ? xcd * (q8 + 1) : r8 * (q8 + 1) + (xcd - r8) * q8) + (orig >> 3);
    const int z = wg / plane;
    const int rem = wg - z * plane;
    const int row0 = (rem / gx) * 128, col0 = (rem % gx) * 128;
    A += (size_t)z * sA;
    W += (size_t)z * sW;
    const size_t zC = (size_t)z * sC;
    const int* rp = (EP == 7) ? rpe + (size_t)z * (N_NODES + 1) : nullptr;
    const float* cv = (EP == 7) ? cvec + (size_t)z * DH : nullptr;
    const int t = threadIdx.x;
    const int lane = t & 63;
    const int w = t >> 6;
    const int wr = w >> 1, wc = w & 1;
    // staging: lane l -> row-in-8block l>>3, src chunk (l&7)^(l>>3)
    const int sr8 = lane >> 3;
    const int csrc = (lane & 7) ^ sr8;
    int gr[4], gc[4];
    #pragma unroll
    for (int p = 0; p < 4; ++p) {
        int rb = w + p * 4;                // 0..15 (8-row blocks)
        gr[p] = row0 + rb * 8 + sr8; if (gr[p] >= M) gr[p] = M - 1;
        gc[p] = col0 + rb * 8 + sr8; if (gc[p] >= N) gc[p] = N - 1;
    }
    const int fr = lane & 15, fq4 = lane >> 4;   // logical chunk q = kk*4 + fq4
    f32x4 acc[4][4] = {};
    for (int k0 = 0; k0 < K; k0 += 64) {
        #pragma unroll
        for (int p = 0; p < 4; ++p) {
            int rb = w + p * 4;
            __builtin_amdgcn_global_load_lds(
                (const __attribute__((address_space(1))) unsigned int*)(A + (size_t)gr[p] * K + k0 + csrc * 8),
                (__attribute__((address_space(3))) unsigned int*)(As + rb * 512), 16, 0, 0);
            __builtin_amdgcn_global_load_lds(
                (const __attribute__((address_space(1))) unsigned int*)(W + (size_t)gc[p] * K + k0 + csrc * 8),
                (__attribute__((address_space(3))) unsigned int*)(Ws + rb * 512), 16, 0, 0);
        }
        __syncthreads();
        bf16x8 af[4][2], bfr[4][2];
        #pragma unroll
        for (int m = 0; m < 4; ++m) {
            int ar = wr * 64 + m * 16 + fr;
            #pragma unroll
            for (int kk = 0; kk < 2; ++kk) {
                int q = kk * 4 + fq4;
                af[m][kk] = *(const bf16x8*)(As + ar * 64 + ((q ^ (ar & 7)) * 8));
            }
        }
        #pragma unroll
        for (int n = 0; n < 4; ++n) {
            int br = wc * 64 + n * 16 + fr;
            #pragma unroll
            for (int kk = 0; kk < 2; ++kk) {
                int q = kk * 4 + fq4;
                bfr[n][kk] = *(const bf16x8*)(Ws + br * 64 + ((q ^ (br & 7)) * 8));
            }
        }
        #pragma unroll
        for (int m = 0; m < 4; ++m)
            #pragma unroll
            for (int n = 0; n < 4; ++n)
                #pragma unroll
                for (int kk = 0; kk < 2; ++kk)
                    acc[m][n] = __builtin_amdgcn_mfma_f32_16x16x32_bf16(
                        af[m][kk], bfr[n][kk], acc[m][n], 0, 0, 0);
        __syncthreads();
    }
    const int cl = lane & 15, rh = (lane >> 4) * 4;
    #pragma unroll
    for (int m = 0; m < 4; ++m) {
        float indf[4];
        if (EP == 7) {
            #pragma unroll
            for (int r = 0; r < 4; ++r) {
                int row = row0 + wr * 64 + m * 16 + rh + r;
                if (row >= M) row = M - 1;
                indf[r] = 1.0f + (float)(rp[row + 1] - rp[row]);
            }
        }
        #pragma unroll
        for (int n = 0; n < 4; ++n) {
            int col = col0 + wc * 64 + n * 16 + cl;
            if (col >= N) continue;
            float bv = bias ? bias[z * sBias + col] : 0.0f;
            float cvc = (EP == 7) ? cv[col] : 0.0f;
            #pragma unroll
            for (int r = 0; r < 4; ++r) {
                int row = row0 + wr * 64 + m * 16 + rh + r;
                if (row >= M) continue;
                float v = acc[m][n][r] + bv;
                size_t idx = zC + (size_t)row * N + col;
                if (EP == 2) ((u16*)outv)[idx] = f2b(sigmoid_fast(v));
                if (EP == 3) ((u16*)outv)[idx] = f2b(fmaxf(v, 0.0f));
                if (EP == 5) ((u16*)outv)[idx] = f2b(v);
                if (EP == 6) ((float*)outv)[idx] = fmaxf(v, 0.0f);
                if (EP == 7) ((u16*)outv)[idx] = f2b(v + indf[r] * cvc);
                if (EP == 8) ((u16*)outv)[idx] = (z == 0) ? f2b(sigmoid_fast(v)) : f2b(v);
            }
        }
    }
}

static inline void gemm_b(int ep, const u16* A, const u16* W, const float* bias, void* out,
                          const int* rpe, const float* cvec,
                          int M, int N, int K, int Z,
                          size_t sA, size_t sW, size_t sC, int sBias, hipStream_t st) {
    dim3 g((N + 127) / 128, (M + 127) / 128, Z);
    switch (ep) {
        case 2: k_gemm_mfma<2><<<g, 256, 0, st>>>(A, W, bias, out, rpe, cvec, M, N, K, sA, sW, sC, sBias); break;
        case 3: k_gemm_mfma<3><<<g, 256, 0, st>>>(A, W, bias, out, rpe, cvec, M, N, K, sA, sW, sC, sBias); break;
        case 5: k_gemm_mfma<5><<<g, 256, 0, st>>>(A, W, bias, out, rpe, cvec, M, N, K, sA, sW, sC, sBias); break;
        case 6: k_gemm_mfma<6><<<g, 256, 0, st>>>(A, W, bias, out, rpe, cvec, M, N, K, sA, sW, sC, sBias); break;
        case 7: k_gemm_mfma<7><<<g, 256, 0, st>>>(A, W, bias, out, rpe, cvec, M, N, K, sA, sW, sC, sBias); break;
        case 8: k_gemm_mfma<8><<<g, 256, 0, st>>>(A, W, bias, out, rpe, cvec, M, N, K, sA, sW, sC, sBias); break;
    }
}

static inline void conv_w(const float* s, u16* d, size_t n, hipStream_t st) {
    int n4 = (int)(n / 4);
    int grid = (n4 + 255) / 256;
    if (grid > 2048) grid = 2048;
    k_f2b<<<grid, 256, 0, st>>>(s, d, n4);
}

extern "C" void kernel_launch(void* const* d_in, const int* in_sizes, int n_in, void* d_out,
                              int out_size, void* d_ws, size_t ws_size, hipStream_t stream) {
    const float* f1 = (const float*)d_in[0];
    const int* adj_src = (const int*)d_in[1];
    const int* adj_dst = (const int*)d_in[2];
    const float* adj_val = (const float*)d_in[3];
    const int* edge_src = (const int*)d_in[4];
    const int* edge_dst = (const int*)d_in[5];
    const int* edge_index = (const int*)d_in[6];
    const int* edge_id = (const int*)d_in[7];
    const float* W_hyp = (const float*)d_in[8];
    const float* b_hyp = (const float*)d_in[9];
    const float* Wd = (const float*)d_in[10];
    const float* bd = (const float*)d_in[11];
    const float* Wg1 = (const float*)d_in[12];
    const float* bg1 = (const float*)d_in[13];
    const float* gamma = (const float*)d_in[14];
    const float* beta = (const float*)d_in[15];
    const float* Wg2 = (const float*)d_in[16];
    const float* bg2 = (const float*)d_in[17];
    const float* Wgate = (const float*)d_in[18];
    const float* bgate = (const float*)d_in[19];
    const float* Wint = (const float*)d_in[20];
    const float* bint = (const float*)d_in[21];
    const float* Wout = (const float*)d_in[22];
    const float* bout = (const float*)d_in[23];
    const float* Wf1 = (const float*)d_in[24];
    const float* bf1 = (const float*)d_in[25];
    const float* Wf2 = (const float*)d_in[26];
    const float* bf2 = (const float*)d_in[27];
    const float* Wf3 = (const float*)d_in[28];
    const float* bf3 = (const float*)d_in[29];
    float* outp = (float*)d_out;

    const bool single = ws_size >= 253400000ull;
    const int ngroups = single ? 1 : 2;
    const int GM = single ? 7 : 4;
    int g0s[2] = {0, 4};
    int gns[2] = {GM, 3};

    // ---- workspace bump allocator ----
    char* base = (char*)d_ws;
    size_t off = 0;
    auto alloc = [&](size_t bytes) -> char* {
        char* p = base + off;
        off += (bytes + 255) & ~(size_t)255;
        return p;
    };
    u16* Whyp_b = (u16*)alloc((size_t)NCH * DH * D_INN * 2);
    u16* Wc_b   = (u16*)alloc((size_t)NCH * DH * DH * 2);   // Wg1 @ Wd
    u16* Wg1_b  = (u16*)alloc((size_t)NCH * DH * DH * 2);
    u16* Wg2_b  = (u16*)alloc((size_t)NCH * DH * DH * 2);
    u16* Wgate_b = (u16*)alloc((size_t)H3 * H3 * 2);        // Wint_b must follow!
    u16* Wint_b  = (u16*)alloc((size_t)H3 * H3 * 2);
    u16* Wcomb_b = (u16*)alloc((size_t)1152 * H3 * 2);      // Wf1 @ Wout
    u16* Wf2_b   = (u16*)alloc((size_t)576 * 1152 * 2);
    u16* S_b = (u16*)alloc((size_t)NB * H3 * 2);            // P_b must follow!
    u16* P_b = (u16*)alloc((size_t)NB * H3 * 2);
    const size_t NDB = (size_t)N_NODES * DH;       // per-channel elems
    u16* buf1 = (u16*)alloc((size_t)GM * NDB * 2); // group ping (buf2 follows)
    u16* buf2 = (u16*)alloc((size_t)GM * NDB * 2); // group pong
    u16* xhyp_b = single ? buf2 : (u16*)alloc((size_t)N_NODES * D_INN * 2);
    // CSR scratch (2*GM slices): adj slices [0,G), edge slices [G,2G).
    // Single mode: final padj/psrcE alias into S_b (26.9MB <= 37.75);
    // cnt/rowptr + binned scratch alias into P_b (29.2MB <= 37.75) -- all
    // dead before S/P get written (pair0/gather_ch run post-GNN).
    int* cntC; int* rowptrC; uint2* padjC; int* psrcE;
    uint2* scrA = nullptr; unsigned int* scrE = nullptr;
    if (single) {
        padjC = (uint2*)S_b;                                   // 17,920,000 B
        psrcE = (int*)((char*)S_b + (size_t)GM * NE * 8);      // +8,960,000 B
        cntC = (int*)P_b;                                      // 1,120,000 B
        rowptrC = (int*)((char*)P_b + (size_t)2 * GM * N_NODES * 4);
        size_t rp_end = (size_t)2 * GM * N_NODES * 4 + (size_t)2 * GM * (N_NODES + 1) * 4;
        rp_end = (rp_end + 63) & ~(size_t)63;
        scrA = (uint2*)((char*)P_b + rp_end);                  // 17,920,000 B
        scrE = (unsigned int*)((char*)scrA + (size_t)GM * NE * 8);  // +8,960,000 B
    } else {
        cntC = (int*)alloc((size_t)2 * GM * N_NODES * 4);
        rowptrC = (int*)alloc((size_t)2 * GM * (N_NODES + 1) * 4);
        padjC = (uint2*)alloc((size_t)GM * NE * 8);
        psrcE = (int*)alloc((size_t)GM * NE * 4);
    }
    float* xhn = (float*)alloc((size_t)N_NODES * 4);
    float* hb = (float*)alloc((size_t)NCH * DH * 4);
    float* hb2 = (float*)alloc(NCH * 4);
    float* csum = (float*)alloc((size_t)GM * DH * 4);        // csq follows
    float* csq = (float*)alloc((size_t)GM * DH * 4);
    float* cvec_d = (float*)alloc((size_t)NCH * DH * 4);
    float* bias2 = (float*)alloc((size_t)2 * H3 * 4);
    float* bcomb = (float*)alloc((size_t)1152 * 4);
    int* bcur = (int*)alloc((size_t)2 * NCH * NBUK * 4);     // bucket cursors
    // precompute-only temp weights alias into buf1 (idle until GNN phase):
    u16* WoutT_b = buf1;                          // 10.62 MB
    u16* Wf1_b = buf1 + (size_t)H3 * H3;          // +5.31 MB
    u16* Wdt_b = Wf1_b + (size_t)1152 * H3;       // +0.92 MB (total 16.8 <= buf1)
    // stage-C overlays: GT spans buf1(+buf2 head); h1 -> buf1; h2 -> buf2.
    u16* GT = buf1;
    u16* h2b = buf2;

    const int EG = (NE + 255) / 256;

    conv_w(W_hyp, Whyp_b, (size_t)NCH * DH * D_INN, stream);
    conv_w(Wg1, Wg1_b, (size_t)NCH * DH * DH, stream);
    conv_w(Wg2, Wg2_b, (size_t)NCH * DH * DH, stream);
    conv_w(Wgate, Wgate_b, (size_t)H3 * H3, stream);
    conv_w(Wint, Wint_b, (size_t)H3 * H3, stream);
    conv_w(Wf1, Wf1_b, (size_t)1152 * H3, stream);
    conv_w(Wf2, Wf2_b, (size_t)576 * 1152, stream);
    k_bias2<<<(2 * H3 + 255) / 256, 256, 0, stream>>>(bgate, bint, bias2);
    // Wc = Wg1 @ Wd (via Wd^T), cvec = Wg1 @ bd
    k_twd<<<dim3(16, 16, NCH), 256, 0, stream>>>(Wd, Wdt_b);
    gemm_b(5, Wg1_b, Wdt_b, nullptr, Wc_b, nullptr, nullptr,
           DH, DH, DH, NCH, (size_t)DH * DH, (size_t)DH * DH, (size_t)DH * DH, 0, stream);
    k_cvec<<<NCH, 256, 0, stream>>>(Wg1, bd, cvec_d);
    // Wcomb = Wf1 @ Wout (Wout GEMM folded into Wf1), bcomb = Wf1@bout + bf1
    k_tr<<<dim3(144, 144), 256, 0, stream>>>(Wout, WoutT_b);
    gemm_b(5, Wf1_b, WoutT_b, nullptr, Wcomb_b, nullptr, nullptr,
           1152, H3, H3, 1, 0, 0, 0, 0, stream);
    k_bvec<<<1152 / 4, 256, 0, stream>>>(Wf1, bout, bf1, bcomb);

    k_expmap_proj_in<<<N_NODES, 256, 0, stream>>>(f1, xhyp_b, xhn);
    k_hb<<<NCH, 256, 0, stream>>>(b_hyp, hb, hb2);
    if (!single) k_pair0<<<NB, 256, 0, stream>>>(edge_index, edge_id, f1, S_b, P_b);

    for (int gi = 0; gi < ngroups; ++gi) {
        const int g0 = g0s[gi], G = gns[gi];
        const size_t eoff = (size_t)g0 * NE;
        const int G2 = 2 * G;
        const int* rpE = rowptrC + (size_t)G * (N_NODES + 1);
        // --- merged CSR build ---
        k_izero<<<(G2 * N_NODES + 255) / 256, 256, 0, stream>>>(cntC, G2 * N_NODES);
        k_hist2<<<dim3(EG, G2), 256, 0, stream>>>(adj_dst + eoff, edge_dst + eoff, cntC, G);
        k_scan<<<G2, 256, 0, stream>>>(cntC, rowptrC);
        if (single) {
            // two-phase bucketed place: bin (LDS-aggregated) then L2-local fine place
            k_bcur<<<(G2 * NBUK + 255) / 256, 256, 0, stream>>>(rowptrC, bcur, G2);
            k_binA<<<dim3(EG, G2), 256, 0, stream>>>(adj_src, adj_dst, adj_val,
                                                     edge_src, edge_dst, bcur,
                                                     scrA, scrE, G);
            k_placeB<<<dim3(NBUK, G2), 256, 0, stream>>>(rowptrC, scrA, scrE,
                                                         padjC, psrcE, G);
        } else {
            k_place2<<<dim3(EG, G2), 256, 0, stream>>>(adj_src + eoff, adj_dst + eoff,
                                                       adj_val + eoff, edge_src + eoff,
                                                       edge_dst + eoff, cntC, padjC,
                                                       psrcE, G);
        }
        // --- batched pipeline ---
        gemm_b(5, xhyp_b, Whyp_b + (size_t)g0 * DH * D_INN, nullptr, buf1, nullptr,
               nullptr, N_NODES, DH, D_INN, G, 0, (size_t)DH * D_INN, NDB, 0, stream);
        k_rowfuse1<<<dim3(N_NODES / 4, G), 256, 0, stream>>>(buf1, xhn, hb + g0 * DH, hb2 + g0);
        k_gather_fuse2<<<dim3(N_NODES / 4, G), 256, 0, stream>>>(rowptrC, padjC, buf1, buf2);
        // ug = (I + S_e) u
        k_gather_add<<<dim3(N_NODES / 4, G), 256, 0, stream>>>(rpE, psrcE, buf2, buf1);
        // z = ug @ Wc^T + (1+indeg)*cvec + bg1   (Wd GEMM fused away)
        gemm_b(7, buf1, Wc_b + (size_t)g0 * DH * DH, bg1 + g0 * DH, buf2,
               rpE, cvec_d + (size_t)g0 * DH, N_NODES, DH, DH, G,
               NDB, (size_t)DH * DH, NDB, DH, stream);
        k_zero<<<(2 * GM * DH + 255) / 256, 256, 0, stream>>>(csum, 2 * GM * DH);
        k_colstats<<<dim3(200, G), 256, 0, stream>>>(buf2, csum, csq);
        {
            int total4 = (int)(G * NDB / 4);
            int blocks = (total4 + 255) / 256;
            if (blocks > 2048) blocks = 2048;
            k_normtanh_v<<<blocks, 256, 0, stream>>>(buf2, csum, csq, gamma + g0 * DH,
                                                     beta + g0 * DH, total4);
        }
        gemm_b(5, buf2, Wg2_b + (size_t)g0 * DH * DH, bg2 + g0 * DH, buf1, nullptr,
               nullptr, N_NODES, DH, DH, G, NDB, (size_t)DH * DH, NDB, DH, stream);
        if (!single)
            k_gather_ch<<<dim3(NB / 4, G), 256, 0, stream>>>(edge_index, edge_id, buf1,
                                                             S_b, P_b, D_INN + g0 * DH);
    }
    if (single) {
        // CSR scratch (aliased in S_b/P_b) is dead now; build S,P.
        k_pair0<<<NB, 256, 0, stream>>>(edge_index, edge_id, f1, S_b, P_b);
        k_gather_ch<<<dim3(NB / 4, 7), 256, 0, stream>>>(edge_index, edge_id, buf1,
                                                         S_b, P_b, D_INN);
    }

    // stage C: batched gate/int (Z=2), gi elementwise, fused h1 (Wout folded
    // into Wf1 via Wcomb), h2 (bf16), final.
    gemm_b(8, S_b, Wgate_b, bias2, GT, nullptr, nullptr, NB, H3, H3, 2,
           (size_t)NB * H3, (size_t)H3 * H3, (size_t)NB * H3, H3, stream);
    {
        int total4 = NB * H3 / 4;
        int blocks = (total4 + 255) / 256;
        if (blocks > 2048) blocks = 2048;
        k_gi<<<blocks, 256, 0, stream>>>(GT, GT + (size_t)NB * H3, S_b, total4);
    }
    // h1 = relu(gi @ Wcomb^T + bcomb)
    gemm_b(3, S_b, Wcomb_b, bcomb, buf1, nullptr, nullptr, NB, 1152, H3, 1, 0, 0, 0, 0, stream);
    // h2 = relu(h1 @ Wf2^T + bf2) -> bf16
    gemm_b(3, buf1, Wf2_b, bf2, h2b, nullptr, nullptr, NB, 576, 1152, 1, 0, 0, 0, 0, stream);
    k_final<<<NB, 64, 0, stream>>>(h2b, Wf3, bf3, outp);
}

// Round 18
// 1459.542 us; speedup vs baseline: 1.6013x; 1.0459x over previous
//
#include <hip/hip_runtime.h>
#include <math.h>

#define N_NODES 20000
#define D_INN   512
#define DH      256
#define NCH     7
#define NE      320000
#define NE2     100000
#define NB      8192
#define H3      2304   // 512 + 7*256
#define MAXN    0.996f
#define LOG2E   1.44269504f
#define NBUK    40     // dst buckets of 512 nodes
#define BSH     9

typedef unsigned short u16;
typedef __attribute__((ext_vector_type(8))) short bf16x8;
typedef __attribute__((ext_vector_type(4))) float f32x4;

__device__ __forceinline__ u16 f2b(float f) {    // RNE f32 -> bf16 bits
    unsigned int x = __float_as_uint(f);
    unsigned int r = (x + 0x7fffu + ((x >> 16) & 1u)) >> 16;
    return (u16)r;
}
__device__ __forceinline__ float b2f(u16 u) {
    return __uint_as_float(((unsigned int)u) << 16);
}
__device__ __forceinline__ float blo(unsigned int u) { return __uint_as_float(u << 16); }
__device__ __forceinline__ float bhi(unsigned int u) { return __uint_as_float(u & 0xffff0000u); }
__device__ __forceinline__ unsigned int pk2(float a, float b) {
    return (unsigned int)f2b(a) | ((unsigned int)f2b(b) << 16);
}

// ---- fast HW transcendentals (rel err ~1e-5, fine for bf16 tolerance) ----
__device__ __forceinline__ float rcp_f(float x) { return __builtin_amdgcn_rcpf(x); }
__device__ __forceinline__ float exp2_f(float x) { return __builtin_amdgcn_exp2f(x); }
__device__ __forceinline__ float log2_f(float x) { return __builtin_amdgcn_logf(x); }
__device__ __forceinline__ float tanh_fast(float x) {
    float xc = fminf(fmaxf(x, -15.f), 15.f);
    float t = exp2_f(xc * (2.f * LOG2E));
    return (t - 1.f) * rcp_f(t + 1.f);
}
__device__ __forceinline__ float artanh_fast(float x) {
    x = fminf(fmaxf(x, -1.0f + 1e-7f), 1.0f - 1e-7f);
    return 0.34657359f * log2_f((1.f + x) * rcp_f(1.f - x));
}
__device__ __forceinline__ float sigmoid_fast(float x) {
    return rcp_f(1.f + exp2_f(-x * LOG2E));
}

__device__ __forceinline__ float wave_sum(float v) {
    #pragma unroll
    for (int off = 32; off > 0; off >>= 1) v += __shfl_xor(v, off, 64);
    return v;
}

__device__ __forceinline__ float block_sum256(float v) {
    __shared__ float sred[4];
    #pragma unroll
    for (int off = 32; off > 0; off >>= 1) v += __shfl_down(v, off, 64);
    int lane = threadIdx.x & 63;
    int w = threadIdx.x >> 6;
    if (lane == 0) sred[w] = v;
    __syncthreads();
    float tot = sred[0] + sred[1] + sred[2] + sred[3];
    __syncthreads();
    return tot;
}

__global__ void k_zero(float* __restrict__ p, int n) {
    int i = blockIdx.x * 256 + threadIdx.x;
    if (i < n) p[i] = 0.0f;
}
__global__ void k_izero(int* __restrict__ p, int n) {
    int i = blockIdx.x * 256 + threadIdx.x;
    if (i < n) p[i] = 0;
}

__global__ void k_f2b(const float* __restrict__ s, u16* __restrict__ d, int n4) {
    int i = blockIdx.x * 256 + threadIdx.x;
    int stride = gridDim.x * 256;
    for (; i < n4; i += stride) {
        float4 v = ((const float4*)s)[i];
        uint2 o; o.x = pk2(v.x, v.y); o.y = pk2(v.z, v.w);
        ((uint2*)d)[i] = o;
    }
}

// pack two bias vectors contiguously (for batched gate/int GEMM)
__global__ void k_bias2(const float* __restrict__ a, const float* __restrict__ b,
                        float* __restrict__ o) {
    int i = blockIdx.x * 256 + threadIdx.x;
    if (i < H3) o[i] = a[i];
    else if (i < 2 * H3) o[i] = b[i - H3];
}

// gi = gate * relu(tmp), all bf16, vectorized
__global__ void k_gi(const u16* __restrict__ gate, const u16* __restrict__ tmp,
                     u16* __restrict__ out, int total4) {
    int i = blockIdx.x * 256 + threadIdx.x;
    int stride = gridDim.x * 256;
    for (; i < total4; i += stride) {
        uint2 g = ((const uint2*)gate)[i];
        uint2 t = ((const uint2*)tmp)[i];
        uint2 o;
        o.x = pk2(blo(g.x) * fmaxf(blo(t.x), 0.f), bhi(g.x) * fmaxf(bhi(t.x), 0.f));
        o.y = pk2(blo(g.y) * fmaxf(blo(t.y), 0.f), bhi(g.y) * fmaxf(bhi(t.y), 0.f));
        ((uint2*)out)[i] = o;
    }
}

// Wd transpose -> bf16 (for Wc = Wg1 @ Wd via A@W^T kernel)
__global__ void k_twd(const float* __restrict__ Wd, u16* __restrict__ Wdt) {
    __shared__ float tile[16][17];
    int z = blockIdx.z;
    int bx = blockIdx.x * 16, by = blockIdx.y * 16;
    int tx = threadIdx.x & 15, ty = threadIdx.x >> 4;
    tile[ty][tx] = Wd[(size_t)z * DH * DH + (size_t)(by + ty) * DH + bx + tx];
    __syncthreads();
    Wdt[(size_t)z * DH * DH + (size_t)(bx + ty) * DH + by + tx] = f2b(tile[tx][ty]);
}

// 2304x2304 transpose f32 -> bf16 (WoutT[i][j] = Wout[j][i])
__global__ void k_tr(const float* __restrict__ Win, u16* __restrict__ Wt) {
    __shared__ float tile[16][17];
    int bx = blockIdx.x * 16, by = blockIdx.y * 16;
    int tx = threadIdx.x & 15, ty = threadIdx.x >> 4;
    tile[ty][tx] = Win[(size_t)(by + ty) * H3 + bx + tx];
    __syncthreads();
    Wt[(size_t)(bx + ty) * H3 + by + tx] = f2b(tile[tx][ty]);
}

// bcomb[r] = sum_j Wf1[r][j]*bout[j] + bf1[r]  (wave per row, 4 rows/block)
__global__ void k_bvec(const float* __restrict__ Wf1, const float* __restrict__ bout,
                       const float* __restrict__ bf1, float* __restrict__ bcomb) {
    int r = blockIdx.x * 4 + (threadIdx.x >> 6);
    int lane = threadIdx.x & 63;
    const float* row = Wf1 + (size_t)r * H3;
    float s = 0.f;
    for (int j = lane; j < H3; j += 64) s = fmaf(row[j], bout[j], s);
    s = wave_sum(s);
    if (lane == 0) bcomb[r] = s + bf1[r];
}

// cvec[z][j] = sum_k Wg1[z][j][k] * bd[z][k]   (f32)
__global__ void k_cvec(const float* __restrict__ Wg1, const float* __restrict__ bd,
                       float* __restrict__ cvec) {
    int z = blockIdx.x, j = threadIdx.x;
    const float* row = Wg1 + (size_t)z * DH * DH + (size_t)j * DH;
    const float* b = bd + (size_t)z * DH;
    float s = 0.f;
    for (int k = 0; k < DH; ++k) s = fmaf(row[k], b[k], s);
    cvec[(size_t)z * DH + j] = s;
}

// ===== merged CSR build: 2G z-slices (z<G: adj graph, z>=G: edge graph) =====
__global__ void k_hist2(const int* __restrict__ adjd, const int* __restrict__ edged,
                        int* __restrict__ cnt, int G) {
    int z = blockIdx.y;
    const int* dst = (z < G) ? adjd + (size_t)z * NE : edged + (size_t)(z - G) * NE;
    cnt += (size_t)z * N_NODES;
    int i = blockIdx.x * 256 + threadIdx.x;
    if (i < NE) atomicAdd(&cnt[dst[i]], 1);
}

// one block per slice; cnt becomes the cursor array in-place
__global__ void k_scan(int* __restrict__ cnt, int* __restrict__ rowptr) {
    int z = blockIdx.x;
    cnt += (size_t)z * N_NODES;
    rowptr += (size_t)z * (N_NODES + 1);
    __shared__ int part[256];
    int t = threadIdx.x;
    const int CH = (N_NODES + 255) / 256;
    int beg = t * CH;
    int end = beg + CH; if (end > N_NODES) end = N_NODES;
    int s = 0;
    for (int i = beg; i < end; ++i) s += cnt[i];
    part[t] = s;
    __syncthreads();
    for (int off = 1; off < 256; off <<= 1) {
        int v = (t >= off) ? part[t - off] : 0;
        __syncthreads();
        part[t] += v;
        __syncthreads();
    }
    int run = (t == 0) ? 0 : part[t - 1];
    for (int i = beg; i < end; ++i) {
        int c = cnt[i];
        rowptr[i] = run;
        cnt[i] = run;      // cursor init (in-place)
        run += c;
    }
    if (t == 255) rowptr[N_NODES] = part[255];
}

// legacy 1-phase place (2-group fallback path)
__global__ void k_place2(const int* __restrict__ adjs, const int* __restrict__ adjd,
                         const float* __restrict__ adjv, const int* __restrict__ edges,
                         const int* __restrict__ edged, int* __restrict__ cursor,
                         uint2* __restrict__ padj, int* __restrict__ psrcE, int G) {
    int z = blockIdx.y;
    bool isadj = z < G;
    const int* src = isadj ? adjs + (size_t)z * NE : edges + (size_t)(z - G) * NE;
    const int* dst = isadj ? adjd + (size_t)z * NE : edged + (size_t)(z - G) * NE;
    cursor += (size_t)z * N_NODES;
    int i = blockIdx.x * 256 + threadIdx.x;
    if (i < NE) {
        int d = dst[i];
        int pos = atomicAdd(&cursor[d], 1);
        if (isadj) {
            uint2 p;
            p.x = (unsigned int)src[i];
            p.y = __float_as_uint(adjv[(size_t)z * NE + i]);
            padj[(size_t)z * NE + pos] = p;
        } else {
            psrcE[(size_t)(z - G) * NE + pos] = src[i];
        }
    }
}

// bucket cursors init: bcur[z][b] = rowptr[z][b*512]
__global__ void k_bcur(const int* __restrict__ rowptr, int* __restrict__ bcur, int G2) {
    int i = blockIdx.x * 256 + threadIdx.x;
    if (i < G2 * NBUK) {
        int z = i / NBUK, b = i - z * NBUK;
        bcur[i] = rowptr[(size_t)z * (N_NODES + 1) + (b << BSH)];
    }
}

// phase A: bin edges into bucket-contiguous scratch (regions = final CSR
// bucket ranges). LDS-aggregated claims: one global atomic per bucket/block,
// writes land in ~contiguous runs. (src,dst) packed 15+15 bits.
__global__ void k_binA(const int* __restrict__ adjs, const int* __restrict__ adjd,
                       const float* __restrict__ adjv, const int* __restrict__ edges,
                       const int* __restrict__ edged, int* __restrict__ bcur,
                       uint2* __restrict__ scrA, unsigned int* __restrict__ scrE, int G) {
    int z = blockIdx.y;
    bool isadj = z < G;
    const int* src = isadj ? adjs + (size_t)z * NE : edges + (size_t)(z - G) * NE;
    const int* dst = isadj ? adjd + (size_t)z * NE : edged + (size_t)(z - G) * NE;
    __shared__ int hcnt[NBUK];
    __shared__ int gbase[NBUK];
    int t = threadIdx.x;
    int i = blockIdx.x * 256 + t;
    if (t < NBUK) hcnt[t] = 0;
    __syncthreads();
    int s = 0, d = 0, buk = 0, rank = 0;
    bool valid = i < NE;
    if (valid) {
        s = src[i]; d = dst[i];
        buk = d >> BSH;
        rank = atomicAdd(&hcnt[buk], 1);
    }
    __syncthreads();
    if (t < NBUK && hcnt[t] > 0)
        gbase[t] = atomicAdd(&bcur[z * NBUK + t], hcnt[t]);
    __syncthreads();
    if (valid) {
        int pos = gbase[buk] + rank;
        unsigned int sd = (unsigned int)s | ((unsigned int)d << 15);
        if (isadj) {
            uint2 p; p.x = sd; p.y = __float_as_uint(adjv[(size_t)z * NE + i]);
            scrA[(size_t)z * NE + pos] = p;
        } else {
            scrE[(size_t)(z - G) * NE + pos] = sd;
        }
    }
}

// phase B: one block per (bucket, z). LDS cursors for the bucket's 512 nodes;
// reads coalesced from bucket region; final scatter confined to the bucket's
// ~64KB CSR window (L2-absorbed).
__global__ void k_placeB(const int* __restrict__ rowptr, const uint2* __restrict__ scrA,
                         const unsigned int* __restrict__ scrE, uint2* __restrict__ padj,
                         int* __restrict__ psrcE, int G) {
    int z = blockIdx.y;
    int b = blockIdx.x;
    bool isadj = z < G;
    const int* rp = rowptr + (size_t)z * (N_NODES + 1);
    __shared__ int cur[512];
    int t = threadIdx.x;
    int n0 = b << BSH;
    for (int k = t; k < 512; k += 256) {
        int node = n0 + k;
        cur[k] = (node < N_NODES) ? rp[node] : 0;
    }
    __syncthreads();
    int beg = rp[n0];
    int nend = n0 + 512; if (nend > N_NODES) nend = N_NODES;
    int end = rp[nend];
    if (isadj) {
        const uint2* sc = scrA + (size_t)z * NE;
        uint2* out = padj + (size_t)z * NE;
        for (int i = beg + t; i < end; i += 256) {
            uint2 p = sc[i];
            int d = (int)((p.x >> 15) & 0x7fffu);
            int pos = atomicAdd(&cur[d - n0], 1);
            uint2 o; o.x = p.x & 0x7fffu; o.y = p.y;
            out[pos] = o;
        }
    } else {
        const unsigned int* sc = scrE + (size_t)(z - G) * NE;
        int* out = psrcE + (size_t)(z - G) * NE;
        for (int i = beg + t; i < end; i += 256) {
            unsigned int p = sc[i];
            int d = (int)((p >> 15) & 0x7fffu);
            int pos = atomicAdd(&cur[d - n0], 1);
            out[pos] = (int)(p & 0x7fffu);
        }
    }
}

// x_hyp = proj(expmap0(f1)) -> bf16; clamped row norm -> xhn (f32)
__global__ void k_expmap_proj_in(const float* __restrict__ f1,
                                 u16* __restrict__ xhyp, float* __restrict__ xhn) {
    int r = blockIdx.x, t = threadIdx.x;
    const float* u = f1 + (size_t)r * D_INN;
    float v0 = u[t], v1 = u[t + 256];
    float ss = block_sum256(v0 * v0 + v1 * v1);
    float nraw = sqrtf(ss);
    float n = fmaxf(nraw, 1e-15f);
    float c = tanh_fast(n) * rcp_f(n);
    float ny = c * nraw;
    float np = fmaxf(ny, 1e-15f);
    float s = (np > MAXN) ? MAXN * rcp_f(np) : 1.0f;
    float cs = c * s;
    u16* o = xhyp + (size_t)r * D_INN;
    o[t] = f2b(cs * v0);
    o[t + 256] = f2b(cs * v1);
    if (t == 0) xhn[r] = fminf(np, MAXN);
}

__global__ void k_hb(const float* __restrict__ b_hyp,
                     float* __restrict__ hb, float* __restrict__ hb2) {
    int i = blockIdx.x, t = threadIdx.x;
    float v = b_hyp[i * DH + t];
    float ss = block_sum256(v * v);
    float nraw = sqrtf(ss);
    float n = fmaxf(nraw, 1e-15f);
    float c = tanh_fast(n) * rcp_f(n);
    float ny = c * nraw;
    float np = fmaxf(ny, 1e-15f);
    float s = (np > MAXN) ? MAXN * rcp_f(np) : 1.0f;
    float hv = c * s * v;
    hb[i * DH + t] = hv;
    float s2 = block_sum256(hv * hv);
    if (t == 0) hb2[i] = s2;
}

// wave-per-node (4 nodes/block), lane = 4 feats via uint2; in-place bf16.
__global__ void k_rowfuse1(u16* __restrict__ T, const float* __restrict__ xhn,
                           const float* __restrict__ hb, const float* __restrict__ hb2) {
    int z = blockIdx.y;
    int n = blockIdx.x * 4 + (threadIdx.x >> 6);
    int lane = threadIdx.x & 63;
    u16* row = T + ((size_t)z * N_NODES + n) * DH;
    const float* hbz = hb + (size_t)z * DH;
    uint2 u = *(const uint2*)(row + lane * 4);
    float m0 = blo(u.x), m1 = bhi(u.x), m2 = blo(u.y), m3 = bhi(u.y);
    float ss = wave_sum(m0 * m0 + m1 * m1 + m2 * m2 + m3 * m3);
    float mxn_raw = sqrtf(ss);
    float mxn = fmaxf(mxn_raw, 1e-15f);
    float xn = xhn[n];
    float tt = tanh_fast(mxn * rcp_f(xn) * artanh_fast(xn));
    float coef = tt * rcp_f(mxn);
    float nres = coef * mxn_raw;
    float np = fmaxf(nres, 1e-15f);
    float s1 = (np > MAXN) ? MAXN * rcp_f(np) : 1.0f;
    float cs = coef * s1;
    float r0 = cs * m0, r1 = cs * m1, r2 = cs * m2, r3 = cs * m3;
    float n1 = fminf(np, MAXN);
    float4 hv = *(const float4*)(hbz + lane * 4);
    float xy = wave_sum(r0 * hv.x + r1 * hv.y + r2 * hv.z + r3 * hv.w);
    float x2 = n1 * n1, y2 = hb2[z];
    float ca = 1.0f + 2.0f * xy + y2;
    float cb = 1.0f - x2;
    float rden = rcp_f(fmaxf(1.0f + 2.0f * xy + x2 * y2, 1e-15f));
    float o0 = (ca * r0 + cb * hv.x) * rden;
    float o1 = (ca * r1 + cb * hv.y) * rden;
    float o2 = (ca * r2 + cb * hv.z) * rden;
    float o3 = (ca * r3 + cb * hv.w) * rden;
    float no2 = wave_sum(o0 * o0 + o1 * o1 + o2 * o2 + o3 * o3);
    float nop = fmaxf(sqrtf(no2), 1e-15f);
    float s2 = (nop > MAXN) ? MAXN * rcp_f(nop) : 1.0f;
    float n2 = fminf(nop, MAXN);
    float fin = artanh_fast(n2) * rcp_f(n2) * s2;
    uint2 o; o.x = pk2(fin * o0, fin * o1); o.y = pk2(fin * o2, fin * o3);
    *(uint2*)(row + lane * 4) = o;
}

// wave-per-node CSR gather (packed (src,val)), 2-way ILP unroll, + fused
// rowfuse2 hyperbolic chain -> bf16 out
__global__ void k_gather_fuse2(const int* __restrict__ rowptr, const uint2* __restrict__ padj,
                               const u16* __restrict__ xt, u16* __restrict__ out) {
    int z = blockIdx.y;
    rowptr += (size_t)z * (N_NODES + 1);
    padj += (size_t)z * NE;
    xt += (size_t)z * N_NODES * DH;
    out += (size_t)z * N_NODES * DH;
    int n = blockIdx.x * 4 + (threadIdx.x >> 6);
    int lane = threadIdx.x & 63;
    int beg = rowptr[n], end = rowptr[n + 1];
    float a0 = 0.f, a1 = 0.f, a2 = 0.f, a3 = 0.f;
    float b0 = 0.f, b1 = 0.f, b2 = 0.f, b3 = 0.f;
    int i = beg;
    for (; i + 2 <= end; i += 2) {
        uint2 p0 = padj[i];
        uint2 p1 = padj[i + 1];
        uint2 x0 = *(const uint2*)(xt + (size_t)p0.x * DH + lane * 4);
        uint2 x1 = *(const uint2*)(xt + (size_t)p1.x * DH + lane * 4);
        float v0 = __uint_as_float(p0.y), v1 = __uint_as_float(p1.y);
        a0 = fmaf(v0, blo(x0.x), a0);
        a1 = fmaf(v0, bhi(x0.x), a1);
        a2 = fmaf(v0, blo(x0.y), a2);
        a3 = fmaf(v0, bhi(x0.y), a3);
        b0 = fmaf(v1, blo(x1.x), b0);
        b1 = fmaf(v1, bhi(x1.x), b1);
        b2 = fmaf(v1, blo(x1.y), b2);
        b3 = fmaf(v1, bhi(x1.y), b3);
    }
    if (i < end) {
        uint2 p = padj[i];
        uint2 x0 = *(const uint2*)(xt + (size_t)p.x * DH + lane * 4);
        float v = __uint_as_float(p.y);
        a0 = fmaf(v, blo(x0.x), a0);
        a1 = fmaf(v, bhi(x0.x), a1);
        a2 = fmaf(v, blo(x0.y), a2);
        a3 = fmaf(v, bhi(x0.y), a3);
    }
    a0 += b0; a1 += b1; a2 += b2; a3 += b3;
    float ss = wave_sum(a0 * a0 + a1 * a1 + a2 * a2 + a3 * a3);
    float nraw = sqrtf(ss);
    float n_ = fmaxf(nraw, 1e-15f);
    float c1 = tanh_fast(n_) * rcp_f(n_);
    float nh = c1 * nraw;
    float np1 = fmaxf(nh, 1e-15f);
    float s1 = (np1 > MAXN) ? MAXN * rcp_f(np1) : 1.0f;
    float n1 = fminf(np1, MAXN);
    float cu = artanh_fast(n1) * rcp_f(n1) * s1 * c1;
    float u0 = fmaxf(cu * a0, 0.f), u1 = fmaxf(cu * a1, 0.f);
    float u2 = fmaxf(cu * a2, 0.f), u3 = fmaxf(cu * a3, 0.f);
    float ss2 = wave_sum(u0 * u0 + u1 * u1 + u2 * u2 + u3 * u3);
    float n2raw = sqrtf(ss2);
    float n2 = fmaxf(n2raw, 1e-15f);
    float c3 = tanh_fast(n2) * rcp_f(n2);
    float ne = c3 * n2raw;
    float np3 = fmaxf(ne, 1e-15f);
    float s3 = (np3 > MAXN) ? MAXN * rcp_f(np3) : 1.0f;
    float n3 = fminf(np3, MAXN);
    float cf = artanh_fast(n3) * rcp_f(n3) * s3 * c3;
    uint2 o; o.x = pk2(cf * u0, cf * u1); o.y = pk2(cf * u2, cf * u3);
    *(uint2*)(out + (size_t)n * DH + lane * 4) = o;
}

// wave-per-node: out[n] = d[n] + sum_in d[src]; 2-way ILP unroll; bf16 in/out
__global__ void k_gather_add(const int* __restrict__ rowptr, const int* __restrict__ psrc,
                             const u16* __restrict__ d, u16* __restrict__ out) {
    int z = blockIdx.y;
    rowptr += (size_t)z * (N_NODES + 1);
    psrc += (size_t)z * NE;
    d += (size_t)z * N_NODES * DH;
    out += (size_t)z * N_NODES * DH;
    int n = blockIdx.x * 4 + (threadIdx.x >> 6);
    int lane = threadIdx.x & 63;
    int beg = rowptr[n], end = rowptr[n + 1];
    uint2 u0v = *(const uint2*)(d + (size_t)n * DH + lane * 4);
    float a0 = blo(u0v.x), a1 = bhi(u0v.x), a2 = blo(u0v.y), a3 = bhi(u0v.y);
    float b0 = 0.f, b1 = 0.f, b2 = 0.f, b3 = 0.f;
    int i = beg;
    for (; i + 2 <= end; i += 2) {
        int s0 = psrc[i], s1 = psrc[i + 1];
        uint2 x0 = *(const uint2*)(d + (size_t)s0 * DH + lane * 4);
        uint2 x1 = *(const uint2*)(d + (size_t)s1 * DH + lane * 4);
        a0 += blo(x0.x); a1 += bhi(x0.x); a2 += blo(x0.y); a3 += bhi(x0.y);
        b0 += blo(x1.x); b1 += bhi(x1.x); b2 += blo(x1.y); b3 += bhi(x1.y);
    }
    if (i < end) {
        int s0 = psrc[i];
        uint2 x0 = *(const uint2*)(d + (size_t)s0 * DH + lane * 4);
        a0 += blo(x0.x); a1 += bhi(x0.x); a2 += blo(x0.y); a3 += bhi(x0.y);
    }
    a0 += b0; a1 += b1; a2 += b2; a3 += b3;
    uint2 o; o.x = pk2(a0, a1); o.y = pk2(a2, a3);
    *(uint2*)(out + (size_t)n * DH + lane * 4) = o;
}

// batched column stats from bf16
__global__ void k_colstats(const u16* __restrict__ zp,
                           float* __restrict__ csum, float* __restrict__ csq) {
    int z = blockIdx.y;
    zp += (size_t)z * N_NODES * DH;
    csum += (size_t)z * DH;
    csq += (size_t)z * DH;
    int t = threadIdx.x;
    int r0 = blockIdx.x * 100;
    float s = 0.0f, q = 0.0f;
    for (int r = r0; r < r0 + 100; ++r) {
        float v = b2f(zp[(size_t)r * DH + t]);
        s += v;
        q += v * v;
    }
    atomicAdd(&csum[t], s);
    atomicAdd(&csq[t], q);
}

// grid-stride uint2 batchnorm + tanh, in-place bf16 (total4 = G*N*DH/4)
__global__ void k_normtanh_v(u16* __restrict__ zp, const float* __restrict__ csum,
                             const float* __restrict__ csq, const float* __restrict__ gamma,
                             const float* __restrict__ beta, int total4) {
    const float inv_n = 1.0f / N_NODES;
    int i = blockIdx.x * 256 + threadIdx.x;
    int stride = gridDim.x * 256;
    for (; i < total4; i += stride) {
        int e0 = i * 4;
        int z = e0 / (N_NODES * DH);
        int j0 = e0 & (DH - 1);
        int zb = z * DH + j0;
        uint2 u = ((uint2*)zp)[i];
        float v[4] = {blo(u.x), bhi(u.x), blo(u.y), bhi(u.y)};
        #pragma unroll
        for (int k = 0; k < 4; ++k) {
            float mu = csum[zb + k] * inv_n;
            float var = csq[zb + k] * inv_n - mu * mu;
            float inv = __builtin_amdgcn_rsqf(var + 1e-5f);
            v[k] = tanh_fast((v[k] - mu) * inv * gamma[zb + k] + beta[zb + k]);
        }
        uint2 o; o.x = pk2(v[0], v[1]); o.y = pk2(v[2], v[3]);
        ((uint2*)zp)[i] = o;
    }
}

// f1 slice of S,P (cols 0..511): thread t -> 2 cols via float2, packed u32 store
__global__ void k_pair0(const int* __restrict__ ei, const int* __restrict__ eid,
                        const float* __restrict__ f1, u16* __restrict__ S,
                        u16* __restrict__ P) {
    int b = blockIdx.x, t = threadIdx.x;
    int e = eid[b];
    int n0 = ei[e], n1 = ei[NE2 + e];
    float2 a = *(const float2*)(f1 + (size_t)n0 * D_INN + t * 2);
    float2 c = *(const float2*)(f1 + (size_t)n1 * D_INN + t * 2);
    ((unsigned int*)(S + (size_t)b * H3))[t] = pk2(a.x + c.x, a.y + c.y);
    ((unsigned int*)(P + (size_t)b * H3))[t] = pk2(a.x * c.x, a.y * c.y);
}

// batched channel slice of S,P from z_ch; 4 edges/block, uint2 lanes
__global__ void k_gather_ch(const int* __restrict__ ei, const int* __restrict__ eid,
                            const u16* __restrict__ zch, u16* __restrict__ S,
                            u16* __restrict__ P, int col0base) {
    int z = blockIdx.y;
    const u16* zp = zch + (size_t)z * N_NODES * DH;
    int col0 = col0base + z * DH;
    int b = blockIdx.x * 4 + (threadIdx.x >> 6);
    int lane = threadIdx.x & 63;
    int e = eid[b];
    int n0 = ei[e], n1 = ei[NE2 + e];
    uint2 ua = *(const uint2*)(zp + (size_t)n0 * DH + lane * 4);
    uint2 ub = *(const uint2*)(zp + (size_t)n1 * DH + lane * 4);
    float a0 = blo(ua.x), a1 = bhi(ua.x), a2 = blo(ua.y), a3 = bhi(ua.y);
    float c0 = blo(ub.x), c1 = bhi(ub.x), c2 = blo(ub.y), c3 = bhi(ub.y);
    uint2 so; so.x = pk2(a0 + c0, a1 + c1); so.y = pk2(a2 + c2, a3 + c3);
    uint2 po; po.x = pk2(a0 * c0, a1 * c1); po.y = pk2(a2 * c2, a3 * c3);
    *(uint2*)(S + (size_t)b * H3 + col0 + lane * 4) = so;
    *(uint2*)(P + (size_t)b * H3 + col0 + lane * 4) = po;
}

__global__ void k_final(const u16* __restrict__ h2, const float* __restrict__ Wf3,
                        const float* __restrict__ bf3, float* __restrict__ out) {
    int r = blockIdx.x, t = threadIdx.x;
    const u16* hr = h2 + (size_t)r * 576;
    float acc[7] = {0, 0, 0, 0, 0, 0, 0};
    for (int cb = t; cb < 576; cb += 64) {
        float h = b2f(hr[cb]);
        #pragma unroll
        for (int o = 0; o < 7; ++o) acc[o] = fmaf(h, Wf3[o * 576 + cb], acc[o]);
    }
    #pragma unroll
    for (int o = 0; o < 7; ++o) {
        #pragma unroll
        for (int off = 32; off > 0; off >>= 1) acc[o] += __shfl_down(acc[o], off, 64);
    }
    if (t == 0) {
        #pragma unroll
        for (int o = 0; o < 7; ++o) out[(size_t)r * 7 + o] = acc[o] + bf3[o];
    }
}

// ===== bf16 MFMA GEMM, BK=64, 8-WAVE (512-thr) blocks for occupancy:
// 32KB LDS -> 4 blocks/CU x 8 waves = 32 waves/CU (vs ~20 at 4-wave).
// Wave grid 2Mx4N; per-wave output 64x32 (acc[4][2]); staging 2 gload_lds
// per matrix per wave (same chunk^row involution swizzle, linear LDS dest,
// 2-way bank alias = free). FULL-GRID 3D bijective XCD swizzle.
// EP: 2=sigmoid->bf16, 3=relu->bf16, 5=bf16, 6=relu->f32,
//     7=bf16 + bias + (1+indeg[row])*cvec[col],
//     8=z==0? sigmoid->bf16 : bf16 (for batched gate/int)
template <int EP>
__global__ __launch_bounds__(512, 4) void k_gemm_mfma(
    const u16* __restrict__ A, const u16* __restrict__ W,
    const float* __restrict__ bias, void* __restrict__ outv,
    const int* __restrict__ rpe, const float* __restrict__ cvec,
    int M, int N, int K, size_t sA, size_t sW, size_t sC, int sBias) {
    __shared__ short As[8192];   // 128 rows x 64 cols bf16
    __shared__ short Ws[8192];
    // 3D bijective XCD swizzle over the whole grid
    const int gx = gridDim.x, gy = gridDim.y;
    const int plane = gx * gy;
    const int total = plane * gridDim.z;
    const int orig = (blockIdx.z * gy + blockIdx.y) * gx + blockIdx.x;
    const int q8 = total >> 3, r8 = total & 7, xcd = orig & 7;
    const int wg = (xcd < r8 ? xcd * (q8 + 1) : r8 * (q8 + 1) + (xcd - r8) * q8) + (orig >> 3);
    const int z = wg / plane;
    const int rem = wg - z * plane;
    const int row0 = (rem / gx) * 128, col0 = (rem % gx) * 128;
    A += (size_t)z * sA;
    W += (size_t)z * sW;
    const size_t zC = (size_t)z * sC;
    const int* rp = (EP == 7) ? rpe + (size_t)z * (N_NODES + 1) : nullptr;
    const float* cv = (EP == 7) ? cvec + (size_t)z * DH : nullptr;
    const int t = threadIdx.x;
    const int lane = t & 63;
    const int w = t >> 6;          // 0..7
    const int wr = w >> 2;         // 0..1 (M half)
    const int wc = w & 3;          // 0..3 (N quarter)
    // staging: lane l -> row-in-8block l>>3, src chunk (l&7)^(l>>3)
    const int sr8 = lane >> 3;
    const int csrc = (lane & 7) ^ sr8;
    int gr[2], gc[2];
    #pragma unroll
    for (int p = 0; p < 2; ++p) {
        int rb = w + p * 8;                // 0..15 (8-row blocks)
        gr[p] = row0 + rb * 8 + sr8; if (gr[p] >= M) gr[p] = M - 1;
        gc[p] = col0 + rb * 8 + sr8; if (gc[p] >= N) gc[p] = N - 1;
    }
    const int fr = lane & 15, fq4 = lane >> 4;   // logical chunk q = kk*4 + fq4
    f32x4 acc[4][2] = {};
    for (int k0 = 0; k0 < K; k0 += 64) {
        #pragma unroll
        for (int p = 0; p < 2; ++p) {
            int rb = w + p * 8;
            __builtin_amdgcn_global_load_lds(
                (const __attribute__((address_space(1))) unsigned int*)(A + (size_t)gr[p] * K + k0 + csrc * 8),
                (__attribute__((address_space(3))) unsigned int*)(As + rb * 512), 16, 0, 0);
            __builtin_amdgcn_global_load_lds(
                (const __attribute__((address_space(1))) unsigned int*)(W + (size_t)gc[p] * K + k0 + csrc * 8),
                (__attribute__((address_space(3))) unsigned int*)(Ws + rb * 512), 16, 0, 0);
        }
        __syncthreads();
        bf16x8 af[4][2], bfr[2][2];
        #pragma unroll
        for (int m = 0; m < 4; ++m) {
            int ar = wr * 64 + m * 16 + fr;
            #pragma unroll
            for (int kk = 0; kk < 2; ++kk) {
                int q = kk * 4 + fq4;
                af[m][kk] = *(const bf16x8*)(As + ar * 64 + ((q ^ (ar & 7)) * 8));
            }
        }
        #pragma unroll
        for (int n = 0; n < 2; ++n) {
            int br = wc * 32 + n * 16 + fr;
            #pragma unroll
            for (int kk = 0; kk < 2; ++kk) {
                int q = kk * 4 + fq4;
                bfr[n][kk] = *(const bf16x8*)(Ws + br * 64 + ((q ^ (br & 7)) * 8));
            }
        }
        #pragma unroll
        for (int m = 0; m < 4; ++m)
            #pragma unroll
            for (int n = 0; n < 2; ++n)
                #pragma unroll
                for (int kk = 0; kk < 2; ++kk)
                    acc[m][n] = __builtin_amdgcn_mfma_f32_16x16x32_bf16(
                        af[m][kk], bfr[n][kk], acc[m][n], 0, 0, 0);
        __syncthreads();
    }
    const int cl = lane & 15, rh = (lane >> 4) * 4;
    #pragma unroll
    for (int m = 0; m < 4; ++m) {
        float indf[4];
        if (EP == 7) {
            #pragma unroll
            for (int r = 0; r < 4; ++r) {
                int row = row0 + wr * 64 + m * 16 + rh + r;
                if (row >= M) row = M - 1;
                indf[r] = 1.0f + (float)(rp[row + 1] - rp[row]);
            }
        }
        #pragma unroll
        for (int n = 0; n < 2; ++n) {
            int col = col0 + wc * 32 + n * 16 + cl;
            if (col >= N) continue;
            float bv = bias ? bias[z * sBias + col] : 0.0f;
            float cvc = (EP == 7) ? cv[col] : 0.0f;
            #pragma unroll
            for (int r = 0; r < 4; ++r) {
                int row = row0 + wr * 64 + m * 16 + rh + r;
                if (row >= M) continue;
                float v = acc[m][n][r] + bv;
                size_t idx = zC + (size_t)row * N + col;
                if (EP == 2) ((u16*)outv)[idx] = f2b(sigmoid_fast(v));
                if (EP == 3) ((u16*)outv)[idx] = f2b(fmaxf(v, 0.0f));
                if (EP == 5) ((u16*)outv)[idx] = f2b(v);
                if (EP == 6) ((float*)outv)[idx] = fmaxf(v, 0.0f);
                if (EP == 7) ((u16*)outv)[idx] = f2b(v + indf[r] * cvc);
                if (EP == 8) ((u16*)outv)[idx] = (z == 0) ? f2b(sigmoid_fast(v)) : f2b(v);
            }
        }
    }
}

static inline void gemm_b(int ep, const u16* A, const u16* W, const float* bias, void* out,
                          const int* rpe, const float* cvec,
                          int M, int N, int K, int Z,
                          size_t sA, size_t sW, size_t sC, int sBias, hipStream_t st) {
    dim3 g((N + 127) / 128, (M + 127) / 128, Z);
    switch (ep) {
        case 2: k_gemm_mfma<2><<<g, 512, 0, st>>>(A, W, bias, out, rpe, cvec, M, N, K, sA, sW, sC, sBias); break;
        case 3: k_gemm_mfma<3><<<g, 512, 0, st>>>(A, W, bias, out, rpe, cvec, M, N, K, sA, sW, sC, sBias); break;
        case 5: k_gemm_mfma<5><<<g, 512, 0, st>>>(A, W, bias, out, rpe, cvec, M, N, K, sA, sW, sC, sBias); break;
        case 6: k_gemm_mfma<6><<<g, 512, 0, st>>>(A, W, bias, out, rpe, cvec, M, N, K, sA, sW, sC, sBias); break;
        case 7: k_gemm_mfma<7><<<g, 512, 0, st>>>(A, W, bias, out, rpe, cvec, M, N, K, sA, sW, sC, sBias); break;
        case 8: k_gemm_mfma<8><<<g, 512, 0, st>>>(A, W, bias, out, rpe, cvec, M, N, K, sA, sW, sC, sBias); break;
    }
}

static inline void conv_w(const float* s, u16* d, size_t n, hipStream_t st) {
    int n4 = (int)(n / 4);
    int grid = (n4 + 255) / 256;
    if (grid > 2048) grid = 2048;
    k_f2b<<<grid, 256, 0, st>>>(s, d, n4);
}

extern "C" void kernel_launch(void* const* d_in, const int* in_sizes, int n_in, void* d_out,
                              int out_size, void* d_ws, size_t ws_size, hipStream_t stream) {
    const float* f1 = (const float*)d_in[0];
    const int* adj_src = (const int*)d_in[1];
    const int* adj_dst = (const int*)d_in[2];
    const float* adj_val = (const float*)d_in[3];
    const int* edge_src = (const int*)d_in[4];
    const int* edge_dst = (const int*)d_in[5];
    const int* edge_index = (const int*)d_in[6];
    const int* edge_id = (const int*)d_in[7];
    const float* W_hyp = (const float*)d_in[8];
    const float* b_hyp = (const float*)d_in[9];
    const float* Wd = (const float*)d_in[10];
    const float* bd = (const float*)d_in[11];
    const float* Wg1 = (const float*)d_in[12];
    const float* bg1 = (const float*)d_in[13];
    const float* gamma = (const float*)d_in[14];
    const float* beta = (const float*)d_in[15];
    const float* Wg2 = (const float*)d_in[16];
    const float* bg2 = (const float*)d_in[17];
    const float* Wgate = (const float*)d_in[18];
    const float* bgate = (const float*)d_in[19];
    const float* Wint = (const float*)d_in[20];
    const float* bint = (const float*)d_in[21];
    const float* Wout = (const float*)d_in[22];
    const float* bout = (const float*)d_in[23];
    const float* Wf1 = (const float*)d_in[24];
    const float* bf1 = (const float*)d_in[25];
    const float* Wf2 = (const float*)d_in[26];
    const float* bf2 = (const float*)d_in[27];
    const float* Wf3 = (const float*)d_in[28];
    const float* bf3 = (const float*)d_in[29];
    float* outp = (float*)d_out;

    const bool single = ws_size >= 253400000ull;
    const int ngroups = single ? 1 : 2;
    const int GM = single ? 7 : 4;
    int g0s[2] = {0, 4};
    int gns[2] = {GM, 3};

    // ---- workspace bump allocator ----
    char* base = (char*)d_ws;
    size_t off = 0;
    auto alloc = [&](size_t bytes) -> char* {
        char* p = base + off;
        off += (bytes + 255) & ~(size_t)255;
        return p;
    };
    u16* Whyp_b = (u16*)alloc((size_t)NCH * DH * D_INN * 2);
    u16* Wc_b   = (u16*)alloc((size_t)NCH * DH * DH * 2);   // Wg1 @ Wd
    u16* Wg1_b  = (u16*)alloc((size_t)NCH * DH * DH * 2);
    u16* Wg2_b  = (u16*)alloc((size_t)NCH * DH * DH * 2);
    u16* Wgate_b = (u16*)alloc((size_t)H3 * H3 * 2);        // Wint_b must follow!
    u16* Wint_b  = (u16*)alloc((size_t)H3 * H3 * 2);
    u16* Wcomb_b = (u16*)alloc((size_t)1152 * H3 * 2);      // Wf1 @ Wout
    u16* Wf2_b   = (u16*)alloc((size_t)576 * 1152 * 2);
    u16* S_b = (u16*)alloc((size_t)NB * H3 * 2);            // P_b must follow!
    u16* P_b = (u16*)alloc((size_t)NB * H3 * 2);
    const size_t NDB = (size_t)N_NODES * DH;       // per-channel elems
    u16* buf1 = (u16*)alloc((size_t)GM * NDB * 2); // group ping (buf2 follows)
    u16* buf2 = (u16*)alloc((size_t)GM * NDB * 2); // group pong
    u16* xhyp_b = single ? buf2 : (u16*)alloc((size_t)N_NODES * D_INN * 2);
    // CSR scratch (2*GM slices): adj slices [0,G), edge slices [G,2G).
    // Single mode: final padj/psrcE alias into S_b; cnt/rowptr + binned
    // scratch alias into P_b -- all dead before S/P get written.
    int* cntC; int* rowptrC; uint2* padjC; int* psrcE;
    uint2* scrA = nullptr; unsigned int* scrE = nullptr;
    if (single) {
        padjC = (uint2*)S_b;                                   // 17,920,000 B
        psrcE = (int*)((char*)S_b + (size_t)GM * NE * 8);      // +8,960,000 B
        cntC = (int*)P_b;                                      // 1,120,000 B
        rowptrC = (int*)((char*)P_b + (size_t)2 * GM * N_NODES * 4);
        size_t rp_end = (size_t)2 * GM * N_NODES * 4 + (size_t)2 * GM * (N_NODES + 1) * 4;
        rp_end = (rp_end + 63) & ~(size_t)63;
        scrA = (uint2*)((char*)P_b + rp_end);                  // 17,920,000 B
        scrE = (unsigned int*)((char*)scrA + (size_t)GM * NE * 8);  // +8,960,000 B
    } else {
        cntC = (int*)alloc((size_t)2 * GM * N_NODES * 4);
        rowptrC = (int*)alloc((size_t)2 * GM * (N_NODES + 1) * 4);
        padjC = (uint2*)alloc((size_t)GM * NE * 8);
        psrcE = (int*)alloc((size_t)GM * NE * 4);
    }
    float* xhn = (float*)alloc((size_t)N_NODES * 4);
    float* hb = (float*)alloc((size_t)NCH * DH * 4);
    float* hb2 = (float*)alloc(NCH * 4);
    float* csum = (float*)alloc((size_t)GM * DH * 4);        // csq follows
    float* csq = (float*)alloc((size_t)GM * DH * 4);
    float* cvec_d = (float*)alloc((size_t)NCH * DH * 4);
    float* bias2 = (float*)alloc((size_t)2 * H3 * 4);
    float* bcomb = (float*)alloc((size_t)1152 * 4);
    int* bcur = (int*)alloc((size_t)2 * NCH * NBUK * 4);     // bucket cursors
    // precompute-only temp weights alias into buf1 (idle until GNN phase):
    u16* WoutT_b = buf1;                          // 10.62 MB
    u16* Wf1_b = buf1 + (size_t)H3 * H3;          // +5.31 MB
    u16* Wdt_b = Wf1_b + (size_t)1152 * H3;       // +0.92 MB (total 16.8 <= buf1)
    // stage-C overlays: GT spans buf1(+buf2 head); h1 -> buf1; h2 -> buf2.
    u16* GT = buf1;
    u16* h2b = buf2;

    const int EG = (NE + 255) / 256;

    conv_w(W_hyp, Whyp_b, (size_t)NCH * DH * D_INN, stream);
    conv_w(Wg1, Wg1_b, (size_t)NCH * DH * DH, stream);
    conv_w(Wg2, Wg2_b, (size_t)NCH * DH * DH, stream);
    conv_w(Wgate, Wgate_b, (size_t)H3 * H3, stream);
    conv_w(Wint, Wint_b, (size_t)H3 * H3, stream);
    conv_w(Wf1, Wf1_b, (size_t)1152 * H3, stream);
    conv_w(Wf2, Wf2_b, (size_t)576 * 1152, stream);
    k_bias2<<<(2 * H3 + 255) / 256, 256, 0, stream>>>(bgate, bint, bias2);
    // Wc = Wg1 @ Wd (via Wd^T), cvec = Wg1 @ bd
    k_twd<<<dim3(16, 16, NCH), 256, 0, stream>>>(Wd, Wdt_b);
    gemm_b(5, Wg1_b, Wdt_b, nullptr, Wc_b, nullptr, nullptr,
           DH, DH, DH, NCH, (size_t)DH * DH, (size_t)DH * DH, (size_t)DH * DH, 0, stream);
    k_cvec<<<NCH, 256, 0, stream>>>(Wg1, bd, cvec_d);
    // Wcomb = Wf1 @ Wout (Wout GEMM folded into Wf1), bcomb = Wf1@bout + bf1
    k_tr<<<dim3(144, 144), 256, 0, stream>>>(Wout, WoutT_b);
    gemm_b(5, Wf1_b, WoutT_b, nullptr, Wcomb_b, nullptr, nullptr,
           1152, H3, H3, 1, 0, 0, 0, 0, stream);
    k_bvec<<<1152 / 4, 256, 0, stream>>>(Wf1, bout, bf1, bcomb);

    k_expmap_proj_in<<<N_NODES, 256, 0, stream>>>(f1, xhyp_b, xhn);
    k_hb<<<NCH, 256, 0, stream>>>(b_hyp, hb, hb2);
    if (!single) k_pair0<<<NB, 256, 0, stream>>>(edge_index, edge_id, f1, S_b, P_b);

    for (int gi = 0; gi < ngroups; ++gi) {
        const int g0 = g0s[gi], G = gns[gi];
        const size_t eoff = (size_t)g0 * NE;
        const int G2 = 2 * G;
        const int* rpE = rowptrC + (size_t)G * (N_NODES + 1);
        // --- merged CSR build ---
        k_izero<<<(G2 * N_NODES + 255) / 256, 256, 0, stream>>>(cntC, G2 * N_NODES);
        k_hist2<<<dim3(EG, G2), 256, 0, stream>>>(adj_dst + eoff, edge_dst + eoff, cntC, G);
        k_scan<<<G2, 256, 0, stream>>>(cntC, rowptrC);
        if (single) {
            k_bcur<<<(G2 * NBUK + 255) / 256, 256, 0, stream>>>(rowptrC, bcur, G2);
            k_binA<<<dim3(EG, G2), 256, 0, stream>>>(adj_src, adj_dst, adj_val,
                                                     edge_src, edge_dst, bcur,
                                                     scrA, scrE, G);
            k_placeB<<<dim3(NBUK, G2), 256, 0, stream>>>(rowptrC, scrA, scrE,
                                                         padjC, psrcE, G);
        } else {
            k_place2<<<dim3(EG, G2), 256, 0, stream>>>(adj_src + eoff, adj_dst + eoff,
                                                       adj_val + eoff, edge_src + eoff,
                                                       edge_dst + eoff, cntC, padjC,
                                                       psrcE, G);
        }
        // --- batched pipeline ---
        gemm_b(5, xhyp_b, Whyp_b + (size_t)g0 * DH * D_INN, nullptr, buf1, nullptr,
               nullptr, N_NODES, DH, D_INN, G, 0, (size_t)DH * D_INN, NDB, 0, stream);
        k_rowfuse1<<<dim3(N_NODES / 4, G), 256, 0, stream>>>(buf1, xhn, hb + g0 * DH, hb2 + g0);
        k_gather_fuse2<<<dim3(N_NODES / 4, G), 256, 0, stream>>>(rowptrC, padjC, buf1, buf2);
        // ug = (I + S_e) u
        k_gather_add<<<dim3(N_NODES / 4, G), 256, 0, stream>>>(rpE, psrcE, buf2, buf1);
        // z = ug @ Wc^T + (1+indeg)*cvec + bg1   (Wd GEMM fused away)
        gemm_b(7, buf1, Wc_b + (size_t)g0 * DH * DH, bg1 + g0 * DH, buf2,
               rpE, cvec_d + (size_t)g0 * DH, N_NODES, DH, DH, G,
               NDB, (size_t)DH * DH, NDB, DH, stream);
        k_zero<<<(2 * GM * DH + 255) / 256, 256, 0, stream>>>(csum, 2 * GM * DH);
        k_colstats<<<dim3(200, G), 256, 0, stream>>>(buf2, csum, csq);
        {
            int total4 = (int)(G * NDB / 4);
            int blocks = (total4 + 255) / 256;
            if (blocks > 2048) blocks = 2048;
            k_normtanh_v<<<blocks, 256, 0, stream>>>(buf2, csum, csq, gamma + g0 * DH,
                                                     beta + g0 * DH, total4);
        }
        gemm_b(5, buf2, Wg2_b + (size_t)g0 * DH * DH, bg2 + g0 * DH, buf1, nullptr,
               nullptr, N_NODES, DH, DH, G, NDB, (size_t)DH * DH, NDB, DH, stream);
        if (!single)
            k_gather_ch<<<dim3(NB / 4, G), 256, 0, stream>>>(edge_index, edge_id, buf1,
                                                             S_b, P_b, D_INN + g0 * DH);
    }
    if (single) {
        // CSR scratch (aliased in S_b/P_b) is dead now; build S,P.
        k_pair0<<<NB, 256, 0, stream>>>(edge_index, edge_id, f1, S_b, P_b);
        k_gather_ch<<<dim3(NB / 4, 7), 256, 0, stream>>>(edge_index, edge_id, buf1,
                                                         S_b, P_b, D_INN);
    }

    // stage C: batched gate/int (Z=2), gi elementwise, fused h1 (Wout folded
    // into Wf1 via Wcomb), h2 (bf16), final.
    gemm_b(8, S_b, Wgate_b, bias2, GT, nullptr, nullptr, NB, H3, H3, 2,
           (size_t)NB * H3, (size_t)H3 * H3, (size_t)NB * H3, H3, stream);
    {
        int total4 = NB * H3 / 4;
        int blocks = (total4 + 255) / 256;
        if (blocks > 2048) blocks = 2048;
        k_gi<<<blocks, 256, 0, stream>>>(GT, GT + (size_t)NB * H3, S_b, total4);
    }
    // h1 = relu(gi @ Wcomb^T + bcomb)
    gemm_b(3, S_b, Wcomb_b, bcomb, buf1, nullptr, nullptr, NB, 1152, H3, 1, 0, 0, 0, 0, stream);
    // h2 = relu(h1 @ Wf2^T + bf2) -> bf16
    gemm_b(3, buf1, Wf2_b, bf2, h2b, nullptr, nullptr, NB, 576, 1152, 1, 0, 0, 0, 0, stream);
    k_final<<<NB, 64, 0, stream>>>(h2b, Wf3, bf3, outp);
}

// Round 19
// 1413.702 us; speedup vs baseline: 1.6532x; 1.0324x over previous
//
#include <hip/hip_runtime.h>
#include <math.h>

#define N_NODES 20000
#define D_INN   512
#define DH      256
#define NCH     7
#define NE      320000
#define NE2     100000
#define NB      8192
#define H3      2304   // 512 + 7*256
#define MAXN    0.996f
#define LOG2E   1.44269504f
#define NBUK    40     // dst buckets of 512 nodes
#define BSH     9

typedef unsigned short u16;
typedef __attribute__((ext_vector_type(8))) short bf16x8;
typedef __attribute__((ext_vector_type(4))) float f32x4;

__device__ __forceinline__ u16 f2b(float f) {    // RNE f32 -> bf16 bits
    unsigned int x = __float_as_uint(f);
    unsigned int r = (x + 0x7fffu + ((x >> 16) & 1u)) >> 16;
    return (u16)r;
}
__device__ __forceinline__ float b2f(u16 u) {
    return __uint_as_float(((unsigned int)u) << 16);
}
__device__ __forceinline__ float blo(unsigned int u) { return __uint_as_float(u << 16); }
__device__ __forceinline__ float bhi(unsigned int u) { return __uint_as_float(u & 0xffff0000u); }
__device__ __forceinline__ unsigned int pk2(float a, float b) {
    return (unsigned int)f2b(a) | ((unsigned int)f2b(b) << 16);
}

// ---- fast HW transcendentals (rel err ~1e-5, fine for bf16 tolerance) ----
__device__ __forceinline__ float rcp_f(float x) { return __builtin_amdgcn_rcpf(x); }
__device__ __forceinline__ float exp2_f(float x) { return __builtin_amdgcn_exp2f(x); }
__device__ __forceinline__ float log2_f(float x) { return __builtin_amdgcn_logf(x); }
__device__ __forceinline__ float tanh_fast(float x) {
    float xc = fminf(fmaxf(x, -15.f), 15.f);
    float t = exp2_f(xc * (2.f * LOG2E));
    return (t - 1.f) * rcp_f(t + 1.f);
}
__device__ __forceinline__ float artanh_fast(float x) {
    x = fminf(fmaxf(x, -1.0f + 1e-7f), 1.0f - 1e-7f);
    return 0.34657359f * log2_f((1.f + x) * rcp_f(1.f - x));
}
__device__ __forceinline__ float sigmoid_fast(float x) {
    return rcp_f(1.f + exp2_f(-x * LOG2E));
}

__device__ __forceinline__ float wave_sum(float v) {
    #pragma unroll
    for (int off = 32; off > 0; off >>= 1) v += __shfl_xor(v, off, 64);
    return v;
}

__device__ __forceinline__ float block_sum256(float v) {
    __shared__ float sred[4];
    #pragma unroll
    for (int off = 32; off > 0; off >>= 1) v += __shfl_down(v, off, 64);
    int lane = threadIdx.x & 63;
    int w = threadIdx.x >> 6;
    if (lane == 0) sred[w] = v;
    __syncthreads();
    float tot = sred[0] + sred[1] + sred[2] + sred[3];
    __syncthreads();
    return tot;
}

__global__ void k_zero(float* __restrict__ p, int n) {
    int i = blockIdx.x * 256 + threadIdx.x;
    if (i < n) p[i] = 0.0f;
}
__global__ void k_izero(int* __restrict__ p, int n) {
    int i = blockIdx.x * 256 + threadIdx.x;
    if (i < n) p[i] = 0;
}

__global__ void k_f2b(const float* __restrict__ s, u16* __restrict__ d, int n4) {
    int i = blockIdx.x * 256 + threadIdx.x;
    int stride = gridDim.x * 256;
    for (; i < n4; i += stride) {
        float4 v = ((const float4*)s)[i];
        uint2 o; o.x = pk2(v.x, v.y); o.y = pk2(v.z, v.w);
        ((uint2*)d)[i] = o;
    }
}

// pack two bias vectors contiguously (for batched gate/int GEMM)
__global__ void k_bias2(const float* __restrict__ a, const float* __restrict__ b,
                        float* __restrict__ o) {
    int i = blockIdx.x * 256 + threadIdx.x;
    if (i < H3) o[i] = a[i];
    else if (i < 2 * H3) o[i] = b[i - H3];
}

// gi = gate * relu(tmp), all bf16, vectorized
__global__ void k_gi(const u16* __restrict__ gate, const u16* __restrict__ tmp,
                     u16* __restrict__ out, int total4) {
    int i = blockIdx.x * 256 + threadIdx.x;
    int stride = gridDim.x * 256;
    for (; i < total4; i += stride) {
        uint2 g = ((const uint2*)gate)[i];
        uint2 t = ((const uint2*)tmp)[i];
        uint2 o;
        o.x = pk2(blo(g.x) * fmaxf(blo(t.x), 0.f), bhi(g.x) * fmaxf(bhi(t.x), 0.f));
        o.y = pk2(blo(g.y) * fmaxf(blo(t.y), 0.f), bhi(g.y) * fmaxf(bhi(t.y), 0.f));
        ((uint2*)out)[i] = o;
    }
}

// Wd transpose -> bf16 (for Wc = Wg1 @ Wd via A@W^T kernel)
__global__ void k_twd(const float* __restrict__ Wd, u16* __restrict__ Wdt) {
    __shared__ float tile[16][17];
    int z = blockIdx.z;
    int bx = blockIdx.x * 16, by = blockIdx.y * 16;
    int tx = threadIdx.x & 15, ty = threadIdx.x >> 4;
    tile[ty][tx] = Wd[(size_t)z * DH * DH + (size_t)(by + ty) * DH + bx + tx];
    __syncthreads();
    Wdt[(size_t)z * DH * DH + (size_t)(bx + ty) * DH + by + tx] = f2b(tile[tx][ty]);
}

// 2304x2304 transpose f32 -> bf16 (WoutT[i][j] = Wout[j][i])
__global__ void k_tr(const float* __restrict__ Win, u16* __restrict__ Wt) {
    __shared__ float tile[16][17];
    int bx = blockIdx.x * 16, by = blockIdx.y * 16;
    int tx = threadIdx.x & 15, ty = threadIdx.x >> 4;
    tile[ty][tx] = Win[(size_t)(by + ty) * H3 + bx + tx];
    __syncthreads();
    Wt[(size_t)(bx + ty) * H3 + by + tx] = f2b(tile[tx][ty]);
}

// bcomb[r] = sum_j Wf1[r][j]*bout[j] + bf1[r]  (wave per row, 4 rows/block)
__global__ void k_bvec(const float* __restrict__ Wf1, const float* __restrict__ bout,
                       const float* __restrict__ bf1, float* __restrict__ bcomb) {
    int r = blockIdx.x * 4 + (threadIdx.x >> 6);
    int lane = threadIdx.x & 63;
    const float* row = Wf1 + (size_t)r * H3;
    float s = 0.f;
    for (int j = lane; j < H3; j += 64) s = fmaf(row[j], bout[j], s);
    s = wave_sum(s);
    if (lane == 0) bcomb[r] = s + bf1[r];
}

// cvec[z][j] = sum_k Wg1[z][j][k] * bd[z][k]   (f32)
__global__ void k_cvec(const float* __restrict__ Wg1, const float* __restrict__ bd,
                       float* __restrict__ cvec) {
    int z = blockIdx.x, j = threadIdx.x;
    const float* row = Wg1 + (size_t)z * DH * DH + (size_t)j * DH;
    const float* b = bd + (size_t)z * DH;
    float s = 0.f;
    for (int k = 0; k < DH; ++k) s = fmaf(row[k], b[k], s);
    cvec[(size_t)z * DH + j] = s;
}

// ===== merged CSR build: 2G z-slices (z<G: adj graph, z>=G: edge graph) =====
__global__ void k_hist2(const int* __restrict__ adjd, const int* __restrict__ edged,
                        int* __restrict__ cnt, int G) {
    int z = blockIdx.y;
    const int* dst = (z < G) ? adjd + (size_t)z * NE : edged + (size_t)(z - G) * NE;
    cnt += (size_t)z * N_NODES;
    int i = blockIdx.x * 256 + threadIdx.x;
    if (i < NE) atomicAdd(&cnt[dst[i]], 1);
}

// one block per slice; cnt becomes the cursor array in-place
__global__ void k_scan(int* __restrict__ cnt, int* __restrict__ rowptr) {
    int z = blockIdx.x;
    cnt += (size_t)z * N_NODES;
    rowptr += (size_t)z * (N_NODES + 1);
    __shared__ int part[256];
    int t = threadIdx.x;
    const int CH = (N_NODES + 255) / 256;
    int beg = t * CH;
    int end = beg + CH; if (end > N_NODES) end = N_NODES;
    int s = 0;
    for (int i = beg; i < end; ++i) s += cnt[i];
    part[t] = s;
    __syncthreads();
    for (int off = 1; off < 256; off <<= 1) {
        int v = (t >= off) ? part[t - off] : 0;
        __syncthreads();
        part[t] += v;
        __syncthreads();
    }
    int run = (t == 0) ? 0 : part[t - 1];
    for (int i = beg; i < end; ++i) {
        int c = cnt[i];
        rowptr[i] = run;
        cnt[i] = run;      // cursor init (in-place)
        run += c;
    }
    if (t == 255) rowptr[N_NODES] = part[255];
}

// legacy 1-phase place (2-group fallback path)
__global__ void k_place2(const int* __restrict__ adjs, const int* __restrict__ adjd,
                         const float* __restrict__ adjv, const int* __restrict__ edges,
                         const int* __restrict__ edged, int* __restrict__ cursor,
                         uint2* __restrict__ padj, int* __restrict__ psrcE, int G) {
    int z = blockIdx.y;
    bool isadj = z < G;
    const int* src = isadj ? adjs + (size_t)z * NE : edges + (size_t)(z - G) * NE;
    const int* dst = isadj ? adjd + (size_t)z * NE : edged + (size_t)(z - G) * NE;
    cursor += (size_t)z * N_NODES;
    int i = blockIdx.x * 256 + threadIdx.x;
    if (i < NE) {
        int d = dst[i];
        int pos = atomicAdd(&cursor[d], 1);
        if (isadj) {
            uint2 p;
            p.x = (unsigned int)src[i];
            p.y = __float_as_uint(adjv[(size_t)z * NE + i]);
            padj[(size_t)z * NE + pos] = p;
        } else {
            psrcE[(size_t)(z - G) * NE + pos] = src[i];
        }
    }
}

// bucket cursors init: bcur[z][b] = rowptr[z][b*512]
__global__ void k_bcur(const int* __restrict__ rowptr, int* __restrict__ bcur, int G2) {
    int i = blockIdx.x * 256 + threadIdx.x;
    if (i < G2 * NBUK) {
        int z = i / NBUK, b = i - z * NBUK;
        bcur[i] = rowptr[(size_t)z * (N_NODES + 1) + (b << BSH)];
    }
}

// phase A: bin edges into bucket-contiguous scratch (regions = final CSR
// bucket ranges). LDS-aggregated claims: one global atomic per bucket/block,
// writes land in ~contiguous runs. (src,dst) packed 15+15 bits.
__global__ void k_binA(const int* __restrict__ adjs, const int* __restrict__ adjd,
                       const float* __restrict__ adjv, const int* __restrict__ edges,
                       const int* __restrict__ edged, int* __restrict__ bcur,
                       uint2* __restrict__ scrA, unsigned int* __restrict__ scrE, int G) {
    int z = blockIdx.y;
    bool isadj = z < G;
    const int* src = isadj ? adjs + (size_t)z * NE : edges + (size_t)(z - G) * NE;
    const int* dst = isadj ? adjd + (size_t)z * NE : edged + (size_t)(z - G) * NE;
    __shared__ int hcnt[NBUK];
    __shared__ int gbase[NBUK];
    int t = threadIdx.x;
    int i = blockIdx.x * 256 + t;
    if (t < NBUK) hcnt[t] = 0;
    __syncthreads();
    int s = 0, d = 0, buk = 0, rank = 0;
    bool valid = i < NE;
    if (valid) {
        s = src[i]; d = dst[i];
        buk = d >> BSH;
        rank = atomicAdd(&hcnt[buk], 1);
    }
    __syncthreads();
    if (t < NBUK && hcnt[t] > 0)
        gbase[t] = atomicAdd(&bcur[z * NBUK + t], hcnt[t]);
    __syncthreads();
    if (valid) {
        int pos = gbase[buk] + rank;
        unsigned int sd = (unsigned int)s | ((unsigned int)d << 15);
        if (isadj) {
            uint2 p; p.x = sd; p.y = __float_as_uint(adjv[(size_t)z * NE + i]);
            scrA[(size_t)z * NE + pos] = p;
        } else {
            scrE[(size_t)(z - G) * NE + pos] = sd;
        }
    }
}

// phase B: one block per (bucket, z). LDS cursors for the bucket's 512 nodes;
// reads coalesced from bucket region; final scatter confined to the bucket's
// ~64KB CSR window (L2-absorbed).
__global__ void k_placeB(const int* __restrict__ rowptr, const uint2* __restrict__ scrA,
                         const unsigned int* __restrict__ scrE, uint2* __restrict__ padj,
                         int* __restrict__ psrcE, int G) {
    int z = blockIdx.y;
    int b = blockIdx.x;
    bool isadj = z < G;
    const int* rp = rowptr + (size_t)z * (N_NODES + 1);
    __shared__ int cur[512];
    int t = threadIdx.x;
    int n0 = b << BSH;
    for (int k = t; k < 512; k += 256) {
        int node = n0 + k;
        cur[k] = (node < N_NODES) ? rp[node] : 0;
    }
    __syncthreads();
    int beg = rp[n0];
    int nend = n0 + 512; if (nend > N_NODES) nend = N_NODES;
    int end = rp[nend];
    if (isadj) {
        const uint2* sc = scrA + (size_t)z * NE;
        uint2* out = padj + (size_t)z * NE;
        for (int i = beg + t; i < end; i += 256) {
            uint2 p = sc[i];
            int d = (int)((p.x >> 15) & 0x7fffu);
            int pos = atomicAdd(&cur[d - n0], 1);
            uint2 o; o.x = p.x & 0x7fffu; o.y = p.y;
            out[pos] = o;
        }
    } else {
        const unsigned int* sc = scrE + (size_t)(z - G) * NE;
        int* out = psrcE + (size_t)(z - G) * NE;
        for (int i = beg + t; i < end; i += 256) {
            unsigned int p = sc[i];
            int d = (int)((p >> 15) & 0x7fffu);
            int pos = atomicAdd(&cur[d - n0], 1);
            out[pos] = (int)(p & 0x7fffu);
        }
    }
}

// x_hyp = proj(expmap0(f1)) -> bf16; clamped row norm -> xhn (f32)
__global__ void k_expmap_proj_in(const float* __restrict__ f1,
                                 u16* __restrict__ xhyp, float* __restrict__ xhn) {
    int r = blockIdx.x, t = threadIdx.x;
    const float* u = f1 + (size_t)r * D_INN;
    float v0 = u[t], v1 = u[t + 256];
    float ss = block_sum256(v0 * v0 + v1 * v1);
    float nraw = sqrtf(ss);
    float n = fmaxf(nraw, 1e-15f);
    float c = tanh_fast(n) * rcp_f(n);
    float ny = c * nraw;
    float np = fmaxf(ny, 1e-15f);
    float s = (np > MAXN) ? MAXN * rcp_f(np) : 1.0f;
    float cs = c * s;
    u16* o = xhyp + (size_t)r * D_INN;
    o[t] = f2b(cs * v0);
    o[t + 256] = f2b(cs * v1);
    if (t == 0) xhn[r] = fminf(np, MAXN);
}

__global__ void k_hb(const float* __restrict__ b_hyp,
                     float* __restrict__ hb, float* __restrict__ hb2) {
    int i = blockIdx.x, t = threadIdx.x;
    float v = b_hyp[i * DH + t];
    float ss = block_sum256(v * v);
    float nraw = sqrtf(ss);
    float n = fmaxf(nraw, 1e-15f);
    float c = tanh_fast(n) * rcp_f(n);
    float ny = c * nraw;
    float np = fmaxf(ny, 1e-15f);
    float s = (np > MAXN) ? MAXN * rcp_f(np) : 1.0f;
    float hv = c * s * v;
    hb[i * DH + t] = hv;
    float s2 = block_sum256(hv * hv);
    if (t == 0) hb2[i] = s2;
}

// wave-per-node (4 nodes/block), lane = 4 feats via uint2; in-place bf16.
__global__ void k_rowfuse1(u16* __restrict__ T, const float* __restrict__ xhn,
                           const float* __restrict__ hb, const float* __restrict__ hb2) {
    int z = blockIdx.y;
    int n = blockIdx.x * 4 + (threadIdx.x >> 6);
    int lane = threadIdx.x & 63;
    u16* row = T + ((size_t)z * N_NODES + n) * DH;
    const float* hbz = hb + (size_t)z * DH;
    uint2 u = *(const uint2*)(row + lane * 4);
    float m0 = blo(u.x), m1 = bhi(u.x), m2 = blo(u.y), m3 = bhi(u.y);
    float ss = wave_sum(m0 * m0 + m1 * m1 + m2 * m2 + m3 * m3);
    float mxn_raw = sqrtf(ss);
    float mxn = fmaxf(mxn_raw, 1e-15f);
    float xn = xhn[n];
    float tt = tanh_fast(mxn * rcp_f(xn) * artanh_fast(xn));
    float coef = tt * rcp_f(mxn);
    float nres = coef * mxn_raw;
    float np = fmaxf(nres, 1e-15f);
    float s1 = (np > MAXN) ? MAXN * rcp_f(np) : 1.0f;
    float cs = coef * s1;
    float r0 = cs * m0, r1 = cs * m1, r2 = cs * m2, r3 = cs * m3;
    float n1 = fminf(np, MAXN);
    float4 hv = *(const float4*)(hbz + lane * 4);
    float xy = wave_sum(r0 * hv.x + r1 * hv.y + r2 * hv.z + r3 * hv.w);
    float x2 = n1 * n1, y2 = hb2[z];
    float ca = 1.0f + 2.0f * xy + y2;
    float cb = 1.0f - x2;
    float rden = rcp_f(fmaxf(1.0f + 2.0f * xy + x2 * y2, 1e-15f));
    float o0 = (ca * r0 + cb * hv.x) * rden;
    float o1 = (ca * r1 + cb * hv.y) * rden;
    float o2 = (ca * r2 + cb * hv.z) * rden;
    float o3 = (ca * r3 + cb * hv.w) * rden;
    float no2 = wave_sum(o0 * o0 + o1 * o1 + o2 * o2 + o3 * o3);
    float nop = fmaxf(sqrtf(no2), 1e-15f);
    float s2 = (nop > MAXN) ? MAXN * rcp_f(nop) : 1.0f;
    float n2 = fminf(nop, MAXN);
    float fin = artanh_fast(n2) * rcp_f(n2) * s2;
    uint2 o; o.x = pk2(fin * o0, fin * o1); o.y = pk2(fin * o2, fin * o3);
    *(uint2*)(row + lane * 4) = o;
}

// wave-per-node CSR gather (packed (src,val)), 4-way ILP unroll, + fused
// rowfuse2 hyperbolic chain -> bf16 out
__global__ void k_gather_fuse2(const int* __restrict__ rowptr, const uint2* __restrict__ padj,
                               const u16* __restrict__ xt, u16* __restrict__ out) {
    int z = blockIdx.y;
    rowptr += (size_t)z * (N_NODES + 1);
    padj += (size_t)z * NE;
    xt += (size_t)z * N_NODES * DH;
    out += (size_t)z * N_NODES * DH;
    int n = blockIdx.x * 4 + (threadIdx.x >> 6);
    int lane = threadIdx.x & 63;
    int beg = rowptr[n], end = rowptr[n + 1];
    float a0 = 0.f, a1 = 0.f, a2 = 0.f, a3 = 0.f;
    float b0 = 0.f, b1 = 0.f, b2 = 0.f, b3 = 0.f;
    float c0 = 0.f, c1 = 0.f, c2 = 0.f, c3 = 0.f;
    float d0 = 0.f, d1 = 0.f, d2 = 0.f, d3 = 0.f;
    int i = beg;
    for (; i + 4 <= end; i += 4) {
        uint2 p0 = padj[i];
        uint2 p1 = padj[i + 1];
        uint2 p2 = padj[i + 2];
        uint2 p3 = padj[i + 3];
        uint2 x0 = *(const uint2*)(xt + (size_t)p0.x * DH + lane * 4);
        uint2 x1 = *(const uint2*)(xt + (size_t)p1.x * DH + lane * 4);
        uint2 x2 = *(const uint2*)(xt + (size_t)p2.x * DH + lane * 4);
        uint2 x3 = *(const uint2*)(xt + (size_t)p3.x * DH + lane * 4);
        float v0 = __uint_as_float(p0.y), v1 = __uint_as_float(p1.y);
        float v2 = __uint_as_float(p2.y), v3 = __uint_as_float(p3.y);
        a0 = fmaf(v0, blo(x0.x), a0); a1 = fmaf(v0, bhi(x0.x), a1);
        a2 = fmaf(v0, blo(x0.y), a2); a3 = fmaf(v0, bhi(x0.y), a3);
        b0 = fmaf(v1, blo(x1.x), b0); b1 = fmaf(v1, bhi(x1.x), b1);
        b2 = fmaf(v1, blo(x1.y), b2); b3 = fmaf(v1, bhi(x1.y), b3);
        c0 = fmaf(v2, blo(x2.x), c0); c1 = fmaf(v2, bhi(x2.x), c1);
        c2 = fmaf(v2, blo(x2.y), c2); c3 = fmaf(v2, bhi(x2.y), c3);
        d0 = fmaf(v3, blo(x3.x), d0); d1 = fmaf(v3, bhi(x3.x), d1);
        d2 = fmaf(v3, blo(x3.y), d2); d3 = fmaf(v3, bhi(x3.y), d3);
    }
    if (i + 2 <= end) {
        uint2 p0 = padj[i];
        uint2 p1 = padj[i + 1];
        uint2 x0 = *(const uint2*)(xt + (size_t)p0.x * DH + lane * 4);
        uint2 x1 = *(const uint2*)(xt + (size_t)p1.x * DH + lane * 4);
        float v0 = __uint_as_float(p0.y), v1 = __uint_as_float(p1.y);
        a0 = fmaf(v0, blo(x0.x), a0); a1 = fmaf(v0, bhi(x0.x), a1);
        a2 = fmaf(v0, blo(x0.y), a2); a3 = fmaf(v0, bhi(x0.y), a3);
        b0 = fmaf(v1, blo(x1.x), b0); b1 = fmaf(v1, bhi(x1.x), b1);
        b2 = fmaf(v1, blo(x1.y), b2); b3 = fmaf(v1, bhi(x1.y), b3);
        i += 2;
    }
    if (i < end) {
        uint2 p = padj[i];
        uint2 x0 = *(const uint2*)(xt + (size_t)p.x * DH + lane * 4);
        float v = __uint_as_float(p.y);
        a0 = fmaf(v, blo(x0.x), a0); a1 = fmaf(v, bhi(x0.x), a1);
        a2 = fmaf(v, blo(x0.y), a2); a3 = fmaf(v, bhi(x0.y), a3);
    }
    a0 += b0 + c0 + d0; a1 += b1 + c1 + d1;
    a2 += b2 + c2 + d2; a3 += b3 + c3 + d3;
    float ss = wave_sum(a0 * a0 + a1 * a1 + a2 * a2 + a3 * a3);
    float nraw = sqrtf(ss);
    float n_ = fmaxf(nraw, 1e-15f);
    float cc1 = tanh_fast(n_) * rcp_f(n_);
    float nh = cc1 * nraw;
    float np1 = fmaxf(nh, 1e-15f);
    float s1 = (np1 > MAXN) ? MAXN * rcp_f(np1) : 1.0f;
    float n1 = fminf(np1, MAXN);
    float cu = artanh_fast(n1) * rcp_f(n1) * s1 * cc1;
    float u0 = fmaxf(cu * a0, 0.f), u1 = fmaxf(cu * a1, 0.f);
    float u2 = fmaxf(cu * a2, 0.f), u3 = fmaxf(cu * a3, 0.f);
    float ss2 = wave_sum(u0 * u0 + u1 * u1 + u2 * u2 + u3 * u3);
    float n2raw = sqrtf(ss2);
    float n2 = fmaxf(n2raw, 1e-15f);
    float cc3 = tanh_fast(n2) * rcp_f(n2);
    float ne = cc3 * n2raw;
    float np3 = fmaxf(ne, 1e-15f);
    float s3 = (np3 > MAXN) ? MAXN * rcp_f(np3) : 1.0f;
    float n3 = fminf(np3, MAXN);
    float cf = artanh_fast(n3) * rcp_f(n3) * s3 * cc3;
    uint2 o; o.x = pk2(cf * u0, cf * u1); o.y = pk2(cf * u2, cf * u3);
    *(uint2*)(out + (size_t)n * DH + lane * 4) = o;
}

// wave-per-node: out[n] = d[n] + sum_in d[src]; 4-way ILP unroll; bf16 in/out
__global__ void k_gather_add(const int* __restrict__ rowptr, const int* __restrict__ psrc,
                             const u16* __restrict__ d, u16* __restrict__ out) {
    int z = blockIdx.y;
    rowptr += (size_t)z * (N_NODES + 1);
    psrc += (size_t)z * NE;
    d += (size_t)z * N_NODES * DH;
    out += (size_t)z * N_NODES * DH;
    int n = blockIdx.x * 4 + (threadIdx.x >> 6);
    int lane = threadIdx.x & 63;
    int beg = rowptr[n], end = rowptr[n + 1];
    uint2 u0v = *(const uint2*)(d + (size_t)n * DH + lane * 4);
    float a0 = blo(u0v.x), a1 = bhi(u0v.x), a2 = blo(u0v.y), a3 = bhi(u0v.y);
    float b0 = 0.f, b1 = 0.f, b2 = 0.f, b3 = 0.f;
    float c0 = 0.f, c1 = 0.f, c2 = 0.f, c3 = 0.f;
    float e0 = 0.f, e1 = 0.f, e2 = 0.f, e3 = 0.f;
    int i = beg;
    for (; i + 4 <= end; i += 4) {
        int s0 = psrc[i], s1 = psrc[i + 1], s2 = psrc[i + 2], s3 = psrc[i + 3];
        uint2 x0 = *(const uint2*)(d + (size_t)s0 * DH + lane * 4);
        uint2 x1 = *(const uint2*)(d + (size_t)s1 * DH + lane * 4);
        uint2 x2 = *(const uint2*)(d + (size_t)s2 * DH + lane * 4);
        uint2 x3 = *(const uint2*)(d + (size_t)s3 * DH + lane * 4);
        a0 += blo(x0.x); a1 += bhi(x0.x); a2 += blo(x0.y); a3 += bhi(x0.y);
        b0 += blo(x1.x); b1 += bhi(x1.x); b2 += blo(x1.y); b3 += bhi(x1.y);
        c0 += blo(x2.x); c1 += bhi(x2.x); c2 += blo(x2.y); c3 += bhi(x2.y);
        e0 += blo(x3.x); e1 += bhi(x3.x); e2 += blo(x3.y); e3 += bhi(x3.y);
    }
    if (i + 2 <= end) {
        int s0 = psrc[i], s1 = psrc[i + 1];
        uint2 x0 = *(const uint2*)(d + (size_t)s0 * DH + lane * 4);
        uint2 x1 = *(const uint2*)(d + (size_t)s1 * DH + lane * 4);
        a0 += blo(x0.x); a1 += bhi(x0.x); a2 += blo(x0.y); a3 += bhi(x0.y);
        b0 += blo(x1.x); b1 += bhi(x1.x); b2 += blo(x1.y); b3 += bhi(x1.y);
        i += 2;
    }
    if (i < end) {
        int s0 = psrc[i];
        uint2 x0 = *(const uint2*)(d + (size_t)s0 * DH + lane * 4);
        a0 += blo(x0.x); a1 += bhi(x0.x); a2 += blo(x0.y); a3 += bhi(x0.y);
    }
    a0 += b0 + c0 + e0; a1 += b1 + c1 + e1;
    a2 += b2 + c2 + e2; a3 += b3 + c3 + e3;
    uint2 o; o.x = pk2(a0, a1); o.y = pk2(a2, a3);
    *(uint2*)(out + (size_t)n * DH + lane * 4) = o;
}

// batched column stats from bf16
__global__ void k_colstats(const u16* __restrict__ zp,
                           float* __restrict__ csum, float* __restrict__ csq) {
    int z = blockIdx.y;
    zp += (size_t)z * N_NODES * DH;
    csum += (size_t)z * DH;
    csq += (size_t)z * DH;
    int t = threadIdx.x;
    int r0 = blockIdx.x * 100;
    float s = 0.0f, q = 0.0f;
    for (int r = r0; r < r0 + 100; ++r) {
        float v = b2f(zp[(size_t)r * DH + t]);
        s += v;
        q += v * v;
    }
    atomicAdd(&csum[t], s);
    atomicAdd(&csq[t], q);
}

// grid-stride uint2 batchnorm + tanh, in-place bf16 (total4 = G*N*DH/4)
__global__ void k_normtanh_v(u16* __restrict__ zp, const float* __restrict__ csum,
                             const float* __restrict__ csq, const float* __restrict__ gamma,
                             const float* __restrict__ beta, int total4) {
    const float inv_n = 1.0f / N_NODES;
    int i = blockIdx.x * 256 + threadIdx.x;
    int stride = gridDim.x * 256;
    for (; i < total4; i += stride) {
        int e0 = i * 4;
        int z = e0 / (N_NODES * DH);
        int j0 = e0 & (DH - 1);
        int zb = z * DH + j0;
        uint2 u = ((uint2*)zp)[i];
        float v[4] = {blo(u.x), bhi(u.x), blo(u.y), bhi(u.y)};
        #pragma unroll
        for (int k = 0; k < 4; ++k) {
            float mu = csum[zb + k] * inv_n;
            float var = csq[zb + k] * inv_n - mu * mu;
            float inv = __builtin_amdgcn_rsqf(var + 1e-5f);
            v[k] = tanh_fast((v[k] - mu) * inv * gamma[zb + k] + beta[zb + k]);
        }
        uint2 o; o.x = pk2(v[0], v[1]); o.y = pk2(v[2], v[3]);
        ((uint2*)zp)[i] = o;
    }
}

// f1 slice of S,P (cols 0..511): thread t -> 2 cols via float2, packed u32 store
__global__ void k_pair0(const int* __restrict__ ei, const int* __restrict__ eid,
                        const float* __restrict__ f1, u16* __restrict__ S,
                        u16* __restrict__ P) {
    int b = blockIdx.x, t = threadIdx.x;
    int e = eid[b];
    int n0 = ei[e], n1 = ei[NE2 + e];
    float2 a = *(const float2*)(f1 + (size_t)n0 * D_INN + t * 2);
    float2 c = *(const float2*)(f1 + (size_t)n1 * D_INN + t * 2);
    ((unsigned int*)(S + (size_t)b * H3))[t] = pk2(a.x + c.x, a.y + c.y);
    ((unsigned int*)(P + (size_t)b * H3))[t] = pk2(a.x * c.x, a.y * c.y);
}

// batched channel slice of S,P from z_ch; 4 edges/block, uint2 lanes
__global__ void k_gather_ch(const int* __restrict__ ei, const int* __restrict__ eid,
                            const u16* __restrict__ zch, u16* __restrict__ S,
                            u16* __restrict__ P, int col0base) {
    int z = blockIdx.y;
    const u16* zp = zch + (size_t)z * N_NODES * DH;
    int col0 = col0base + z * DH;
    int b = blockIdx.x * 4 + (threadIdx.x >> 6);
    int lane = threadIdx.x & 63;
    int e = eid[b];
    int n0 = ei[e], n1 = ei[NE2 + e];
    uint2 ua = *(const uint2*)(zp + (size_t)n0 * DH + lane * 4);
    uint2 ub = *(const uint2*)(zp + (size_t)n1 * DH + lane * 4);
    float a0 = blo(ua.x), a1 = bhi(ua.x), a2 = blo(ua.y), a3 = bhi(ua.y);
    float c0 = blo(ub.x), c1 = bhi(ub.x), c2 = blo(ub.y), c3 = bhi(ub.y);
    uint2 so; so.x = pk2(a0 + c0, a1 + c1); so.y = pk2(a2 + c2, a3 + c3);
    uint2 po; po.x = pk2(a0 * c0, a1 * c1); po.y = pk2(a2 * c2, a3 * c3);
    *(uint2*)(S + (size_t)b * H3 + col0 + lane * 4) = so;
    *(uint2*)(P + (size_t)b * H3 + col0 + lane * 4) = po;
}

__global__ void k_final(const u16* __restrict__ h2, const float* __restrict__ Wf3,
                        const float* __restrict__ bf3, float* __restrict__ out) {
    int r = blockIdx.x, t = threadIdx.x;
    const u16* hr = h2 + (size_t)r * 576;
    float acc[7] = {0, 0, 0, 0, 0, 0, 0};
    for (int cb = t; cb < 576; cb += 64) {
        float h = b2f(hr[cb]);
        #pragma unroll
        for (int o = 0; o < 7; ++o) acc[o] = fmaf(h, Wf3[o * 576 + cb], acc[o]);
    }
    #pragma unroll
    for (int o = 0; o < 7; ++o) {
        #pragma unroll
        for (int off = 32; off > 0; off >>= 1) acc[o] += __shfl_down(acc[o], off, 64);
    }
    if (t == 0) {
        #pragma unroll
        for (int o = 0; o < 7; ++o) out[(size_t)r * 7 + o] = acc[o] + bf3[o];
    }
}

// ===== bf16 MFMA GEMM, BK=64, 8-WAVE (512-thr) blocks (32 waves/CU).
// Logical block enumeration: when gx%3==0, blocks walk (z, 3-col tile, row,
// col-in-tile) so each XCD chunk keeps its 3 W-panels (1.77MB) L2-resident
// across the row sweep (kills the ~1.4GB L3 W-refetch of plain row-major);
// A panels still used 3x consecutively, cross-XCD A reuse absorbed by L3.
// Bijective: mixed-radix decomposition of wg over [0, 3*gy*TC*gz)=total.
// Staging/read swizzle and epilogues unchanged (proven, 0 bank conflicts).
// EP: 2=sigmoid->bf16, 3=relu->bf16, 5=bf16, 6=relu->f32,
//     7=bf16 + bias + (1+indeg[row])*cvec[col],
//     8=z==0? sigmoid->bf16 : bf16 (for batched gate/int)
template <int EP>
__global__ __launch_bounds__(512, 4) void k_gemm_mfma(
    const u16* __restrict__ A, const u16* __restrict__ W,
    const float* __restrict__ bias, void* __restrict__ outv,
    const int* __restrict__ rpe, const float* __restrict__ cvec,
    int M, int N, int K, size_t sA, size_t sW, size_t sC, int sBias) {
    __shared__ short As[8192];   // 128 rows x 64 cols bf16
    __shared__ short Ws[8192];
    // 3D bijective XCD swizzle over the whole grid
    const int gx = gridDim.x, gy = gridDim.y;
    const int plane = gx * gy;
    const int total = plane * gridDim.z;
    const int orig = (blockIdx.z * gy + blockIdx.y) * gx + blockIdx.x;
    const int q8 = total >> 3, r8 = total & 7, xcd = orig & 7;
    const int wg = (xcd < r8 ? xcd * (q8 + 1) : r8 * (q8 + 1) + (xcd - r8) * q8) + (orig >> 3);
    int z_, row0_, col0_;
    if (gx % 3 == 0) {
        int cc = wg % 3;
        int y = (wg / 3) % gy;
        int rest = wg / (3 * gy);
        int TC = gx / 3;
        int tc = rest % TC;
        z_ = rest / TC;
        row0_ = y * 128;
        col0_ = (tc * 3 + cc) * 128;
    } else {
        z_ = wg / plane;
        int rem = wg - z_ * plane;
        row0_ = (rem / gx) * 128;
        col0_ = (rem % gx) * 128;
    }
    const int z = z_;
    const int row0 = row0_, col0 = col0_;
    A += (size_t)z * sA;
    W += (size_t)z * sW;
    const size_t zC = (size_t)z * sC;
    const int* rp = (EP == 7) ? rpe + (size_t)z * (N_NODES + 1) : nullptr;
    const float* cv = (EP == 7) ? cvec + (size_t)z * DH : nullptr;
    const int t = threadIdx.x;
    const int lane = t & 63;
    const int w = t >> 6;          // 0..7
    const int wr = w >> 2;         // 0..1 (M half)
    const int wc = w & 3;          // 0..3 (N quarter)
    // staging: lane l -> row-in-8block l>>3, src chunk (l&7)^(l>>3)
    const int sr8 = lane >> 3;
    const int csrc = (lane & 7) ^ sr8;
    int gr[2], gc[2];
    #pragma unroll
    for (int p = 0; p < 2; ++p) {
        int rb = w + p * 8;                // 0..15 (8-row blocks)
        gr[p] = row0 + rb * 8 + sr8; if (gr[p] >= M) gr[p] = M - 1;
        gc[p] = col0 + rb * 8 + sr8; if (gc[p] >= N) gc[p] = N - 1;
    }
    const int fr = lane & 15, fq4 = lane >> 4;   // logical chunk q = kk*4 + fq4
    f32x4 acc[4][2] = {};
    for (int k0 = 0; k0 < K; k0 += 64) {
        #pragma unroll
        for (int p = 0; p < 2; ++p) {
            int rb = w + p * 8;
            __builtin_amdgcn_global_load_lds(
                (const __attribute__((address_space(1))) unsigned int*)(A + (size_t)gr[p] * K + k0 + csrc * 8),
                (__attribute__((address_space(3))) unsigned int*)(As + rb * 512), 16, 0, 0);
            __builtin_amdgcn_global_load_lds(
                (const __attribute__((address_space(1))) unsigned int*)(W + (size_t)gc[p] * K + k0 + csrc * 8),
                (__attribute__((address_space(3))) unsigned int*)(Ws + rb * 512), 16, 0, 0);
        }
        __syncthreads();
        bf16x8 af[4][2], bfr[2][2];
        #pragma unroll
        for (int m = 0; m < 4; ++m) {
            int ar = wr * 64 + m * 16 + fr;
            #pragma unroll
            for (int kk = 0; kk < 2; ++kk) {
                int q = kk * 4 + fq4;
                af[m][kk] = *(const bf16x8*)(As + ar * 64 + ((q ^ (ar & 7)) * 8));
            }
        }
        #pragma unroll
        for (int n = 0; n < 2; ++n) {
            int br = wc * 32 + n * 16 + fr;
            #pragma unroll
            for (int kk = 0; kk < 2; ++kk) {
                int q = kk * 4 + fq4;
                bfr[n][kk] = *(const bf16x8*)(Ws + br * 64 + ((q ^ (br & 7)) * 8));
            }
        }
        #pragma unroll
        for (int m = 0; m < 4; ++m)
            #pragma unroll
            for (int n = 0; n < 2; ++n)
                #pragma unroll
                for (int kk = 0; kk < 2; ++kk)
                    acc[m][n] = __builtin_amdgcn_mfma_f32_16x16x32_bf16(
                        af[m][kk], bfr[n][kk], acc[m][n], 0, 0, 0);
        __syncthreads();
    }
    const int cl = lane & 15, rh = (lane >> 4) * 4;
    #pragma unroll
    for (int m = 0; m < 4; ++m) {
        float indf[4];
        if (EP == 7) {
            #pragma unroll
            for (int r = 0; r < 4; ++r) {
                int row = row0 + wr * 64 + m * 16 + rh + r;
                if (row >= M) row = M - 1;
                indf[r] = 1.0f + (float)(rp[row + 1] - rp[row]);
            }
        }
        #pragma unroll
        for (int n = 0; n < 2; ++n) {
            int col = col0 + wc * 32 + n * 16 + cl;
            if (col >= N) continue;
            float bv = bias ? bias[z * sBias + col] : 0.0f;
            float cvc = (EP == 7) ? cv[col] : 0.0f;
            #pragma unroll
            for (int r = 0; r < 4; ++r) {
                int row = row0 + wr * 64 + m * 16 + rh + r;
                if (row >= M) continue;
                float v = acc[m][n][r] + bv;
                size_t idx = zC + (size_t)row * N + col;
                if (EP == 2) ((u16*)outv)[idx] = f2b(sigmoid_fast(v));
                if (EP == 3) ((u16*)outv)[idx] = f2b(fmaxf(v, 0.0f));
                if (EP == 5) ((u16*)outv)[idx] = f2b(v);
                if (EP == 6) ((float*)outv)[idx] = fmaxf(v, 0.0f);
                if (EP == 7) ((u16*)outv)[idx] = f2b(v + indf[r] * cvc);
                if (EP == 8) ((u16*)outv)[idx] = (z == 0) ? f2b(sigmoid_fast(v)) : f2b(v);
            }
        }
    }
}

static inline void gemm_b(int ep, const u16* A, const u16* W, const float* bias, void* out,
                          const int* rpe, const float* cvec,
                          int M, int N, int K, int Z,
                          size_t sA, size_t sW, size_t sC, int sBias, hipStream_t st) {
    dim3 g((N + 127) / 128, (M + 127) / 128, Z);
    switch (ep) {
        case 2: k_gemm_mfma<2><<<g, 512, 0, st>>>(A, W, bias, out, rpe, cvec, M, N, K, sA, sW, sC, sBias); break;
        case 3: k_gemm_mfma<3><<<g, 512, 0, st>>>(A, W, bias, out, rpe, cvec, M, N, K, sA, sW, sC, sBias); break;
        case 5: k_gemm_mfma<5><<<g, 512, 0, st>>>(A, W, bias, out, rpe, cvec, M, N, K, sA, sW, sC, sBias); break;
        case 6: k_gemm_mfma<6><<<g, 512, 0, st>>>(A, W, bias, out, rpe, cvec, M, N, K, sA, sW, sC, sBias); break;
        case 7: k_gemm_mfma<7><<<g, 512, 0, st>>>(A, W, bias, out, rpe, cvec, M, N, K, sA, sW, sC, sBias); break;
        case 8: k_gemm_mfma<8><<<g, 512, 0, st>>>(A, W, bias, out, rpe, cvec, M, N, K, sA, sW, sC, sBias); break;
    }
}

static inline void conv_w(const float* s, u16* d, size_t n, hipStream_t st) {
    int n4 = (int)(n / 4);
    int grid = (n4 + 255) / 256;
    if (grid > 2048) grid = 2048;
    k_f2b<<<grid, 256, 0, st>>>(s, d, n4);
}

extern "C" void kernel_launch(void* const* d_in, const int* in_sizes, int n_in, void* d_out,
                              int out_size, void* d_ws, size_t ws_size, hipStream_t stream) {
    const float* f1 = (const float*)d_in[0];
    const int* adj_src = (const int*)d_in[1];
    const int* adj_dst = (const int*)d_in[2];
    const float* adj_val = (const float*)d_in[3];
    const int* edge_src = (const int*)d_in[4];
    const int* edge_dst = (const int*)d_in[5];
    const int* edge_index = (const int*)d_in[6];
    const int* edge_id = (const int*)d_in[7];
    const float* W_hyp = (const float*)d_in[8];
    const float* b_hyp = (const float*)d_in[9];
    const float* Wd = (const float*)d_in[10];
    const float* bd = (const float*)d_in[11];
    const float* Wg1 = (const float*)d_in[12];
    const float* bg1 = (const float*)d_in[13];
    const float* gamma = (const float*)d_in[14];
    const float* beta = (const float*)d_in[15];
    const float* Wg2 = (const float*)d_in[16];
    const float* bg2 = (const float*)d_in[17];
    const float* Wgate = (const float*)d_in[18];
    const float* bgate = (const float*)d_in[19];
    const float* Wint = (const float*)d_in[20];
    const float* bint = (const float*)d_in[21];
    const float* Wout = (const float*)d_in[22];
    const float* bout = (const float*)d_in[23];
    const float* Wf1 = (const float*)d_in[24];
    const float* bf1 = (const float*)d_in[25];
    const float* Wf2 = (const float*)d_in[26];
    const float* bf2 = (const float*)d_in[27];
    const float* Wf3 = (const float*)d_in[28];
    const float* bf3 = (const float*)d_in[29];
    float* outp = (float*)d_out;

    const bool single = ws_size >= 253400000ull;
    const int ngroups = single ? 1 : 2;
    const int GM = single ? 7 : 4;
    int g0s[2] = {0, 4};
    int gns[2] = {GM, 3};

    // ---- workspace bump allocator ----
    char* base = (char*)d_ws;
    size_t off = 0;
    auto alloc = [&](size_t bytes) -> char* {
        char* p = base + off;
        off += (bytes + 255) & ~(size_t)255;
        return p;
    };
    u16* Whyp_b = (u16*)alloc((size_t)NCH * DH * D_INN * 2);
    u16* Wc_b   = (u16*)alloc((size_t)NCH * DH * DH * 2);   // Wg1 @ Wd
    u16* Wg1_b  = (u16*)alloc((size_t)NCH * DH * DH * 2);
    u16* Wg2_b  = (u16*)alloc((size_t)NCH * DH * DH * 2);
    u16* Wgate_b = (u16*)alloc((size_t)H3 * H3 * 2);        // Wint_b must follow!
    u16* Wint_b  = (u16*)alloc((size_t)H3 * H3 * 2);
    u16* Wcomb_b = (u16*)alloc((size_t)1152 * H3 * 2);      // Wf1 @ Wout
    u16* Wf2_b   = (u16*)alloc((size_t)576 * 1152 * 2);
    u16* S_b = (u16*)alloc((size_t)NB * H3 * 2);            // P_b must follow!
    u16* P_b = (u16*)alloc((size_t)NB * H3 * 2);
    const size_t NDB = (size_t)N_NODES * DH;       // per-channel elems
    u16* buf1 = (u16*)alloc((size_t)GM * NDB * 2); // group ping (buf2 follows)
    u16* buf2 = (u16*)alloc((size_t)GM * NDB * 2); // group pong
    u16* xhyp_b = single ? buf2 : (u16*)alloc((size_t)N_NODES * D_INN * 2);
    // CSR scratch (2*GM slices): adj slices [0,G), edge slices [G,2G).
    // Single mode: final padj/psrcE alias into S_b; cnt/rowptr + binned
    // scratch alias into P_b -- all dead before S/P get written.
    int* cntC; int* rowptrC; uint2* padjC; int* psrcE;
    uint2* scrA = nullptr; unsigned int* scrE = nullptr;
    if (single) {
        padjC = (uint2*)S_b;                                   // 17,920,000 B
        psrcE = (int*)((char*)S_b + (size_t)GM * NE * 8);      // +8,960,000 B
        cntC = (int*)P_b;                                      // 1,120,000 B
        rowptrC = (int*)((char*)P_b + (size_t)2 * GM * N_NODES * 4);
        size_t rp_end = (size_t)2 * GM * N_NODES * 4 + (size_t)2 * GM * (N_NODES + 1) * 4;
        rp_end = (rp_end + 63) & ~(size_t)63;
        scrA = (uint2*)((char*)P_b + rp_end);                  // 17,920,000 B
        scrE = (unsigned int*)((char*)scrA + (size_t)GM * NE * 8);  // +8,960,000 B
    } else {
        cntC = (int*)alloc((size_t)2 * GM * N_NODES * 4);
        rowptrC = (int*)alloc((size_t)2 * GM * (N_NODES + 1) * 4);
        padjC = (uint2*)alloc((size_t)GM * NE * 8);
        psrcE = (int*)alloc((size_t)GM * NE * 4);
    }
    float* xhn = (float*)alloc((size_t)N_NODES * 4);
    float* hb = (float*)alloc((size_t)NCH * DH * 4);
    float* hb2 = (float*)alloc(NCH * 4);
    float* csum = (float*)alloc((size_t)GM * DH * 4);        // csq follows
    float* csq = (float*)alloc((size_t)GM * DH * 4);
    float* cvec_d = (float*)alloc((size_t)NCH * DH * 4);
    float* bias2 = (float*)alloc((size_t)2 * H3 * 4);
    float* bcomb = (float*)alloc((size_t)1152 * 4);
    int* bcur = (int*)alloc((size_t)2 * NCH * NBUK * 4);     // bucket cursors
    // precompute-only temp weights alias into buf1 (idle until GNN phase):
    u16* WoutT_b = buf1;                          // 10.62 MB
    u16* Wf1_b = buf1 + (size_t)H3 * H3;          // +5.31 MB
    u16* Wdt_b = Wf1_b + (size_t)1152 * H3;       // +0.92 MB (total 16.8 <= buf1)
    // stage-C overlays: GT spans buf1(+buf2 head); h1 -> buf1; h2 -> buf2.
    u16* GT = buf1;
    u16* h2b = buf2;

    const int EG = (NE + 255) / 256;

    conv_w(W_hyp, Whyp_b, (size_t)NCH * DH * D_INN, stream);
    conv_w(Wg1, Wg1_b, (size_t)NCH * DH * DH, stream);
    conv_w(Wg2, Wg2_b, (size_t)NCH * DH * DH, stream);
    conv_w(Wgate, Wgate_b, (size_t)H3 * H3, stream);
    conv_w(Wint, Wint_b, (size_t)H3 * H3, stream);
    conv_w(Wf1, Wf1_b, (size_t)1152 * H3, stream);
    conv_w(Wf2, Wf2_b, (size_t)576 * 1152, stream);
    k_bias2<<<(2 * H3 + 255) / 256, 256, 0, stream>>>(bgate, bint, bias2);
    // Wc = Wg1 @ Wd (via Wd^T), cvec = Wg1 @ bd
    k_twd<<<dim3(16, 16, NCH), 256, 0, stream>>>(Wd, Wdt_b);
    gemm_b(5, Wg1_b, Wdt_b, nullptr, Wc_b, nullptr, nullptr,
           DH, DH, DH, NCH, (size_t)DH * DH, (size_t)DH * DH, (size_t)DH * DH, 0, stream);
    k_cvec<<<NCH, 256, 0, stream>>>(Wg1, bd, cvec_d);
    // Wcomb = Wf1 @ Wout (Wout GEMM folded into Wf1), bcomb = Wf1@bout + bf1
    k_tr<<<dim3(144, 144), 256, 0, stream>>>(Wout, WoutT_b);
    gemm_b(5, Wf1_b, WoutT_b, nullptr, Wcomb_b, nullptr, nullptr,
           1152, H3, H3, 1, 0, 0, 0, 0, stream);
    k_bvec<<<1152 / 4, 256, 0, stream>>>(Wf1, bout, bf1, bcomb);

    k_expmap_proj_in<<<N_NODES, 256, 0, stream>>>(f1, xhyp_b, xhn);
    k_hb<<<NCH, 256, 0, stream>>>(b_hyp, hb, hb2);
    if (!single) k_pair0<<<NB, 256, 0, stream>>>(edge_index, edge_id, f1, S_b, P_b);

    for (int gi = 0; gi < ngroups; ++gi) {
        const int g0 = g0s[gi], G = gns[gi];
        const size_t eoff = (size_t)g0 * NE;
        const int G2 = 2 * G;
        const int* rpE = rowptrC + (size_t)G * (N_NODES + 1);
        // --- merged CSR build ---
        k_izero<<<(G2 * N_NODES + 255) / 256, 256, 0, stream>>>(cntC, G2 * N_NODES);
        k_hist2<<<dim3(EG, G2), 256, 0, stream>>>(adj_dst + eoff, edge_dst + eoff, cntC, G);
        k_scan<<<G2, 256, 0, stream>>>(cntC, rowptrC);
        if (single) {
            k_bcur<<<(G2 * NBUK + 255) / 256, 256, 0, stream>>>(rowptrC, bcur, G2);
            k_binA<<<dim3(EG, G2), 256, 0, stream>>>(adj_src, adj_dst, adj_val,
                                                     edge_src, edge_dst, bcur,
                                                     scrA, scrE, G);
            k_placeB<<<dim3(NBUK, G2), 256, 0, stream>>>(rowptrC, scrA, scrE,
                                                         padjC, psrcE, G);
        } else {
            k_place2<<<dim3(EG, G2), 256, 0, stream>>>(adj_src + eoff, adj_dst + eoff,
                                                       adj_val + eoff, edge_src + eoff,
                                                       edge_dst + eoff, cntC, padjC,
                                                       psrcE, G);
        }
        // --- batched pipeline ---
        gemm_b(5, xhyp_b, Whyp_b + (size_t)g0 * DH * D_INN, nullptr, buf1, nullptr,
               nullptr, N_NODES, DH, D_INN, G, 0, (size_t)DH * D_INN, NDB, 0, stream);
        k_rowfuse1<<<dim3(N_NODES / 4, G), 256, 0, stream>>>(buf1, xhn, hb + g0 * DH, hb2 + g0);
        k_gather_fuse2<<<dim3(N_NODES / 4, G), 256, 0, stream>>>(rowptrC, padjC, buf1, buf2);
        // ug = (I + S_e) u
        k_gather_add<<<dim3(N_NODES / 4, G), 256, 0, stream>>>(rpE, psrcE, buf2, buf1);
        // z = ug @ Wc^T + (1+indeg)*cvec + bg1   (Wd GEMM fused away)
        gemm_b(7, buf1, Wc_b + (size_t)g0 * DH * DH, bg1 + g0 * DH, buf2,
               rpE, cvec_d + (size_t)g0 * DH, N_NODES, DH, DH, G,
               NDB, (size_t)DH * DH, NDB, DH, stream);
        k_zero<<<(2 * GM * DH + 255) / 256, 256, 0, stream>>>(csum, 2 * GM * DH);
        k_colstats<<<dim3(200, G), 256, 0, stream>>>(buf2, csum, csq);
        {
            int total4 = (int)(G * NDB / 4);
            int blocks = (total4 + 255) / 256;
            if (blocks > 2048) blocks = 2048;
            k_normtanh_v<<<blocks, 256, 0, stream>>>(buf2, csum, csq, gamma + g0 * DH,
                                                     beta + g0 * DH, total4);
        }
        gemm_b(5, buf2, Wg2_b + (size_t)g0 * DH * DH, bg2 + g0 * DH, buf1, nullptr,
               nullptr, N_NODES, DH, DH, G, NDB, (size_t)DH * DH, NDB, DH, stream);
        if (!single)
            k_gather_ch<<<dim3(NB / 4, G), 256, 0, stream>>>(edge_index, edge_id, buf1,
                                                             S_b, P_b, D_INN + g0 * DH);
    }
    if (single) {
        // CSR scratch (aliased in S_b/P_b) is dead now; build S,P.
        k_pair0<<<NB, 256, 0, stream>>>(edge_index, edge_id, f1, S_b, P_b);
        k_gather_ch<<<dim3(NB / 4, 7), 256, 0, stream>>>(edge_index, edge_id, buf1,
                                                         S_b, P_b, D_INN);
    }

    // stage C: batched gate/int (Z=2), gi elementwise, fused h1 (Wout folded
    // into Wf1 via Wcomb), h2 (bf16), final.
    gemm_b(8, S_b, Wgate_b, bias2, GT, nullptr, nullptr, NB, H3, H3, 2,
           (size_t)NB * H3, (size_t)H3 * H3, (size_t)NB * H3, H3, stream);
    {
        int total4 = NB * H3 / 4;
        int blocks = (total4 + 255) / 256;
        if (blocks > 2048) blocks = 2048;
        k_gi<<<blocks, 256, 0, stream>>>(GT, GT + (size_t)NB * H3, S_b, total4);
    }
    // h1 = relu(gi @ Wcomb^T + bcomb)
    gemm_b(3, S_b, Wcomb_b, bcomb, buf1, nullptr, nullptr, NB, 1152, H3, 1, 0, 0, 0, 0, stream);
    // h2 = relu(h1 @ Wf2^T + bf2) -> bf16
    gemm_b(3, buf1, Wf2_b, bf2, h2b, nullptr, nullptr, NB, 576, 1152, 1, 0, 0, 0, 0, stream);
    k_final<<<NB, 64, 0, stream>>>(h2b, Wf3, bf3, outp);
}

// Round 20
// 1400.136 us; speedup vs baseline: 1.6692x; 1.0097x over previous
//
#include <hip/hip_runtime.h>
#include <math.h>

#define N_NODES 20000
#define D_INN   512
#define DH      256
#define NCH     7
#define NE      320000
#define NE2     100000
#define NB      8192
#define H3      2304   // 512 + 7*256
#define MAXN    0.996f
#define LOG2E   1.44269504f
#define NBUK    40     // dst buckets of 512 nodes
#define BSH     9

typedef unsigned short u16;
typedef __attribute__((ext_vector_type(8))) short bf16x8;
typedef __attribute__((ext_vector_type(4))) float f32x4;

__device__ __forceinline__ u16 f2b(float f) {    // RNE f32 -> bf16 bits
    unsigned int x = __float_as_uint(f);
    unsigned int r = (x + 0x7fffu + ((x >> 16) & 1u)) >> 16;
    return (u16)r;
}
__device__ __forceinline__ float b2f(u16 u) {
    return __uint_as_float(((unsigned int)u) << 16);
}
__device__ __forceinline__ float blo(unsigned int u) { return __uint_as_float(u << 16); }
__device__ __forceinline__ float bhi(unsigned int u) { return __uint_as_float(u & 0xffff0000u); }
__device__ __forceinline__ unsigned int pk2(float a, float b) {
    return (unsigned int)f2b(a) | ((unsigned int)f2b(b) << 16);
}

// ---- fast HW transcendentals (rel err ~1e-5, fine for bf16 tolerance) ----
__device__ __forceinline__ float rcp_f(float x) { return __builtin_amdgcn_rcpf(x); }
__device__ __forceinline__ float exp2_f(float x) { return __builtin_amdgcn_exp2f(x); }
__device__ __forceinline__ float log2_f(float x) { return __builtin_amdgcn_logf(x); }
__device__ __forceinline__ float tanh_fast(float x) {
    float xc = fminf(fmaxf(x, -15.f), 15.f);
    float t = exp2_f(xc * (2.f * LOG2E));
    return (t - 1.f) * rcp_f(t + 1.f);
}
__device__ __forceinline__ float artanh_fast(float x) {
    x = fminf(fmaxf(x, -1.0f + 1e-7f), 1.0f - 1e-7f);
    return 0.34657359f * log2_f((1.f + x) * rcp_f(1.f - x));
}
__device__ __forceinline__ float sigmoid_fast(float x) {
    return rcp_f(1.f + exp2_f(-x * LOG2E));
}

__device__ __forceinline__ float wave_sum(float v) {
    #pragma unroll
    for (int off = 32; off > 0; off >>= 1) v += __shfl_xor(v, off, 64);
    return v;
}

__device__ __forceinline__ float block_sum256(float v) {
    __shared__ float sred[4];
    #pragma unroll
    for (int off = 32; off > 0; off >>= 1) v += __shfl_down(v, off, 64);
    int lane = threadIdx.x & 63;
    int w = threadIdx.x >> 6;
    if (lane == 0) sred[w] = v;
    __syncthreads();
    float tot = sred[0] + sred[1] + sred[2] + sred[3];
    __syncthreads();
    return tot;
}

__global__ void k_zero(float* __restrict__ p, int n) {
    int i = blockIdx.x * 256 + threadIdx.x;
    if (i < n) p[i] = 0.0f;
}
__global__ void k_izero(int* __restrict__ p, int n) {
    int i = blockIdx.x * 256 + threadIdx.x;
    if (i < n) p[i] = 0;
}

__global__ void k_f2b(const float* __restrict__ s, u16* __restrict__ d, int n4) {
    int i = blockIdx.x * 256 + threadIdx.x;
    int stride = gridDim.x * 256;
    for (; i < n4; i += stride) {
        float4 v = ((const float4*)s)[i];
        uint2 o; o.x = pk2(v.x, v.y); o.y = pk2(v.z, v.w);
        ((uint2*)d)[i] = o;
    }
}

// pack two bias vectors contiguously (for batched gate/int GEMM)
__global__ void k_bias2(const float* __restrict__ a, const float* __restrict__ b,
                        float* __restrict__ o) {
    int i = blockIdx.x * 256 + threadIdx.x;
    if (i < H3) o[i] = a[i];
    else if (i < 2 * H3) o[i] = b[i - H3];
}

// gi = gate * relu(tmp), all bf16, vectorized
__global__ void k_gi(const u16* __restrict__ gate, const u16* __restrict__ tmp,
                     u16* __restrict__ out, int total4) {
    int i = blockIdx.x * 256 + threadIdx.x;
    int stride = gridDim.x * 256;
    for (; i < total4; i += stride) {
        uint2 g = ((const uint2*)gate)[i];
        uint2 t = ((const uint2*)tmp)[i];
        uint2 o;
        o.x = pk2(blo(g.x) * fmaxf(blo(t.x), 0.f), bhi(g.x) * fmaxf(bhi(t.x), 0.f));
        o.y = pk2(blo(g.y) * fmaxf(blo(t.y), 0.f), bhi(g.y) * fmaxf(bhi(t.y), 0.f));
        ((uint2*)out)[i] = o;
    }
}

// Wd transpose -> bf16 (for Wc = Wg1 @ Wd via A@W^T kernel)
__global__ void k_twd(const float* __restrict__ Wd, u16* __restrict__ Wdt) {
    __shared__ float tile[16][17];
    int z = blockIdx.z;
    int bx = blockIdx.x * 16, by = blockIdx.y * 16;
    int tx = threadIdx.x & 15, ty = threadIdx.x >> 4;
    tile[ty][tx] = Wd[(size_t)z * DH * DH + (size_t)(by + ty) * DH + bx + tx];
    __syncthreads();
    Wdt[(size_t)z * DH * DH + (size_t)(bx + ty) * DH + by + tx] = f2b(tile[tx][ty]);
}

// 2304x2304 transpose f32 -> bf16 (WoutT[i][j] = Wout[j][i])
__global__ void k_tr(const float* __restrict__ Win, u16* __restrict__ Wt) {
    __shared__ float tile[16][17];
    int bx = blockIdx.x * 16, by = blockIdx.y * 16;
    int tx = threadIdx.x & 15, ty = threadIdx.x >> 4;
    tile[ty][tx] = Win[(size_t)(by + ty) * H3 + bx + tx];
    __syncthreads();
    Wt[(size_t)(bx + ty) * H3 + by + tx] = f2b(tile[tx][ty]);
}

// bcomb[r] = sum_j Wf1[r][j]*bout[j] + bf1[r]  (wave per row, 4 rows/block)
__global__ void k_bvec(const float* __restrict__ Wf1, const float* __restrict__ bout,
                       const float* __restrict__ bf1, float* __restrict__ bcomb) {
    int r = blockIdx.x * 4 + (threadIdx.x >> 6);
    int lane = threadIdx.x & 63;
    const float* row = Wf1 + (size_t)r * H3;
    float s = 0.f;
    for (int j = lane; j < H3; j += 64) s = fmaf(row[j], bout[j], s);
    s = wave_sum(s);
    if (lane == 0) bcomb[r] = s + bf1[r];
}

// cvec[z][j] = sum_k Wg1[z][j][k] * bd[z][k]   (f32)
__global__ void k_cvec(const float* __restrict__ Wg1, const float* __restrict__ bd,
                       float* __restrict__ cvec) {
    int z = blockIdx.x, j = threadIdx.x;
    const float* row = Wg1 + (size_t)z * DH * DH + (size_t)j * DH;
    const float* b = bd + (size_t)z * DH;
    float s = 0.f;
    for (int k = 0; k < DH; ++k) s = fmaf(row[k], b[k], s);
    cvec[(size_t)z * DH + j] = s;
}

// ===== merged CSR build: 2G z-slices (z<G: adj graph, z>=G: edge graph) =====
__global__ void k_hist2(const int* __restrict__ adjd, const int* __restrict__ edged,
                        int* __restrict__ cnt, int G) {
    int z = blockIdx.y;
    const int* dst = (z < G) ? adjd + (size_t)z * NE : edged + (size_t)(z - G) * NE;
    cnt += (size_t)z * N_NODES;
    int i = blockIdx.x * 256 + threadIdx.x;
    if (i < NE) atomicAdd(&cnt[dst[i]], 1);
}

// one block per slice; cnt becomes the cursor array in-place
__global__ void k_scan(int* __restrict__ cnt, int* __restrict__ rowptr) {
    int z = blockIdx.x;
    cnt += (size_t)z * N_NODES;
    rowptr += (size_t)z * (N_NODES + 1);
    __shared__ int part[256];
    int t = threadIdx.x;
    const int CH = (N_NODES + 255) / 256;
    int beg = t * CH;
    int end = beg + CH; if (end > N_NODES) end = N_NODES;
    int s = 0;
    for (int i = beg; i < end; ++i) s += cnt[i];
    part[t] = s;
    __syncthreads();
    for (int off = 1; off < 256; off <<= 1) {
        int v = (t >= off) ? part[t - off] : 0;
        __syncthreads();
        part[t] += v;
        __syncthreads();
    }
    int run = (t == 0) ? 0 : part[t - 1];
    for (int i = beg; i < end; ++i) {
        int c = cnt[i];
        rowptr[i] = run;
        cnt[i] = run;      // cursor init (in-place)
        run += c;
    }
    if (t == 255) rowptr[N_NODES] = part[255];
}

// legacy 1-phase place (2-group fallback path)
__global__ void k_place2(const int* __restrict__ adjs, const int* __restrict__ adjd,
                         const float* __restrict__ adjv, const int* __restrict__ edges,
                         const int* __restrict__ edged, int* __restrict__ cursor,
                         uint2* __restrict__ padj, int* __restrict__ psrcE, int G) {
    int z = blockIdx.y;
    bool isadj = z < G;
    const int* src = isadj ? adjs + (size_t)z * NE : edges + (size_t)(z - G) * NE;
    const int* dst = isadj ? adjd + (size_t)z * NE : edged + (size_t)(z - G) * NE;
    cursor += (size_t)z * N_NODES;
    int i = blockIdx.x * 256 + threadIdx.x;
    if (i < NE) {
        int d = dst[i];
        int pos = atomicAdd(&cursor[d], 1);
        if (isadj) {
            uint2 p;
            p.x = (unsigned int)src[i];
            p.y = __float_as_uint(adjv[(size_t)z * NE + i]);
            padj[(size_t)z * NE + pos] = p;
        } else {
            psrcE[(size_t)(z - G) * NE + pos] = src[i];
        }
    }
}

// bucket cursors init: bcur[z][b] = rowptr[z][b*512]
__global__ void k_bcur(const int* __restrict__ rowptr, int* __restrict__ bcur, int G2) {
    int i = blockIdx.x * 256 + threadIdx.x;
    if (i < G2 * NBUK) {
        int z = i / NBUK, b = i - z * NBUK;
        bcur[i] = rowptr[(size_t)z * (N_NODES + 1) + (b << BSH)];
    }
}

// phase A: bin edges into bucket-contiguous scratch (regions = final CSR
// bucket ranges). LDS-aggregated claims: one global atomic per bucket/block,
// writes land in ~contiguous runs. (src,dst) packed 15+15 bits.
__global__ void k_binA(const int* __restrict__ adjs, const int* __restrict__ adjd,
                       const float* __restrict__ adjv, const int* __restrict__ edges,
                       const int* __restrict__ edged, int* __restrict__ bcur,
                       uint2* __restrict__ scrA, unsigned int* __restrict__ scrE, int G) {
    int z = blockIdx.y;
    bool isadj = z < G;
    const int* src = isadj ? adjs + (size_t)z * NE : edges + (size_t)(z - G) * NE;
    const int* dst = isadj ? adjd + (size_t)z * NE : edged + (size_t)(z - G) * NE;
    __shared__ int hcnt[NBUK];
    __shared__ int gbase[NBUK];
    int t = threadIdx.x;
    int i = blockIdx.x * 256 + t;
    if (t < NBUK) hcnt[t] = 0;
    __syncthreads();
    int s = 0, d = 0, buk = 0, rank = 0;
    bool valid = i < NE;
    if (valid) {
        s = src[i]; d = dst[i];
        buk = d >> BSH;
        rank = atomicAdd(&hcnt[buk], 1);
    }
    __syncthreads();
    if (t < NBUK && hcnt[t] > 0)
        gbase[t] = atomicAdd(&bcur[z * NBUK + t], hcnt[t]);
    __syncthreads();
    if (valid) {
        int pos = gbase[buk] + rank;
        unsigned int sd = (unsigned int)s | ((unsigned int)d << 15);
        if (isadj) {
            uint2 p; p.x = sd; p.y = __float_as_uint(adjv[(size_t)z * NE + i]);
            scrA[(size_t)z * NE + pos] = p;
        } else {
            scrE[(size_t)(z - G) * NE + pos] = sd;
        }
    }
}

// phase B: one block per (bucket, z). LDS cursors for the bucket's 512 nodes;
// reads coalesced from bucket region; final scatter confined to the bucket's
// ~64KB CSR window (L2-absorbed).
__global__ void k_placeB(const int* __restrict__ rowptr, const uint2* __restrict__ scrA,
                         const unsigned int* __restrict__ scrE, uint2* __restrict__ padj,
                         int* __restrict__ psrcE, int G) {
    int z = blockIdx.y;
    int b = blockIdx.x;
    bool isadj = z < G;
    const int* rp = rowptr + (size_t)z * (N_NODES + 1);
    __shared__ int cur[512];
    int t = threadIdx.x;
    int n0 = b << BSH;
    for (int k = t; k < 512; k += 256) {
        int node = n0 + k;
        cur[k] = (node < N_NODES) ? rp[node] : 0;
    }
    __syncthreads();
    int beg = rp[n0];
    int nend = n0 + 512; if (nend > N_NODES) nend = N_NODES;
    int end = rp[nend];
    if (isadj) {
        const uint2* sc = scrA + (size_t)z * NE;
        uint2* out = padj + (size_t)z * NE;
        for (int i = beg + t; i < end; i += 256) {
            uint2 p = sc[i];
            int d = (int)((p.x >> 15) & 0x7fffu);
            int pos = atomicAdd(&cur[d - n0], 1);
            uint2 o; o.x = p.x & 0x7fffu; o.y = p.y;
            out[pos] = o;
        }
    } else {
        const unsigned int* sc = scrE + (size_t)(z - G) * NE;
        int* out = psrcE + (size_t)(z - G) * NE;
        for (int i = beg + t; i < end; i += 256) {
            unsigned int p = sc[i];
            int d = (int)((p >> 15) & 0x7fffu);
            int pos = atomicAdd(&cur[d - n0], 1);
            out[pos] = (int)(p & 0x7fffu);
        }
    }
}

// x_hyp = proj(expmap0(f1)) -> bf16; clamped row norm -> xhn (f32)
__global__ void k_expmap_proj_in(const float* __restrict__ f1,
                                 u16* __restrict__ xhyp, float* __restrict__ xhn) {
    int r = blockIdx.x, t = threadIdx.x;
    const float* u = f1 + (size_t)r * D_INN;
    float v0 = u[t], v1 = u[t + 256];
    float ss = block_sum256(v0 * v0 + v1 * v1);
    float nraw = sqrtf(ss);
    float n = fmaxf(nraw, 1e-15f);
    float c = tanh_fast(n) * rcp_f(n);
    float ny = c * nraw;
    float np = fmaxf(ny, 1e-15f);
    float s = (np > MAXN) ? MAXN * rcp_f(np) : 1.0f;
    float cs = c * s;
    u16* o = xhyp + (size_t)r * D_INN;
    o[t] = f2b(cs * v0);
    o[t + 256] = f2b(cs * v1);
    if (t == 0) xhn[r] = fminf(np, MAXN);
}

__global__ void k_hb(const float* __restrict__ b_hyp,
                     float* __restrict__ hb, float* __restrict__ hb2) {
    int i = blockIdx.x, t = threadIdx.x;
    float v = b_hyp[i * DH + t];
    float ss = block_sum256(v * v);
    float nraw = sqrtf(ss);
    float n = fmaxf(nraw, 1e-15f);
    float c = tanh_fast(n) * rcp_f(n);
    float ny = c * nraw;
    float np = fmaxf(ny, 1e-15f);
    float s = (np > MAXN) ? MAXN * rcp_f(np) : 1.0f;
    float hv = c * s * v;
    hb[i * DH + t] = hv;
    float s2 = block_sum256(hv * hv);
    if (t == 0) hb2[i] = s2;
}

// wave-per-node (4 nodes/block), lane = 4 feats via uint2; in-place bf16.
__global__ void k_rowfuse1(u16* __restrict__ T, const float* __restrict__ xhn,
                           const float* __restrict__ hb, const float* __restrict__ hb2) {
    int z = blockIdx.y;
    int n = blockIdx.x * 4 + (threadIdx.x >> 6);
    int lane = threadIdx.x & 63;
    u16* row = T + ((size_t)z * N_NODES + n) * DH;
    const float* hbz = hb + (size_t)z * DH;
    uint2 u = *(const uint2*)(row + lane * 4);
    float m0 = blo(u.x), m1 = bhi(u.x), m2 = blo(u.y), m3 = bhi(u.y);
    float ss = wave_sum(m0 * m0 + m1 * m1 + m2 * m2 + m3 * m3);
    float mxn_raw = sqrtf(ss);
    float mxn = fmaxf(mxn_raw, 1e-15f);
    float xn = xhn[n];
    float tt = tanh_fast(mxn * rcp_f(xn) * artanh_fast(xn));
    float coef = tt * rcp_f(mxn);
    float nres = coef * mxn_raw;
    float np = fmaxf(nres, 1e-15f);
    float s1 = (np > MAXN) ? MAXN * rcp_f(np) : 1.0f;
    float cs = coef * s1;
    float r0 = cs * m0, r1 = cs * m1, r2 = cs * m2, r3 = cs * m3;
    float n1 = fminf(np, MAXN);
    float4 hv = *(const float4*)(hbz + lane * 4);
    float xy = wave_sum(r0 * hv.x + r1 * hv.y + r2 * hv.z + r3 * hv.w);
    float x2 = n1 * n1, y2 = hb2[z];
    float ca = 1.0f + 2.0f * xy + y2;
    float cb = 1.0f - x2;
    float rden = rcp_f(fmaxf(1.0f + 2.0f * xy + x2 * y2, 1e-15f));
    float o0 = (ca * r0 + cb * hv.x) * rden;
    float o1 = (ca * r1 + cb * hv.y) * rden;
    float o2 = (ca * r2 + cb * hv.z) * rden;
    float o3 = (ca * r3 + cb * hv.w) * rden;
    float no2 = wave_sum(o0 * o0 + o1 * o1 + o2 * o2 + o3 * o3);
    float nop = fmaxf(sqrtf(no2), 1e-15f);
    float s2 = (nop > MAXN) ? MAXN * rcp_f(nop) : 1.0f;
    float n2 = fminf(nop, MAXN);
    float fin = artanh_fast(n2) * rcp_f(n2) * s2;
    uint2 o; o.x = pk2(fin * o0, fin * o1); o.y = pk2(fin * o2, fin * o3);
    *(uint2*)(row + lane * 4) = o;
}

// wave-per-node CSR gather (packed (src,val)), 4-way ILP unroll, + fused
// rowfuse2 hyperbolic chain -> bf16 out
__global__ void k_gather_fuse2(const int* __restrict__ rowptr, const uint2* __restrict__ padj,
                               const u16* __restrict__ xt, u16* __restrict__ out) {
    int z = blockIdx.y;
    rowptr += (size_t)z * (N_NODES + 1);
    padj += (size_t)z * NE;
    xt += (size_t)z * N_NODES * DH;
    out += (size_t)z * N_NODES * DH;
    int n = blockIdx.x * 4 + (threadIdx.x >> 6);
    int lane = threadIdx.x & 63;
    int beg = rowptr[n], end = rowptr[n + 1];
    float a0 = 0.f, a1 = 0.f, a2 = 0.f, a3 = 0.f;
    float b0 = 0.f, b1 = 0.f, b2 = 0.f, b3 = 0.f;
    float c0 = 0.f, c1 = 0.f, c2 = 0.f, c3 = 0.f;
    float d0 = 0.f, d1 = 0.f, d2 = 0.f, d3 = 0.f;
    int i = beg;
    for (; i + 4 <= end; i += 4) {
        uint2 p0 = padj[i];
        uint2 p1 = padj[i + 1];
        uint2 p2 = padj[i + 2];
        uint2 p3 = padj[i + 3];
        uint2 x0 = *(const uint2*)(xt + (size_t)p0.x * DH + lane * 4);
        uint2 x1 = *(const uint2*)(xt + (size_t)p1.x * DH + lane * 4);
        uint2 x2 = *(const uint2*)(xt + (size_t)p2.x * DH + lane * 4);
        uint2 x3 = *(const uint2*)(xt + (size_t)p3.x * DH + lane * 4);
        float v0 = __uint_as_float(p0.y), v1 = __uint_as_float(p1.y);
        float v2 = __uint_as_float(p2.y), v3 = __uint_as_float(p3.y);
        a0 = fmaf(v0, blo(x0.x), a0); a1 = fmaf(v0, bhi(x0.x), a1);
        a2 = fmaf(v0, blo(x0.y), a2); a3 = fmaf(v0, bhi(x0.y), a3);
        b0 = fmaf(v1, blo(x1.x), b0); b1 = fmaf(v1, bhi(x1.x), b1);
        b2 = fmaf(v1, blo(x1.y), b2); b3 = fmaf(v1, bhi(x1.y), b3);
        c0 = fmaf(v2, blo(x2.x), c0); c1 = fmaf(v2, bhi(x2.x), c1);
        c2 = fmaf(v2, blo(x2.y), c2); c3 = fmaf(v2, bhi(x2.y), c3);
        d0 = fmaf(v3, blo(x3.x), d0); d1 = fmaf(v3, bhi(x3.x), d1);
        d2 = fmaf(v3, blo(x3.y), d2); d3 = fmaf(v3, bhi(x3.y), d3);
    }
    if (i + 2 <= end) {
        uint2 p0 = padj[i];
        uint2 p1 = padj[i + 1];
        uint2 x0 = *(const uint2*)(xt + (size_t)p0.x * DH + lane * 4);
        uint2 x1 = *(const uint2*)(xt + (size_t)p1.x * DH + lane * 4);
        float v0 = __uint_as_float(p0.y), v1 = __uint_as_float(p1.y);
        a0 = fmaf(v0, blo(x0.x), a0); a1 = fmaf(v0, bhi(x0.x), a1);
        a2 = fmaf(v0, blo(x0.y), a2); a3 = fmaf(v0, bhi(x0.y), a3);
        b0 = fmaf(v1, blo(x1.x), b0); b1 = fmaf(v1, bhi(x1.x), b1);
        b2 = fmaf(v1, blo(x1.y), b2); b3 = fmaf(v1, bhi(x1.y), b3);
        i += 2;
    }
    if (i < end) {
        uint2 p = padj[i];
        uint2 x0 = *(const uint2*)(xt + (size_t)p.x * DH + lane * 4);
        float v = __uint_as_float(p.y);
        a0 = fmaf(v, blo(x0.x), a0); a1 = fmaf(v, bhi(x0.x), a1);
        a2 = fmaf(v, blo(x0.y), a2); a3 = fmaf(v, bhi(x0.y), a3);
    }
    a0 += b0 + c0 + d0; a1 += b1 + c1 + d1;
    a2 += b2 + c2 + d2; a3 += b3 + c3 + d3;
    float ss = wave_sum(a0 * a0 + a1 * a1 + a2 * a2 + a3 * a3);
    float nraw = sqrtf(ss);
    float n_ = fmaxf(nraw, 1e-15f);
    float cc1 = tanh_fast(n_) * rcp_f(n_);
    float nh = cc1 * nraw;
    float np1 = fmaxf(nh, 1e-15f);
    float s1 = (np1 > MAXN) ? MAXN * rcp_f(np1) : 1.0f;
    float n1 = fminf(np1, MAXN);
    float cu = artanh_fast(n1) * rcp_f(n1) * s1 * cc1;
    float u0 = fmaxf(cu * a0, 0.f), u1 = fmaxf(cu * a1, 0.f);
    float u2 = fmaxf(cu * a2, 0.f), u3 = fmaxf(cu * a3, 0.f);
    float ss2 = wave_sum(u0 * u0 + u1 * u1 + u2 * u2 + u3 * u3);
    float n2raw = sqrtf(ss2);
    float n2 = fmaxf(n2raw, 1e-15f);
    float cc3 = tanh_fast(n2) * rcp_f(n2);
    float ne = cc3 * n2raw;
    float np3 = fmaxf(ne, 1e-15f);
    float s3 = (np3 > MAXN) ? MAXN * rcp_f(np3) : 1.0f;
    float n3 = fminf(np3, MAXN);
    float cf = artanh_fast(n3) * rcp_f(n3) * s3 * cc3;
    uint2 o; o.x = pk2(cf * u0, cf * u1); o.y = pk2(cf * u2, cf * u3);
    *(uint2*)(out + (size_t)n * DH + lane * 4) = o;
}

// wave-per-node: out[n] = d[n] + sum_in d[src]; 4-way ILP unroll; bf16 in/out
__global__ void k_gather_add(const int* __restrict__ rowptr, const int* __restrict__ psrc,
                             const u16* __restrict__ d, u16* __restrict__ out) {
    int z = blockIdx.y;
    rowptr += (size_t)z * (N_NODES + 1);
    psrc += (size_t)z * NE;
    d += (size_t)z * N_NODES * DH;
    out += (size_t)z * N_NODES * DH;
    int n = blockIdx.x * 4 + (threadIdx.x >> 6);
    int lane = threadIdx.x & 63;
    int beg = rowptr[n], end = rowptr[n + 1];
    uint2 u0v = *(const uint2*)(d + (size_t)n * DH + lane * 4);
    float a0 = blo(u0v.x), a1 = bhi(u0v.x), a2 = blo(u0v.y), a3 = bhi(u0v.y);
    float b0 = 0.f, b1 = 0.f, b2 = 0.f, b3 = 0.f;
    float c0 = 0.f, c1 = 0.f, c2 = 0.f, c3 = 0.f;
    float e0 = 0.f, e1 = 0.f, e2 = 0.f, e3 = 0.f;
    int i = beg;
    for (; i + 4 <= end; i += 4) {
        int s0 = psrc[i], s1 = psrc[i + 1], s2 = psrc[i + 2], s3 = psrc[i + 3];
        uint2 x0 = *(const uint2*)(d + (size_t)s0 * DH + lane * 4);
        uint2 x1 = *(const uint2*)(d + (size_t)s1 * DH + lane * 4);
        uint2 x2 = *(const uint2*)(d + (size_t)s2 * DH + lane * 4);
        uint2 x3 = *(const uint2*)(d + (size_t)s3 * DH + lane * 4);
        a0 += blo(x0.x); a1 += bhi(x0.x); a2 += blo(x0.y); a3 += bhi(x0.y);
        b0 += blo(x1.x); b1 += bhi(x1.x); b2 += blo(x1.y); b3 += bhi(x1.y);
        c0 += blo(x2.x); c1 += bhi(x2.x); c2 += blo(x2.y); c3 += bhi(x2.y);
        e0 += blo(x3.x); e1 += bhi(x3.x); e2 += blo(x3.y); e3 += bhi(x3.y);
    }
    if (i + 2 <= end) {
        int s0 = psrc[i], s1 = psrc[i + 1];
        uint2 x0 = *(const uint2*)(d + (size_t)s0 * DH + lane * 4);
        uint2 x1 = *(const uint2*)(d + (size_t)s1 * DH + lane * 4);
        a0 += blo(x0.x); a1 += bhi(x0.x); a2 += blo(x0.y); a3 += bhi(x0.y);
        b0 += blo(x1.x); b1 += bhi(x1.x); b2 += blo(x1.y); b3 += bhi(x1.y);
        i += 2;
    }
    if (i < end) {
        int s0 = psrc[i];
        uint2 x0 = *(const uint2*)(d + (size_t)s0 * DH + lane * 4);
        a0 += blo(x0.x); a1 += bhi(x0.x); a2 += blo(x0.y); a3 += bhi(x0.y);
    }
    a0 += b0 + c0 + e0; a1 += b1 + c1 + e1;
    a2 += b2 + c2 + e2; a3 += b3 + c3 + e3;
    uint2 o; o.x = pk2(a0, a1); o.y = pk2(a2, a3);
    *(uint2*)(out + (size_t)n * DH + lane * 4) = o;
}

// batched column stats from bf16
__global__ void k_colstats(const u16* __restrict__ zp,
                           float* __restrict__ csum, float* __restrict__ csq) {
    int z = blockIdx.y;
    zp += (size_t)z * N_NODES * DH;
    csum += (size_t)z * DH;
    csq += (size_t)z * DH;
    int t = threadIdx.x;
    int r0 = blockIdx.x * 100;
    float s = 0.0f, q = 0.0f;
    for (int r = r0; r < r0 + 100; ++r) {
        float v = b2f(zp[(size_t)r * DH + t]);
        s += v;
        q += v * v;
    }
    atomicAdd(&csum[t], s);
    atomicAdd(&csq[t], q);
}

// grid-stride uint2 batchnorm + tanh, in-place bf16 (total4 = G*N*DH/4)
__global__ void k_normtanh_v(u16* __restrict__ zp, const float* __restrict__ csum,
                             const float* __restrict__ csq, const float* __restrict__ gamma,
                             const float* __restrict__ beta, int total4) {
    const float inv_n = 1.0f / N_NODES;
    int i = blockIdx.x * 256 + threadIdx.x;
    int stride = gridDim.x * 256;
    for (; i < total4; i += stride) {
        int e0 = i * 4;
        int z = e0 / (N_NODES * DH);
        int j0 = e0 & (DH - 1);
        int zb = z * DH + j0;
        uint2 u = ((uint2*)zp)[i];
        float v[4] = {blo(u.x), bhi(u.x), blo(u.y), bhi(u.y)};
        #pragma unroll
        for (int k = 0; k < 4; ++k) {
            float mu = csum[zb + k] * inv_n;
            float var = csq[zb + k] * inv_n - mu * mu;
            float inv = __builtin_amdgcn_rsqf(var + 1e-5f);
            v[k] = tanh_fast((v[k] - mu) * inv * gamma[zb + k] + beta[zb + k]);
        }
        uint2 o; o.x = pk2(v[0], v[1]); o.y = pk2(v[2], v[3]);
        ((uint2*)zp)[i] = o;
    }
}

// f1 slice of S,P (cols 0..511): thread t -> 2 cols via float2, packed u32 store
__global__ void k_pair0(const int* __restrict__ ei, const int* __restrict__ eid,
                        const float* __restrict__ f1, u16* __restrict__ S,
                        u16* __restrict__ P) {
    int b = blockIdx.x, t = threadIdx.x;
    int e = eid[b];
    int n0 = ei[e], n1 = ei[NE2 + e];
    float2 a = *(const float2*)(f1 + (size_t)n0 * D_INN + t * 2);
    float2 c = *(const float2*)(f1 + (size_t)n1 * D_INN + t * 2);
    ((unsigned int*)(S + (size_t)b * H3))[t] = pk2(a.x + c.x, a.y + c.y);
    ((unsigned int*)(P + (size_t)b * H3))[t] = pk2(a.x * c.x, a.y * c.y);
}

// batched channel slice of S,P from z_ch; 4 edges/block, uint2 lanes
__global__ void k_gather_ch(const int* __restrict__ ei, const int* __restrict__ eid,
                            const u16* __restrict__ zch, u16* __restrict__ S,
                            u16* __restrict__ P, int col0base) {
    int z = blockIdx.y;
    const u16* zp = zch + (size_t)z * N_NODES * DH;
    int col0 = col0base + z * DH;
    int b = blockIdx.x * 4 + (threadIdx.x >> 6);
    int lane = threadIdx.x & 63;
    int e = eid[b];
    int n0 = ei[e], n1 = ei[NE2 + e];
    uint2 ua = *(const uint2*)(zp + (size_t)n0 * DH + lane * 4);
    uint2 ub = *(const uint2*)(zp + (size_t)n1 * DH + lane * 4);
    float a0 = blo(ua.x), a1 = bhi(ua.x), a2 = blo(ua.y), a3 = bhi(ua.y);
    float c0 = blo(ub.x), c1 = bhi(ub.x), c2 = blo(ub.y), c3 = bhi(ub.y);
    uint2 so; so.x = pk2(a0 + c0, a1 + c1); so.y = pk2(a2 + c2, a3 + c3);
    uint2 po; po.x = pk2(a0 * c0, a1 * c1); po.y = pk2(a2 * c2, a3 * c3);
    *(uint2*)(S + (size_t)b * H3 + col0 + lane * 4) = so;
    *(uint2*)(P + (size_t)b * H3 + col0 + lane * 4) = po;
}

// single-mode merged pair builder: y==0 -> f1 slice (wave-per-edge, 8 f32
// cols/lane); y in [1,8) -> channel y-1 slice from z_ch. One launch replaces
// k_pair0 + 7-slice k_gather_ch.
__global__ void k_pairall(const int* __restrict__ ei, const int* __restrict__ eid,
                          const float* __restrict__ f1, const u16* __restrict__ zch,
                          u16* __restrict__ S, u16* __restrict__ P) {
    int y = blockIdx.y;
    int b = blockIdx.x * 4 + (threadIdx.x >> 6);
    int lane = threadIdx.x & 63;
    int e = eid[b];
    int n0 = ei[e], n1 = ei[NE2 + e];
    if (y == 0) {
        const float* xa = f1 + (size_t)n0 * D_INN + lane * 8;
        const float* xb = f1 + (size_t)n1 * D_INN + lane * 8;
        float4 a0 = *(const float4*)xa;
        float4 a1 = *(const float4*)(xa + 4);
        float4 q0 = *(const float4*)xb;
        float4 q1 = *(const float4*)(xb + 4);
        uint4 so, po;
        so.x = pk2(a0.x + q0.x, a0.y + q0.y);
        so.y = pk2(a0.z + q0.z, a0.w + q0.w);
        so.z = pk2(a1.x + q1.x, a1.y + q1.y);
        so.w = pk2(a1.z + q1.z, a1.w + q1.w);
        po.x = pk2(a0.x * q0.x, a0.y * q0.y);
        po.y = pk2(a0.z * q0.z, a0.w * q0.w);
        po.z = pk2(a1.x * q1.x, a1.y * q1.y);
        po.w = pk2(a1.z * q1.z, a1.w * q1.w);
        *(uint4*)(S + (size_t)b * H3 + lane * 8) = so;
        *(uint4*)(P + (size_t)b * H3 + lane * 8) = po;
    } else {
        int z = y - 1;
        const u16* zp = zch + (size_t)z * N_NODES * DH;
        int col0 = D_INN + z * DH;
        uint2 ua = *(const uint2*)(zp + (size_t)n0 * DH + lane * 4);
        uint2 ub = *(const uint2*)(zp + (size_t)n1 * DH + lane * 4);
        float a0 = blo(ua.x), a1 = bhi(ua.x), a2 = blo(ua.y), a3 = bhi(ua.y);
        float c0 = blo(ub.x), c1 = bhi(ub.x), c2 = blo(ub.y), c3 = bhi(ub.y);
        uint2 so; so.x = pk2(a0 + c0, a1 + c1); so.y = pk2(a2 + c2, a3 + c3);
        uint2 po; po.x = pk2(a0 * c0, a1 * c1); po.y = pk2(a2 * c2, a3 * c3);
        *(uint2*)(S + (size_t)b * H3 + col0 + lane * 4) = so;
        *(uint2*)(P + (size_t)b * H3 + col0 + lane * 4) = po;
    }
}

__global__ void k_final(const u16* __restrict__ h2, const float* __restrict__ Wf3,
                        const float* __restrict__ bf3, float* __restrict__ out) {
    int r = blockIdx.x, t = threadIdx.x;
    const u16* hr = h2 + (size_t)r * 576;
    float acc[7] = {0, 0, 0, 0, 0, 0, 0};
    for (int cb = t; cb < 576; cb += 64) {
        float h = b2f(hr[cb]);
        #pragma unroll
        for (int o = 0; o < 7; ++o) acc[o] = fmaf(h, Wf3[o * 576 + cb], acc[o]);
    }
    #pragma unroll
    for (int o = 0; o < 7; ++o) {
        #pragma unroll
        for (int off = 32; off > 0; off >>= 1) acc[o] += __shfl_down(acc[o], off, 64);
    }
    if (t == 0) {
        #pragma unroll
        for (int o = 0; o < 7; ++o) out[(size_t)r * 7 + o] = acc[o] + bf3[o];
    }
}

// ===== bf16 MFMA GEMM, BK=64, 8-WAVE (512-thr) blocks (32 waves/CU).
// Plain (z,y,x) enumeration after bijective XCD swizzle (R18-proven); when A
// is z-shared (sA==0, e.g. the Whyp GEMM), enumerate (y,z,x) instead so
// consecutive blocks across z reuse the same A row-panel (L2-resident).
// Staging/read chunk^row involution swizzle, linear LDS dest, 0 bank
// conflicts (proven).
// EP: 2=sigmoid->bf16, 3=relu->bf16, 5=bf16, 6=relu->f32,
//     7=bf16 + bias + (1+indeg[row])*cvec[col],
//     8=z==0? sigmoid->bf16 : bf16 (for batched gate/int)
template <int EP>
__global__ __launch_bounds__(512, 4) void k_gemm_mfma(
    const u16* __restrict__ A, const u16* __restrict__ W,
    const float* __restrict__ bias, void* __restrict__ outv,
    const int* __restrict__ rpe, const float* __restrict__ cvec,
    int M, int N, int K, size_t sA, size_t sW, size_t sC, int sBias) {
    __shared__ short As[8192];   // 128 rows x 64 cols bf16
    __shared__ short Ws[8192];
    // 3D bijective XCD swizzle over the whole grid
    const int gx = gridDim.x, gy = gridDim.y, gz = gridDim.z;
    const int plane = gx * gy;
    const int total = plane * gz;
    const int orig = (blockIdx.z * gy + blockIdx.y) * gx + blockIdx.x;
    const int q8 = total >> 3, r8 = total & 7, xcd = orig & 7;
    const int wg = (xcd < r8 ? xcd * (q8 + 1) : r8 * (q8 + 1) + (xcd - r8) * q8) + (orig >> 3);
    int z_, row0_, col0_;
    if (sA == 0 && gz > 1) {
        // A shared across z: (y, z, x) order -> A row-panel reused across z
        int x = wg % gx;
        int zz = (wg / gx) % gz;
        int y = wg / (gx * gz);
        z_ = zz; row0_ = y * 128; col0_ = x * 128;
    } else {
        z_ = wg / plane;
        int rem = wg - z_ * plane;
        row0_ = (rem / gx) * 128;
        col0_ = (rem % gx) * 128;
    }
    const int z = z_;
    const int row0 = row0_, col0 = col0_;
    A += (size_t)z * sA;
    W += (size_t)z * sW;
    const size_t zC = (size_t)z * sC;
    const int* rp = (EP == 7) ? rpe + (size_t)z * (N_NODES + 1) : nullptr;
    const float* cv = (EP == 7) ? cvec + (size_t)z * DH : nullptr;
    const int t = threadIdx.x;
    const int lane = t & 63;
    const int w = t >> 6;          // 0..7
    const int wr = w >> 2;         // 0..1 (M half)
    const int wc = w & 3;          // 0..3 (N quarter)
    // staging: lane l -> row-in-8block l>>3, src chunk (l&7)^(l>>3)
    const int sr8 = lane >> 3;
    const int csrc = (lane & 7) ^ sr8;
    int gr[2], gc[2];
    #pragma unroll
    for (int p = 0; p < 2; ++p) {
        int rb = w + p * 8;                // 0..15 (8-row blocks)
        gr[p] = row0 + rb * 8 + sr8; if (gr[p] >= M) gr[p] = M - 1;
        gc[p] = col0 + rb * 8 + sr8; if (gc[p] >= N) gc[p] = N - 1;
    }
    const int fr = lane & 15, fq4 = lane >> 4;   // logical chunk q = kk*4 + fq4
    f32x4 acc[4][2] = {};
    for (int k0 = 0; k0 < K; k0 += 64) {
        #pragma unroll
        for (int p = 0; p < 2; ++p) {
            int rb = w + p * 8;
            __builtin_amdgcn_global_load_lds(
                (const __attribute__((address_space(1))) unsigned int*)(A + (size_t)gr[p] * K + k0 + csrc * 8),
                (__attribute__((address_space(3))) unsigned int*)(As + rb * 512), 16, 0, 0);
            __builtin_amdgcn_global_load_lds(
                (const __attribute__((address_space(1))) unsigned int*)(W + (size_t)gc[p] * K + k0 + csrc * 8),
                (__attribute__((address_space(3))) unsigned int*)(Ws + rb * 512), 16, 0, 0);
        }
        __syncthreads();
        bf16x8 af[4][2], bfr[2][2];
        #pragma unroll
        for (int m = 0; m < 4; ++m) {
            int ar = wr * 64 + m * 16 + fr;
            #pragma unroll
            for (int kk = 0; kk < 2; ++kk) {
                int q = kk * 4 + fq4;
                af[m][kk] = *(const bf16x8*)(As + ar * 64 + ((q ^ (ar & 7)) * 8));
            }
        }
        #pragma unroll
        for (int n = 0; n < 2; ++n) {
            int br = wc * 32 + n * 16 + fr;
            #pragma unroll
            for (int kk = 0; kk < 2; ++kk) {
                int q = kk * 4 + fq4;
                bfr[n][kk] = *(const bf16x8*)(Ws + br * 64 + ((q ^ (br & 7)) * 8));
            }
        }
        #pragma unroll
        for (int m = 0; m < 4; ++m)
            #pragma unroll
            for (int n = 0; n < 2; ++n)
                #pragma unroll
                for (int kk = 0; kk < 2; ++kk)
                    acc[m][n] = __builtin_amdgcn_mfma_f32_16x16x32_bf16(
                        af[m][kk], bfr[n][kk], acc[m][n], 0, 0, 0);
        __syncthreads();
    }
    const int cl = lane & 15, rh = (lane >> 4) * 4;
    #pragma unroll
    for (int m = 0; m < 4; ++m) {
        float indf[4];
        if (EP == 7) {
            #pragma unroll
            for (int r = 0; r < 4; ++r) {
                int row = row0 + wr * 64 + m * 16 + rh + r;
                if (row >= M) row = M - 1;
                indf[r] = 1.0f + (float)(rp[row + 1] - rp[row]);
            }
        }
        #pragma unroll
        for (int n = 0; n < 2; ++n) {
            int col = col0 + wc * 32 + n * 16 + cl;
            if (col >= N) continue;
            float bv = bias ? bias[z * sBias + col] : 0.0f;
            float cvc = (EP == 7) ? cv[col] : 0.0f;
            #pragma unroll
            for (int r = 0; r < 4; ++r) {
                int row = row0 + wr * 64 + m * 16 + rh + r;
                if (row >= M) continue;
                float v = acc[m][n][r] + bv;
                size_t idx = zC + (size_t)row * N + col;
                if (EP == 2) ((u16*)outv)[idx] = f2b(sigmoid_fast(v));
                if (EP == 3) ((u16*)outv)[idx] = f2b(fmaxf(v, 0.0f));
                if (EP == 5) ((u16*)outv)[idx] = f2b(v);
                if (EP == 6) ((float*)outv)[idx] = fmaxf(v, 0.0f);
                if (EP == 7) ((u16*)outv)[idx] = f2b(v + indf[r] * cvc);
                if (EP == 8) ((u16*)outv)[idx] = (z == 0) ? f2b(sigmoid_fast(v)) : f2b(v);
            }
        }
    }
}

static inline void gemm_b(int ep, const u16* A, const u16* W, const float* bias, void* out,
                          const int* rpe, const float* cvec,
                          int M, int N, int K, int Z,
                          size_t sA, size_t sW, size_t sC, int sBias, hipStream_t st) {
    dim3 g((N + 127) / 128, (M + 127) / 128, Z);
    switch (ep) {
        case 2: k_gemm_mfma<2><<<g, 512, 0, st>>>(A, W, bias, out, rpe, cvec, M, N, K, sA, sW, sC, sBias); break;
        case 3: k_gemm_mfma<3><<<g, 512, 0, st>>>(A, W, bias, out, rpe, cvec, M, N, K, sA, sW, sC, sBias); break;
        case 5: k_gemm_mfma<5><<<g, 512, 0, st>>>(A, W, bias, out, rpe, cvec, M, N, K, sA, sW, sC, sBias); break;
        case 6: k_gemm_mfma<6><<<g, 512, 0, st>>>(A, W, bias, out, rpe, cvec, M, N, K, sA, sW, sC, sBias); break;
        case 7: k_gemm_mfma<7><<<g, 512, 0, st>>>(A, W, bias, out, rpe, cvec, M, N, K, sA, sW, sC, sBias); break;
        case 8: k_gemm_mfma<8><<<g, 512, 0, st>>>(A, W, bias, out, rpe, cvec, M, N, K, sA, sW, sC, sBias); break;
    }
}

static inline void conv_w(const float* s, u16* d, size_t n, hipStream_t st) {
    int n4 = (int)(n / 4);
    int grid = (n4 + 255) / 256;
    if (grid > 2048) grid = 2048;
    k_f2b<<<grid, 256, 0, st>>>(s, d, n4);
}

extern "C" void kernel_launch(void* const* d_in, const int* in_sizes, int n_in, void* d_out,
                              int out_size, void* d_ws, size_t ws_size, hipStream_t stream) {
    const float* f1 = (const float*)d_in[0];
    const int* adj_src = (const int*)d_in[1];
    const int* adj_dst = (const int*)d_in[2];
    const float* adj_val = (const float*)d_in[3];
    const int* edge_src = (const int*)d_in[4];
    const int* edge_dst = (const int*)d_in[5];
    const int* edge_index = (const int*)d_in[6];
    const int* edge_id = (const int*)d_in[7];
    const float* W_hyp = (const float*)d_in[8];
    const float* b_hyp = (const float*)d_in[9];
    const float* Wd = (const float*)d_in[10];
    const float* bd = (const float*)d_in[11];
    const float* Wg1 = (const float*)d_in[12];
    const float* bg1 = (const float*)d_in[13];
    const float* gamma = (const float*)d_in[14];
    const float* beta = (const float*)d_in[15];
    const float* Wg2 = (const float*)d_in[16];
    const float* bg2 = (const float*)d_in[17];
    const float* Wgate = (const float*)d_in[18];
    const float* bgate = (const float*)d_in[19];
    const float* Wint = (const float*)d_in[20];
    const float* bint = (const float*)d_in[21];
    const float* Wout = (const float*)d_in[22];
    const float* bout = (const float*)d_in[23];
    const float* Wf1 = (const float*)d_in[24];
    const float* bf1 = (const float*)d_in[25];
    const float* Wf2 = (const float*)d_in[26];
    const float* bf2 = (const float*)d_in[27];
    const float* Wf3 = (const float*)d_in[28];
    const float* bf3 = (const float*)d_in[29];
    float* outp = (float*)d_out;

    const bool single = ws_size >= 253400000ull;
    const int ngroups = single ? 1 : 2;
    const int GM = single ? 7 : 4;
    int g0s[2] = {0, 4};
    int gns[2] = {GM, 3};

    // ---- workspace bump allocator ----
    char* base = (char*)d_ws;
    size_t off = 0;
    auto alloc = [&](size_t bytes) -> char* {
        char* p = base + off;
        off += (bytes + 255) & ~(size_t)255;
        return p;
    };
    u16* Whyp_b = (u16*)alloc((size_t)NCH * DH * D_INN * 2);
    u16* Wc_b   = (u16*)alloc((size_t)NCH * DH * DH * 2);   // Wg1 @ Wd
    u16* Wg1_b  = (u16*)alloc((size_t)NCH * DH * DH * 2);
    u16* Wg2_b  = (u16*)alloc((size_t)NCH * DH * DH * 2);
    u16* Wgate_b = (u16*)alloc((size_t)H3 * H3 * 2);        // Wint_b must follow!
    u16* Wint_b  = (u16*)alloc((size_t)H3 * H3 * 2);
    u16* Wcomb_b = (u16*)alloc((size_t)1152 * H3 * 2);      // Wf1 @ Wout
    u16* Wf2_b   = (u16*)alloc((size_t)576 * 1152 * 2);
    u16* S_b = (u16*)alloc((size_t)NB * H3 * 2);            // P_b must follow!
    u16* P_b = (u16*)alloc((size_t)NB * H3 * 2);
    const size_t NDB = (size_t)N_NODES * DH;       // per-channel elems
    u16* buf1 = (u16*)alloc((size_t)GM * NDB * 2); // group ping (buf2 follows)
    u16* buf2 = (u16*)alloc((size_t)GM * NDB * 2); // group pong
    u16* xhyp_b = single ? buf2 : (u16*)alloc((size_t)N_NODES * D_INN * 2);
    // CSR scratch (2*GM slices): adj slices [0,G), edge slices [G,2G).
    // Single mode: final padj/psrcE alias into S_b; cnt/rowptr + binned
    // scratch alias into P_b -- all dead before S/P get written.
    int* cntC; int* rowptrC; uint2* padjC; int* psrcE;
    uint2* scrA = nullptr; unsigned int* scrE = nullptr;
    if (single) {
        padjC = (uint2*)S_b;                                   // 17,920,000 B
        psrcE = (int*)((char*)S_b + (size_t)GM * NE * 8);      // +8,960,000 B
        cntC = (int*)P_b;                                      // 1,120,000 B
        rowptrC = (int*)((char*)P_b + (size_t)2 * GM * N_NODES * 4);
        size_t rp_end = (size_t)2 * GM * N_NODES * 4 + (size_t)2 * GM * (N_NODES + 1) * 4;
        rp_end = (rp_end + 63) & ~(size_t)63;
        scrA = (uint2*)((char*)P_b + rp_end);                  // 17,920,000 B
        scrE = (unsigned int*)((char*)scrA + (size_t)GM * NE * 8);  // +8,960,000 B
    } else {
        cntC = (int*)alloc((size_t)2 * GM * N_NODES * 4);
        rowptrC = (int*)alloc((size_t)2 * GM * (N_NODES + 1) * 4);
        padjC = (uint2*)alloc((size_t)GM * NE * 8);
        psrcE = (int*)alloc((size_t)GM * NE * 4);
    }
    float* xhn = (float*)alloc((size_t)N_NODES * 4);
    float* hb = (float*)alloc((size_t)NCH * DH * 4);
    float* hb2 = (float*)alloc(NCH * 4);
    float* csum = (float*)alloc((size_t)GM * DH * 4);        // csq follows
    float* csq = (float*)alloc((size_t)GM * DH * 4);
    float* cvec_d = (float*)alloc((size_t)NCH * DH * 4);
    float* bias2 = (float*)alloc((size_t)2 * H3 * 4);
    float* bcomb = (float*)alloc((size_t)1152 * 4);
    int* bcur = (int*)alloc((size_t)2 * NCH * NBUK * 4);     // bucket cursors
    // precompute-only temp weights alias into buf1 (idle until GNN phase):
    u16* WoutT_b = buf1;                          // 10.62 MB
    u16* Wf1_b = buf1 + (size_t)H3 * H3;          // +5.31 MB
    u16* Wdt_b = Wf1_b + (size_t)1152 * H3;       // +0.92 MB (total 16.8 <= buf1)
    // stage-C overlays: GT spans buf1(+buf2 head); h1 -> buf1; h2 -> buf2.
    u16* GT = buf1;
    u16* h2b = buf2;

    const int EG = (NE + 255) / 256;

    conv_w(W_hyp, Whyp_b, (size_t)NCH * DH * D_INN, stream);
    conv_w(Wg1, Wg1_b, (size_t)NCH * DH * DH, stream);
    conv_w(Wg2, Wg2_b, (size_t)NCH * DH * DH, stream);
    conv_w(Wgate, Wgate_b, (size_t)H3 * H3, stream);
    conv_w(Wint, Wint_b, (size_t)H3 * H3, stream);
    conv_w(Wf1, Wf1_b, (size_t)1152 * H3, stream);
    conv_w(Wf2, Wf2_b, (size_t)576 * 1152, stream);
    k_bias2<<<(2 * H3 + 255) / 256, 256, 0, stream>>>(bgate, bint, bias2);
    // Wc = Wg1 @ Wd (via Wd^T), cvec = Wg1 @ bd
    k_twd<<<dim3(16, 16, NCH), 256, 0, stream>>>(Wd, Wdt_b);
    gemm_b(5, Wg1_b, Wdt_b, nullptr, Wc_b, nullptr, nullptr,
           DH, DH, DH, NCH, (size_t)DH * DH, (size_t)DH * DH, (size_t)DH * DH, 0, stream);
    k_cvec<<<NCH, 256, 0, stream>>>(Wg1, bd, cvec_d);
    // Wcomb = Wf1 @ Wout (Wout GEMM folded into Wf1), bcomb = Wf1@bout + bf1
    k_tr<<<dim3(144, 144), 256, 0, stream>>>(Wout, WoutT_b);
    gemm_b(5, Wf1_b, WoutT_b, nullptr, Wcomb_b, nullptr, nullptr,
           1152, H3, H3, 1, 0, 0, 0, 0, stream);
    k_bvec<<<1152 / 4, 256, 0, stream>>>(Wf1, bout, bf1, bcomb);

    k_expmap_proj_in<<<N_NODES, 256, 0, stream>>>(f1, xhyp_b, xhn);
    k_hb<<<NCH, 256, 0, stream>>>(b_hyp, hb, hb2);
    if (!single) k_pair0<<<NB, 256, 0, stream>>>(edge_index, edge_id, f1, S_b, P_b);

    for (int gi = 0; gi < ngroups; ++gi) {
        const int g0 = g0s[gi], G = gns[gi];
        const size_t eoff = (size_t)g0 * NE;
        const int G2 = 2 * G;
        const int* rpE = rowptrC + (size_t)G * (N_NODES + 1);
        // --- merged CSR build ---
        k_izero<<<(G2 * N_NODES + 255) / 256, 256, 0, stream>>>(cntC, G2 * N_NODES);
        k_hist2<<<dim3(EG, G2), 256, 0, stream>>>(adj_dst + eoff, edge_dst + eoff, cntC, G);
        k_scan<<<G2, 256, 0, stream>>>(cntC, rowptrC);
        if (single) {
            k_bcur<<<(G2 * NBUK + 255) / 256, 256, 0, stream>>>(rowptrC, bcur, G2);
            k_binA<<<dim3(EG, G2), 256, 0, stream>>>(adj_src, adj_dst, adj_val,
                                                     edge_src, edge_dst, bcur,
                                                     scrA, scrE, G);
            k_placeB<<<dim3(NBUK, G2), 256, 0, stream>>>(rowptrC, scrA, scrE,
                                                         padjC, psrcE, G);
        } else {
            k_place2<<<dim3(EG, G2), 256, 0, stream>>>(adj_src + eoff, adj_dst + eoff,
                                                       adj_val + eoff, edge_src + eoff,
                                                       edge_dst + eoff, cntC, padjC,
                                                       psrcE, G);
        }
        // --- batched pipeline ---
        gemm_b(5, xhyp_b, Whyp_b + (size_t)g0 * DH * D_INN, nullptr, buf1, nullptr,
               nullptr, N_NODES, DH, D_INN, G, 0, (size_t)DH * D_INN, NDB, 0, stream);
        k_rowfuse1<<<dim3(N_NODES / 4, G), 256, 0, stream>>>(buf1, xhn, hb + g0 * DH, hb2 + g0);
        k_gather_fuse2<<<dim3(N_NODES / 4, G), 256, 0, stream>>>(rowptrC, padjC, buf1, buf2);
        // ug = (I + S_e) u
        k_gather_add<<<dim3(N_NODES / 4, G), 256, 0, stream>>>(rpE, psrcE, buf2, buf1);
        // z = ug @ Wc^T + (1+indeg)*cvec + bg1   (Wd GEMM fused away)
        gemm_b(7, buf1, Wc_b + (size_t)g0 * DH * DH, bg1 + g0 * DH, buf2,
               rpE, cvec_d + (size_t)g0 * DH, N_NODES, DH, DH, G,
               NDB, (size_t)DH * DH, NDB, DH, stream);
        k_zero<<<(2 * GM * DH + 255) / 256, 256, 0, stream>>>(csum, 2 * GM * DH);
        k_colstats<<<dim3(200, G), 256, 0, stream>>>(buf2, csum, csq);
        {
            int total4 = (int)(G * NDB / 4);
            int blocks = (total4 + 255) / 256;
            if (blocks > 2048) blocks = 2048;
            k_normtanh_v<<<blocks, 256, 0, stream>>>(buf2, csum, csq, gamma + g0 * DH,
                                                     beta + g0 * DH, total4);
        }
        gemm_b(5, buf2, Wg2_b + (size_t)g0 * DH * DH, bg2 + g0 * DH, buf1, nullptr,
               nullptr, N_NODES, DH, DH, G, NDB, (size_t)DH * DH, NDB, DH, stream);
        if (!single)
            k_gather_ch<<<dim3(NB / 4, G), 256, 0, stream>>>(edge_index, edge_id, buf1,
                                                             S_b, P_b, D_INN + g0 * DH);
    }
    if (single) {
        // CSR scratch (aliased in S_b/P_b) is dead now; build S,P in one launch.
        k_pairall<<<dim3(NB / 4, 8), 256, 0, stream>>>(edge_index, edge_id, f1, buf1,
                                                       S_b, P_b);
    }

    // stage C: batched gate/int (Z=2), gi elementwise, fused h1 (Wout folded
    // into Wf1 via Wcomb), h2 (bf16), final.
    gemm_b(8, S_b, Wgate_b, bias2, GT, nullptr, nullptr, NB, H3, H3, 2,
           (size_t)NB * H3, (size_t)H3 * H3, (size_t)NB * H3, H3, stream);
    {
        int total4 = NB * H3 / 4;
        int blocks = (total4 + 255) / 256;
        if (blocks > 2048) blocks = 2048;
        k_gi<<<blocks, 256, 0, stream>>>(GT, GT + (size_t)NB * H3, S_b, total4);
    }
    // h1 = relu(gi @ Wcomb^T + bcomb)
    gemm_b(3, S_b, Wcomb_b, bcomb, buf1, nullptr, nullptr, NB, 1152, H3, 1, 0, 0, 0, 0, stream);
    // h2 = relu(h1 @ Wf2^T + bf2) -> bf16
    gemm_b(3, buf1, Wf2_b, bf2, h2b, nullptr, nullptr, NB, 576, 1152, 1, 0, 0, 0, 0, stream);
    k_final<<<NB, 64, 0, stream>>>(h2b, Wf3, bf3, outp);
}